// Round 9
// baseline (289.093 us; speedup 1.0000x reference)
//
#include <hip/hip_runtime.h>
#include <math.h>

#define BB 4
#define NN 2048
#define MM 8192
#define EPSF 1e-5f

typedef _Float16 half8 __attribute__((ext_vector_type(8)));
typedef float f32x4 __attribute__((ext_vector_type(4)));

__device__ __forceinline__ unsigned short f2h(float x) {
    _Float16 h = (_Float16)x;
    return __builtin_bit_cast(unsigned short, h);
}
__device__ __forceinline__ float h2f(unsigned short u) {
    return (float)__builtin_bit_cast(_Float16, u);
}

// wave64 sum via DPP: row_shr 1/2/4/8 + row_bcast 15/31; total lands in lane 63
__device__ __forceinline__ int wave_sum_dpp(int v) {
    v += __builtin_amdgcn_update_dpp(0, v, 0x111, 0xF, 0xF, true);
    v += __builtin_amdgcn_update_dpp(0, v, 0x112, 0xF, 0xF, true);
    v += __builtin_amdgcn_update_dpp(0, v, 0x114, 0xF, 0xF, true);
    v += __builtin_amdgcn_update_dpp(0, v, 0x118, 0xF, 0xF, true);
    v += __builtin_amdgcn_update_dpp(0, v, 0x142, 0xa, 0xF, true);
    v += __builtin_amdgcn_update_dpp(0, v, 0x143, 0xc, 0xF, true);
    return __builtin_amdgcn_readlane(v, 63);
}

__device__ __forceinline__ float angle3(float ux, float uy, float uz,
                                        float vx, float vy, float vz) {
    float crx = uy * vz - uz * vy;
    float cry = uz * vx - ux * vz;
    float crz = ux * vy - uy * vx;
    float s = sqrtf(crx * crx + cry * cry + crz * crz);
    float c = ux * vx + uy * vy + uz * vz;
    return atan2f(s, c);
}

// ---------------------------------------------------------------------------
// fused preamble: wconv (blocks 0..3455) | stats (3456..3459) |
// zero SUMS+MAXB (3460..3531) | onehot (3532..3563)
// ---------------------------------------------------------------------------
__global__ __launch_bounds__(256) void prep_k(const float* __restrict__ in,
                                              const float* __restrict__ w1, const float* __restrict__ w2,
                                              const float* __restrict__ w3, const float* __restrict__ w4,
                                              const float* __restrict__ w5, const float* __restrict__ w6,
                                              const float* __restrict__ w7,
                                              unsigned short* __restrict__ Wb,
                                              float* __restrict__ st,
                                              float* __restrict__ zp,
                                              unsigned short* __restrict__ XCb) {
    int blk = blockIdx.x;
    int t = threadIdx.x;
    if (blk < 3456) {
        int idx = blk * 256 + t;
        unsigned short v;
        if (idx < 8192) v = f2h(w1[idx]);
        else if (idx < 24576) v = f2h(w2[idx - 8192]);
        else if (idx < 155648) v = f2h(w3[idx - 24576]);
        else if (idx < 770048) {
            int l = idx - 155648;
            int o = l / 2400, k = l - o * 2400;
            v = (k < 2384) ? f2h(w4[o * 2384 + k]) : (unsigned short)0;
        } else if (idx < 835584) v = f2h(w5[idx - 770048]);
        else if (idx < 868352) v = f2h(w6[idx - 835584]);
        else {
            int l = idx - 868352;
            int o = l >> 7, k = l & 127;
            v = (o < 50) ? f2h(w7[o * 128 + k]) : (unsigned short)0;
        }
        Wb[idx] = v;
    } else if (blk < 3460) {
        int b = blk - 3456;
        const float* base = in + (size_t)b * 22 * NN;
        float cs0 = 0.f, cs1 = 0.f, cs2 = 0.f, ns0 = 0.f, ns1 = 0.f, ns2 = 0.f;
        for (int n = t; n < NN; n += 256) {
            float cx = base[0 * NN + n], cy = base[1 * NN + n], cz = base[2 * NN + n];
            float nx = base[3 * NN + n], ny = base[4 * NN + n], nz = base[5 * NN + n];
            float inv = 1.0f / sqrtf(nx * nx + ny * ny + nz * nz);
            cs0 += cx; cs1 += cy; cs2 += cz;
            ns0 += nx * inv; ns1 += ny * inv; ns2 += nz * inv;
        }
        __shared__ float red[6][256];
        red[0][t] = cs0; red[1][t] = cs1; red[2][t] = cs2;
        red[3][t] = ns0; red[4][t] = ns1; red[5][t] = ns2;
        __syncthreads();
        for (int s = 128; s > 0; s >>= 1) {
            if (t < s) {
                #pragma unroll
                for (int i = 0; i < 6; ++i) red[i][t] += red[i][t + s];
            }
            __syncthreads();
        }
        if (t == 0) {
            float ccx = red[0][0] / (float)NN, ccy = red[1][0] / (float)NN, ccz = red[2][0] / (float)NN;
            float cnx = red[3][0] / (float)NN, cny = red[4][0] / (float)NN, cnz = red[5][0] / (float)NN;
            float inv = 1.0f / sqrtf(cnx * cnx + cny * cny + cnz * cnz);
            float* s9 = st + b * 16;
            s9[0] = ccx; s9[1] = ccy; s9[2] = ccz;
            s9[3] = cnx; s9[4] = cny; s9[5] = cnz;
            s9[6] = cnx * inv; s9[7] = cny * inv; s9[8] = cnz * inv;
        }
    } else if (blk < 3532) {
        zp[(blk - 3460) * 256 + t] = 0.f;
    } else {
        int m = (blk - 3532) * 256 + t;
        int b = m >> 11, n = m & (NN - 1);
        const float* src = in + (size_t)b * 22 * NN + 6 * NN + n;
        unsigned short vals[16];
        #pragma unroll
        for (int r = 0; r < 16; ++r) vals[r] = f2h(src[(size_t)r * NN]);
        ushort4* dst = (ushort4*)&XCb[(size_t)m * 2400];
        #pragma unroll
        for (int q = 0; q < 4; ++q)
            dst[q] = make_ushort4(vals[4 * q], vals[4 * q + 1], vals[4 * q + 2], vals[4 * q + 3]);
        ushort4 z = make_ushort4(0, 0, 0, 0);
        ushort4* pz = (ushort4*)&XCb[(size_t)m * 2400 + 2384];
        pz[0] = z; pz[1] = z; pz[2] = z; pz[3] = z;
    }
}

// ---------------------------------------------------------------------------
// per-point PPF (F0 rows 0..3) + packed projected vectors PQ = (x,y,z,|P|)
// ---------------------------------------------------------------------------
__global__ __launch_bounds__(256) void point_k(const float* __restrict__ in,
                                               const float* __restrict__ st,
                                               float4* __restrict__ PQ,
                                               float* __restrict__ F0) {
    int idx = blockIdx.x * 256 + threadIdx.x;
    int b = idx >> 11, n = idx & (NN - 1);
    const float* base = in + (size_t)b * 22 * NN;
    const float* s9 = st + b * 16;
    float cx = base[0 * NN + n], cy = base[1 * NN + n], cz = base[2 * NN + n];
    float nx = base[3 * NN + n], ny = base[4 * NN + n], nz = base[5 * NN + n];
    float inv = 1.0f / sqrtf(nx * nx + ny * ny + nz * nz);
    nx *= inv; ny *= inv; nz *= inv;
    float ccx = s9[0], ccy = s9[1], ccz = s9[2];
    float cnx = s9[3], cny = s9[4], cnz = s9[5];
    float ex = s9[6], ey = s9[7], ez = s9[8];
    float dx = cx - ccx, dy = cy - ccy, dz = cz - ccz;
    F0[0 * MM + idx] = angle3(cnx, cny, cnz, dx, dy, dz);
    F0[1 * MM + idx] = angle3(nx, ny, nz, dx, dy, dz);
    F0[2 * MM + idx] = angle3(cnx, cny, cnz, nx, ny, nz);
    F0[3 * MM + idx] = sqrtf(dx * dx + dy * dy + dz * dz);
    float dot = dx * ex + dy * ey + dz * ez;
    float px = dx - dot * cnx;
    float py = dy - dot * cny;
    float pz = dz - dot * cnz;
    PQ[idx] = make_float4(px, py, pz, sqrtf(px * px + py * py + pz * pz));
}

// ---------------------------------------------------------------------------
// per-row median of pairwise angles. ONE row per wave, u[32] register-
// resident. Monotone key = tan^2(th/2); key<=2.5e-11 -> +INF (reference's
// at<=1e-5 -> 100, sorts last). Greedy 20-bit MSB search for largest T with
// #{u < T} <= 1023. Counting is per-lane VALU (v_cmp+addc) + one DPP wave
// reduce per bit — no scalar-unit chain. launch_bounds(256,4) caps VGPR<=128.
// ---------------------------------------------------------------------------
__global__ __launch_bounds__(256, 4) void alpha_k(const float4* __restrict__ PQ,
                                                  float* __restrict__ F0) {
    int row = blockIdx.x * 4 + (threadIdx.x >> 6);
    int lane = threadIdx.x & 63;
    int b = row >> 11;
    const float4* base = PQ + (size_t)b * NN;
    float4 a = base[row & (NN - 1)];
    unsigned u[32];
    #pragma unroll
    for (int s2 = 0; s2 < 32; ++s2) {
        float4 bv = base[s2 * 64 + lane];
        float cx = a.y * bv.z - a.z * bv.y;
        float cy = a.z * bv.x - a.x * bv.z;
        float cz = a.x * bv.y - a.y * bv.x;
        float ss = cx * cx + cy * cy + cz * cz;
        float dc = a.x * bv.x + a.y * bv.y + a.z * bv.z;
        float den = dc + a.w * bv.w;
        float rc = __builtin_amdgcn_rcpf(den);
        float key = ss * rc * rc;
        u[s2] = (key <= 2.5e-11f) ? 0x7F800000u : __float_as_uint(key);
    }
    unsigned T = 0u;
    for (int bit = 30; bit >= 11; --bit) {
        unsigned c = T | (1u << bit);
        int c0 = 0, c1 = 0, c2 = 0, c3 = 0;
        #pragma unroll
        for (int s2 = 0; s2 < 8; ++s2) {
            c0 += (int)(u[4 * s2 + 0] < c);
            c1 += (int)(u[4 * s2 + 1] < c);
            c2 += (int)(u[4 * s2 + 2] < c);
            c3 += (int)(u[4 * s2 + 3] < c);
        }
        int total = wave_sum_dpp(c0 + c1 + c2 + c3);
        if (total <= 1023) T = c;
    }
    if (lane == 0)
        F0[4 * MM + row] = 2.0f * atanf(sqrtf(__uint_as_float(T)));
}

// ---------------------------------------------------------------------------
// pf0: tiny K=5 GEMM, Y (M,64) fp32
// ---------------------------------------------------------------------------
__global__ __launch_bounds__(256) void pf0_k(const float* __restrict__ F0,
                                             const float* __restrict__ W,
                                             float* __restrict__ Y) {
    __shared__ float ws[320];
    int t = threadIdx.x;
    for (int i = t; i < 320; i += 256) ws[i] = W[i];
    __syncthreads();
    int m = blockIdx.x * 256 + t;
    float x0 = F0[m], x1 = F0[MM + m], x2 = F0[2 * MM + m], x3 = F0[3 * MM + m], x4 = F0[4 * MM + m];
    float* ym = Y + (size_t)m * 64;
    #pragma unroll
    for (int o = 0; o < 64; ++o) {
        const float* wo = &ws[o * 5];
        ym[o] = wo[0] * x0 + wo[1] * x1 + wo[2] * x2 + wo[3] * x3 + wo[4] * x4;
    }
}

// ---------------------------------------------------------------------------
// fp16 MFMA GEMM, pipelined: BM=64, BO=128, 4 waves, wave=32x64.
// MODE 0: fp32 Y write, no stats (supports K-split via blockIdx.z).
// MODE 1: fp16 Y write + fused BN-stat epilogue into sums slice.
// ---------------------------------------------------------------------------
template<int MODE>
__global__ __launch_bounds__(256) void mgemm3_k(const unsigned short* __restrict__ X, int ldx,
                                                const unsigned short* __restrict__ W, int ldw,
                                                void* __restrict__ Yv, int Co, int K, int kchunk,
                                                float* __restrict__ sums) {
    __shared__ unsigned short As[64 * 32];    // 4KB
    __shared__ unsigned short Bs[128 * 32];   // 8KB
    int t = threadIdx.x;
    int mBase = blockIdx.x * 64;
    int oBase = blockIdx.y * 128;
    int k0c = blockIdx.z * kchunk;
    int k1c = k0c + kchunk; if (k1c > K) k1c = K;
    int lane = t & 63, w = t >> 6;
    int warpM = (w & 1) * 32, warpO = (w >> 1) * 64;
    f32x4 acc[2][4];
    #pragma unroll
    for (int i = 0; i < 2; ++i)
        #pragma unroll
        for (int j = 0; j < 4; ++j) acc[i][j] = (f32x4){0.f, 0.f, 0.f, 0.f};
    int lr = t >> 2;
    int lc = (t & 3) * 8;
    const unsigned short* Xp = X + (size_t)(mBase + lr) * ldx + lc;
    const unsigned short* Wp0 = W + (size_t)(oBase + lr) * ldw + lc;
    const unsigned short* Wp1 = W + (size_t)(oBase + lr + 64) * ldw + lc;
    int ar0 = (warpM + (lane & 15)) * 32 + (lane >> 4) * 8;
    int br0 = (warpO + (lane & 15)) * 32 + (lane >> 4) * 8;
    uint4 xa = *(const uint4*)(Xp + k0c);
    uint4 wb0 = *(const uint4*)(Wp0 + k0c);
    uint4 wb1 = *(const uint4*)(Wp1 + k0c);
    for (int k = k0c; k < k1c; k += 32) {
        __syncthreads();
        *(uint4*)&As[lr * 32 + lc] = xa;
        *(uint4*)&Bs[lr * 32 + lc] = wb0;
        *(uint4*)&Bs[(lr + 64) * 32 + lc] = wb1;
        if (k + 32 < k1c) {
            xa = *(const uint4*)(Xp + k + 32);
            wb0 = *(const uint4*)(Wp0 + k + 32);
            wb1 = *(const uint4*)(Wp1 + k + 32);
        }
        __syncthreads();
        half8 a0 = __builtin_bit_cast(half8, *(const uint4*)&As[ar0]);
        half8 a1 = __builtin_bit_cast(half8, *(const uint4*)&As[ar0 + 16 * 32]);
        half8 b0 = __builtin_bit_cast(half8, *(const uint4*)&Bs[br0]);
        half8 b1 = __builtin_bit_cast(half8, *(const uint4*)&Bs[br0 + 16 * 32]);
        half8 b2 = __builtin_bit_cast(half8, *(const uint4*)&Bs[br0 + 32 * 32]);
        half8 b3 = __builtin_bit_cast(half8, *(const uint4*)&Bs[br0 + 48 * 32]);
        acc[0][0] = __builtin_amdgcn_mfma_f32_16x16x32_f16(a0, b0, acc[0][0], 0, 0, 0);
        acc[0][1] = __builtin_amdgcn_mfma_f32_16x16x32_f16(a0, b1, acc[0][1], 0, 0, 0);
        acc[0][2] = __builtin_amdgcn_mfma_f32_16x16x32_f16(a0, b2, acc[0][2], 0, 0, 0);
        acc[0][3] = __builtin_amdgcn_mfma_f32_16x16x32_f16(a0, b3, acc[0][3], 0, 0, 0);
        acc[1][0] = __builtin_amdgcn_mfma_f32_16x16x32_f16(a1, b0, acc[1][0], 0, 0, 0);
        acc[1][1] = __builtin_amdgcn_mfma_f32_16x16x32_f16(a1, b1, acc[1][1], 0, 0, 0);
        acc[1][2] = __builtin_amdgcn_mfma_f32_16x16x32_f16(a1, b2, acc[1][2], 0, 0, 0);
        acc[1][3] = __builtin_amdgcn_mfma_f32_16x16x32_f16(a1, b3, acc[1][3], 0, 0, 0);
    }
    if (MODE == 0) {
        float* Yp = (float*)Yv + (size_t)blockIdx.z * MM * Co;
        #pragma unroll
        for (int i = 0; i < 2; ++i)
            #pragma unroll
            for (int j = 0; j < 4; ++j) {
                int m0 = mBase + warpM + i * 16 + (lane >> 4) * 4;
                int o = oBase + warpO + j * 16 + (lane & 15);
                #pragma unroll
                for (int r = 0; r < 4; ++r)
                    Yp[(size_t)(m0 + r) * Co + o] = acc[i][j][r];
            }
    } else {
        unsigned short* Yh = (unsigned short*)Yv;
        #pragma unroll
        for (int i = 0; i < 2; ++i)
            #pragma unroll
            for (int j = 0; j < 4; ++j) {
                int m0 = mBase + warpM + i * 16 + (lane >> 4) * 4;
                int o = oBase + warpO + j * 16 + (lane & 15);
                #pragma unroll
                for (int r = 0; r < 4; ++r)
                    Yh[(size_t)(m0 + r) * Co + o] = f2h(acc[i][j][r]);
            }
        __syncthreads();
        float* ssum = (float*)As;
        float* ssq = (float*)Bs;
        if (t < 128) { ssum[t] = 0.f; ssq[t] = 0.f; }
        __syncthreads();
        #pragma unroll
        for (int j = 0; j < 4; ++j) {
            int oc = warpO + j * 16 + (lane & 15);
            float s = 0.f, q = 0.f;
            #pragma unroll
            for (int i = 0; i < 2; ++i)
                #pragma unroll
                for (int r = 0; r < 4; ++r) { float v = acc[i][j][r]; s += v; q += v * v; }
            atomicAdd(&ssum[oc], s);
            atomicAdd(&ssq[oc], q);
        }
        __syncthreads();
        if (t < 128) {
            atomicAdd(&sums[oBase + t], ssum[t]);
            atomicAdd(&sums[1024 + oBase + t], ssq[t]);
        }
    }
}

// ---------------------------------------------------------------------------
// fused: sum 4 cls0 K-split partials into partial 0 + BN stats, one pass.
// ---------------------------------------------------------------------------
__global__ __launch_bounds__(256) void red4stat_k(float* __restrict__ Y,
                                                  float* __restrict__ sums) {
    int o0 = blockIdx.x * 64;
    int m0 = blockIdx.y * 128;
    int t = threadIdx.x, ol = t & 63, mg = t >> 6;
    const size_t stride = (size_t)MM * 256;
    float s = 0.f, q = 0.f;
    float* p = Y + (size_t)(m0 + mg) * 256 + o0 + ol;
    for (int i = 0; i < 32; ++i) {
        float* pp = p + (size_t)i * 4 * 256;
        float v = pp[0] + pp[stride] + pp[2 * stride] + pp[3 * stride];
        pp[0] = v;
        s += v; q += v * v;
    }
    __shared__ float ls[4][64], lq[4][64];
    ls[mg][ol] = s; lq[mg][ol] = q;
    __syncthreads();
    if (mg == 0) {
        s = ls[0][ol] + ls[1][ol] + ls[2][ol] + ls[3][ol];
        q = lq[0][ol] + lq[1][ol] + lq[2][ol] + lq[3][ol];
        atomicAdd(&sums[o0 + ol], s);
        atomicAdd(&sums[1024 + o0 + ol], q);
    }
}

// ---------------------------------------------------------------------------
// BN stats from fp32 Y (pf0) into a sums slice
// ---------------------------------------------------------------------------
__global__ __launch_bounds__(256) void bnstat_k(const float* __restrict__ Y, int Co,
                                                float* __restrict__ sums) {
    int o0 = blockIdx.x * 64;
    int m0 = blockIdx.y * 512;
    int t = threadIdx.x, ol = t & 63, mg = t >> 6;
    float s = 0.f, q = 0.f;
    const float* p = Y + (size_t)(m0 + mg) * Co + o0 + ol;
    for (int i = 0; i < 128; ++i) {
        float v = p[(size_t)i * 4 * Co];
        s += v; q += v * v;
    }
    __shared__ float ls[4][64], lq[4][64];
    ls[mg][ol] = s; lq[mg][ol] = q;
    __syncthreads();
    if (mg == 0) {
        s = ls[0][ol] + ls[1][ol] + ls[2][ol] + ls[3][ol];
        q = lq[0][ol] + lq[1][ol] + lq[2][ol] + lq[3][ol];
        atomicAdd(&sums[o0 + ol], s);
        atomicAdd(&sums[1024 + o0 + ol], q);
    }
}

// inline BN coefficient from sums slice
__device__ __forceinline__ void bncoef(const float* __restrict__ sums,
                                       const float* __restrict__ g,
                                       const float* __restrict__ bb,
                                       int o, float& a, float& c) {
    float mu = sums[o] * (1.f / 8192.f);
    float var = sums[1024 + o] * (1.f / 8192.f) - mu * mu;
    var = fmaxf(var, 0.f);
    a = g[o] * (1.0f / sqrtf(var + EPSF));
    c = bb[o] - mu * a;
}

// ---------------------------------------------------------------------------
// BN normalize + ReLU + fp16 store (fp32 source)
// ---------------------------------------------------------------------------
__global__ __launch_bounds__(256) void bnorm_f(const float* __restrict__ Y,
                                               const float* __restrict__ sums,
                                               const float* __restrict__ g,
                                               const float* __restrict__ bb,
                                               unsigned short* __restrict__ dst, int ldd, int shift) {
    int idx4 = blockIdx.x * 256 + threadIdx.x;
    int m = idx4 >> shift;
    int o4 = (idx4 & ((1 << shift) - 1)) * 4;
    float4 v = ((const float4*)Y)[idx4];
    float vv[4] = {v.x, v.y, v.z, v.w};
    unsigned short r[4];
    #pragma unroll
    for (int j = 0; j < 4; ++j) {
        float a, c;
        bncoef(sums, g, bb, o4 + j, a, c);
        r[j] = f2h(fmaxf(vv[j] * a + c, 0.f));
    }
    *(ushort4*)&dst[(size_t)m * ldd + o4] = make_ushort4(r[0], r[1], r[2], r[3]);
}

// ---------------------------------------------------------------------------
// BN normalize + ReLU + fp16 store (fp16 source)
// ---------------------------------------------------------------------------
__global__ __launch_bounds__(256) void bnorm_h(const unsigned short* __restrict__ Yh,
                                               const float* __restrict__ sums,
                                               const float* __restrict__ g,
                                               const float* __restrict__ bb,
                                               unsigned short* __restrict__ dst, int ldd, int shift) {
    int idx4 = blockIdx.x * 256 + threadIdx.x;
    int m = idx4 >> shift;
    int o4 = (idx4 & ((1 << shift) - 1)) * 4;
    ushort4 hv = ((const ushort4*)Yh)[idx4];
    float vv[4] = {h2f(hv.x), h2f(hv.y), h2f(hv.z), h2f(hv.w)};
    unsigned short r[4];
    #pragma unroll
    for (int j = 0; j < 4; ++j) {
        float a, c;
        bncoef(sums, g, bb, o4 + j, a, c);
        r[j] = f2h(fmaxf(vv[j] * a + c, 0.f));
    }
    *(ushort4*)&dst[(size_t)m * ldd + o4] = make_ushort4(r[0], r[1], r[2], r[3]);
}

// ---------------------------------------------------------------------------
// max over N per (b, channel) from pf3's fp16 slice
// ---------------------------------------------------------------------------
__global__ __launch_bounds__(256) void maxred_k(const unsigned short* __restrict__ Xs,
                                                float* __restrict__ maxbuf) {
    int o0 = blockIdx.x * 64;
    int b = blockIdx.y;
    int rc = blockIdx.z;
    int t = threadIdx.x, ol = t & 63, mg = t >> 6;
    float mx = 0.f;
    for (int i = 0; i < 128; ++i) {
        int m = b * NN + rc * 512 + i * 4 + mg;
        mx = fmaxf(mx, h2f(Xs[(size_t)m * 2400 + o0 + ol]));
    }
    __shared__ float ls[4][64];
    ls[mg][ol] = mx;
    __syncthreads();
    if (mg == 0) {
        mx = fmaxf(fmaxf(ls[0][ol], ls[1][ol]), fmaxf(ls[2][ol], ls[3][ol]));
        atomicMax((unsigned*)&maxbuf[b * 1024 + o0 + ol], __builtin_bit_cast(unsigned, mx));
    }
}

__global__ __launch_bounds__(256) void maxbc_k(const float* __restrict__ maxbuf,
                                               unsigned short* __restrict__ XCb) {
    int idx8 = blockIdx.x * 256 + threadIdx.x;
    int m = idx8 >> 7;
    int o8 = (idx8 & 127) * 8;
    int b = m >> 11;
    const float* mb = maxbuf + b * 1024 + o8;
    ushort4 u0 = make_ushort4(f2h(mb[0]), f2h(mb[1]), f2h(mb[2]), f2h(mb[3]));
    ushort4 u1 = make_ushort4(f2h(mb[4]), f2h(mb[5]), f2h(mb[6]), f2h(mb[7]));
    *(ushort4*)&XCb[(size_t)m * 2400 + 1360 + o8] = u0;
    *(ushort4*)&XCb[(size_t)m * 2400 + 1360 + o8 + 4] = u1;
}

// ---------------------------------------------------------------------------
// final: OT(M,128) fp32 -> out (B,50,N) + bias, via LDS transpose
// ---------------------------------------------------------------------------
__global__ __launch_bounds__(256) void wout_k(const float* __restrict__ OT,
                                              const float* __restrict__ bias,
                                              float* __restrict__ out) {
    __shared__ float ts[128][65];
    int t = threadIdx.x;
    int m0 = blockIdx.x * 128;
    #pragma unroll
    for (int i = 0; i < 8; ++i) {
        int idx4 = t + 256 * i;
        int row = idx4 >> 4, c4 = (idx4 & 15) * 4;
        float4 v = *(const float4*)&OT[(size_t)(m0 + row) * 128 + c4];
        ts[row][c4] = v.x; ts[row][c4 + 1] = v.y; ts[row][c4 + 2] = v.z; ts[row][c4 + 3] = v.w;
    }
    __syncthreads();
    int b = m0 >> 11, n0 = m0 & (NN - 1);
    #pragma unroll
    for (int j = 0; j < 25; ++j) {
        int idx = t + 256 * j;
        int o = idx >> 7, nl = idx & 127;
        out[((size_t)b * 50 + o) * NN + n0 + nl] = ts[nl][o] + bias[o];
    }
}

// ---------------------------------------------------------------------------
extern "C" void kernel_launch(void* const* d_in, const int* in_sizes, int n_in,
                              void* d_out, int out_size, void* d_ws, size_t ws_size,
                              hipStream_t stream) {
    const float* in = (const float*)d_in[0];
    const float* pf0_w = (const float*)d_in[1];
    const float* pf_g[4] = {(const float*)d_in[2], (const float*)d_in[5], (const float*)d_in[8], (const float*)d_in[11]};
    const float* pf_b[4] = {(const float*)d_in[3], (const float*)d_in[6], (const float*)d_in[9], (const float*)d_in[12]};
    const float* pf_w[4] = {(const float*)d_in[1], (const float*)d_in[4], (const float*)d_in[7], (const float*)d_in[10]};
    const float* cls_w[3] = {(const float*)d_in[13], (const float*)d_in[16], (const float*)d_in[19]};
    const float* cls_g[3] = {(const float*)d_in[14], (const float*)d_in[17], (const float*)d_in[20]};
    const float* cls_b[3] = {(const float*)d_in[15], (const float*)d_in[18], (const float*)d_in[21]};
    const float* cls3_w = (const float*)d_in[22];
    const float* cls3_bias = (const float*)d_in[23];
    float* out = (float*)d_out;

    char* wsb = (char*)d_ws;
    float* ST = (float*)(wsb + 0);                      // 256 B
    float4* PQ = (float4*)(wsb + 256);                  // 131072 B
    float* F0 = (float*)(wsb + 131328);                 // 163840 B
    float* SUMS = (float*)(wsb + 295168);               // 7 slices x 8192 B = 57344 B
    float* MAXB = (float*)(wsb + 352512);               // 16384 B (right after SUMS)
    unsigned short* WB = (unsigned short*)(wsb + 368896);    // 1769472 B
    unsigned short* XCb = (unsigned short*)(wsb + 2138368);  // 39321600 B
    unsigned short* C1b = (unsigned short*)(wsb + 41459968); // 4194304 B (aliased as C3b)
    unsigned short* C2b = (unsigned short*)(wsb + 45654272); // 4194304 B
    unsigned short* C3b = C1b;
    float* Y = (float*)(wsb + 49848576);                // 33554432 B (4 cls0 partials)
    unsigned short* Yh = (unsigned short*)Y;

    auto SL = [&](int s) { return SUMS + (size_t)s * 2048; };

    // fused preamble: wconv + stats + zero(SUMS+MAXB) + onehot
    prep_k<<<3564, 256, 0, stream>>>(in, pf_w[1], pf_w[2], pf_w[3], cls_w[0], cls_w[1], cls_w[2], cls3_w,
                                     WB, ST, SUMS, XCb);
    point_k<<<MM / 256, 256, 0, stream>>>(in, ST, PQ, F0);
    alpha_k<<<MM / 4, 256, 0, stream>>>(PQ, F0);

    // pf0 (fp32 path)
    pf0_k<<<MM / 256, 256, 0, stream>>>(F0, pf0_w, Y);
    bnstat_k<<<dim3(1, 16), 256, 0, stream>>>(Y, 64, SL(0));
    bnorm_f<<<512, 256, 0, stream>>>(Y, SL(0), pf_g[0], pf_b[0], XCb + 16, 2400, 4);
    // pf1 (Co=128, K=64)
    mgemm3_k<1><<<dim3(128, 1, 1), 256, 0, stream>>>(XCb + 16, 2400, WB, 64, Yh, 128, 64, 64, SL(1));
    bnorm_h<<<1024, 256, 0, stream>>>(Yh, SL(1), pf_g[1], pf_b[1], XCb + 80, 2400, 5);
    // pf2 (Co=128, K=128)
    mgemm3_k<1><<<dim3(128, 1, 1), 256, 0, stream>>>(XCb + 80, 2400, WB + 8192, 128, Yh, 128, 128, 128, SL(2));
    bnorm_h<<<1024, 256, 0, stream>>>(Yh, SL(2), pf_g[2], pf_b[2], XCb + 208, 2400, 5);
    // pf3 (Co=1024, K=128)
    mgemm3_k<1><<<dim3(128, 8, 1), 256, 0, stream>>>(XCb + 208, 2400, WB + 24576, 128, Yh, 1024, 128, 128, SL(3));
    bnorm_h<<<8192, 256, 0, stream>>>(Yh, SL(3), pf_g[3], pf_b[3], XCb + 336, 2400, 8);
    // max feature
    maxred_k<<<dim3(16, 4, 4), 256, 0, stream>>>(XCb + 336, MAXB);
    maxbc_k<<<4096, 256, 0, stream>>>(MAXB, XCb);
    // cls0 (Co=256, K=2400): K-split x4, fp32 partials, fused reduce+stats, norm
    mgemm3_k<0><<<dim3(128, 2, 4), 256, 0, stream>>>(XCb, 2400, WB + 155648, 2400, Y, 256, 2400, 608, SL(4));
    red4stat_k<<<dim3(4, 64), 256, 0, stream>>>(Y, SL(4));
    bnorm_f<<<2048, 256, 0, stream>>>(Y, SL(4), cls_g[0], cls_b[0], C1b, 256, 6);
    // cls1 (Co=256, K=256)
    mgemm3_k<1><<<dim3(128, 2, 1), 256, 0, stream>>>(C1b, 256, WB + 770048, 256, Yh, 256, 256, 256, SL(5));
    bnorm_h<<<2048, 256, 0, stream>>>(Yh, SL(5), cls_g[1], cls_b[1], C2b, 256, 6);
    // cls2 (Co=128, K=256)
    mgemm3_k<1><<<dim3(128, 1, 1), 256, 0, stream>>>(C2b, 256, WB + 835584, 256, Yh, 128, 256, 256, SL(6));
    bnorm_h<<<1024, 256, 0, stream>>>(Yh, SL(6), cls_g[2], cls_b[2], C3b, 128, 5);
    // cls3 (padded to 128 outputs, rows 50..127 zero) -> fp32 Y
    mgemm3_k<0><<<dim3(128, 1, 1), 256, 0, stream>>>(C3b, 128, WB + 868352, 128, Y, 128, 128, 128, SL(0));
    wout_k<<<MM / 128, 256, 0, stream>>>(Y, cls3_bias, out);

    (void)in_sizes; (void)n_in; (void)out_size; (void)ws_size;
}

// Round 10
// 249.283 us; speedup vs baseline: 1.1597x; 1.1597x over previous
//
#include <hip/hip_runtime.h>
#include <math.h>

#define BB 4
#define NN 2048
#define MM 8192
#define EPSF 1e-5f

typedef _Float16 half8 __attribute__((ext_vector_type(8)));
typedef float f32x4 __attribute__((ext_vector_type(4)));

__device__ __forceinline__ unsigned short f2h(float x) {
    _Float16 h = (_Float16)x;
    return __builtin_bit_cast(unsigned short, h);
}
__device__ __forceinline__ float h2f(unsigned short u) {
    return (float)__builtin_bit_cast(_Float16, u);
}

// wave64 sum via DPP: row_shr 1/2/4/8 + row_bcast 15/31; total lands in lane 63
__device__ __forceinline__ int wave_sum_dpp(int v) {
    v += __builtin_amdgcn_update_dpp(0, v, 0x111, 0xF, 0xF, true);
    v += __builtin_amdgcn_update_dpp(0, v, 0x112, 0xF, 0xF, true);
    v += __builtin_amdgcn_update_dpp(0, v, 0x114, 0xF, 0xF, true);
    v += __builtin_amdgcn_update_dpp(0, v, 0x118, 0xF, 0xF, true);
    v += __builtin_amdgcn_update_dpp(0, v, 0x142, 0xa, 0xF, true);
    v += __builtin_amdgcn_update_dpp(0, v, 0x143, 0xc, 0xF, true);
    return __builtin_amdgcn_readlane(v, 63);
}

__device__ __forceinline__ float angle3(float ux, float uy, float uz,
                                        float vx, float vy, float vz) {
    float crx = uy * vz - uz * vy;
    float cry = uz * vx - ux * vz;
    float crz = ux * vy - uy * vx;
    float s = sqrtf(crx * crx + cry * cry + crz * crz);
    float c = ux * vx + uy * vy + uz * vz;
    return atan2f(s, c);
}

// ---------------------------------------------------------------------------
// fused preamble: wconv (blocks 0..3455) | stats (3456..3459) |
// zero SUMS+MAXB (3460..3531) | onehot (3532..3563)
// ---------------------------------------------------------------------------
__global__ __launch_bounds__(256) void prep_k(const float* __restrict__ in,
                                              const float* __restrict__ w1, const float* __restrict__ w2,
                                              const float* __restrict__ w3, const float* __restrict__ w4,
                                              const float* __restrict__ w5, const float* __restrict__ w6,
                                              const float* __restrict__ w7,
                                              unsigned short* __restrict__ Wb,
                                              float* __restrict__ st,
                                              float* __restrict__ zp,
                                              unsigned short* __restrict__ XCb) {
    int blk = blockIdx.x;
    int t = threadIdx.x;
    if (blk < 3456) {
        int idx = blk * 256 + t;
        unsigned short v;
        if (idx < 8192) v = f2h(w1[idx]);
        else if (idx < 24576) v = f2h(w2[idx - 8192]);
        else if (idx < 155648) v = f2h(w3[idx - 24576]);
        else if (idx < 770048) {
            int l = idx - 155648;
            int o = l / 2400, k = l - o * 2400;
            v = (k < 2384) ? f2h(w4[o * 2384 + k]) : (unsigned short)0;
        } else if (idx < 835584) v = f2h(w5[idx - 770048]);
        else if (idx < 868352) v = f2h(w6[idx - 835584]);
        else {
            int l = idx - 868352;
            int o = l >> 7, k = l & 127;
            v = (o < 50) ? f2h(w7[o * 128 + k]) : (unsigned short)0;
        }
        Wb[idx] = v;
    } else if (blk < 3460) {
        int b = blk - 3456;
        const float* base = in + (size_t)b * 22 * NN;
        float cs0 = 0.f, cs1 = 0.f, cs2 = 0.f, ns0 = 0.f, ns1 = 0.f, ns2 = 0.f;
        for (int n = t; n < NN; n += 256) {
            float cx = base[0 * NN + n], cy = base[1 * NN + n], cz = base[2 * NN + n];
            float nx = base[3 * NN + n], ny = base[4 * NN + n], nz = base[5 * NN + n];
            float inv = 1.0f / sqrtf(nx * nx + ny * ny + nz * nz);
            cs0 += cx; cs1 += cy; cs2 += cz;
            ns0 += nx * inv; ns1 += ny * inv; ns2 += nz * inv;
        }
        __shared__ float red[6][256];
        red[0][t] = cs0; red[1][t] = cs1; red[2][t] = cs2;
        red[3][t] = ns0; red[4][t] = ns1; red[5][t] = ns2;
        __syncthreads();
        for (int s = 128; s > 0; s >>= 1) {
            if (t < s) {
                #pragma unroll
                for (int i = 0; i < 6; ++i) red[i][t] += red[i][t + s];
            }
            __syncthreads();
        }
        if (t == 0) {
            float ccx = red[0][0] / (float)NN, ccy = red[1][0] / (float)NN, ccz = red[2][0] / (float)NN;
            float cnx = red[3][0] / (float)NN, cny = red[4][0] / (float)NN, cnz = red[5][0] / (float)NN;
            float inv = 1.0f / sqrtf(cnx * cnx + cny * cny + cnz * cnz);
            float* s9 = st + b * 16;
            s9[0] = ccx; s9[1] = ccy; s9[2] = ccz;
            s9[3] = cnx; s9[4] = cny; s9[5] = cnz;
            s9[6] = cnx * inv; s9[7] = cny * inv; s9[8] = cnz * inv;
        }
    } else if (blk < 3532) {
        zp[(blk - 3460) * 256 + t] = 0.f;
    } else {
        int m = (blk - 3532) * 256 + t;
        int b = m >> 11, n = m & (NN - 1);
        const float* src = in + (size_t)b * 22 * NN + 6 * NN + n;
        unsigned short vals[16];
        #pragma unroll
        for (int r = 0; r < 16; ++r) vals[r] = f2h(src[(size_t)r * NN]);
        ushort4* dst = (ushort4*)&XCb[(size_t)m * 2400];
        #pragma unroll
        for (int q = 0; q < 4; ++q)
            dst[q] = make_ushort4(vals[4 * q], vals[4 * q + 1], vals[4 * q + 2], vals[4 * q + 3]);
        ushort4 z = make_ushort4(0, 0, 0, 0);
        ushort4* pz = (ushort4*)&XCb[(size_t)m * 2400 + 2384];
        pz[0] = z; pz[1] = z; pz[2] = z; pz[3] = z;
    }
}

// ---------------------------------------------------------------------------
// per-point PPF (F0 rows 0..3) + packed projected vectors PQ = (x,y,z,|P|)
// ---------------------------------------------------------------------------
__global__ __launch_bounds__(256) void point_k(const float* __restrict__ in,
                                               const float* __restrict__ st,
                                               float4* __restrict__ PQ,
                                               float* __restrict__ F0) {
    int idx = blockIdx.x * 256 + threadIdx.x;
    int b = idx >> 11, n = idx & (NN - 1);
    const float* base = in + (size_t)b * 22 * NN;
    const float* s9 = st + b * 16;
    float cx = base[0 * NN + n], cy = base[1 * NN + n], cz = base[2 * NN + n];
    float nx = base[3 * NN + n], ny = base[4 * NN + n], nz = base[5 * NN + n];
    float inv = 1.0f / sqrtf(nx * nx + ny * ny + nz * nz);
    nx *= inv; ny *= inv; nz *= inv;
    float ccx = s9[0], ccy = s9[1], ccz = s9[2];
    float cnx = s9[3], cny = s9[4], cnz = s9[5];
    float ex = s9[6], ey = s9[7], ez = s9[8];
    float dx = cx - ccx, dy = cy - ccy, dz = cz - ccz;
    F0[0 * MM + idx] = angle3(cnx, cny, cnz, dx, dy, dz);
    F0[1 * MM + idx] = angle3(nx, ny, nz, dx, dy, dz);
    F0[2 * MM + idx] = angle3(cnx, cny, cnz, nx, ny, nz);
    F0[3 * MM + idx] = sqrtf(dx * dx + dy * dy + dz * dz);
    float dot = dx * ex + dy * ey + dz * ez;
    float px = dx - dot * cnx;
    float py = dy - dot * cny;
    float pz = dz - dot * cnz;
    PQ[idx] = make_float4(px, py, pz, sqrtf(px * px + py * py + pz * pz));
}

// ---------------------------------------------------------------------------
// per-row median of pairwise angles. ONE row per wave, u[32] register-
// resident (plain launch_bounds(256): R8 measured 124 VGPR, no spill —
// the (256,4) variant forced 64 VGPR + 280MB scratch traffic, R9 ERRATA).
// Monotone key = tan^2(th/2); key<=2.5e-11 -> +INF. Greedy 20-bit MSB
// search for largest T with #{u < T} <= 1023; per-lane VALU counting +
// DPP wave reduce (no serial scalar chain).
// ---------------------------------------------------------------------------
__global__ __launch_bounds__(256) void alpha_k(const float4* __restrict__ PQ,
                                               float* __restrict__ F0) {
    int row = blockIdx.x * 4 + (threadIdx.x >> 6);
    int lane = threadIdx.x & 63;
    int b = row >> 11;
    const float4* base = PQ + (size_t)b * NN;
    float4 a = base[row & (NN - 1)];
    unsigned u[32];
    #pragma unroll
    for (int s2 = 0; s2 < 32; ++s2) {
        float4 bv = base[s2 * 64 + lane];
        float cx = a.y * bv.z - a.z * bv.y;
        float cy = a.z * bv.x - a.x * bv.z;
        float cz = a.x * bv.y - a.y * bv.x;
        float ss = cx * cx + cy * cy + cz * cz;
        float dc = a.x * bv.x + a.y * bv.y + a.z * bv.z;
        float den = dc + a.w * bv.w;
        float rc = __builtin_amdgcn_rcpf(den);
        float key = ss * rc * rc;
        u[s2] = (key <= 2.5e-11f) ? 0x7F800000u : __float_as_uint(key);
    }
    unsigned T = 0u;
    for (int bit = 30; bit >= 11; --bit) {
        unsigned c = T | (1u << bit);
        int c0 = 0, c1 = 0, c2 = 0, c3 = 0;
        #pragma unroll
        for (int s2 = 0; s2 < 8; ++s2) {
            c0 += (int)(u[4 * s2 + 0] < c);
            c1 += (int)(u[4 * s2 + 1] < c);
            c2 += (int)(u[4 * s2 + 2] < c);
            c3 += (int)(u[4 * s2 + 3] < c);
        }
        int total = wave_sum_dpp(c0 + c1 + c2 + c3);
        if (total <= 1023) T = c;
    }
    if (lane == 0)
        F0[4 * MM + row] = 2.0f * atanf(sqrtf(__uint_as_float(T)));
}

// ---------------------------------------------------------------------------
// pf0: tiny K=5 GEMM, Y (M,64) fp32
// ---------------------------------------------------------------------------
__global__ __launch_bounds__(256) void pf0_k(const float* __restrict__ F0,
                                             const float* __restrict__ W,
                                             float* __restrict__ Y) {
    __shared__ float ws[320];
    int t = threadIdx.x;
    for (int i = t; i < 320; i += 256) ws[i] = W[i];
    __syncthreads();
    int m = blockIdx.x * 256 + t;
    float x0 = F0[m], x1 = F0[MM + m], x2 = F0[2 * MM + m], x3 = F0[3 * MM + m], x4 = F0[4 * MM + m];
    float* ym = Y + (size_t)m * 64;
    #pragma unroll
    for (int o = 0; o < 64; ++o) {
        const float* wo = &ws[o * 5];
        ym[o] = wo[0] * x0 + wo[1] * x1 + wo[2] * x2 + wo[3] * x3 + wo[4] * x4;
    }
}

// ---------------------------------------------------------------------------
// fp16 MFMA GEMM, pipelined: BM=64, BO=128, 4 waves, wave=32x64.
// MODE 0: fp32 Y write, no stats (supports K-split via blockIdx.z).
// MODE 1: fp16 Y write + fused BN-stat epilogue into sums slice.
// ---------------------------------------------------------------------------
template<int MODE>
__global__ __launch_bounds__(256) void mgemm3_k(const unsigned short* __restrict__ X, int ldx,
                                                const unsigned short* __restrict__ W, int ldw,
                                                void* __restrict__ Yv, int Co, int K, int kchunk,
                                                float* __restrict__ sums) {
    __shared__ unsigned short As[64 * 32];    // 4KB
    __shared__ unsigned short Bs[128 * 32];   // 8KB
    int t = threadIdx.x;
    int mBase = blockIdx.x * 64;
    int oBase = blockIdx.y * 128;
    int k0c = blockIdx.z * kchunk;
    int k1c = k0c + kchunk; if (k1c > K) k1c = K;
    int lane = t & 63, w = t >> 6;
    int warpM = (w & 1) * 32, warpO = (w >> 1) * 64;
    f32x4 acc[2][4];
    #pragma unroll
    for (int i = 0; i < 2; ++i)
        #pragma unroll
        for (int j = 0; j < 4; ++j) acc[i][j] = (f32x4){0.f, 0.f, 0.f, 0.f};
    int lr = t >> 2;
    int lc = (t & 3) * 8;
    const unsigned short* Xp = X + (size_t)(mBase + lr) * ldx + lc;
    const unsigned short* Wp0 = W + (size_t)(oBase + lr) * ldw + lc;
    const unsigned short* Wp1 = W + (size_t)(oBase + lr + 64) * ldw + lc;
    int ar0 = (warpM + (lane & 15)) * 32 + (lane >> 4) * 8;
    int br0 = (warpO + (lane & 15)) * 32 + (lane >> 4) * 8;
    uint4 xa = *(const uint4*)(Xp + k0c);
    uint4 wb0 = *(const uint4*)(Wp0 + k0c);
    uint4 wb1 = *(const uint4*)(Wp1 + k0c);
    for (int k = k0c; k < k1c; k += 32) {
        __syncthreads();
        *(uint4*)&As[lr * 32 + lc] = xa;
        *(uint4*)&Bs[lr * 32 + lc] = wb0;
        *(uint4*)&Bs[(lr + 64) * 32 + lc] = wb1;
        if (k + 32 < k1c) {
            xa = *(const uint4*)(Xp + k + 32);
            wb0 = *(const uint4*)(Wp0 + k + 32);
            wb1 = *(const uint4*)(Wp1 + k + 32);
        }
        __syncthreads();
        half8 a0 = __builtin_bit_cast(half8, *(const uint4*)&As[ar0]);
        half8 a1 = __builtin_bit_cast(half8, *(const uint4*)&As[ar0 + 16 * 32]);
        half8 b0 = __builtin_bit_cast(half8, *(const uint4*)&Bs[br0]);
        half8 b1 = __builtin_bit_cast(half8, *(const uint4*)&Bs[br0 + 16 * 32]);
        half8 b2 = __builtin_bit_cast(half8, *(const uint4*)&Bs[br0 + 32 * 32]);
        half8 b3 = __builtin_bit_cast(half8, *(const uint4*)&Bs[br0 + 48 * 32]);
        acc[0][0] = __builtin_amdgcn_mfma_f32_16x16x32_f16(a0, b0, acc[0][0], 0, 0, 0);
        acc[0][1] = __builtin_amdgcn_mfma_f32_16x16x32_f16(a0, b1, acc[0][1], 0, 0, 0);
        acc[0][2] = __builtin_amdgcn_mfma_f32_16x16x32_f16(a0, b2, acc[0][2], 0, 0, 0);
        acc[0][3] = __builtin_amdgcn_mfma_f32_16x16x32_f16(a0, b3, acc[0][3], 0, 0, 0);
        acc[1][0] = __builtin_amdgcn_mfma_f32_16x16x32_f16(a1, b0, acc[1][0], 0, 0, 0);
        acc[1][1] = __builtin_amdgcn_mfma_f32_16x16x32_f16(a1, b1, acc[1][1], 0, 0, 0);
        acc[1][2] = __builtin_amdgcn_mfma_f32_16x16x32_f16(a1, b2, acc[1][2], 0, 0, 0);
        acc[1][3] = __builtin_amdgcn_mfma_f32_16x16x32_f16(a1, b3, acc[1][3], 0, 0, 0);
    }
    if (MODE == 0) {
        float* Yp = (float*)Yv + (size_t)blockIdx.z * MM * Co;
        #pragma unroll
        for (int i = 0; i < 2; ++i)
            #pragma unroll
            for (int j = 0; j < 4; ++j) {
                int m0 = mBase + warpM + i * 16 + (lane >> 4) * 4;
                int o = oBase + warpO + j * 16 + (lane & 15);
                #pragma unroll
                for (int r = 0; r < 4; ++r)
                    Yp[(size_t)(m0 + r) * Co + o] = acc[i][j][r];
            }
    } else {
        unsigned short* Yh = (unsigned short*)Yv;
        #pragma unroll
        for (int i = 0; i < 2; ++i)
            #pragma unroll
            for (int j = 0; j < 4; ++j) {
                int m0 = mBase + warpM + i * 16 + (lane >> 4) * 4;
                int o = oBase + warpO + j * 16 + (lane & 15);
                #pragma unroll
                for (int r = 0; r < 4; ++r)
                    Yh[(size_t)(m0 + r) * Co + o] = f2h(acc[i][j][r]);
            }
        __syncthreads();
        float* ssum = (float*)As;
        float* ssq = (float*)Bs;
        if (t < 128) { ssum[t] = 0.f; ssq[t] = 0.f; }
        __syncthreads();
        #pragma unroll
        for (int j = 0; j < 4; ++j) {
            int oc = warpO + j * 16 + (lane & 15);
            float s = 0.f, q = 0.f;
            #pragma unroll
            for (int i = 0; i < 2; ++i)
                #pragma unroll
                for (int r = 0; r < 4; ++r) { float v = acc[i][j][r]; s += v; q += v * v; }
            atomicAdd(&ssum[oc], s);
            atomicAdd(&ssq[oc], q);
        }
        __syncthreads();
        if (t < 128) {
            atomicAdd(&sums[oBase + t], ssum[t]);
            atomicAdd(&sums[1024 + oBase + t], ssq[t]);
        }
    }
}

// ---------------------------------------------------------------------------
// fused: sum 4 cls0 K-split partials into partial 0 + BN stats, one pass.
// ---------------------------------------------------------------------------
__global__ __launch_bounds__(256) void red4stat_k(float* __restrict__ Y,
                                                  float* __restrict__ sums) {
    int o0 = blockIdx.x * 64;
    int m0 = blockIdx.y * 128;
    int t = threadIdx.x, ol = t & 63, mg = t >> 6;
    const size_t stride = (size_t)MM * 256;
    float s = 0.f, q = 0.f;
    float* p = Y + (size_t)(m0 + mg) * 256 + o0 + ol;
    for (int i = 0; i < 32; ++i) {
        float* pp = p + (size_t)i * 4 * 256;
        float v = pp[0] + pp[stride] + pp[2 * stride] + pp[3 * stride];
        pp[0] = v;
        s += v; q += v * v;
    }
    __shared__ float ls[4][64], lq[4][64];
    ls[mg][ol] = s; lq[mg][ol] = q;
    __syncthreads();
    if (mg == 0) {
        s = ls[0][ol] + ls[1][ol] + ls[2][ol] + ls[3][ol];
        q = lq[0][ol] + lq[1][ol] + lq[2][ol] + lq[3][ol];
        atomicAdd(&sums[o0 + ol], s);
        atomicAdd(&sums[1024 + o0 + ol], q);
    }
}

// ---------------------------------------------------------------------------
// BN stats from fp32 Y (pf0) into a sums slice
// ---------------------------------------------------------------------------
__global__ __launch_bounds__(256) void bnstat_k(const float* __restrict__ Y, int Co,
                                                float* __restrict__ sums) {
    int o0 = blockIdx.x * 64;
    int m0 = blockIdx.y * 512;
    int t = threadIdx.x, ol = t & 63, mg = t >> 6;
    float s = 0.f, q = 0.f;
    const float* p = Y + (size_t)(m0 + mg) * Co + o0 + ol;
    for (int i = 0; i < 128; ++i) {
        float v = p[(size_t)i * 4 * Co];
        s += v; q += v * v;
    }
    __shared__ float ls[4][64], lq[4][64];
    ls[mg][ol] = s; lq[mg][ol] = q;
    __syncthreads();
    if (mg == 0) {
        s = ls[0][ol] + ls[1][ol] + ls[2][ol] + ls[3][ol];
        q = lq[0][ol] + lq[1][ol] + lq[2][ol] + lq[3][ol];
        atomicAdd(&sums[o0 + ol], s);
        atomicAdd(&sums[1024 + o0 + ol], q);
    }
}

// inline BN coefficient from sums slice
__device__ __forceinline__ void bncoef(const float* __restrict__ sums,
                                       const float* __restrict__ g,
                                       const float* __restrict__ bb,
                                       int o, float& a, float& c) {
    float mu = sums[o] * (1.f / 8192.f);
    float var = sums[1024 + o] * (1.f / 8192.f) - mu * mu;
    var = fmaxf(var, 0.f);
    a = g[o] * (1.0f / sqrtf(var + EPSF));
    c = bb[o] - mu * a;
}

// ---------------------------------------------------------------------------
// BN normalize + ReLU + fp16 store (fp32 source)
// ---------------------------------------------------------------------------
__global__ __launch_bounds__(256) void bnorm_f(const float* __restrict__ Y,
                                               const float* __restrict__ sums,
                                               const float* __restrict__ g,
                                               const float* __restrict__ bb,
                                               unsigned short* __restrict__ dst, int ldd, int shift) {
    int idx4 = blockIdx.x * 256 + threadIdx.x;
    int m = idx4 >> shift;
    int o4 = (idx4 & ((1 << shift) - 1)) * 4;
    float4 v = ((const float4*)Y)[idx4];
    float vv[4] = {v.x, v.y, v.z, v.w};
    unsigned short r[4];
    #pragma unroll
    for (int j = 0; j < 4; ++j) {
        float a, c;
        bncoef(sums, g, bb, o4 + j, a, c);
        r[j] = f2h(fmaxf(vv[j] * a + c, 0.f));
    }
    *(ushort4*)&dst[(size_t)m * ldd + o4] = make_ushort4(r[0], r[1], r[2], r[3]);
}

// ---------------------------------------------------------------------------
// BN normalize + ReLU + fp16 store (fp16 source)
// ---------------------------------------------------------------------------
__global__ __launch_bounds__(256) void bnorm_h(const unsigned short* __restrict__ Yh,
                                               const float* __restrict__ sums,
                                               const float* __restrict__ g,
                                               const float* __restrict__ bb,
                                               unsigned short* __restrict__ dst, int ldd, int shift) {
    int idx4 = blockIdx.x * 256 + threadIdx.x;
    int m = idx4 >> shift;
    int o4 = (idx4 & ((1 << shift) - 1)) * 4;
    ushort4 hv = ((const ushort4*)Yh)[idx4];
    float vv[4] = {h2f(hv.x), h2f(hv.y), h2f(hv.z), h2f(hv.w)};
    unsigned short r[4];
    #pragma unroll
    for (int j = 0; j < 4; ++j) {
        float a, c;
        bncoef(sums, g, bb, o4 + j, a, c);
        r[j] = f2h(fmaxf(vv[j] * a + c, 0.f));
    }
    *(ushort4*)&dst[(size_t)m * ldd + o4] = make_ushort4(r[0], r[1], r[2], r[3]);
}

// ---------------------------------------------------------------------------
// max over N per (b, channel) from pf3's fp16 slice
// ---------------------------------------------------------------------------
__global__ __launch_bounds__(256) void maxred_k(const unsigned short* __restrict__ Xs,
                                                float* __restrict__ maxbuf) {
    int o0 = blockIdx.x * 64;
    int b = blockIdx.y;
    int rc = blockIdx.z;
    int t = threadIdx.x, ol = t & 63, mg = t >> 6;
    float mx = 0.f;
    for (int i = 0; i < 128; ++i) {
        int m = b * NN + rc * 512 + i * 4 + mg;
        mx = fmaxf(mx, h2f(Xs[(size_t)m * 2400 + o0 + ol]));
    }
    __shared__ float ls[4][64];
    ls[mg][ol] = mx;
    __syncthreads();
    if (mg == 0) {
        mx = fmaxf(fmaxf(ls[0][ol], ls[1][ol]), fmaxf(ls[2][ol], ls[3][ol]));
        atomicMax((unsigned*)&maxbuf[b * 1024 + o0 + ol], __builtin_bit_cast(unsigned, mx));
    }
}

__global__ __launch_bounds__(256) void maxbc_k(const float* __restrict__ maxbuf,
                                               unsigned short* __restrict__ XCb) {
    int idx8 = blockIdx.x * 256 + threadIdx.x;
    int m = idx8 >> 7;
    int o8 = (idx8 & 127) * 8;
    int b = m >> 11;
    const float* mb = maxbuf + b * 1024 + o8;
    ushort4 u0 = make_ushort4(f2h(mb[0]), f2h(mb[1]), f2h(mb[2]), f2h(mb[3]));
    ushort4 u1 = make_ushort4(f2h(mb[4]), f2h(mb[5]), f2h(mb[6]), f2h(mb[7]));
    *(ushort4*)&XCb[(size_t)m * 2400 + 1360 + o8] = u0;
    *(ushort4*)&XCb[(size_t)m * 2400 + 1360 + o8 + 4] = u1;
}

// ---------------------------------------------------------------------------
// final: OT(M,128) fp32 -> out (B,50,N) + bias, via LDS transpose
// ---------------------------------------------------------------------------
__global__ __launch_bounds__(256) void wout_k(const float* __restrict__ OT,
                                              const float* __restrict__ bias,
                                              float* __restrict__ out) {
    __shared__ float ts[128][65];
    int t = threadIdx.x;
    int m0 = blockIdx.x * 128;
    #pragma unroll
    for (int i = 0; i < 8; ++i) {
        int idx4 = t + 256 * i;
        int row = idx4 >> 4, c4 = (idx4 & 15) * 4;
        float4 v = *(const float4*)&OT[(size_t)(m0 + row) * 128 + c4];
        ts[row][c4] = v.x; ts[row][c4 + 1] = v.y; ts[row][c4 + 2] = v.z; ts[row][c4 + 3] = v.w;
    }
    __syncthreads();
    int b = m0 >> 11, n0 = m0 & (NN - 1);
    #pragma unroll
    for (int j = 0; j < 25; ++j) {
        int idx = t + 256 * j;
        int o = idx >> 7, nl = idx & 127;
        out[((size_t)b * 50 + o) * NN + n0 + nl] = ts[nl][o] + bias[o];
    }
}

// ---------------------------------------------------------------------------
extern "C" void kernel_launch(void* const* d_in, const int* in_sizes, int n_in,
                              void* d_out, int out_size, void* d_ws, size_t ws_size,
                              hipStream_t stream) {
    const float* in = (const float*)d_in[0];
    const float* pf0_w = (const float*)d_in[1];
    const float* pf_g[4] = {(const float*)d_in[2], (const float*)d_in[5], (const float*)d_in[8], (const float*)d_in[11]};
    const float* pf_b[4] = {(const float*)d_in[3], (const float*)d_in[6], (const float*)d_in[9], (const float*)d_in[12]};
    const float* pf_w[4] = {(const float*)d_in[1], (const float*)d_in[4], (const float*)d_in[7], (const float*)d_in[10]};
    const float* cls_w[3] = {(const float*)d_in[13], (const float*)d_in[16], (const float*)d_in[19]};
    const float* cls_g[3] = {(const float*)d_in[14], (const float*)d_in[17], (const float*)d_in[20]};
    const float* cls_b[3] = {(const float*)d_in[15], (const float*)d_in[18], (const float*)d_in[21]};
    const float* cls3_w = (const float*)d_in[22];
    const float* cls3_bias = (const float*)d_in[23];
    float* out = (float*)d_out;

    char* wsb = (char*)d_ws;
    float* ST = (float*)(wsb + 0);                      // 256 B
    float4* PQ = (float4*)(wsb + 256);                  // 131072 B
    float* F0 = (float*)(wsb + 131328);                 // 163840 B
    float* SUMS = (float*)(wsb + 295168);               // 7 slices x 8192 B = 57344 B
    float* MAXB = (float*)(wsb + 352512);               // 16384 B (right after SUMS)
    unsigned short* WB = (unsigned short*)(wsb + 368896);    // 1769472 B
    unsigned short* XCb = (unsigned short*)(wsb + 2138368);  // 39321600 B
    unsigned short* C1b = (unsigned short*)(wsb + 41459968); // 4194304 B (aliased as C3b)
    unsigned short* C2b = (unsigned short*)(wsb + 45654272); // 4194304 B
    unsigned short* C3b = C1b;
    float* Y = (float*)(wsb + 49848576);                // 33554432 B (4 cls0 partials)
    unsigned short* Yh = (unsigned short*)Y;

    auto SL = [&](int s) { return SUMS + (size_t)s * 2048; };

    // fused preamble: wconv + stats + zero(SUMS+MAXB) + onehot
    prep_k<<<3564, 256, 0, stream>>>(in, pf_w[1], pf_w[2], pf_w[3], cls_w[0], cls_w[1], cls_w[2], cls3_w,
                                     WB, ST, SUMS, XCb);
    point_k<<<MM / 256, 256, 0, stream>>>(in, ST, PQ, F0);
    alpha_k<<<MM / 4, 256, 0, stream>>>(PQ, F0);

    // pf0 (fp32 path)
    pf0_k<<<MM / 256, 256, 0, stream>>>(F0, pf0_w, Y);
    bnstat_k<<<dim3(1, 16), 256, 0, stream>>>(Y, 64, SL(0));
    bnorm_f<<<512, 256, 0, stream>>>(Y, SL(0), pf_g[0], pf_b[0], XCb + 16, 2400, 4);
    // pf1 (Co=128, K=64)
    mgemm3_k<1><<<dim3(128, 1, 1), 256, 0, stream>>>(XCb + 16, 2400, WB, 64, Yh, 128, 64, 64, SL(1));
    bnorm_h<<<1024, 256, 0, stream>>>(Yh, SL(1), pf_g[1], pf_b[1], XCb + 80, 2400, 5);
    // pf2 (Co=128, K=128)
    mgemm3_k<1><<<dim3(128, 1, 1), 256, 0, stream>>>(XCb + 80, 2400, WB + 8192, 128, Yh, 128, 128, 128, SL(2));
    bnorm_h<<<1024, 256, 0, stream>>>(Yh, SL(2), pf_g[2], pf_b[2], XCb + 208, 2400, 5);
    // pf3 (Co=1024, K=128)
    mgemm3_k<1><<<dim3(128, 8, 1), 256, 0, stream>>>(XCb + 208, 2400, WB + 24576, 128, Yh, 1024, 128, 128, SL(3));
    bnorm_h<<<8192, 256, 0, stream>>>(Yh, SL(3), pf_g[3], pf_b[3], XCb + 336, 2400, 8);
    // max feature
    maxred_k<<<dim3(16, 4, 4), 256, 0, stream>>>(XCb + 336, MAXB);
    maxbc_k<<<4096, 256, 0, stream>>>(MAXB, XCb);
    // cls0 (Co=256, K=2400): K-split x4, fp32 partials, fused reduce+stats, norm
    mgemm3_k<0><<<dim3(128, 2, 4), 256, 0, stream>>>(XCb, 2400, WB + 155648, 2400, Y, 256, 2400, 608, SL(4));
    red4stat_k<<<dim3(4, 64), 256, 0, stream>>>(Y, SL(4));
    bnorm_f<<<2048, 256, 0, stream>>>(Y, SL(4), cls_g[0], cls_b[0], C1b, 256, 6);
    // cls1 (Co=256, K=256)
    mgemm3_k<1><<<dim3(128, 2, 1), 256, 0, stream>>>(C1b, 256, WB + 770048, 256, Yh, 256, 256, 256, SL(5));
    bnorm_h<<<2048, 256, 0, stream>>>(Yh, SL(5), cls_g[1], cls_b[1], C2b, 256, 6);
    // cls2 (Co=128, K=256)
    mgemm3_k<1><<<dim3(128, 1, 1), 256, 0, stream>>>(C2b, 256, WB + 835584, 256, Yh, 128, 256, 256, SL(6));
    bnorm_h<<<1024, 256, 0, stream>>>(Yh, SL(6), cls_g[2], cls_b[2], C3b, 128, 5);
    // cls3 (padded to 128 outputs, rows 50..127 zero) -> fp32 Y
    mgemm3_k<0><<<dim3(128, 1, 1), 256, 0, stream>>>(C3b, 128, WB + 868352, 128, Y, 128, 128, 128, SL(0));
    wout_k<<<MM / 128, 256, 0, stream>>>(Y, cls3_bias, out);

    (void)in_sizes; (void)n_in; (void)out_size; (void)ws_size;
}

// Round 11
// 219.005 us; speedup vs baseline: 1.3200x; 1.1383x over previous
//
#include <hip/hip_runtime.h>
#include <math.h>

#define BB 4
#define NN 2048
#define MM 8192
#define EPSF 1e-5f

typedef _Float16 half8 __attribute__((ext_vector_type(8)));
typedef float f32x4 __attribute__((ext_vector_type(4)));

__device__ __forceinline__ unsigned short f2h(float x) {
    _Float16 h = (_Float16)x;
    return __builtin_bit_cast(unsigned short, h);
}
__device__ __forceinline__ float h2f(unsigned short u) {
    return (float)__builtin_bit_cast(_Float16, u);
}

// wave64 sum via DPP: row_shr 1/2/4/8 + row_bcast 15/31; total lands in lane 63
__device__ __forceinline__ int wave_sum_dpp(int v) {
    v += __builtin_amdgcn_update_dpp(0, v, 0x111, 0xF, 0xF, true);
    v += __builtin_amdgcn_update_dpp(0, v, 0x112, 0xF, 0xF, true);
    v += __builtin_amdgcn_update_dpp(0, v, 0x114, 0xF, 0xF, true);
    v += __builtin_amdgcn_update_dpp(0, v, 0x118, 0xF, 0xF, true);
    v += __builtin_amdgcn_update_dpp(0, v, 0x142, 0xa, 0xF, true);
    v += __builtin_amdgcn_update_dpp(0, v, 0x143, 0xc, 0xF, true);
    return __builtin_amdgcn_readlane(v, 63);
}

__device__ __forceinline__ float angle3(float ux, float uy, float uz,
                                        float vx, float vy, float vz) {
    float crx = uy * vz - uz * vy;
    float cry = uz * vx - ux * vz;
    float crz = ux * vy - uy * vx;
    float s = sqrtf(crx * crx + cry * cry + crz * crz);
    float c = ux * vx + uy * vy + uz * vz;
    return atan2f(s, c);
}

// ---------------------------------------------------------------------------
// fused preamble: wconv x4-vectorized (blocks 0..863) | stats (864..867) |
// zero SUMS+MAXB (868..939) | onehot (940..971)
// ---------------------------------------------------------------------------
__global__ __launch_bounds__(256) void prep_k(const float* __restrict__ in,
                                              const float* __restrict__ w1, const float* __restrict__ w2,
                                              const float* __restrict__ w3, const float* __restrict__ w4,
                                              const float* __restrict__ w5, const float* __restrict__ w6,
                                              const float* __restrict__ w7,
                                              unsigned short* __restrict__ Wb,
                                              float* __restrict__ st,
                                              float* __restrict__ zp,
                                              unsigned short* __restrict__ XCb) {
    int blk = blockIdx.x;
    int t = threadIdx.x;
    if (blk < 864) {
        int idx0 = blk * 1024 + t * 4;
        ushort4 r;
        unsigned short* rp = (unsigned short*)&r;
        #pragma unroll
        for (int e = 0; e < 4; ++e) {
            int idx = idx0 + e;
            unsigned short v;
            if (idx < 8192) v = f2h(w1[idx]);
            else if (idx < 24576) v = f2h(w2[idx - 8192]);
            else if (idx < 155648) v = f2h(w3[idx - 24576]);
            else if (idx < 770048) {
                int l = idx - 155648;
                int o = l / 2400, k = l - o * 2400;
                v = (k < 2384) ? f2h(w4[o * 2384 + k]) : (unsigned short)0;
            } else if (idx < 835584) v = f2h(w5[idx - 770048]);
            else if (idx < 868352) v = f2h(w6[idx - 835584]);
            else {
                int l = idx - 868352;
                int o = l >> 7, k = l & 127;
                v = (o < 50) ? f2h(w7[o * 128 + k]) : (unsigned short)0;
            }
            rp[e] = v;
        }
        *(ushort4*)&Wb[idx0] = r;
    } else if (blk < 868) {
        int b = blk - 864;
        const float* base = in + (size_t)b * 22 * NN;
        float cs0 = 0.f, cs1 = 0.f, cs2 = 0.f, ns0 = 0.f, ns1 = 0.f, ns2 = 0.f;
        for (int n = t; n < NN; n += 256) {
            float cx = base[0 * NN + n], cy = base[1 * NN + n], cz = base[2 * NN + n];
            float nx = base[3 * NN + n], ny = base[4 * NN + n], nz = base[5 * NN + n];
            float inv = 1.0f / sqrtf(nx * nx + ny * ny + nz * nz);
            cs0 += cx; cs1 += cy; cs2 += cz;
            ns0 += nx * inv; ns1 += ny * inv; ns2 += nz * inv;
        }
        __shared__ float red[6][256];
        red[0][t] = cs0; red[1][t] = cs1; red[2][t] = cs2;
        red[3][t] = ns0; red[4][t] = ns1; red[5][t] = ns2;
        __syncthreads();
        for (int s = 128; s > 0; s >>= 1) {
            if (t < s) {
                #pragma unroll
                for (int i = 0; i < 6; ++i) red[i][t] += red[i][t + s];
            }
            __syncthreads();
        }
        if (t == 0) {
            float ccx = red[0][0] / (float)NN, ccy = red[1][0] / (float)NN, ccz = red[2][0] / (float)NN;
            float cnx = red[3][0] / (float)NN, cny = red[4][0] / (float)NN, cnz = red[5][0] / (float)NN;
            float inv = 1.0f / sqrtf(cnx * cnx + cny * cny + cnz * cnz);
            float* s9 = st + b * 16;
            s9[0] = ccx; s9[1] = ccy; s9[2] = ccz;
            s9[3] = cnx; s9[4] = cny; s9[5] = cnz;
            s9[6] = cnx * inv; s9[7] = cny * inv; s9[8] = cnz * inv;
        }
    } else if (blk < 940) {
        zp[(blk - 868) * 256 + t] = 0.f;
    } else {
        int m = (blk - 940) * 256 + t;
        int b = m >> 11, n = m & (NN - 1);
        const float* src = in + (size_t)b * 22 * NN + 6 * NN + n;
        unsigned short vals[16];
        #pragma unroll
        for (int r = 0; r < 16; ++r) vals[r] = f2h(src[(size_t)r * NN]);
        ushort4* dst = (ushort4*)&XCb[(size_t)m * 2400];
        #pragma unroll
        for (int q = 0; q < 4; ++q)
            dst[q] = make_ushort4(vals[4 * q], vals[4 * q + 1], vals[4 * q + 2], vals[4 * q + 3]);
        ushort4 z = make_ushort4(0, 0, 0, 0);
        ushort4* pz = (ushort4*)&XCb[(size_t)m * 2400 + 2384];
        pz[0] = z; pz[1] = z; pz[2] = z; pz[3] = z;
    }
}

// ---------------------------------------------------------------------------
// per-point PPF (F0 rows 0..3) + packed projected vectors PQ = (x,y,z,|P|)
// ---------------------------------------------------------------------------
__global__ __launch_bounds__(256) void point_k(const float* __restrict__ in,
                                               const float* __restrict__ st,
                                               float4* __restrict__ PQ,
                                               float* __restrict__ F0) {
    int idx = blockIdx.x * 256 + threadIdx.x;
    int b = idx >> 11, n = idx & (NN - 1);
    const float* base = in + (size_t)b * 22 * NN;
    const float* s9 = st + b * 16;
    float cx = base[0 * NN + n], cy = base[1 * NN + n], cz = base[2 * NN + n];
    float nx = base[3 * NN + n], ny = base[4 * NN + n], nz = base[5 * NN + n];
    float inv = 1.0f / sqrtf(nx * nx + ny * ny + nz * nz);
    nx *= inv; ny *= inv; nz *= inv;
    float ccx = s9[0], ccy = s9[1], ccz = s9[2];
    float cnx = s9[3], cny = s9[4], cnz = s9[5];
    float ex = s9[6], ey = s9[7], ez = s9[8];
    float dx = cx - ccx, dy = cy - ccy, dz = cz - ccz;
    F0[0 * MM + idx] = angle3(cnx, cny, cnz, dx, dy, dz);
    F0[1 * MM + idx] = angle3(nx, ny, nz, dx, dy, dz);
    F0[2 * MM + idx] = angle3(cnx, cny, cnz, nx, ny, nz);
    F0[3 * MM + idx] = sqrtf(dx * dx + dy * dy + dz * dz);
    float dot = dx * ex + dy * ey + dz * ez;
    float px = dx - dot * cnx;
    float py = dy - dot * cny;
    float pz = dz - dot * cnz;
    PQ[idx] = make_float4(px, py, pz, sqrtf(px * px + py * py + pz * pz));
}

// ---------------------------------------------------------------------------
// per-row median of pairwise angles. ONE row per wave, u[32] register-
// resident. Hybrid counting per bit: 16 values on VALU (cmp+addc + DPP
// reduce) and 16 via __ballot+popcll on the scalar pipe — both pipes busy
// concurrently (R8 was scalar-bound @VALU32%, R10 VALU-bound @77%).
// 17-bit greedy MSB search (bits 30..14), midpoint reconstruction (+2^13):
// key rel err <= 2^-10 -> alpha err <= fp16 feature noise.
// ---------------------------------------------------------------------------
__global__ __launch_bounds__(256) void alpha_k(const float4* __restrict__ PQ,
                                               float* __restrict__ F0) {
    int row = blockIdx.x * 4 + (threadIdx.x >> 6);
    int lane = threadIdx.x & 63;
    int b = row >> 11;
    const float4* base = PQ + (size_t)b * NN;
    float4 a = base[row & (NN - 1)];
    unsigned u[32];
    #pragma unroll
    for (int s2 = 0; s2 < 32; ++s2) {
        float4 bv = base[s2 * 64 + lane];
        float cx = a.y * bv.z - a.z * bv.y;
        float cy = a.z * bv.x - a.x * bv.z;
        float cz = a.x * bv.y - a.y * bv.x;
        float ss = cx * cx + cy * cy + cz * cz;
        float dc = a.x * bv.x + a.y * bv.y + a.z * bv.z;
        float den = dc + a.w * bv.w;
        float rc = __builtin_amdgcn_rcpf(den);
        float key = ss * rc * rc;
        u[s2] = (key <= 2.5e-11f) ? 0x7F800000u : __float_as_uint(key);
    }
    unsigned T = 0u;
    for (int bit = 30; bit >= 14; --bit) {
        unsigned c = T | (1u << bit);
        // scalar-pipe half: values 16..31 via ballot + s_bcnt1 (2 indep chains)
        int s0 = 0, s1 = 0;
        #pragma unroll
        for (int q = 0; q < 8; ++q) {
            s0 += (int)__popcll(__ballot(u[16 + q] < c));
            s1 += (int)__popcll(__ballot(u[24 + q] < c));
        }
        // VALU half: values 0..15 per-lane count + DPP wave reduce
        int v0 = 0, v1 = 0, v2 = 0, v3 = 0;
        #pragma unroll
        for (int q = 0; q < 4; ++q) {
            v0 += (int)(u[q] < c);
            v1 += (int)(u[4 + q] < c);
            v2 += (int)(u[8 + q] < c);
            v3 += (int)(u[12 + q] < c);
        }
        int vsum = wave_sum_dpp(v0 + v1 + v2 + v3);
        if (vsum + s0 + s1 <= 1023) T = c;
    }
    if (lane == 0)
        F0[4 * MM + row] = 2.0f * atanf(sqrtf(__uint_as_float(T + 8192u)));
}

// ---------------------------------------------------------------------------
// pf0: tiny K=5 GEMM, Y (M,64) fp32
// ---------------------------------------------------------------------------
__global__ __launch_bounds__(256) void pf0_k(const float* __restrict__ F0,
                                             const float* __restrict__ W,
                                             float* __restrict__ Y) {
    __shared__ float ws[320];
    int t = threadIdx.x;
    for (int i = t; i < 320; i += 256) ws[i] = W[i];
    __syncthreads();
    int m = blockIdx.x * 256 + t;
    float x0 = F0[m], x1 = F0[MM + m], x2 = F0[2 * MM + m], x3 = F0[3 * MM + m], x4 = F0[4 * MM + m];
    float* ym = Y + (size_t)m * 64;
    #pragma unroll
    for (int o = 0; o < 64; ++o) {
        const float* wo = &ws[o * 5];
        ym[o] = wo[0] * x0 + wo[1] * x1 + wo[2] * x2 + wo[3] * x3 + wo[4] * x4;
    }
}

// ---------------------------------------------------------------------------
// fp16 MFMA GEMM, pipelined: BM=64, BO=128, 4 waves, wave=32x64.
// MODE 0: fp32 Y write, no stats (supports K-split via blockIdx.z).
// MODE 1: fp16 Y write + fused BN-stat epilogue into sums slice.
// ---------------------------------------------------------------------------
template<int MODE>
__global__ __launch_bounds__(256) void mgemm3_k(const unsigned short* __restrict__ X, int ldx,
                                                const unsigned short* __restrict__ W, int ldw,
                                                void* __restrict__ Yv, int Co, int K, int kchunk,
                                                float* __restrict__ sums) {
    __shared__ unsigned short As[64 * 32];    // 4KB
    __shared__ unsigned short Bs[128 * 32];   // 8KB
    int t = threadIdx.x;
    int mBase = blockIdx.x * 64;
    int oBase = blockIdx.y * 128;
    int k0c = blockIdx.z * kchunk;
    int k1c = k0c + kchunk; if (k1c > K) k1c = K;
    int lane = t & 63, w = t >> 6;
    int warpM = (w & 1) * 32, warpO = (w >> 1) * 64;
    f32x4 acc[2][4];
    #pragma unroll
    for (int i = 0; i < 2; ++i)
        #pragma unroll
        for (int j = 0; j < 4; ++j) acc[i][j] = (f32x4){0.f, 0.f, 0.f, 0.f};
    int lr = t >> 2;
    int lc = (t & 3) * 8;
    const unsigned short* Xp = X + (size_t)(mBase + lr) * ldx + lc;
    const unsigned short* Wp0 = W + (size_t)(oBase + lr) * ldw + lc;
    const unsigned short* Wp1 = W + (size_t)(oBase + lr + 64) * ldw + lc;
    int ar0 = (warpM + (lane & 15)) * 32 + (lane >> 4) * 8;
    int br0 = (warpO + (lane & 15)) * 32 + (lane >> 4) * 8;
    uint4 xa = *(const uint4*)(Xp + k0c);
    uint4 wb0 = *(const uint4*)(Wp0 + k0c);
    uint4 wb1 = *(const uint4*)(Wp1 + k0c);
    for (int k = k0c; k < k1c; k += 32) {
        __syncthreads();
        *(uint4*)&As[lr * 32 + lc] = xa;
        *(uint4*)&Bs[lr * 32 + lc] = wb0;
        *(uint4*)&Bs[(lr + 64) * 32 + lc] = wb1;
        if (k + 32 < k1c) {
            xa = *(const uint4*)(Xp + k + 32);
            wb0 = *(const uint4*)(Wp0 + k + 32);
            wb1 = *(const uint4*)(Wp1 + k + 32);
        }
        __syncthreads();
        half8 a0 = __builtin_bit_cast(half8, *(const uint4*)&As[ar0]);
        half8 a1 = __builtin_bit_cast(half8, *(const uint4*)&As[ar0 + 16 * 32]);
        half8 b0 = __builtin_bit_cast(half8, *(const uint4*)&Bs[br0]);
        half8 b1 = __builtin_bit_cast(half8, *(const uint4*)&Bs[br0 + 16 * 32]);
        half8 b2 = __builtin_bit_cast(half8, *(const uint4*)&Bs[br0 + 32 * 32]);
        half8 b3 = __builtin_bit_cast(half8, *(const uint4*)&Bs[br0 + 48 * 32]);
        acc[0][0] = __builtin_amdgcn_mfma_f32_16x16x32_f16(a0, b0, acc[0][0], 0, 0, 0);
        acc[0][1] = __builtin_amdgcn_mfma_f32_16x16x32_f16(a0, b1, acc[0][1], 0, 0, 0);
        acc[0][2] = __builtin_amdgcn_mfma_f32_16x16x32_f16(a0, b2, acc[0][2], 0, 0, 0);
        acc[0][3] = __builtin_amdgcn_mfma_f32_16x16x32_f16(a0, b3, acc[0][3], 0, 0, 0);
        acc[1][0] = __builtin_amdgcn_mfma_f32_16x16x32_f16(a1, b0, acc[1][0], 0, 0, 0);
        acc[1][1] = __builtin_amdgcn_mfma_f32_16x16x32_f16(a1, b1, acc[1][1], 0, 0, 0);
        acc[1][2] = __builtin_amdgcn_mfma_f32_16x16x32_f16(a1, b2, acc[1][2], 0, 0, 0);
        acc[1][3] = __builtin_amdgcn_mfma_f32_16x16x32_f16(a1, b3, acc[1][3], 0, 0, 0);
    }
    if (MODE == 0) {
        float* Yp = (float*)Yv + (size_t)blockIdx.z * MM * Co;
        #pragma unroll
        for (int i = 0; i < 2; ++i)
            #pragma unroll
            for (int j = 0; j < 4; ++j) {
                int m0 = mBase + warpM + i * 16 + (lane >> 4) * 4;
                int o = oBase + warpO + j * 16 + (lane & 15);
                #pragma unroll
                for (int r = 0; r < 4; ++r)
                    Yp[(size_t)(m0 + r) * Co + o] = acc[i][j][r];
            }
    } else {
        unsigned short* Yh = (unsigned short*)Yv;
        #pragma unroll
        for (int i = 0; i < 2; ++i)
            #pragma unroll
            for (int j = 0; j < 4; ++j) {
                int m0 = mBase + warpM + i * 16 + (lane >> 4) * 4;
                int o = oBase + warpO + j * 16 + (lane & 15);
                #pragma unroll
                for (int r = 0; r < 4; ++r)
                    Yh[(size_t)(m0 + r) * Co + o] = f2h(acc[i][j][r]);
            }
        __syncthreads();
        float* ssum = (float*)As;
        float* ssq = (float*)Bs;
        if (t < 128) { ssum[t] = 0.f; ssq[t] = 0.f; }
        __syncthreads();
        #pragma unroll
        for (int j = 0; j < 4; ++j) {
            int oc = warpO + j * 16 + (lane & 15);
            float s = 0.f, q = 0.f;
            #pragma unroll
            for (int i = 0; i < 2; ++i)
                #pragma unroll
                for (int r = 0; r < 4; ++r) { float v = acc[i][j][r]; s += v; q += v * v; }
            atomicAdd(&ssum[oc], s);
            atomicAdd(&ssq[oc], q);
        }
        __syncthreads();
        if (t < 128) {
            atomicAdd(&sums[oBase + t], ssum[t]);
            atomicAdd(&sums[1024 + oBase + t], ssq[t]);
        }
    }
}

// ---------------------------------------------------------------------------
// fused: sum 4 cls0 K-split partials into partial 0 + BN stats, one pass.
// ---------------------------------------------------------------------------
__global__ __launch_bounds__(256) void red4stat_k(float* __restrict__ Y,
                                                  float* __restrict__ sums) {
    int o0 = blockIdx.x * 64;
    int m0 = blockIdx.y * 128;
    int t = threadIdx.x, ol = t & 63, mg = t >> 6;
    const size_t stride = (size_t)MM * 256;
    float s = 0.f, q = 0.f;
    float* p = Y + (size_t)(m0 + mg) * 256 + o0 + ol;
    for (int i = 0; i < 32; ++i) {
        float* pp = p + (size_t)i * 4 * 256;
        float v = pp[0] + pp[stride] + pp[2 * stride] + pp[3 * stride];
        pp[0] = v;
        s += v; q += v * v;
    }
    __shared__ float ls[4][64], lq[4][64];
    ls[mg][ol] = s; lq[mg][ol] = q;
    __syncthreads();
    if (mg == 0) {
        s = ls[0][ol] + ls[1][ol] + ls[2][ol] + ls[3][ol];
        q = lq[0][ol] + lq[1][ol] + lq[2][ol] + lq[3][ol];
        atomicAdd(&sums[o0 + ol], s);
        atomicAdd(&sums[1024 + o0 + ol], q);
    }
}

// ---------------------------------------------------------------------------
// BN stats from fp32 Y (pf0) into a sums slice
// ---------------------------------------------------------------------------
__global__ __launch_bounds__(256) void bnstat_k(const float* __restrict__ Y, int Co,
                                                float* __restrict__ sums) {
    int o0 = blockIdx.x * 64;
    int m0 = blockIdx.y * 512;
    int t = threadIdx.x, ol = t & 63, mg = t >> 6;
    float s = 0.f, q = 0.f;
    const float* p = Y + (size_t)(m0 + mg) * Co + o0 + ol;
    for (int i = 0; i < 128; ++i) {
        float v = p[(size_t)i * 4 * Co];
        s += v; q += v * v;
    }
    __shared__ float ls[4][64], lq[4][64];
    ls[mg][ol] = s; lq[mg][ol] = q;
    __syncthreads();
    if (mg == 0) {
        s = ls[0][ol] + ls[1][ol] + ls[2][ol] + ls[3][ol];
        q = lq[0][ol] + lq[1][ol] + lq[2][ol] + lq[3][ol];
        atomicAdd(&sums[o0 + ol], s);
        atomicAdd(&sums[1024 + o0 + ol], q);
    }
}

// inline BN coefficient from sums slice
__device__ __forceinline__ void bncoef(const float* __restrict__ sums,
                                       const float* __restrict__ g,
                                       const float* __restrict__ bb,
                                       int o, float& a, float& c) {
    float mu = sums[o] * (1.f / 8192.f);
    float var = sums[1024 + o] * (1.f / 8192.f) - mu * mu;
    var = fmaxf(var, 0.f);
    a = g[o] * (1.0f / sqrtf(var + EPSF));
    c = bb[o] - mu * a;
}

// ---------------------------------------------------------------------------
// BN normalize + ReLU + fp16 store (fp32 source)
// ---------------------------------------------------------------------------
__global__ __launch_bounds__(256) void bnorm_f(const float* __restrict__ Y,
                                               const float* __restrict__ sums,
                                               const float* __restrict__ g,
                                               const float* __restrict__ bb,
                                               unsigned short* __restrict__ dst, int ldd, int shift) {
    int idx4 = blockIdx.x * 256 + threadIdx.x;
    int m = idx4 >> shift;
    int o4 = (idx4 & ((1 << shift) - 1)) * 4;
    float4 v = ((const float4*)Y)[idx4];
    float vv[4] = {v.x, v.y, v.z, v.w};
    unsigned short r[4];
    #pragma unroll
    for (int j = 0; j < 4; ++j) {
        float a, c;
        bncoef(sums, g, bb, o4 + j, a, c);
        r[j] = f2h(fmaxf(vv[j] * a + c, 0.f));
    }
    *(ushort4*)&dst[(size_t)m * ldd + o4] = make_ushort4(r[0], r[1], r[2], r[3]);
}

// ---------------------------------------------------------------------------
// BN normalize + ReLU + fp16 store (fp16 source)
// ---------------------------------------------------------------------------
__global__ __launch_bounds__(256) void bnorm_h(const unsigned short* __restrict__ Yh,
                                               const float* __restrict__ sums,
                                               const float* __restrict__ g,
                                               const float* __restrict__ bb,
                                               unsigned short* __restrict__ dst, int ldd, int shift) {
    int idx4 = blockIdx.x * 256 + threadIdx.x;
    int m = idx4 >> shift;
    int o4 = (idx4 & ((1 << shift) - 1)) * 4;
    ushort4 hv = ((const ushort4*)Yh)[idx4];
    float vv[4] = {h2f(hv.x), h2f(hv.y), h2f(hv.z), h2f(hv.w)};
    unsigned short r[4];
    #pragma unroll
    for (int j = 0; j < 4; ++j) {
        float a, c;
        bncoef(sums, g, bb, o4 + j, a, c);
        r[j] = f2h(fmaxf(vv[j] * a + c, 0.f));
    }
    *(ushort4*)&dst[(size_t)m * ldd + o4] = make_ushort4(r[0], r[1], r[2], r[3]);
}

// ---------------------------------------------------------------------------
// pf3 fused BN-normalize + ReLU + store to XCb 336-slice + per-channel max
// via atomicMax into MAXB. grid (4 batches, 128 row-chunks of 16), thread
// owns 4 channels (ushort4 loads/stores, coalesced).
// ---------------------------------------------------------------------------
__global__ __launch_bounds__(256) void bn3max_k(const unsigned short* __restrict__ Yh,
                                                const float* __restrict__ sums,
                                                const float* __restrict__ g,
                                                const float* __restrict__ bb,
                                                unsigned short* __restrict__ XCb,
                                                float* __restrict__ maxbuf) {
    int b = blockIdx.x;
    int rc = blockIdx.y;
    int t = threadIdx.x;
    int o4 = t * 4;
    float a0, c0, a1, c1, a2, c2, a3, c3;
    bncoef(sums, g, bb, o4 + 0, a0, c0);
    bncoef(sums, g, bb, o4 + 1, a1, c1);
    bncoef(sums, g, bb, o4 + 2, a2, c2);
    bncoef(sums, g, bb, o4 + 3, a3, c3);
    float m0 = 0.f, m1 = 0.f, m2 = 0.f, m3 = 0.f;
    int mrow = b * NN + rc * 16;
    for (int i = 0; i < 16; ++i) {
        int m = mrow + i;
        ushort4 hv = *(const ushort4*)&Yh[(size_t)m * 1024 + o4];
        float y0 = fmaxf(h2f(hv.x) * a0 + c0, 0.f);
        float y1 = fmaxf(h2f(hv.y) * a1 + c1, 0.f);
        float y2 = fmaxf(h2f(hv.z) * a2 + c2, 0.f);
        float y3 = fmaxf(h2f(hv.w) * a3 + c3, 0.f);
        m0 = fmaxf(m0, y0); m1 = fmaxf(m1, y1);
        m2 = fmaxf(m2, y2); m3 = fmaxf(m3, y3);
        *(ushort4*)&XCb[(size_t)m * 2400 + 336 + o4] =
            make_ushort4(f2h(y0), f2h(y1), f2h(y2), f2h(y3));
    }
    atomicMax((unsigned*)&maxbuf[b * 1024 + o4 + 0], __builtin_bit_cast(unsigned, m0));
    atomicMax((unsigned*)&maxbuf[b * 1024 + o4 + 1], __builtin_bit_cast(unsigned, m1));
    atomicMax((unsigned*)&maxbuf[b * 1024 + o4 + 2], __builtin_bit_cast(unsigned, m2));
    atomicMax((unsigned*)&maxbuf[b * 1024 + o4 + 3], __builtin_bit_cast(unsigned, m3));
}

__global__ __launch_bounds__(256) void maxbc_k(const float* __restrict__ maxbuf,
                                               unsigned short* __restrict__ XCb) {
    int idx8 = blockIdx.x * 256 + threadIdx.x;
    int m = idx8 >> 7;
    int o8 = (idx8 & 127) * 8;
    int b = m >> 11;
    const float* mb = maxbuf + b * 1024 + o8;
    ushort4 u0 = make_ushort4(f2h(mb[0]), f2h(mb[1]), f2h(mb[2]), f2h(mb[3]));
    ushort4 u1 = make_ushort4(f2h(mb[4]), f2h(mb[5]), f2h(mb[6]), f2h(mb[7]));
    *(ushort4*)&XCb[(size_t)m * 2400 + 1360 + o8] = u0;
    *(ushort4*)&XCb[(size_t)m * 2400 + 1360 + o8 + 4] = u1;
}

// ---------------------------------------------------------------------------
// final: OT(M,128) fp32 -> out (B,50,N) + bias, via LDS transpose
// ---------------------------------------------------------------------------
__global__ __launch_bounds__(256) void wout_k(const float* __restrict__ OT,
                                              const float* __restrict__ bias,
                                              float* __restrict__ out) {
    __shared__ float ts[128][65];
    int t = threadIdx.x;
    int m0 = blockIdx.x * 128;
    #pragma unroll
    for (int i = 0; i < 8; ++i) {
        int idx4 = t + 256 * i;
        int row = idx4 >> 4, c4 = (idx4 & 15) * 4;
        float4 v = *(const float4*)&OT[(size_t)(m0 + row) * 128 + c4];
        ts[row][c4] = v.x; ts[row][c4 + 1] = v.y; ts[row][c4 + 2] = v.z; ts[row][c4 + 3] = v.w;
    }
    __syncthreads();
    int b = m0 >> 11, n0 = m0 & (NN - 1);
    #pragma unroll
    for (int j = 0; j < 25; ++j) {
        int idx = t + 256 * j;
        int o = idx >> 7, nl = idx & 127;
        out[((size_t)b * 50 + o) * NN + n0 + nl] = ts[nl][o] + bias[o];
    }
}

// ---------------------------------------------------------------------------
extern "C" void kernel_launch(void* const* d_in, const int* in_sizes, int n_in,
                              void* d_out, int out_size, void* d_ws, size_t ws_size,
                              hipStream_t stream) {
    const float* in = (const float*)d_in[0];
    const float* pf0_w = (const float*)d_in[1];
    const float* pf_g[4] = {(const float*)d_in[2], (const float*)d_in[5], (const float*)d_in[8], (const float*)d_in[11]};
    const float* pf_b[4] = {(const float*)d_in[3], (const float*)d_in[6], (const float*)d_in[9], (const float*)d_in[12]};
    const float* pf_w[4] = {(const float*)d_in[1], (const float*)d_in[4], (const float*)d_in[7], (const float*)d_in[10]};
    const float* cls_w[3] = {(const float*)d_in[13], (const float*)d_in[16], (const float*)d_in[19]};
    const float* cls_g[3] = {(const float*)d_in[14], (const float*)d_in[17], (const float*)d_in[20]};
    const float* cls_b[3] = {(const float*)d_in[15], (const float*)d_in[18], (const float*)d_in[21]};
    const float* cls3_w = (const float*)d_in[22];
    const float* cls3_bias = (const float*)d_in[23];
    float* out = (float*)d_out;

    char* wsb = (char*)d_ws;
    float* ST = (float*)(wsb + 0);                      // 256 B
    float4* PQ = (float4*)(wsb + 256);                  // 131072 B
    float* F0 = (float*)(wsb + 131328);                 // 163840 B
    float* SUMS = (float*)(wsb + 295168);               // 7 slices x 8192 B = 57344 B
    float* MAXB = (float*)(wsb + 352512);               // 16384 B (right after SUMS)
    unsigned short* WB = (unsigned short*)(wsb + 368896);    // 1769472 B
    unsigned short* XCb = (unsigned short*)(wsb + 2138368);  // 39321600 B
    unsigned short* C1b = (unsigned short*)(wsb + 41459968); // 4194304 B (aliased as C3b)
    unsigned short* C2b = (unsigned short*)(wsb + 45654272); // 4194304 B
    unsigned short* C3b = C1b;
    float* Y = (float*)(wsb + 49848576);                // 33554432 B (4 cls0 partials)
    unsigned short* Yh = (unsigned short*)Y;

    auto SL = [&](int s) { return SUMS + (size_t)s * 2048; };

    // fused preamble: wconv(x4) + stats + zero(SUMS+MAXB) + onehot
    prep_k<<<972, 256, 0, stream>>>(in, pf_w[1], pf_w[2], pf_w[3], cls_w[0], cls_w[1], cls_w[2], cls3_w,
                                    WB, ST, SUMS, XCb);
    point_k<<<MM / 256, 256, 0, stream>>>(in, ST, PQ, F0);
    alpha_k<<<MM / 4, 256, 0, stream>>>(PQ, F0);

    // pf0 (fp32 path)
    pf0_k<<<MM / 256, 256, 0, stream>>>(F0, pf0_w, Y);
    bnstat_k<<<dim3(1, 16), 256, 0, stream>>>(Y, 64, SL(0));
    bnorm_f<<<512, 256, 0, stream>>>(Y, SL(0), pf_g[0], pf_b[0], XCb + 16, 2400, 4);
    // pf1 (Co=128, K=64)
    mgemm3_k<1><<<dim3(128, 1, 1), 256, 0, stream>>>(XCb + 16, 2400, WB, 64, Yh, 128, 64, 64, SL(1));
    bnorm_h<<<1024, 256, 0, stream>>>(Yh, SL(1), pf_g[1], pf_b[1], XCb + 80, 2400, 5);
    // pf2 (Co=128, K=128)
    mgemm3_k<1><<<dim3(128, 1, 1), 256, 0, stream>>>(XCb + 80, 2400, WB + 8192, 128, Yh, 128, 128, 128, SL(2));
    bnorm_h<<<1024, 256, 0, stream>>>(Yh, SL(2), pf_g[2], pf_b[2], XCb + 208, 2400, 5);
    // pf3 (Co=1024, K=128)
    mgemm3_k<1><<<dim3(128, 8, 1), 256, 0, stream>>>(XCb + 208, 2400, WB + 24576, 128, Yh, 1024, 128, 128, SL(3));
    // fused pf3 bnorm + per-channel max, then broadcast
    bn3max_k<<<dim3(4, 128), 256, 0, stream>>>(Yh, SL(3), pf_g[3], pf_b[3], XCb, MAXB);
    maxbc_k<<<4096, 256, 0, stream>>>(MAXB, XCb);
    // cls0 (Co=256, K=2400): K-split x4, fp32 partials, fused reduce+stats, norm
    mgemm3_k<0><<<dim3(128, 2, 4), 256, 0, stream>>>(XCb, 2400, WB + 155648, 2400, Y, 256, 2400, 608, SL(4));
    red4stat_k<<<dim3(4, 64), 256, 0, stream>>>(Y, SL(4));
    bnorm_f<<<2048, 256, 0, stream>>>(Y, SL(4), cls_g[0], cls_b[0], C1b, 256, 6);
    // cls1 (Co=256, K=256)
    mgemm3_k<1><<<dim3(128, 2, 1), 256, 0, stream>>>(C1b, 256, WB + 770048, 256, Yh, 256, 256, 256, SL(5));
    bnorm_h<<<2048, 256, 0, stream>>>(Yh, SL(5), cls_g[1], cls_b[1], C2b, 256, 6);
    // cls2 (Co=128, K=256)
    mgemm3_k<1><<<dim3(128, 1, 1), 256, 0, stream>>>(C2b, 256, WB + 835584, 256, Yh, 128, 256, 256, SL(6));
    bnorm_h<<<1024, 256, 0, stream>>>(Yh, SL(6), cls_g[2], cls_b[2], C3b, 128, 5);
    // cls3 (padded to 128 outputs, rows 50..127 zero) -> fp32 Y
    mgemm3_k<0><<<dim3(128, 1, 1), 256, 0, stream>>>(C3b, 128, WB + 868352, 128, Y, 128, 128, 128, SL(0));
    wout_k<<<MM / 128, 256, 0, stream>>>(Y, cls3_bias, out);

    (void)in_sizes; (void)n_in; (void)out_size; (void)ws_size;
}

// Round 12
// 207.603 us; speedup vs baseline: 1.3925x; 1.0549x over previous
//
#include <hip/hip_runtime.h>
#include <math.h>

#define BB 4
#define NN 2048
#define MM 8192
#define EPSF 1e-5f
#define LDC 1376   // concat channel stride (one-hot 16 | pf0 64 | pf1 128 | pf2 128 | pf3 1024 | pad 16)

typedef _Float16 half8 __attribute__((ext_vector_type(8)));
typedef float f32x4 __attribute__((ext_vector_type(4)));

__device__ __forceinline__ unsigned short f2h(float x) {
    _Float16 h = (_Float16)x;
    return __builtin_bit_cast(unsigned short, h);
}
__device__ __forceinline__ float h2f(unsigned short u) {
    return (float)__builtin_bit_cast(_Float16, u);
}

// wave64 sum via DPP: row_shr 1/2/4/8 + row_bcast 15/31; total lands in lane 63
__device__ __forceinline__ int wave_sum_dpp(int v) {
    v += __builtin_amdgcn_update_dpp(0, v, 0x111, 0xF, 0xF, true);
    v += __builtin_amdgcn_update_dpp(0, v, 0x112, 0xF, 0xF, true);
    v += __builtin_amdgcn_update_dpp(0, v, 0x114, 0xF, 0xF, true);
    v += __builtin_amdgcn_update_dpp(0, v, 0x118, 0xF, 0xF, true);
    v += __builtin_amdgcn_update_dpp(0, v, 0x142, 0xa, 0xF, true);
    v += __builtin_amdgcn_update_dpp(0, v, 0x143, 0xc, 0xF, true);
    return __builtin_amdgcn_readlane(v, 63);
}

__device__ __forceinline__ float angle3(float ux, float uy, float uz,
                                        float vx, float vy, float vz) {
    float crx = uy * vz - uz * vy;
    float cry = uz * vx - ux * vz;
    float crz = ux * vy - uy * vx;
    float s = sqrtf(crx * crx + cry * cry + crz * crz);
    float c = ux * vx + uy * vy + uz * vz;
    return atan2f(s, c);
}

// ---------------------------------------------------------------------------
// fused preamble: wconv x4 (blocks 0..863) | stats (864..867) |
// zero SUMS+MAXB+CONTRIB (868..943) | onehot+pad (944..975)
// WB element layout: pf1 [0,8192) | pf2 [8192,24576) | pf3 [24576,155648) |
//   cls0 256x1376 [155648,507904) | cls1 [507904,573440) | cls2 [573440,606208)
//   | cls3 [606208,622592) | Wmax c-major 1024x256 [622592,884736)
// ---------------------------------------------------------------------------
__global__ __launch_bounds__(256) void prep_k(const float* __restrict__ in,
                                              const float* __restrict__ w1, const float* __restrict__ w2,
                                              const float* __restrict__ w3, const float* __restrict__ w4,
                                              const float* __restrict__ w5, const float* __restrict__ w6,
                                              const float* __restrict__ w7,
                                              unsigned short* __restrict__ Wb,
                                              float* __restrict__ st,
                                              float* __restrict__ zp,
                                              unsigned short* __restrict__ XCb) {
    int blk = blockIdx.x;
    int t = threadIdx.x;
    if (blk < 864) {
        int idx0 = blk * 1024 + t * 4;
        ushort4 r;
        unsigned short* rp = (unsigned short*)&r;
        #pragma unroll
        for (int e = 0; e < 4; ++e) {
            int idx = idx0 + e;
            unsigned short v;
            if (idx < 8192) v = f2h(w1[idx]);
            else if (idx < 24576) v = f2h(w2[idx - 8192]);
            else if (idx < 155648) v = f2h(w3[idx - 24576]);
            else if (idx < 507904) {
                int l = idx - 155648;
                int o = l / 1376, k = l - o * 1376;
                v = (k < 1360) ? f2h(w4[o * 2384 + k]) : (unsigned short)0;
            } else if (idx < 573440) v = f2h(w5[idx - 507904]);
            else if (idx < 606208) v = f2h(w6[idx - 573440]);
            else if (idx < 622592) {
                int l = idx - 606208;
                int o = l >> 7, k = l & 127;
                v = (o < 50) ? f2h(w7[o * 128 + k]) : (unsigned short)0;
            } else {
                int l = idx - 622592;
                int c = l >> 8, o = l & 255;
                v = f2h(w4[o * 2384 + 1360 + c]);
            }
            rp[e] = v;
        }
        *(ushort4*)&Wb[idx0] = r;
    } else if (blk < 868) {
        int b = blk - 864;
        const float* base = in + (size_t)b * 22 * NN;
        float cs0 = 0.f, cs1 = 0.f, cs2 = 0.f, ns0 = 0.f, ns1 = 0.f, ns2 = 0.f;
        for (int n = t; n < NN; n += 256) {
            float cx = base[0 * NN + n], cy = base[1 * NN + n], cz = base[2 * NN + n];
            float nx = base[3 * NN + n], ny = base[4 * NN + n], nz = base[5 * NN + n];
            float inv = 1.0f / sqrtf(nx * nx + ny * ny + nz * nz);
            cs0 += cx; cs1 += cy; cs2 += cz;
            ns0 += nx * inv; ns1 += ny * inv; ns2 += nz * inv;
        }
        __shared__ float red[6][256];
        red[0][t] = cs0; red[1][t] = cs1; red[2][t] = cs2;
        red[3][t] = ns0; red[4][t] = ns1; red[5][t] = ns2;
        __syncthreads();
        for (int s = 128; s > 0; s >>= 1) {
            if (t < s) {
                #pragma unroll
                for (int i = 0; i < 6; ++i) red[i][t] += red[i][t + s];
            }
            __syncthreads();
        }
        if (t == 0) {
            float ccx = red[0][0] / (float)NN, ccy = red[1][0] / (float)NN, ccz = red[2][0] / (float)NN;
            float cnx = red[3][0] / (float)NN, cny = red[4][0] / (float)NN, cnz = red[5][0] / (float)NN;
            float inv = 1.0f / sqrtf(cnx * cnx + cny * cny + cnz * cnz);
            float* s9 = st + b * 16;
            s9[0] = ccx; s9[1] = ccy; s9[2] = ccz;
            s9[3] = cnx; s9[4] = cny; s9[5] = cnz;
            s9[6] = cnx * inv; s9[7] = cny * inv; s9[8] = cnz * inv;
        }
    } else if (blk < 944) {
        zp[(blk - 868) * 256 + t] = 0.f;
    } else {
        int m = (blk - 944) * 256 + t;
        int b = m >> 11, n = m & (NN - 1);
        const float* src = in + (size_t)b * 22 * NN + 6 * NN + n;
        unsigned short vals[16];
        #pragma unroll
        for (int r = 0; r < 16; ++r) vals[r] = f2h(src[(size_t)r * NN]);
        ushort4* dst = (ushort4*)&XCb[(size_t)m * LDC];
        #pragma unroll
        for (int q = 0; q < 4; ++q)
            dst[q] = make_ushort4(vals[4 * q], vals[4 * q + 1], vals[4 * q + 2], vals[4 * q + 3]);
        ushort4 z = make_ushort4(0, 0, 0, 0);
        ushort4* pz = (ushort4*)&XCb[(size_t)m * LDC + 1360];
        pz[0] = z; pz[1] = z; pz[2] = z; pz[3] = z;
    }
}

// ---------------------------------------------------------------------------
// per-point PPF (F0 rows 0..3) + packed projected vectors PQ = (x,y,z,|P|)
// ---------------------------------------------------------------------------
__global__ __launch_bounds__(256) void point_k(const float* __restrict__ in,
                                               const float* __restrict__ st,
                                               float4* __restrict__ PQ,
                                               float* __restrict__ F0) {
    int idx = blockIdx.x * 256 + threadIdx.x;
    int b = idx >> 11, n = idx & (NN - 1);
    const float* base = in + (size_t)b * 22 * NN;
    const float* s9 = st + b * 16;
    float cx = base[0 * NN + n], cy = base[1 * NN + n], cz = base[2 * NN + n];
    float nx = base[3 * NN + n], ny = base[4 * NN + n], nz = base[5 * NN + n];
    float inv = 1.0f / sqrtf(nx * nx + ny * ny + nz * nz);
    nx *= inv; ny *= inv; nz *= inv;
    float ccx = s9[0], ccy = s9[1], ccz = s9[2];
    float cnx = s9[3], cny = s9[4], cnz = s9[5];
    float ex = s9[6], ey = s9[7], ez = s9[8];
    float dx = cx - ccx, dy = cy - ccy, dz = cz - ccz;
    F0[0 * MM + idx] = angle3(cnx, cny, cnz, dx, dy, dz);
    F0[1 * MM + idx] = angle3(nx, ny, nz, dx, dy, dz);
    F0[2 * MM + idx] = angle3(cnx, cny, cnz, nx, ny, nz);
    F0[3 * MM + idx] = sqrtf(dx * dx + dy * dy + dz * dz);
    float dot = dx * ex + dy * ey + dz * ez;
    float px = dx - dot * cnx;
    float py = dy - dot * cny;
    float pz = dz - dot * cnz;
    PQ[idx] = make_float4(px, py, pz, sqrtf(px * px + py * py + pz * pz));
}

// ---------------------------------------------------------------------------
// per-row median of pairwise angles (R11 hybrid: VALU+DPP half, ballot half).
// ---------------------------------------------------------------------------
__global__ __launch_bounds__(256) void alpha_k(const float4* __restrict__ PQ,
                                               float* __restrict__ F0) {
    int row = blockIdx.x * 4 + (threadIdx.x >> 6);
    int lane = threadIdx.x & 63;
    int b = row >> 11;
    const float4* base = PQ + (size_t)b * NN;
    float4 a = base[row & (NN - 1)];
    unsigned u[32];
    #pragma unroll
    for (int s2 = 0; s2 < 32; ++s2) {
        float4 bv = base[s2 * 64 + lane];
        float cx = a.y * bv.z - a.z * bv.y;
        float cy = a.z * bv.x - a.x * bv.z;
        float cz = a.x * bv.y - a.y * bv.x;
        float ss = cx * cx + cy * cy + cz * cz;
        float dc = a.x * bv.x + a.y * bv.y + a.z * bv.z;
        float den = dc + a.w * bv.w;
        float rc = __builtin_amdgcn_rcpf(den);
        float key = ss * rc * rc;
        u[s2] = (key <= 2.5e-11f) ? 0x7F800000u : __float_as_uint(key);
    }
    unsigned T = 0u;
    for (int bit = 30; bit >= 14; --bit) {
        unsigned c = T | (1u << bit);
        int s0 = 0, s1 = 0;
        #pragma unroll
        for (int q = 0; q < 8; ++q) {
            s0 += (int)__popcll(__ballot(u[16 + q] < c));
            s1 += (int)__popcll(__ballot(u[24 + q] < c));
        }
        int v0 = 0, v1 = 0, v2 = 0, v3 = 0;
        #pragma unroll
        for (int q = 0; q < 4; ++q) {
            v0 += (int)(u[q] < c);
            v1 += (int)(u[4 + q] < c);
            v2 += (int)(u[8 + q] < c);
            v3 += (int)(u[12 + q] < c);
        }
        int vsum = wave_sum_dpp(v0 + v1 + v2 + v3);
        if (vsum + s0 + s1 <= 1023) T = c;
    }
    if (lane == 0)
        F0[4 * MM + row] = 2.0f * atanf(sqrtf(__uint_as_float(T + 8192u)));
}

// ---------------------------------------------------------------------------
// pf0: tiny K=5 GEMM, Y (M,64) fp32
// ---------------------------------------------------------------------------
__global__ __launch_bounds__(256) void pf0_k(const float* __restrict__ F0,
                                             const float* __restrict__ W,
                                             float* __restrict__ Y) {
    __shared__ float ws[320];
    int t = threadIdx.x;
    for (int i = t; i < 320; i += 256) ws[i] = W[i];
    __syncthreads();
    int m = blockIdx.x * 256 + t;
    float x0 = F0[m], x1 = F0[MM + m], x2 = F0[2 * MM + m], x3 = F0[3 * MM + m], x4 = F0[4 * MM + m];
    float* ym = Y + (size_t)m * 64;
    #pragma unroll
    for (int o = 0; o < 64; ++o) {
        const float* wo = &ws[o * 5];
        ym[o] = wo[0] * x0 + wo[1] * x1 + wo[2] * x2 + wo[3] * x3 + wo[4] * x4;
    }
}

// ---------------------------------------------------------------------------
// fp16 MFMA GEMM, BM=64 BO=128, register-prefetch pipeline.
// MODE 1: fp16 Y + fused BN stats. MODE 2: fp16 K-split partial (blockIdx.z).
// ---------------------------------------------------------------------------
template<int MODE>
__global__ __launch_bounds__(256) void mgemm3_k(const unsigned short* __restrict__ X, int ldx,
                                                const unsigned short* __restrict__ W, int ldw,
                                                unsigned short* __restrict__ Yh, int Co, int K, int kchunk,
                                                float* __restrict__ sums) {
    __shared__ unsigned short As[64 * 32];
    __shared__ unsigned short Bs[128 * 32];
    int t = threadIdx.x;
    int mBase = blockIdx.x * 64;
    int oBase = blockIdx.y * 128;
    int k0c = blockIdx.z * kchunk;
    int k1c = k0c + kchunk; if (k1c > K) k1c = K;
    int lane = t & 63, w = t >> 6;
    int warpM = (w & 1) * 32, warpO = (w >> 1) * 64;
    f32x4 acc[2][4];
    #pragma unroll
    for (int i = 0; i < 2; ++i)
        #pragma unroll
        for (int j = 0; j < 4; ++j) acc[i][j] = (f32x4){0.f, 0.f, 0.f, 0.f};
    int lr = t >> 2;
    int lc = (t & 3) * 8;
    const unsigned short* Xp = X + (size_t)(mBase + lr) * ldx + lc;
    const unsigned short* Wp0 = W + (size_t)(oBase + lr) * ldw + lc;
    const unsigned short* Wp1 = W + (size_t)(oBase + lr + 64) * ldw + lc;
    int ar0 = (warpM + (lane & 15)) * 32 + (lane >> 4) * 8;
    int br0 = (warpO + (lane & 15)) * 32 + (lane >> 4) * 8;
    uint4 xa = *(const uint4*)(Xp + k0c);
    uint4 wb0 = *(const uint4*)(Wp0 + k0c);
    uint4 wb1 = *(const uint4*)(Wp1 + k0c);
    for (int k = k0c; k < k1c; k += 32) {
        __syncthreads();
        *(uint4*)&As[lr * 32 + lc] = xa;
        *(uint4*)&Bs[lr * 32 + lc] = wb0;
        *(uint4*)&Bs[(lr + 64) * 32 + lc] = wb1;
        if (k + 32 < k1c) {
            xa = *(const uint4*)(Xp + k + 32);
            wb0 = *(const uint4*)(Wp0 + k + 32);
            wb1 = *(const uint4*)(Wp1 + k + 32);
        }
        __syncthreads();
        half8 a0 = __builtin_bit_cast(half8, *(const uint4*)&As[ar0]);
        half8 a1 = __builtin_bit_cast(half8, *(const uint4*)&As[ar0 + 16 * 32]);
        half8 b0 = __builtin_bit_cast(half8, *(const uint4*)&Bs[br0]);
        half8 b1 = __builtin_bit_cast(half8, *(const uint4*)&Bs[br0 + 16 * 32]);
        half8 b2 = __builtin_bit_cast(half8, *(const uint4*)&Bs[br0 + 32 * 32]);
        half8 b3 = __builtin_bit_cast(half8, *(const uint4*)&Bs[br0 + 48 * 32]);
        acc[0][0] = __builtin_amdgcn_mfma_f32_16x16x32_f16(a0, b0, acc[0][0], 0, 0, 0);
        acc[0][1] = __builtin_amdgcn_mfma_f32_16x16x32_f16(a0, b1, acc[0][1], 0, 0, 0);
        acc[0][2] = __builtin_amdgcn_mfma_f32_16x16x32_f16(a0, b2, acc[0][2], 0, 0, 0);
        acc[0][3] = __builtin_amdgcn_mfma_f32_16x16x32_f16(a0, b3, acc[0][3], 0, 0, 0);
        acc[1][0] = __builtin_amdgcn_mfma_f32_16x16x32_f16(a1, b0, acc[1][0], 0, 0, 0);
        acc[1][1] = __builtin_amdgcn_mfma_f32_16x16x32_f16(a1, b1, acc[1][1], 0, 0, 0);
        acc[1][2] = __builtin_amdgcn_mfma_f32_16x16x32_f16(a1, b2, acc[1][2], 0, 0, 0);
        acc[1][3] = __builtin_amdgcn_mfma_f32_16x16x32_f16(a1, b3, acc[1][3], 0, 0, 0);
    }
    unsigned short* Yp = Yh + (MODE == 2 ? (size_t)blockIdx.z * MM * Co : 0);
    #pragma unroll
    for (int i = 0; i < 2; ++i)
        #pragma unroll
        for (int j = 0; j < 4; ++j) {
            int m0 = mBase + warpM + i * 16 + (lane >> 4) * 4;
            int o = oBase + warpO + j * 16 + (lane & 15);
            #pragma unroll
            for (int r = 0; r < 4; ++r)
                Yp[(size_t)(m0 + r) * Co + o] = f2h(acc[i][j][r]);
        }
    if (MODE == 1) {
        __syncthreads();
        float* ssum = (float*)As;
        float* ssq = (float*)Bs;
        if (t < 128) { ssum[t] = 0.f; ssq[t] = 0.f; }
        __syncthreads();
        #pragma unroll
        for (int j = 0; j < 4; ++j) {
            int oc = warpO + j * 16 + (lane & 15);
            float s = 0.f, q = 0.f;
            #pragma unroll
            for (int i = 0; i < 2; ++i)
                #pragma unroll
                for (int r = 0; r < 4; ++r) { float v = acc[i][j][r]; s += v; q += v * v; }
            atomicAdd(&ssum[oc], s);
            atomicAdd(&ssq[oc], q);
        }
        __syncthreads();
        if (t < 128) {
            atomicAdd(&sums[oBase + t], ssum[t]);
            atomicAdd(&sums[1024 + oBase + t], ssq[t]);
        }
    }
}

// ---------------------------------------------------------------------------
// fp16 MFMA GEMM, BM=64 BO=64 (higher occupancy for mid layers).
// MODE 0: fp32 Y. MODE 1: fp16 Y + fused BN stats.
// ---------------------------------------------------------------------------
template<int MODE>
__global__ __launch_bounds__(256) void mgemm64_k(const unsigned short* __restrict__ X, int ldx,
                                                 const unsigned short* __restrict__ W, int ldw,
                                                 void* __restrict__ Yv, int Co, int K,
                                                 float* __restrict__ sums) {
    __shared__ unsigned short As[64 * 32];
    __shared__ unsigned short Bs[64 * 32];
    int t = threadIdx.x;
    int mBase = blockIdx.x * 64;
    int oBase = blockIdx.y * 64;
    int lane = t & 63, w = t >> 6;
    int warpM = (w & 1) * 32, warpO = (w >> 1) * 32;
    f32x4 acc[2][2];
    #pragma unroll
    for (int i = 0; i < 2; ++i)
        #pragma unroll
        for (int j = 0; j < 2; ++j) acc[i][j] = (f32x4){0.f, 0.f, 0.f, 0.f};
    int lr = t >> 2;
    int lc = (t & 3) * 8;
    const unsigned short* Xp = X + (size_t)(mBase + lr) * ldx + lc;
    const unsigned short* Wp = W + (size_t)(oBase + lr) * ldw + lc;
    int ar0 = (warpM + (lane & 15)) * 32 + (lane >> 4) * 8;
    int br0 = (warpO + (lane & 15)) * 32 + (lane >> 4) * 8;
    uint4 xa = *(const uint4*)(Xp);
    uint4 wb = *(const uint4*)(Wp);
    for (int k = 0; k < K; k += 32) {
        __syncthreads();
        *(uint4*)&As[lr * 32 + lc] = xa;
        *(uint4*)&Bs[lr * 32 + lc] = wb;
        if (k + 32 < K) {
            xa = *(const uint4*)(Xp + k + 32);
            wb = *(const uint4*)(Wp + k + 32);
        }
        __syncthreads();
        half8 a0 = __builtin_bit_cast(half8, *(const uint4*)&As[ar0]);
        half8 a1 = __builtin_bit_cast(half8, *(const uint4*)&As[ar0 + 16 * 32]);
        half8 b0 = __builtin_bit_cast(half8, *(const uint4*)&Bs[br0]);
        half8 b1 = __builtin_bit_cast(half8, *(const uint4*)&Bs[br0 + 16 * 32]);
        acc[0][0] = __builtin_amdgcn_mfma_f32_16x16x32_f16(a0, b0, acc[0][0], 0, 0, 0);
        acc[0][1] = __builtin_amdgcn_mfma_f32_16x16x32_f16(a0, b1, acc[0][1], 0, 0, 0);
        acc[1][0] = __builtin_amdgcn_mfma_f32_16x16x32_f16(a1, b0, acc[1][0], 0, 0, 0);
        acc[1][1] = __builtin_amdgcn_mfma_f32_16x16x32_f16(a1, b1, acc[1][1], 0, 0, 0);
    }
    if (MODE == 0) {
        float* Yp = (float*)Yv;
        #pragma unroll
        for (int i = 0; i < 2; ++i)
            #pragma unroll
            for (int j = 0; j < 2; ++j) {
                int m0 = mBase + warpM + i * 16 + (lane >> 4) * 4;
                int o = oBase + warpO + j * 16 + (lane & 15);
                #pragma unroll
                for (int r = 0; r < 4; ++r)
                    Yp[(size_t)(m0 + r) * Co + o] = acc[i][j][r];
            }
    } else {
        unsigned short* Yh = (unsigned short*)Yv;
        #pragma unroll
        for (int i = 0; i < 2; ++i)
            #pragma unroll
            for (int j = 0; j < 2; ++j) {
                int m0 = mBase + warpM + i * 16 + (lane >> 4) * 4;
                int o = oBase + warpO + j * 16 + (lane & 15);
                #pragma unroll
                for (int r = 0; r < 4; ++r)
                    Yh[(size_t)(m0 + r) * Co + o] = f2h(acc[i][j][r]);
            }
        __syncthreads();
        float* ssum = (float*)As;
        float* ssq = (float*)Bs;
        if (t < 64) { ssum[t] = 0.f; ssq[t] = 0.f; }
        __syncthreads();
        #pragma unroll
        for (int j = 0; j < 2; ++j) {
            int oc = warpO + j * 16 + (lane & 15);
            float s = 0.f, q = 0.f;
            #pragma unroll
            for (int i = 0; i < 2; ++i)
                #pragma unroll
                for (int r = 0; r < 4; ++r) { float v = acc[i][j][r]; s += v; q += v * v; }
            atomicAdd(&ssum[oc], s);
            atomicAdd(&ssq[oc], q);
        }
        __syncthreads();
        if (t < 64) {
            atomicAdd(&sums[oBase + t], ssum[t]);
            atomicAdd(&sums[1024 + oBase + t], ssq[t]);
        }
    }
}

// ---------------------------------------------------------------------------
// max-feature GEMV: contrib[b][o] = sum_c Wmax[c][o] * maxv[b][c]
// grid (4 batches x 8 c-chunks), 256 threads = o.
// ---------------------------------------------------------------------------
__global__ __launch_bounds__(256) void gemv_k(const unsigned short* __restrict__ Wmax,
                                              const float* __restrict__ maxv,
                                              float* __restrict__ contrib) {
    int b = blockIdx.x >> 3;
    int cc = (blockIdx.x & 7) * 128;
    int o = threadIdx.x;
    const float* mv = maxv + b * 1024 + cc;
    float acc = 0.f;
    for (int c = 0; c < 128; ++c)
        acc += h2f(Wmax[(size_t)(cc + c) * 256 + o]) * mv[c];
    atomicAdd(&contrib[b * 256 + o], acc);
}

// ---------------------------------------------------------------------------
// cls0 finish: sum 4 fp16 K-split partials + contrib -> fp16 partial0 + stats
// ---------------------------------------------------------------------------
__global__ __launch_bounds__(256) void red4stat_k(unsigned short* __restrict__ Yh,
                                                  const float* __restrict__ contrib,
                                                  float* __restrict__ sums) {
    int o0 = blockIdx.x * 64;
    int m0 = blockIdx.y * 128;
    int t = threadIdx.x, ol = t & 63, mg = t >> 6;
    int b = m0 >> 11;
    float cb = contrib[b * 256 + o0 + ol];
    const size_t stride = (size_t)MM * 256;
    float s = 0.f, q = 0.f;
    unsigned short* p = Yh + (size_t)(m0 + mg) * 256 + o0 + ol;
    for (int i = 0; i < 32; ++i) {
        unsigned short* pp = p + (size_t)i * 4 * 256;
        float v = h2f(pp[0]) + h2f(pp[stride]) + h2f(pp[2 * stride]) + h2f(pp[3 * stride]) + cb;
        pp[0] = f2h(v);
        s += v; q += v * v;
    }
    __shared__ float ls[4][64], lq[4][64];
    ls[mg][ol] = s; lq[mg][ol] = q;
    __syncthreads();
    if (mg == 0) {
        s = ls[0][ol] + ls[1][ol] + ls[2][ol] + ls[3][ol];
        q = lq[0][ol] + lq[1][ol] + lq[2][ol] + lq[3][ol];
        atomicAdd(&sums[o0 + ol], s);
        atomicAdd(&sums[1024 + o0 + ol], q);
    }
}

// ---------------------------------------------------------------------------
// BN stats from fp32 Y (pf0) into a sums slice
// ---------------------------------------------------------------------------
__global__ __launch_bounds__(256) void bnstat_k(const float* __restrict__ Y, int Co,
                                                float* __restrict__ sums) {
    int o0 = blockIdx.x * 64;
    int m0 = blockIdx.y * 512;
    int t = threadIdx.x, ol = t & 63, mg = t >> 6;
    float s = 0.f, q = 0.f;
    const float* p = Y + (size_t)(m0 + mg) * Co + o0 + ol;
    for (int i = 0; i < 128; ++i) {
        float v = p[(size_t)i * 4 * Co];
        s += v; q += v * v;
    }
    __shared__ float ls[4][64], lq[4][64];
    ls[mg][ol] = s; lq[mg][ol] = q;
    __syncthreads();
    if (mg == 0) {
        s = ls[0][ol] + ls[1][ol] + ls[2][ol] + ls[3][ol];
        q = lq[0][ol] + lq[1][ol] + lq[2][ol] + lq[3][ol];
        atomicAdd(&sums[o0 + ol], s);
        atomicAdd(&sums[1024 + o0 + ol], q);
    }
}

// inline BN coefficient from sums slice
__device__ __forceinline__ void bncoef(const float* __restrict__ sums,
                                       const float* __restrict__ g,
                                       const float* __restrict__ bb,
                                       int o, float& a, float& c) {
    float mu = sums[o] * (1.f / 8192.f);
    float var = sums[1024 + o] * (1.f / 8192.f) - mu * mu;
    var = fmaxf(var, 0.f);
    a = g[o] * (1.0f / sqrtf(var + EPSF));
    c = bb[o] - mu * a;
}

// ---------------------------------------------------------------------------
// BN normalize + ReLU + fp16 store (fp32 source)
// ---------------------------------------------------------------------------
__global__ __launch_bounds__(256) void bnorm_f(const float* __restrict__ Y,
                                               const float* __restrict__ sums,
                                               const float* __restrict__ g,
                                               const float* __restrict__ bb,
                                               unsigned short* __restrict__ dst, int ldd, int shift) {
    int idx4 = blockIdx.x * 256 + threadIdx.x;
    int m = idx4 >> shift;
    int o4 = (idx4 & ((1 << shift) - 1)) * 4;
    float4 v = ((const float4*)Y)[idx4];
    float vv[4] = {v.x, v.y, v.z, v.w};
    unsigned short r[4];
    #pragma unroll
    for (int j = 0; j < 4; ++j) {
        float a, c;
        bncoef(sums, g, bb, o4 + j, a, c);
        r[j] = f2h(fmaxf(vv[j] * a + c, 0.f));
    }
    *(ushort4*)&dst[(size_t)m * ldd + o4] = make_ushort4(r[0], r[1], r[2], r[3]);
}

// ---------------------------------------------------------------------------
// BN normalize + ReLU + fp16 store (fp16 source)
// ---------------------------------------------------------------------------
__global__ __launch_bounds__(256) void bnorm_h(const unsigned short* __restrict__ Yh,
                                               const float* __restrict__ sums,
                                               const float* __restrict__ g,
                                               const float* __restrict__ bb,
                                               unsigned short* __restrict__ dst, int ldd, int shift) {
    int idx4 = blockIdx.x * 256 + threadIdx.x;
    int m = idx4 >> shift;
    int o4 = (idx4 & ((1 << shift) - 1)) * 4;
    ushort4 hv = ((const ushort4*)Yh)[idx4];
    float vv[4] = {h2f(hv.x), h2f(hv.y), h2f(hv.z), h2f(hv.w)};
    unsigned short r[4];
    #pragma unroll
    for (int j = 0; j < 4; ++j) {
        float a, c;
        bncoef(sums, g, bb, o4 + j, a, c);
        r[j] = f2h(fmaxf(vv[j] * a + c, 0.f));
    }
    *(ushort4*)&dst[(size_t)m * ldd + o4] = make_ushort4(r[0], r[1], r[2], r[3]);
}

// ---------------------------------------------------------------------------
// pf3 fused BN-normalize + ReLU + store to XCb 336-slice + per-channel max
// ---------------------------------------------------------------------------
__global__ __launch_bounds__(256) void bn3max_k(const unsigned short* __restrict__ Yh,
                                                const float* __restrict__ sums,
                                                const float* __restrict__ g,
                                                const float* __restrict__ bb,
                                                unsigned short* __restrict__ XCb,
                                                float* __restrict__ maxbuf) {
    int b = blockIdx.x;
    int rc = blockIdx.y;
    int t = threadIdx.x;
    int o4 = t * 4;
    float a0, c0, a1, c1, a2, c2, a3, c3;
    bncoef(sums, g, bb, o4 + 0, a0, c0);
    bncoef(sums, g, bb, o4 + 1, a1, c1);
    bncoef(sums, g, bb, o4 + 2, a2, c2);
    bncoef(sums, g, bb, o4 + 3, a3, c3);
    float m0 = 0.f, m1 = 0.f, m2 = 0.f, m3 = 0.f;
    int mrow = b * NN + rc * 16;
    for (int i = 0; i < 16; ++i) {
        int m = mrow + i;
        ushort4 hv = *(const ushort4*)&Yh[(size_t)m * 1024 + o4];
        float y0 = fmaxf(h2f(hv.x) * a0 + c0, 0.f);
        float y1 = fmaxf(h2f(hv.y) * a1 + c1, 0.f);
        float y2 = fmaxf(h2f(hv.z) * a2 + c2, 0.f);
        float y3 = fmaxf(h2f(hv.w) * a3 + c3, 0.f);
        m0 = fmaxf(m0, y0); m1 = fmaxf(m1, y1);
        m2 = fmaxf(m2, y2); m3 = fmaxf(m3, y3);
        *(ushort4*)&XCb[(size_t)m * LDC + 336 + o4] =
            make_ushort4(f2h(y0), f2h(y1), f2h(y2), f2h(y3));
    }
    atomicMax((unsigned*)&maxbuf[b * 1024 + o4 + 0], __builtin_bit_cast(unsigned, m0));
    atomicMax((unsigned*)&maxbuf[b * 1024 + o4 + 1], __builtin_bit_cast(unsigned, m1));
    atomicMax((unsigned*)&maxbuf[b * 1024 + o4 + 2], __builtin_bit_cast(unsigned, m2));
    atomicMax((unsigned*)&maxbuf[b * 1024 + o4 + 3], __builtin_bit_cast(unsigned, m3));
}

// ---------------------------------------------------------------------------
// final: OT(M,128) fp32 -> out (B,50,N) + bias, via LDS transpose
// ---------------------------------------------------------------------------
__global__ __launch_bounds__(256) void wout_k(const float* __restrict__ OT,
                                              const float* __restrict__ bias,
                                              float* __restrict__ out) {
    __shared__ float ts[128][65];
    int t = threadIdx.x;
    int m0 = blockIdx.x * 128;
    #pragma unroll
    for (int i = 0; i < 8; ++i) {
        int idx4 = t + 256 * i;
        int row = idx4 >> 4, c4 = (idx4 & 15) * 4;
        float4 v = *(const float4*)&OT[(size_t)(m0 + row) * 128 + c4];
        ts[row][c4] = v.x; ts[row][c4 + 1] = v.y; ts[row][c4 + 2] = v.z; ts[row][c4 + 3] = v.w;
    }
    __syncthreads();
    int b = m0 >> 11, n0 = m0 & (NN - 1);
    #pragma unroll
    for (int j = 0; j < 25; ++j) {
        int idx = t + 256 * j;
        int o = idx >> 7, nl = idx & 127;
        out[((size_t)b * 50 + o) * NN + n0 + nl] = ts[nl][o] + bias[o];
    }
}

// ---------------------------------------------------------------------------
extern "C" void kernel_launch(void* const* d_in, const int* in_sizes, int n_in,
                              void* d_out, int out_size, void* d_ws, size_t ws_size,
                              hipStream_t stream) {
    const float* in = (const float*)d_in[0];
    const float* pf0_w = (const float*)d_in[1];
    const float* pf_g[4] = {(const float*)d_in[2], (const float*)d_in[5], (const float*)d_in[8], (const float*)d_in[11]};
    const float* pf_b[4] = {(const float*)d_in[3], (const float*)d_in[6], (const float*)d_in[9], (const float*)d_in[12]};
    const float* pf_w[4] = {(const float*)d_in[1], (const float*)d_in[4], (const float*)d_in[7], (const float*)d_in[10]};
    const float* cls_w[3] = {(const float*)d_in[13], (const float*)d_in[16], (const float*)d_in[19]};
    const float* cls_g[3] = {(const float*)d_in[14], (const float*)d_in[17], (const float*)d_in[20]};
    const float* cls_b[3] = {(const float*)d_in[15], (const float*)d_in[18], (const float*)d_in[21]};
    const float* cls3_w = (const float*)d_in[22];
    const float* cls3_bias = (const float*)d_in[23];
    float* out = (float*)d_out;

    char* wsb = (char*)d_ws;
    float* ST = (float*)(wsb + 0);                           // 256 B
    float4* PQ = (float4*)(wsb + 256);                       // 131072
    float* F0 = (float*)(wsb + 131328);                      // 163840
    float* SUMS = (float*)(wsb + 295168);                    // 7 x 8192 = 57344
    float* MAXB = (float*)(wsb + 352512);                    // 16384
    float* CONTRIB = (float*)(wsb + 368896);                 // 4096
    unsigned short* WB = (unsigned short*)(wsb + 372992);    // 1769472
    unsigned short* XCb = (unsigned short*)(wsb + 2142464);  // 8192*1376*2 = 22544384
    unsigned short* C1b = (unsigned short*)(wsb + 24686848); // 4194304
    unsigned short* C2b = (unsigned short*)(wsb + 28881152); // 4194304
    unsigned short* C3b = C1b;
    float* Y = (float*)(wsb + 33075456);                     // 33554432
    unsigned short* Yh = (unsigned short*)Y;

    auto SL = [&](int s) { return SUMS + (size_t)s * 2048; };

    // fused preamble: wconv(x4) + stats + zero(SUMS+MAXB+CONTRIB) + onehot/pad
    prep_k<<<976, 256, 0, stream>>>(in, pf_w[1], pf_w[2], pf_w[3], cls_w[0], cls_w[1], cls_w[2], cls3_w,
                                    WB, ST, SUMS, XCb);
    point_k<<<MM / 256, 256, 0, stream>>>(in, ST, PQ, F0);
    alpha_k<<<MM / 4, 256, 0, stream>>>(PQ, F0);

    // pf0 (fp32 path)
    pf0_k<<<MM / 256, 256, 0, stream>>>(F0, pf0_w, Y);
    bnstat_k<<<dim3(1, 16), 256, 0, stream>>>(Y, 64, SL(0));
    bnorm_f<<<512, 256, 0, stream>>>(Y, SL(0), pf_g[0], pf_b[0], XCb + 16, LDC, 4);
    // pf1 (Co=128, K=64) 64-wide, grid 256
    mgemm64_k<1><<<dim3(128, 2), 256, 0, stream>>>(XCb + 16, LDC, WB, 64, Yh, 128, 64, SL(1));
    bnorm_h<<<1024, 256, 0, stream>>>(Yh, SL(1), pf_g[1], pf_b[1], XCb + 80, LDC, 5);
    // pf2 (Co=128, K=128)
    mgemm64_k<1><<<dim3(128, 2), 256, 0, stream>>>(XCb + 80, LDC, WB + 8192, 128, Yh, 128, 128, SL(2));
    bnorm_h<<<1024, 256, 0, stream>>>(Yh, SL(2), pf_g[2], pf_b[2], XCb + 208, LDC, 5);
    // pf3 (Co=1024, K=128) 128-wide, grid 1024
    mgemm3_k<1><<<dim3(128, 8, 1), 256, 0, stream>>>(XCb + 208, LDC, WB + 24576, 128, Yh, 1024, 128, 128, SL(3));
    bn3max_k<<<dim3(4, 128), 256, 0, stream>>>(Yh, SL(3), pf_g[3], pf_b[3], XCb, MAXB);
    // max-feature contribution GEMV (replaces maxbc + 1024 concat channels)
    gemv_k<<<32, 256, 0, stream>>>(WB + 622592, MAXB, CONTRIB);
    // cls0 (Co=256, K=1376): K-split x4 fp16 partials, fused reduce+contrib+stats
    mgemm3_k<2><<<dim3(128, 2, 4), 256, 0, stream>>>(XCb, LDC, WB + 155648, 1376, Yh, 256, 1376, 352, SL(4));
    red4stat_k<<<dim3(4, 64), 256, 0, stream>>>(Yh, CONTRIB, SL(4));
    bnorm_h<<<2048, 256, 0, stream>>>(Yh, SL(4), cls_g[0], cls_b[0], C1b, 256, 6);
    // cls1 (Co=256, K=256) 64-wide, grid 512
    mgemm64_k<1><<<dim3(128, 4), 256, 0, stream>>>(C1b, 256, WB + 507904, 256, Yh, 256, 256, SL(5));
    bnorm_h<<<2048, 256, 0, stream>>>(Yh, SL(5), cls_g[1], cls_b[1], C2b, 256, 6);
    // cls2 (Co=128, K=256)
    mgemm64_k<1><<<dim3(128, 2), 256, 0, stream>>>(C2b, 256, WB + 573440, 256, Yh, 128, 256, SL(6));
    bnorm_h<<<1024, 256, 0, stream>>>(Yh, SL(6), cls_g[2], cls_b[2], C3b, 128, 5);
    // cls3 (padded 128 outputs) -> fp32 Y
    mgemm64_k<0><<<dim3(128, 2), 256, 0, stream>>>(C3b, 128, WB + 606208, 128, Y, 128, 128, SL(0));
    wout_k<<<MM / 128, 256, 0, stream>>>(Y, cls3_bias, out);

    (void)in_sizes; (void)n_in; (void)out_size; (void)ws_size;
}

// Round 13
// 202.810 us; speedup vs baseline: 1.4254x; 1.0236x over previous
//
#include <hip/hip_runtime.h>
#include <math.h>

#define BB 4
#define NN 2048
#define MM 8192
#define EPSF 1e-5f
#define LDC 1376   // concat channel stride (one-hot 16 | pf0 64 | pf1 128 | pf2 128 | pf3 1024 | pad 16)

typedef _Float16 half8 __attribute__((ext_vector_type(8)));
typedef float f32x4 __attribute__((ext_vector_type(4)));

__device__ __forceinline__ unsigned short f2h(float x) {
    _Float16 h = (_Float16)x;
    return __builtin_bit_cast(unsigned short, h);
}
__device__ __forceinline__ float h2f(unsigned short u) {
    return (float)__builtin_bit_cast(_Float16, u);
}

// wave64 sum via DPP: row_shr 1/2/4/8 + row_bcast 15/31; total lands in lane 63
__device__ __forceinline__ int wave_sum_dpp(int v) {
    v += __builtin_amdgcn_update_dpp(0, v, 0x111, 0xF, 0xF, true);
    v += __builtin_amdgcn_update_dpp(0, v, 0x112, 0xF, 0xF, true);
    v += __builtin_amdgcn_update_dpp(0, v, 0x114, 0xF, 0xF, true);
    v += __builtin_amdgcn_update_dpp(0, v, 0x118, 0xF, 0xF, true);
    v += __builtin_amdgcn_update_dpp(0, v, 0x142, 0xa, 0xF, true);
    v += __builtin_amdgcn_update_dpp(0, v, 0x143, 0xc, 0xF, true);
    return __builtin_amdgcn_readlane(v, 63);
}

__device__ __forceinline__ float angle3(float ux, float uy, float uz,
                                        float vx, float vy, float vz) {
    float crx = uy * vz - uz * vy;
    float cry = uz * vx - ux * vz;
    float crz = ux * vy - uy * vx;
    float s = sqrtf(crx * crx + cry * cry + crz * crz);
    float c = ux * vx + uy * vy + uz * vz;
    return atan2f(s, c);
}

// ---------------------------------------------------------------------------
// fused preamble: wconv x4 (blocks 0..863) | stats (864..867) |
// zero SUMS+MAXB+CONTRIB (868..943) | onehot+pad (944..975)
// WB element layout: pf1 [0,8192) | pf2 [8192,24576) | pf3 [24576,155648) |
//   cls0 256x1376 [155648,507904) | cls1 [507904,573440) | cls2 [573440,606208)
//   | cls3 64x128 [606208,614400) | Wmax c-major 1024x256 [614400,876544)
// ---------------------------------------------------------------------------
__global__ __launch_bounds__(256) void prep_k(const float* __restrict__ in,
                                              const float* __restrict__ w1, const float* __restrict__ w2,
                                              const float* __restrict__ w3, const float* __restrict__ w4,
                                              const float* __restrict__ w5, const float* __restrict__ w6,
                                              const float* __restrict__ w7,
                                              unsigned short* __restrict__ Wb,
                                              float* __restrict__ st,
                                              float* __restrict__ zp,
                                              unsigned short* __restrict__ XCb) {
    int blk = blockIdx.x;
    int t = threadIdx.x;
    if (blk < 864) {
        int idx0 = blk * 1024 + t * 4;
        ushort4 r;
        unsigned short* rp = (unsigned short*)&r;
        #pragma unroll
        for (int e = 0; e < 4; ++e) {
            int idx = idx0 + e;
            unsigned short v;
            if (idx < 8192) v = f2h(w1[idx]);
            else if (idx < 24576) v = f2h(w2[idx - 8192]);
            else if (idx < 155648) v = f2h(w3[idx - 24576]);
            else if (idx < 507904) {
                int l = idx - 155648;
                int o = l / 1376, k = l - o * 1376;
                v = (k < 1360) ? f2h(w4[o * 2384 + k]) : (unsigned short)0;
            } else if (idx < 573440) v = f2h(w5[idx - 507904]);
            else if (idx < 606208) v = f2h(w6[idx - 573440]);
            else if (idx < 614400) {
                int l = idx - 606208;
                int o = l >> 7, k = l & 127;
                v = (o < 50) ? f2h(w7[o * 128 + k]) : (unsigned short)0;
            } else {
                int l = idx - 614400;
                int c = l >> 8, o = l & 255;
                v = (c < 1024) ? f2h(w4[o * 2384 + 1360 + c]) : (unsigned short)0;
            }
            rp[e] = v;
        }
        *(ushort4*)&Wb[idx0] = r;
    } else if (blk < 868) {
        int b = blk - 864;
        const float* base = in + (size_t)b * 22 * NN;
        float cs0 = 0.f, cs1 = 0.f, cs2 = 0.f, ns0 = 0.f, ns1 = 0.f, ns2 = 0.f;
        for (int n = t; n < NN; n += 256) {
            float cx = base[0 * NN + n], cy = base[1 * NN + n], cz = base[2 * NN + n];
            float nx = base[3 * NN + n], ny = base[4 * NN + n], nz = base[5 * NN + n];
            float inv = 1.0f / sqrtf(nx * nx + ny * ny + nz * nz);
            cs0 += cx; cs1 += cy; cs2 += cz;
            ns0 += nx * inv; ns1 += ny * inv; ns2 += nz * inv;
        }
        __shared__ float red[6][256];
        red[0][t] = cs0; red[1][t] = cs1; red[2][t] = cs2;
        red[3][t] = ns0; red[4][t] = ns1; red[5][t] = ns2;
        __syncthreads();
        for (int s = 128; s > 0; s >>= 1) {
            if (t < s) {
                #pragma unroll
                for (int i = 0; i < 6; ++i) red[i][t] += red[i][t + s];
            }
            __syncthreads();
        }
        if (t == 0) {
            float ccx = red[0][0] / (float)NN, ccy = red[1][0] / (float)NN, ccz = red[2][0] / (float)NN;
            float cnx = red[3][0] / (float)NN, cny = red[4][0] / (float)NN, cnz = red[5][0] / (float)NN;
            float inv = 1.0f / sqrtf(cnx * cnx + cny * cny + cnz * cnz);
            float* s9 = st + b * 16;
            s9[0] = ccx; s9[1] = ccy; s9[2] = ccz;
            s9[3] = cnx; s9[4] = cny; s9[5] = cnz;
            s9[6] = cnx * inv; s9[7] = cny * inv; s9[8] = cnz * inv;
        }
    } else if (blk < 944) {
        zp[(blk - 868) * 256 + t] = 0.f;
    } else {
        int m = (blk - 944) * 256 + t;
        int b = m >> 11, n = m & (NN - 1);
        const float* src = in + (size_t)b * 22 * NN + 6 * NN + n;
        unsigned short vals[16];
        #pragma unroll
        for (int r = 0; r < 16; ++r) vals[r] = f2h(src[(size_t)r * NN]);
        ushort4* dst = (ushort4*)&XCb[(size_t)m * LDC];
        #pragma unroll
        for (int q = 0; q < 4; ++q)
            dst[q] = make_ushort4(vals[4 * q], vals[4 * q + 1], vals[4 * q + 2], vals[4 * q + 3]);
        ushort4 z = make_ushort4(0, 0, 0, 0);
        ushort4* pz = (ushort4*)&XCb[(size_t)m * LDC + 1360];
        pz[0] = z; pz[1] = z; pz[2] = z; pz[3] = z;
    }
}

// ---------------------------------------------------------------------------
// per-point PPF (F0 rows 0..3) + packed projected vectors PQ = (x,y,z,|P|)
// ---------------------------------------------------------------------------
__global__ __launch_bounds__(256) void point_k(const float* __restrict__ in,
                                               const float* __restrict__ st,
                                               float4* __restrict__ PQ,
                                               float* __restrict__ F0) {
    int idx = blockIdx.x * 256 + threadIdx.x;
    int b = idx >> 11, n = idx & (NN - 1);
    const float* base = in + (size_t)b * 22 * NN;
    const float* s9 = st + b * 16;
    float cx = base[0 * NN + n], cy = base[1 * NN + n], cz = base[2 * NN + n];
    float nx = base[3 * NN + n], ny = base[4 * NN + n], nz = base[5 * NN + n];
    float inv = 1.0f / sqrtf(nx * nx + ny * ny + nz * nz);
    nx *= inv; ny *= inv; nz *= inv;
    float ccx = s9[0], ccy = s9[1], ccz = s9[2];
    float cnx = s9[3], cny = s9[4], cnz = s9[5];
    float ex = s9[6], ey = s9[7], ez = s9[8];
    float dx = cx - ccx, dy = cy - ccy, dz = cz - ccz;
    F0[0 * MM + idx] = angle3(cnx, cny, cnz, dx, dy, dz);
    F0[1 * MM + idx] = angle3(nx, ny, nz, dx, dy, dz);
    F0[2 * MM + idx] = angle3(cnx, cny, cnz, nx, ny, nz);
    F0[3 * MM + idx] = sqrtf(dx * dx + dy * dy + dz * dz);
    float dot = dx * ex + dy * ey + dz * ez;
    float px = dx - dot * cnx;
    float py = dy - dot * cny;
    float pz = dz - dot * cnz;
    PQ[idx] = make_float4(px, py, pz, sqrtf(px * px + py * py + pz * pz));
}

// ---------------------------------------------------------------------------
// per-row median of pairwise angles. TWO rows per wave: shared column loads,
// two independent select chains interleaved (hides the per-bit DPP/readlane
// latency; R12 measured VALU 62% idle-tail with one chain). u-arrays fully
// register-resident (full unroll). Hybrid counting per row: 16 values on
// scalar pipe (ballot+popcll), 16 on VALU (cmp+add + DPP reduce).
// 17-bit greedy MSB search, midpoint reconstruction.
// ---------------------------------------------------------------------------
__global__ __launch_bounds__(256) void alpha_k(const float4* __restrict__ PQ,
                                               float* __restrict__ F0) {
    int wid = blockIdx.x * 4 + (threadIdx.x >> 6);
    int lane = threadIdx.x & 63;
    int r0 = wid * 2;
    int b = r0 >> 11;
    int rl = r0 & (NN - 1);
    const float4* base = PQ + (size_t)b * NN;
    float4 a0 = base[rl];
    float4 a1 = base[rl + 1];
    unsigned u0[32], u1[32];
    #pragma unroll
    for (int s2 = 0; s2 < 32; ++s2) {
        float4 bv = base[s2 * 64 + lane];
        {
            float cx = a0.y * bv.z - a0.z * bv.y;
            float cy = a0.z * bv.x - a0.x * bv.z;
            float cz = a0.x * bv.y - a0.y * bv.x;
            float ss = cx * cx + cy * cy + cz * cz;
            float dc = a0.x * bv.x + a0.y * bv.y + a0.z * bv.z;
            float den = dc + a0.w * bv.w;
            float rc = __builtin_amdgcn_rcpf(den);
            float key = ss * rc * rc;
            u0[s2] = (key <= 2.5e-11f) ? 0x7F800000u : __float_as_uint(key);
        }
        {
            float cx = a1.y * bv.z - a1.z * bv.y;
            float cy = a1.z * bv.x - a1.x * bv.z;
            float cz = a1.x * bv.y - a1.y * bv.x;
            float ss = cx * cx + cy * cy + cz * cz;
            float dc = a1.x * bv.x + a1.y * bv.y + a1.z * bv.z;
            float den = dc + a1.w * bv.w;
            float rc = __builtin_amdgcn_rcpf(den);
            float key = ss * rc * rc;
            u1[s2] = (key <= 2.5e-11f) ? 0x7F800000u : __float_as_uint(key);
        }
    }
    unsigned T0 = 0u, T1 = 0u;
    for (int bit = 30; bit >= 14; --bit) {
        unsigned c0 = T0 | (1u << bit);
        unsigned c1 = T1 | (1u << bit);
        int sa = 0, sb = 0;
        #pragma unroll
        for (int q = 0; q < 8; ++q) {
            sa += (int)__popcll(__ballot(u0[16 + q] < c0));
            sb += (int)__popcll(__ballot(u1[16 + q] < c1));
            sa += (int)__popcll(__ballot(u0[24 + q] < c0));
            sb += (int)__popcll(__ballot(u1[24 + q] < c1));
        }
        int va = 0, vb = 0;
        #pragma unroll
        for (int q = 0; q < 16; ++q) {
            va += (int)(u0[q] < c0);
            vb += (int)(u1[q] < c1);
        }
        int ra = wave_sum_dpp(va);
        int rb = wave_sum_dpp(vb);
        if (ra + sa <= 1023) T0 = c0;
        if (rb + sb <= 1023) T1 = c1;
    }
    if (lane == 0) {
        F0[4 * MM + r0] = 2.0f * atanf(sqrtf(__uint_as_float(T0 + 8192u)));
        F0[4 * MM + r0 + 1] = 2.0f * atanf(sqrtf(__uint_as_float(T1 + 8192u)));
    }
}

// ---------------------------------------------------------------------------
// pf0: tiny K=5 GEMM, Y (M,64) fp32
// ---------------------------------------------------------------------------
__global__ __launch_bounds__(256) void pf0_k(const float* __restrict__ F0,
                                             const float* __restrict__ W,
                                             float* __restrict__ Y) {
    __shared__ float ws[320];
    int t = threadIdx.x;
    for (int i = t; i < 320; i += 256) ws[i] = W[i];
    __syncthreads();
    int m = blockIdx.x * 256 + t;
    float x0 = F0[m], x1 = F0[MM + m], x2 = F0[2 * MM + m], x3 = F0[3 * MM + m], x4 = F0[4 * MM + m];
    float* ym = Y + (size_t)m * 64;
    #pragma unroll
    for (int o = 0; o < 64; ++o) {
        const float* wo = &ws[o * 5];
        ym[o] = wo[0] * x0 + wo[1] * x1 + wo[2] * x2 + wo[3] * x3 + wo[4] * x4;
    }
}

// ---------------------------------------------------------------------------
// fp16 MFMA GEMM, BM=64 BO=128, register-prefetch pipeline.
// MODE 1: fp16 Y + fused BN stats. MODE 2: fp16 K-split partial (blockIdx.z).
// ---------------------------------------------------------------------------
template<int MODE>
__global__ __launch_bounds__(256) void mgemm3_k(const unsigned short* __restrict__ X, int ldx,
                                                const unsigned short* __restrict__ W, int ldw,
                                                unsigned short* __restrict__ Yh, int Co, int K, int kchunk,
                                                float* __restrict__ sums) {
    __shared__ unsigned short As[64 * 32];
    __shared__ unsigned short Bs[128 * 32];
    int t = threadIdx.x;
    int mBase = blockIdx.x * 64;
    int oBase = blockIdx.y * 128;
    int k0c = blockIdx.z * kchunk;
    int k1c = k0c + kchunk; if (k1c > K) k1c = K;
    int lane = t & 63, w = t >> 6;
    int warpM = (w & 1) * 32, warpO = (w >> 1) * 64;
    f32x4 acc[2][4];
    #pragma unroll
    for (int i = 0; i < 2; ++i)
        #pragma unroll
        for (int j = 0; j < 4; ++j) acc[i][j] = (f32x4){0.f, 0.f, 0.f, 0.f};
    int lr = t >> 2;
    int lc = (t & 3) * 8;
    const unsigned short* Xp = X + (size_t)(mBase + lr) * ldx + lc;
    const unsigned short* Wp0 = W + (size_t)(oBase + lr) * ldw + lc;
    const unsigned short* Wp1 = W + (size_t)(oBase + lr + 64) * ldw + lc;
    int ar0 = (warpM + (lane & 15)) * 32 + (lane >> 4) * 8;
    int br0 = (warpO + (lane & 15)) * 32 + (lane >> 4) * 8;
    uint4 xa = *(const uint4*)(Xp + k0c);
    uint4 wb0 = *(const uint4*)(Wp0 + k0c);
    uint4 wb1 = *(const uint4*)(Wp1 + k0c);
    for (int k = k0c; k < k1c; k += 32) {
        __syncthreads();
        *(uint4*)&As[lr * 32 + lc] = xa;
        *(uint4*)&Bs[lr * 32 + lc] = wb0;
        *(uint4*)&Bs[(lr + 64) * 32 + lc] = wb1;
        if (k + 32 < k1c) {
            xa = *(const uint4*)(Xp + k + 32);
            wb0 = *(const uint4*)(Wp0 + k + 32);
            wb1 = *(const uint4*)(Wp1 + k + 32);
        }
        __syncthreads();
        half8 a0 = __builtin_bit_cast(half8, *(const uint4*)&As[ar0]);
        half8 a1 = __builtin_bit_cast(half8, *(const uint4*)&As[ar0 + 16 * 32]);
        half8 b0 = __builtin_bit_cast(half8, *(const uint4*)&Bs[br0]);
        half8 b1 = __builtin_bit_cast(half8, *(const uint4*)&Bs[br0 + 16 * 32]);
        half8 b2 = __builtin_bit_cast(half8, *(const uint4*)&Bs[br0 + 32 * 32]);
        half8 b3 = __builtin_bit_cast(half8, *(const uint4*)&Bs[br0 + 48 * 32]);
        acc[0][0] = __builtin_amdgcn_mfma_f32_16x16x32_f16(a0, b0, acc[0][0], 0, 0, 0);
        acc[0][1] = __builtin_amdgcn_mfma_f32_16x16x32_f16(a0, b1, acc[0][1], 0, 0, 0);
        acc[0][2] = __builtin_amdgcn_mfma_f32_16x16x32_f16(a0, b2, acc[0][2], 0, 0, 0);
        acc[0][3] = __builtin_amdgcn_mfma_f32_16x16x32_f16(a0, b3, acc[0][3], 0, 0, 0);
        acc[1][0] = __builtin_amdgcn_mfma_f32_16x16x32_f16(a1, b0, acc[1][0], 0, 0, 0);
        acc[1][1] = __builtin_amdgcn_mfma_f32_16x16x32_f16(a1, b1, acc[1][1], 0, 0, 0);
        acc[1][2] = __builtin_amdgcn_mfma_f32_16x16x32_f16(a1, b2, acc[1][2], 0, 0, 0);
        acc[1][3] = __builtin_amdgcn_mfma_f32_16x16x32_f16(a1, b3, acc[1][3], 0, 0, 0);
    }
    unsigned short* Yp = Yh + (MODE == 2 ? (size_t)blockIdx.z * MM * Co : 0);
    #pragma unroll
    for (int i = 0; i < 2; ++i)
        #pragma unroll
        for (int j = 0; j < 4; ++j) {
            int m0 = mBase + warpM + i * 16 + (lane >> 4) * 4;
            int o = oBase + warpO + j * 16 + (lane & 15);
            #pragma unroll
            for (int r = 0; r < 4; ++r)
                Yp[(size_t)(m0 + r) * Co + o] = f2h(acc[i][j][r]);
        }
    if (MODE == 1) {
        __syncthreads();
        float* ssum = (float*)As;
        float* ssq = (float*)Bs;
        if (t < 128) { ssum[t] = 0.f; ssq[t] = 0.f; }
        __syncthreads();
        #pragma unroll
        for (int j = 0; j < 4; ++j) {
            int oc = warpO + j * 16 + (lane & 15);
            float s = 0.f, q = 0.f;
            #pragma unroll
            for (int i = 0; i < 2; ++i)
                #pragma unroll
                for (int r = 0; r < 4; ++r) { float v = acc[i][j][r]; s += v; q += v * v; }
            atomicAdd(&ssum[oc], s);
            atomicAdd(&ssq[oc], q);
        }
        __syncthreads();
        if (t < 128) {
            atomicAdd(&sums[oBase + t], ssum[t]);
            atomicAdd(&sums[1024 + oBase + t], ssq[t]);
        }
    }
}

// ---------------------------------------------------------------------------
// fp16 MFMA GEMM, BM=64 BO=64 (higher occupancy for mid layers).
// MODE 0: fp32 Y. MODE 1: fp16 Y + fused BN stats.
// MODE 3: direct transposed output (b,50,n) + bias (cls3; sums = bias).
// ---------------------------------------------------------------------------
template<int MODE>
__global__ __launch_bounds__(256) void mgemm64_k(const unsigned short* __restrict__ X, int ldx,
                                                 const unsigned short* __restrict__ W, int ldw,
                                                 void* __restrict__ Yv, int Co, int K,
                                                 float* __restrict__ sums) {
    __shared__ unsigned short As[64 * 32];
    __shared__ unsigned short Bs[64 * 32];
    int t = threadIdx.x;
    int mBase = blockIdx.x * 64;
    int oBase = blockIdx.y * 64;
    int lane = t & 63, w = t >> 6;
    int warpM = (w & 1) * 32, warpO = (w >> 1) * 32;
    f32x4 acc[2][2];
    #pragma unroll
    for (int i = 0; i < 2; ++i)
        #pragma unroll
        for (int j = 0; j < 2; ++j) acc[i][j] = (f32x4){0.f, 0.f, 0.f, 0.f};
    int lr = t >> 2;
    int lc = (t & 3) * 8;
    const unsigned short* Xp = X + (size_t)(mBase + lr) * ldx + lc;
    const unsigned short* Wp = W + (size_t)(oBase + lr) * ldw + lc;
    int ar0 = (warpM + (lane & 15)) * 32 + (lane >> 4) * 8;
    int br0 = (warpO + (lane & 15)) * 32 + (lane >> 4) * 8;
    uint4 xa = *(const uint4*)(Xp);
    uint4 wb = *(const uint4*)(Wp);
    for (int k = 0; k < K; k += 32) {
        __syncthreads();
        *(uint4*)&As[lr * 32 + lc] = xa;
        *(uint4*)&Bs[lr * 32 + lc] = wb;
        if (k + 32 < K) {
            xa = *(const uint4*)(Xp + k + 32);
            wb = *(const uint4*)(Wp + k + 32);
        }
        __syncthreads();
        half8 a0 = __builtin_bit_cast(half8, *(const uint4*)&As[ar0]);
        half8 a1 = __builtin_bit_cast(half8, *(const uint4*)&As[ar0 + 16 * 32]);
        half8 b0 = __builtin_bit_cast(half8, *(const uint4*)&Bs[br0]);
        half8 b1 = __builtin_bit_cast(half8, *(const uint4*)&Bs[br0 + 16 * 32]);
        acc[0][0] = __builtin_amdgcn_mfma_f32_16x16x32_f16(a0, b0, acc[0][0], 0, 0, 0);
        acc[0][1] = __builtin_amdgcn_mfma_f32_16x16x32_f16(a0, b1, acc[0][1], 0, 0, 0);
        acc[1][0] = __builtin_amdgcn_mfma_f32_16x16x32_f16(a1, b0, acc[1][0], 0, 0, 0);
        acc[1][1] = __builtin_amdgcn_mfma_f32_16x16x32_f16(a1, b1, acc[1][1], 0, 0, 0);
    }
    if (MODE == 0) {
        float* Yp = (float*)Yv;
        #pragma unroll
        for (int i = 0; i < 2; ++i)
            #pragma unroll
            for (int j = 0; j < 2; ++j) {
                int m0 = mBase + warpM + i * 16 + (lane >> 4) * 4;
                int o = oBase + warpO + j * 16 + (lane & 15);
                #pragma unroll
                for (int r = 0; r < 4; ++r)
                    Yp[(size_t)(m0 + r) * Co + o] = acc[i][j][r];
            }
    } else if (MODE == 3) {
        float* outp = (float*)Yv;
        #pragma unroll
        for (int i = 0; i < 2; ++i)
            #pragma unroll
            for (int j = 0; j < 2; ++j) {
                int m0 = mBase + warpM + i * 16 + (lane >> 4) * 4;
                int o = oBase + warpO + j * 16 + (lane & 15);
                if (o < 50) {
                    int bb2 = m0 >> 11, n = m0 & (NN - 1);
                    float bi = sums[o];
                    float4 v = make_float4(acc[i][j][0] + bi, acc[i][j][1] + bi,
                                           acc[i][j][2] + bi, acc[i][j][3] + bi);
                    *(float4*)&outp[((size_t)bb2 * 50 + o) * NN + n] = v;
                }
            }
    } else {
        unsigned short* Yh = (unsigned short*)Yv;
        #pragma unroll
        for (int i = 0; i < 2; ++i)
            #pragma unroll
            for (int j = 0; j < 2; ++j) {
                int m0 = mBase + warpM + i * 16 + (lane >> 4) * 4;
                int o = oBase + warpO + j * 16 + (lane & 15);
                #pragma unroll
                for (int r = 0; r < 4; ++r)
                    Yh[(size_t)(m0 + r) * Co + o] = f2h(acc[i][j][r]);
            }
        __syncthreads();
        float* ssum = (float*)As;
        float* ssq = (float*)Bs;
        if (t < 64) { ssum[t] = 0.f; ssq[t] = 0.f; }
        __syncthreads();
        #pragma unroll
        for (int j = 0; j < 2; ++j) {
            int oc = warpO + j * 16 + (lane & 15);
            float s = 0.f, q = 0.f;
            #pragma unroll
            for (int i = 0; i < 2; ++i)
                #pragma unroll
                for (int r = 0; r < 4; ++r) { float v = acc[i][j][r]; s += v; q += v * v; }
            atomicAdd(&ssum[oc], s);
            atomicAdd(&ssq[oc], q);
        }
        __syncthreads();
        if (t < 64) {
            atomicAdd(&sums[oBase + t], ssum[t]);
            atomicAdd(&sums[1024 + oBase + t], ssq[t]);
        }
    }
}

// ---------------------------------------------------------------------------
// max-feature GEMV: contrib[b][o] = sum_c Wmax[c][o] * maxv[b][c]
// ---------------------------------------------------------------------------
__global__ __launch_bounds__(256) void gemv_k(const unsigned short* __restrict__ Wmax,
                                              const float* __restrict__ maxv,
                                              float* __restrict__ contrib) {
    int b = blockIdx.x >> 3;
    int cc = (blockIdx.x & 7) * 128;
    int o = threadIdx.x;
    const float* mv = maxv + b * 1024 + cc;
    float acc = 0.f;
    for (int c = 0; c < 128; ++c)
        acc += h2f(Wmax[(size_t)(cc + c) * 256 + o]) * mv[c];
    atomicAdd(&contrib[b * 256 + o], acc);
}

// ---------------------------------------------------------------------------
// cls0 finish: sum 4 fp16 K-split partials + contrib -> fp16 partial0 + stats
// ---------------------------------------------------------------------------
__global__ __launch_bounds__(256) void red4stat_k(unsigned short* __restrict__ Yh,
                                                  const float* __restrict__ contrib,
                                                  float* __restrict__ sums) {
    int o0 = blockIdx.x * 64;
    int m0 = blockIdx.y * 128;
    int t = threadIdx.x, ol = t & 63, mg = t >> 6;
    int b = m0 >> 11;
    float cb = contrib[b * 256 + o0 + ol];
    const size_t stride = (size_t)MM * 256;
    float s = 0.f, q = 0.f;
    unsigned short* p = Yh + (size_t)(m0 + mg) * 256 + o0 + ol;
    for (int i = 0; i < 32; ++i) {
        unsigned short* pp = p + (size_t)i * 4 * 256;
        float v = h2f(pp[0]) + h2f(pp[stride]) + h2f(pp[2 * stride]) + h2f(pp[3 * stride]) + cb;
        pp[0] = f2h(v);
        s += v; q += v * v;
    }
    __shared__ float ls[4][64], lq[4][64];
    ls[mg][ol] = s; lq[mg][ol] = q;
    __syncthreads();
    if (mg == 0) {
        s = ls[0][ol] + ls[1][ol] + ls[2][ol] + ls[3][ol];
        q = lq[0][ol] + lq[1][ol] + lq[2][ol] + lq[3][ol];
        atomicAdd(&sums[o0 + ol], s);
        atomicAdd(&sums[1024 + o0 + ol], q);
    }
}

// ---------------------------------------------------------------------------
// BN stats from fp32 Y (pf0) into a sums slice
// ---------------------------------------------------------------------------
__global__ __launch_bounds__(256) void bnstat_k(const float* __restrict__ Y, int Co,
                                                float* __restrict__ sums) {
    int o0 = blockIdx.x * 64;
    int m0 = blockIdx.y * 512;
    int t = threadIdx.x, ol = t & 63, mg = t >> 6;
    float s = 0.f, q = 0.f;
    const float* p = Y + (size_t)(m0 + mg) * Co + o0 + ol;
    for (int i = 0; i < 128; ++i) {
        float v = p[(size_t)i * 4 * Co];
        s += v; q += v * v;
    }
    __shared__ float ls[4][64], lq[4][64];
    ls[mg][ol] = s; lq[mg][ol] = q;
    __syncthreads();
    if (mg == 0) {
        s = ls[0][ol] + ls[1][ol] + ls[2][ol] + ls[3][ol];
        q = lq[0][ol] + lq[1][ol] + lq[2][ol] + lq[3][ol];
        atomicAdd(&sums[o0 + ol], s);
        atomicAdd(&sums[1024 + o0 + ol], q);
    }
}

// inline BN coefficient from sums slice
__device__ __forceinline__ void bncoef(const float* __restrict__ sums,
                                       const float* __restrict__ g,
                                       const float* __restrict__ bb,
                                       int o, float& a, float& c) {
    float mu = sums[o] * (1.f / 8192.f);
    float var = sums[1024 + o] * (1.f / 8192.f) - mu * mu;
    var = fmaxf(var, 0.f);
    a = g[o] * (1.0f / sqrtf(var + EPSF));
    c = bb[o] - mu * a;
}

// ---------------------------------------------------------------------------
// BN normalize + ReLU + fp16 store (fp32 source)
// ---------------------------------------------------------------------------
__global__ __launch_bounds__(256) void bnorm_f(const float* __restrict__ Y,
                                               const float* __restrict__ sums,
                                               const float* __restrict__ g,
                                               const float* __restrict__ bb,
                                               unsigned short* __restrict__ dst, int ldd, int shift) {
    int idx4 = blockIdx.x * 256 + threadIdx.x;
    int m = idx4 >> shift;
    int o4 = (idx4 & ((1 << shift) - 1)) * 4;
    float4 v = ((const float4*)Y)[idx4];
    float vv[4] = {v.x, v.y, v.z, v.w};
    unsigned short r[4];
    #pragma unroll
    for (int j = 0; j < 4; ++j) {
        float a, c;
        bncoef(sums, g, bb, o4 + j, a, c);
        r[j] = f2h(fmaxf(vv[j] * a + c, 0.f));
    }
    *(ushort4*)&dst[(size_t)m * ldd + o4] = make_ushort4(r[0], r[1], r[2], r[3]);
}

// ---------------------------------------------------------------------------
// BN normalize + ReLU + fp16 store (fp16 source)
// ---------------------------------------------------------------------------
__global__ __launch_bounds__(256) void bnorm_h(const unsigned short* __restrict__ Yh,
                                               const float* __restrict__ sums,
                                               const float* __restrict__ g,
                                               const float* __restrict__ bb,
                                               unsigned short* __restrict__ dst, int ldd, int shift) {
    int idx4 = blockIdx.x * 256 + threadIdx.x;
    int m = idx4 >> shift;
    int o4 = (idx4 & ((1 << shift) - 1)) * 4;
    ushort4 hv = ((const ushort4*)Yh)[idx4];
    float vv[4] = {h2f(hv.x), h2f(hv.y), h2f(hv.z), h2f(hv.w)};
    unsigned short r[4];
    #pragma unroll
    for (int j = 0; j < 4; ++j) {
        float a, c;
        bncoef(sums, g, bb, o4 + j, a, c);
        r[j] = f2h(fmaxf(vv[j] * a + c, 0.f));
    }
    *(ushort4*)&dst[(size_t)m * ldd + o4] = make_ushort4(r[0], r[1], r[2], r[3]);
}

// ---------------------------------------------------------------------------
// pf3 fused BN-normalize + ReLU + store to XCb 336-slice + per-channel max
// ---------------------------------------------------------------------------
__global__ __launch_bounds__(256) void bn3max_k(const unsigned short* __restrict__ Yh,
                                                const float* __restrict__ sums,
                                                const float* __restrict__ g,
                                                const float* __restrict__ bb,
                                                unsigned short* __restrict__ XCb,
                                                float* __restrict__ maxbuf) {
    int b = blockIdx.x;
    int rc = blockIdx.y;
    int t = threadIdx.x;
    int o4 = t * 4;
    float a0, c0, a1, c1, a2, c2, a3, c3;
    bncoef(sums, g, bb, o4 + 0, a0, c0);
    bncoef(sums, g, bb, o4 + 1, a1, c1);
    bncoef(sums, g, bb, o4 + 2, a2, c2);
    bncoef(sums, g, bb, o4 + 3, a3, c3);
    float m0 = 0.f, m1 = 0.f, m2 = 0.f, m3 = 0.f;
    int mrow = b * NN + rc * 16;
    for (int i = 0; i < 16; ++i) {
        int m = mrow + i;
        ushort4 hv = *(const ushort4*)&Yh[(size_t)m * 1024 + o4];
        float y0 = fmaxf(h2f(hv.x) * a0 + c0, 0.f);
        float y1 = fmaxf(h2f(hv.y) * a1 + c1, 0.f);
        float y2 = fmaxf(h2f(hv.z) * a2 + c2, 0.f);
        float y3 = fmaxf(h2f(hv.w) * a3 + c3, 0.f);
        m0 = fmaxf(m0, y0); m1 = fmaxf(m1, y1);
        m2 = fmaxf(m2, y2); m3 = fmaxf(m3, y3);
        *(ushort4*)&XCb[(size_t)m * LDC + 336 + o4] =
            make_ushort4(f2h(y0), f2h(y1), f2h(y2), f2h(y3));
    }
    atomicMax((unsigned*)&maxbuf[b * 1024 + o4 + 0], __builtin_bit_cast(unsigned, m0));
    atomicMax((unsigned*)&maxbuf[b * 1024 + o4 + 1], __builtin_bit_cast(unsigned, m1));
    atomicMax((unsigned*)&maxbuf[b * 1024 + o4 + 2], __builtin_bit_cast(unsigned, m2));
    atomicMax((unsigned*)&maxbuf[b * 1024 + o4 + 3], __builtin_bit_cast(unsigned, m3));
}

// ---------------------------------------------------------------------------
extern "C" void kernel_launch(void* const* d_in, const int* in_sizes, int n_in,
                              void* d_out, int out_size, void* d_ws, size_t ws_size,
                              hipStream_t stream) {
    const float* in = (const float*)d_in[0];
    const float* pf0_w = (const float*)d_in[1];
    const float* pf_g[4] = {(const float*)d_in[2], (const float*)d_in[5], (const float*)d_in[8], (const float*)d_in[11]};
    const float* pf_b[4] = {(const float*)d_in[3], (const float*)d_in[6], (const float*)d_in[9], (const float*)d_in[12]};
    const float* pf_w[4] = {(const float*)d_in[1], (const float*)d_in[4], (const float*)d_in[7], (const float*)d_in[10]};
    const float* cls_w[3] = {(const float*)d_in[13], (const float*)d_in[16], (const float*)d_in[19]};
    const float* cls_g[3] = {(const float*)d_in[14], (const float*)d_in[17], (const float*)d_in[20]};
    const float* cls_b[3] = {(const float*)d_in[15], (const float*)d_in[18], (const float*)d_in[21]};
    const float* cls3_w = (const float*)d_in[22];
    const float* cls3_bias = (const float*)d_in[23];
    float* out = (float*)d_out;

    char* wsb = (char*)d_ws;
    float* ST = (float*)(wsb + 0);                           // 256 B
    float4* PQ = (float4*)(wsb + 256);                       // 131072
    float* F0 = (float*)(wsb + 131328);                      // 163840
    float* SUMS = (float*)(wsb + 295168);                    // 7 x 8192 = 57344
    float* MAXB = (float*)(wsb + 352512);                    // 16384
    float* CONTRIB = (float*)(wsb + 368896);                 // 4096
    unsigned short* WB = (unsigned short*)(wsb + 372992);    // 1769472
    unsigned short* XCb = (unsigned short*)(wsb + 2142464);  // 22544384
    unsigned short* C1b = (unsigned short*)(wsb + 24686848); // 4194304
    unsigned short* C2b = (unsigned short*)(wsb + 28881152); // 4194304
    unsigned short* C3b = C1b;
    float* Y = (float*)(wsb + 33075456);                     // 33554432
    unsigned short* Yh = (unsigned short*)Y;

    auto SL = [&](int s) { return SUMS + (size_t)s * 2048; };

    // fused preamble: wconv(x4) + stats + zero(SUMS+MAXB+CONTRIB) + onehot/pad
    prep_k<<<976, 256, 0, stream>>>(in, pf_w[1], pf_w[2], pf_w[3], cls_w[0], cls_w[1], cls_w[2], cls3_w,
                                    WB, ST, SUMS, XCb);
    point_k<<<MM / 256, 256, 0, stream>>>(in, ST, PQ, F0);
    alpha_k<<<MM / 8, 256, 0, stream>>>(PQ, F0);

    // pf0 (fp32 path)
    pf0_k<<<MM / 256, 256, 0, stream>>>(F0, pf0_w, Y);
    bnstat_k<<<dim3(1, 16), 256, 0, stream>>>(Y, 64, SL(0));
    bnorm_f<<<512, 256, 0, stream>>>(Y, SL(0), pf_g[0], pf_b[0], XCb + 16, LDC, 4);
    // pf1 (Co=128, K=64)
    mgemm64_k<1><<<dim3(128, 2), 256, 0, stream>>>(XCb + 16, LDC, WB, 64, Yh, 128, 64, SL(1));
    bnorm_h<<<1024, 256, 0, stream>>>(Yh, SL(1), pf_g[1], pf_b[1], XCb + 80, LDC, 5);
    // pf2 (Co=128, K=128)
    mgemm64_k<1><<<dim3(128, 2), 256, 0, stream>>>(XCb + 80, LDC, WB + 8192, 128, Yh, 128, 128, SL(2));
    bnorm_h<<<1024, 256, 0, stream>>>(Yh, SL(2), pf_g[2], pf_b[2], XCb + 208, LDC, 5);
    // pf3 (Co=1024, K=128)
    mgemm3_k<1><<<dim3(128, 8, 1), 256, 0, stream>>>(XCb + 208, LDC, WB + 24576, 128, Yh, 1024, 128, 128, SL(3));
    bn3max_k<<<dim3(4, 128), 256, 0, stream>>>(Yh, SL(3), pf_g[3], pf_b[3], XCb, MAXB);
    // max-feature contribution GEMV
    gemv_k<<<32, 256, 0, stream>>>(WB + 614400, MAXB, CONTRIB);
    // cls0 (Co=256, K=1376): K-split x4 fp16 partials, fused reduce+contrib+stats
    mgemm3_k<2><<<dim3(128, 2, 4), 256, 0, stream>>>(XCb, LDC, WB + 155648, 1376, Yh, 256, 1376, 352, SL(4));
    red4stat_k<<<dim3(4, 64), 256, 0, stream>>>(Yh, CONTRIB, SL(4));
    bnorm_h<<<2048, 256, 0, stream>>>(Yh, SL(4), cls_g[0], cls_b[0], C1b, 256, 6);
    // cls1 (Co=256, K=256)
    mgemm64_k<1><<<dim3(128, 4), 256, 0, stream>>>(C1b, 256, WB + 507904, 256, Yh, 256, 256, SL(5));
    bnorm_h<<<2048, 256, 0, stream>>>(Yh, SL(5), cls_g[1], cls_b[1], C2b, 256, 6);
    // cls2 (Co=128, K=256)
    mgemm64_k<1><<<dim3(128, 2), 256, 0, stream>>>(C2b, 256, WB + 573440, 256, Yh, 128, 256, SL(6));
    bnorm_h<<<1024, 256, 0, stream>>>(Yh, SL(6), cls_g[2], cls_b[2], C3b, 128, 5);
    // cls3 (Co=64, o<50 real): direct transposed output + bias
    mgemm64_k<3><<<dim3(128, 1), 256, 0, stream>>>(C3b, 128, WB + 606208, 128, (void*)out, 64, 128,
                                                   (float*)cls3_bias);

    (void)in_sizes; (void)n_in; (void)out_size; (void)ws_size;
}

// Round 14
// 183.173 us; speedup vs baseline: 1.5783x; 1.1072x over previous
//
#include <hip/hip_runtime.h>
#include <math.h>

#define BB 4
#define NN 2048
#define MM 8192
#define EPSF 1e-5f
#define LDC 1376   // concat stride: onehot16 | pf0 64 | pf1 128 | pf2 128 | pf3 1024 | pad16

typedef _Float16 half8 __attribute__((ext_vector_type(8)));
typedef float f32x4 __attribute__((ext_vector_type(4)));

__device__ __forceinline__ unsigned short f2h(float x) {
    _Float16 h = (_Float16)x;
    return __builtin_bit_cast(unsigned short, h);
}
__device__ __forceinline__ float h2f(unsigned short u) {
    return (float)__builtin_bit_cast(_Float16, u);
}
// order-preserving float<->unsigned for atomicMax over signed floats
__device__ __forceinline__ unsigned fflip(float x) {
    unsigned u = __builtin_bit_cast(unsigned, x);
    return (u >> 31) ? ~u : (u | 0x80000000u);
}
__device__ __forceinline__ float funflip(unsigned s) {
    unsigned u = (s >> 31) ? (s ^ 0x80000000u) : ~s;
    return __builtin_bit_cast(float, u);
}
#define FLIP_NEG_INF 0x007FFFFFu

__device__ __forceinline__ int wave_sum_dpp(int v) {
    v += __builtin_amdgcn_update_dpp(0, v, 0x111, 0xF, 0xF, true);
    v += __builtin_amdgcn_update_dpp(0, v, 0x112, 0xF, 0xF, true);
    v += __builtin_amdgcn_update_dpp(0, v, 0x114, 0xF, 0xF, true);
    v += __builtin_amdgcn_update_dpp(0, v, 0x118, 0xF, 0xF, true);
    v += __builtin_amdgcn_update_dpp(0, v, 0x142, 0xa, 0xF, true);
    v += __builtin_amdgcn_update_dpp(0, v, 0x143, 0xc, 0xF, true);
    return __builtin_amdgcn_readlane(v, 63);
}

__device__ __forceinline__ float angle3(float ux, float uy, float uz,
                                        float vx, float vy, float vz) {
    float crx = uy * vz - uz * vy;
    float cry = uz * vx - ux * vz;
    float crz = ux * vy - uy * vx;
    float s = sqrtf(crx * crx + cry * cry + crz * crz);
    float c = ux * vx + uy * vy + uz * vz;
    return atan2f(s, c);
}

// BN coefficient from a sums slice
__device__ __forceinline__ void bncoef(const float* __restrict__ sums,
                                       const float* __restrict__ g,
                                       const float* __restrict__ bb,
                                       int o, float& a, float& c) {
    float mu = sums[o] * (1.f / 8192.f);
    float var = sums[1024 + o] * (1.f / 8192.f) - mu * mu;
    var = fmaxf(var, 0.f);
    a = g[o] * (1.0f / sqrtf(var + EPSF));
    c = bb[o] - mu * a;
}

// ---------------------------------------------------------------------------
// fused preamble: wconv x4 (0..863) | stats (864..867) | init SUMS/MAXB/CONTRIB
// (868..943; MAXB gets flip(-inf)) | onehot+pad (944..975)
// WB: pf1[0,8192) pf2[8192,24576) pf3[24576,155648) cls0 256x1376[155648,507904)
//     cls1[507904,573440) cls2[573440,606208) cls3 64x128[606208,614400)
//     Wmax c-major 1024x256 [614400,876544)
// ---------------------------------------------------------------------------
__global__ __launch_bounds__(256) void prep_k(const float* __restrict__ in,
                                              const float* __restrict__ w1, const float* __restrict__ w2,
                                              const float* __restrict__ w3, const float* __restrict__ w4,
                                              const float* __restrict__ w5, const float* __restrict__ w6,
                                              const float* __restrict__ w7,
                                              unsigned short* __restrict__ Wb,
                                              float* __restrict__ st,
                                              unsigned* __restrict__ zp,
                                              unsigned short* __restrict__ XCb) {
    int blk = blockIdx.x;
    int t = threadIdx.x;
    if (blk < 864) {
        int idx0 = blk * 1024 + t * 4;
        ushort4 r;
        unsigned short* rp = (unsigned short*)&r;
        #pragma unroll
        for (int e = 0; e < 4; ++e) {
            int idx = idx0 + e;
            unsigned short v;
            if (idx < 8192) v = f2h(w1[idx]);
            else if (idx < 24576) v = f2h(w2[idx - 8192]);
            else if (idx < 155648) v = f2h(w3[idx - 24576]);
            else if (idx < 507904) {
                int l = idx - 155648;
                int o = l / 1376, k = l - o * 1376;
                v = (k < 1360) ? f2h(w4[o * 2384 + k]) : (unsigned short)0;
            } else if (idx < 573440) v = f2h(w5[idx - 507904]);
            else if (idx < 606208) v = f2h(w6[idx - 573440]);
            else if (idx < 614400) {
                int l = idx - 606208;
                int o = l >> 7, k = l & 127;
                v = (o < 50) ? f2h(w7[o * 128 + k]) : (unsigned short)0;
            } else {
                int l = idx - 614400;
                int c = l >> 8, o = l & 255;
                v = (c < 1024) ? f2h(w4[o * 2384 + 1360 + c]) : (unsigned short)0;
            }
            rp[e] = v;
        }
        *(ushort4*)&Wb[idx0] = r;
    } else if (blk < 868) {
        int b = blk - 864;
        const float* base = in + (size_t)b * 22 * NN;
        float cs0 = 0.f, cs1 = 0.f, cs2 = 0.f, ns0 = 0.f, ns1 = 0.f, ns2 = 0.f;
        for (int n = t; n < NN; n += 256) {
            float cx = base[0 * NN + n], cy = base[1 * NN + n], cz = base[2 * NN + n];
            float nx = base[3 * NN + n], ny = base[4 * NN + n], nz = base[5 * NN + n];
            float inv = 1.0f / sqrtf(nx * nx + ny * ny + nz * nz);
            cs0 += cx; cs1 += cy; cs2 += cz;
            ns0 += nx * inv; ns1 += ny * inv; ns2 += nz * inv;
        }
        __shared__ float red[6][256];
        red[0][t] = cs0; red[1][t] = cs1; red[2][t] = cs2;
        red[3][t] = ns0; red[4][t] = ns1; red[5][t] = ns2;
        __syncthreads();
        for (int s = 128; s > 0; s >>= 1) {
            if (t < s) {
                #pragma unroll
                for (int i = 0; i < 6; ++i) red[i][t] += red[i][t + s];
            }
            __syncthreads();
        }
        if (t == 0) {
            float ccx = red[0][0] / (float)NN, ccy = red[1][0] / (float)NN, ccz = red[2][0] / (float)NN;
            float cnx = red[3][0] / (float)NN, cny = red[4][0] / (float)NN, cnz = red[5][0] / (float)NN;
            float inv = 1.0f / sqrtf(cnx * cnx + cny * cny + cnz * cnz);
            float* s9 = st + b * 16;
            s9[0] = ccx; s9[1] = ccy; s9[2] = ccz;
            s9[3] = cnx; s9[4] = cny; s9[5] = cnz;
            s9[6] = cnx * inv; s9[7] = cny * inv; s9[8] = cnz * inv;
        }
    } else if (blk < 944) {
        int idx = (blk - 868) * 256 + t;      // SUMS[0,14336) MAXB[14336,18432) CONTRIB[18432,19456)
        zp[idx] = (idx >= 14336 && idx < 18432) ? FLIP_NEG_INF : 0u;
    } else {
        int m = (blk - 944) * 256 + t;
        int b = m >> 11, n = m & (NN - 1);
        const float* src = in + (size_t)b * 22 * NN + 6 * NN + n;
        unsigned short vals[16];
        #pragma unroll
        for (int r = 0; r < 16; ++r) vals[r] = f2h(src[(size_t)r * NN]);
        ushort4* dst = (ushort4*)&XCb[(size_t)m * LDC];
        #pragma unroll
        for (int q = 0; q < 4; ++q)
            dst[q] = make_ushort4(vals[4 * q], vals[4 * q + 1], vals[4 * q + 2], vals[4 * q + 3]);
        ushort4 z = make_ushort4(0, 0, 0, 0);
        ushort4* pz = (ushort4*)&XCb[(size_t)m * LDC + 1360];
        pz[0] = z; pz[1] = z; pz[2] = z; pz[3] = z;
    }
}

// ---------------------------------------------------------------------------
// per-point PPF + packed projected vectors PQ = (x,y,z,|P|)
// ---------------------------------------------------------------------------
__global__ __launch_bounds__(256) void point_k(const float* __restrict__ in,
                                               const float* __restrict__ st,
                                               float4* __restrict__ PQ,
                                               float* __restrict__ F0) {
    int idx = blockIdx.x * 256 + threadIdx.x;
    int b = idx >> 11, n = idx & (NN - 1);
    const float* base = in + (size_t)b * 22 * NN;
    const float* s9 = st + b * 16;
    float cx = base[0 * NN + n], cy = base[1 * NN + n], cz = base[2 * NN + n];
    float nx = base[3 * NN + n], ny = base[4 * NN + n], nz = base[5 * NN + n];
    float inv = 1.0f / sqrtf(nx * nx + ny * ny + nz * nz);
    nx *= inv; ny *= inv; nz *= inv;
    float ccx = s9[0], ccy = s9[1], ccz = s9[2];
    float cnx = s9[3], cny = s9[4], cnz = s9[5];
    float ex = s9[6], ey = s9[7], ez = s9[8];
    float dx = cx - ccx, dy = cy - ccy, dz = cz - ccz;
    F0[0 * MM + idx] = angle3(cnx, cny, cnz, dx, dy, dz);
    F0[1 * MM + idx] = angle3(nx, ny, nz, dx, dy, dz);
    F0[2 * MM + idx] = angle3(cnx, cny, cnz, nx, ny, nz);
    F0[3 * MM + idx] = sqrtf(dx * dx + dy * dy + dz * dz);
    float dot = dx * ex + dy * ey + dz * ez;
    float px = dx - dot * cnx;
    float py = dy - dot * cny;
    float pz = dz - dot * cnz;
    PQ[idx] = make_float4(px, py, pz, sqrtf(px * px + py * py + pz * pz));
}

// ---------------------------------------------------------------------------
// per-row median (2 rows/wave, hybrid ballot+DPP counting, 17-bit select)
// ---------------------------------------------------------------------------
__global__ __launch_bounds__(256) void alpha_k(const float4* __restrict__ PQ,
                                               float* __restrict__ F0) {
    int wid = blockIdx.x * 4 + (threadIdx.x >> 6);
    int lane = threadIdx.x & 63;
    int r0 = wid * 2;
    int b = r0 >> 11;
    int rl = r0 & (NN - 1);
    const float4* base = PQ + (size_t)b * NN;
    float4 a0 = base[rl];
    float4 a1 = base[rl + 1];
    unsigned u0[32], u1[32];
    #pragma unroll
    for (int s2 = 0; s2 < 32; ++s2) {
        float4 bv = base[s2 * 64 + lane];
        {
            float cx = a0.y * bv.z - a0.z * bv.y;
            float cy = a0.z * bv.x - a0.x * bv.z;
            float cz = a0.x * bv.y - a0.y * bv.x;
            float ss = cx * cx + cy * cy + cz * cz;
            float dc = a0.x * bv.x + a0.y * bv.y + a0.z * bv.z;
            float den = dc + a0.w * bv.w;
            float rc = __builtin_amdgcn_rcpf(den);
            float key = ss * rc * rc;
            u0[s2] = (key <= 2.5e-11f) ? 0x7F800000u : __float_as_uint(key);
        }
        {
            float cx = a1.y * bv.z - a1.z * bv.y;
            float cy = a1.z * bv.x - a1.x * bv.z;
            float cz = a1.x * bv.y - a1.y * bv.x;
            float ss = cx * cx + cy * cy + cz * cz;
            float dc = a1.x * bv.x + a1.y * bv.y + a1.z * bv.z;
            float den = dc + a1.w * bv.w;
            float rc = __builtin_amdgcn_rcpf(den);
            float key = ss * rc * rc;
            u1[s2] = (key <= 2.5e-11f) ? 0x7F800000u : __float_as_uint(key);
        }
    }
    unsigned T0 = 0u, T1 = 0u;
    for (int bit = 30; bit >= 14; --bit) {
        unsigned c0 = T0 | (1u << bit);
        unsigned c1 = T1 | (1u << bit);
        int sa = 0, sb = 0;
        #pragma unroll
        for (int q = 0; q < 8; ++q) {
            sa += (int)__popcll(__ballot(u0[16 + q] < c0));
            sb += (int)__popcll(__ballot(u1[16 + q] < c1));
            sa += (int)__popcll(__ballot(u0[24 + q] < c0));
            sb += (int)__popcll(__ballot(u1[24 + q] < c1));
        }
        int va = 0, vb = 0;
        #pragma unroll
        for (int q = 0; q < 16; ++q) {
            va += (int)(u0[q] < c0);
            vb += (int)(u1[q] < c1);
        }
        int ra = wave_sum_dpp(va);
        int rb = wave_sum_dpp(vb);
        if (ra + sa <= 1023) T0 = c0;
        if (rb + sb <= 1023) T1 = c1;
    }
    if (lane == 0) {
        F0[4 * MM + r0] = 2.0f * atanf(sqrtf(__uint_as_float(T0 + 8192u)));
        F0[4 * MM + r0 + 1] = 2.0f * atanf(sqrtf(__uint_as_float(T1 + 8192u)));
    }
}

// ---------------------------------------------------------------------------
// pf0: K=5 GEMM, raw fp16 into XCb+16 slice
// ---------------------------------------------------------------------------
__global__ __launch_bounds__(256) void pf0_k(const float* __restrict__ F0,
                                             const float* __restrict__ W,
                                             unsigned short* __restrict__ dst) {
    __shared__ float ws[320];
    int t = threadIdx.x;
    for (int i = t; i < 320; i += 256) ws[i] = W[i];
    __syncthreads();
    int m = blockIdx.x * 256 + t;
    float x0 = F0[m], x1 = F0[MM + m], x2 = F0[2 * MM + m], x3 = F0[3 * MM + m], x4 = F0[4 * MM + m];
    unsigned short* dm = dst + (size_t)m * LDC;
    #pragma unroll
    for (int q = 0; q < 16; ++q) {
        unsigned short v[4];
        #pragma unroll
        for (int e = 0; e < 4; ++e) {
            const float* wo = &ws[(q * 4 + e) * 5];
            v[e] = f2h(wo[0] * x0 + wo[1] * x1 + wo[2] * x2 + wo[3] * x3 + wo[4] * x4);
        }
        *(ushort4*)&dm[q * 4] = make_ushort4(v[0], v[1], v[2], v[3]);
    }
}

// ---------------------------------------------------------------------------
// BN stats over a strided fp16 slice (pf0)
// ---------------------------------------------------------------------------
__global__ __launch_bounds__(256) void bnstat_h(const unsigned short* __restrict__ Xs, int ld,
                                                float* __restrict__ sums) {
    int o0 = blockIdx.x * 64;
    int m0 = blockIdx.y * 512;
    int t = threadIdx.x, ol = t & 63, mg = t >> 6;
    float s = 0.f, q = 0.f;
    const unsigned short* p = Xs + (size_t)(m0 + mg) * ld + o0 + ol;
    for (int i = 0; i < 128; ++i) {
        float v = h2f(p[(size_t)i * 4 * ld]);
        s += v; q += v * v;
    }
    __shared__ float ls[4][64], lq[4][64];
    ls[mg][ol] = s; lq[mg][ol] = q;
    __syncthreads();
    if (mg == 0) {
        s = ls[0][ol] + ls[1][ol] + ls[2][ol] + ls[3][ol];
        q = lq[0][ol] + lq[1][ol] + lq[2][ol] + lq[3][ol];
        atomicAdd(&sums[o0 + ol], s);
        atomicAdd(&sums[1024 + o0 + ol], q);
    }
}

// ---------------------------------------------------------------------------
// fp16 MFMA GEMM BM=64 BO=128 with staging-normalization of X.
// TRANS: 0 none, 1 uniform (xs,xg,xb), 2 AB4 table (cls0).
// MODE: 1 raw fp16 out (yld) + stats [+DOMAX raw channel max]; 2 K-split partial.
// ---------------------------------------------------------------------------
template<int MODE, int TRANS, int DOMAX>
__global__ __launch_bounds__(256) void mgemm3_k(const unsigned short* __restrict__ X, int ldx,
                                                const unsigned short* __restrict__ W, int ldw,
                                                unsigned short* __restrict__ Yh, int yld, int Co, int K, int kchunk,
                                                float* __restrict__ sums,
                                                const float* __restrict__ xs, const float* __restrict__ xg,
                                                const float* __restrict__ xb,
                                                const float4* __restrict__ AB4,
                                                unsigned* __restrict__ maxbu) {
    __shared__ unsigned short As[64 * 32];
    __shared__ unsigned short Bs[128 * 32];
    __shared__ float4 ABl[352];
    int t = threadIdx.x;
    int mBase = blockIdx.x * 64;
    int oBase = blockIdx.y * 128;
    int k0c = blockIdx.z * kchunk;
    int k1c = k0c + kchunk; if (k1c > K) k1c = K;
    if (TRANS == 1) {
        float* abf = (float*)ABl;
        for (int i = t; i < K; i += 256) {
            float a, c; bncoef(xs, xg, xb, i, a, c);
            abf[2 * i] = a; abf[2 * i + 1] = c;
        }
    } else if (TRANS == 2) {
        for (int i = t; i < k1c - k0c; i += 256) ABl[i] = AB4[k0c + i];
    }
    int lane = t & 63, w = t >> 6;
    int warpM = (w & 1) * 32, warpO = (w >> 1) * 64;
    f32x4 acc[2][4];
    #pragma unroll
    for (int i = 0; i < 2; ++i)
        #pragma unroll
        for (int j = 0; j < 4; ++j) acc[i][j] = (f32x4){0.f, 0.f, 0.f, 0.f};
    int lr = t >> 2;
    int lc = (t & 3) * 8;
    const unsigned short* Xp = X + (size_t)(mBase + lr) * ldx + lc;
    const unsigned short* Wp0 = W + (size_t)(oBase + lr) * ldw + lc;
    const unsigned short* Wp1 = W + (size_t)(oBase + lr + 64) * ldw + lc;
    int ar0 = (warpM + (lane & 15)) * 32 + (lane >> 4) * 8;
    int br0 = (warpO + (lane & 15)) * 32 + (lane >> 4) * 8;
    uint4 xa = *(const uint4*)(Xp + k0c);
    uint4 wb0 = *(const uint4*)(Wp0 + k0c);
    uint4 wb1 = *(const uint4*)(Wp1 + k0c);
    for (int k = k0c; k < k1c; k += 32) {
        __syncthreads();
        uint4 xc = xa;
        if (TRANS == 1) {
            const float* abf = (const float*)ABl;
            unsigned short* p = (unsigned short*)&xc;
            int kb = k + lc;
            #pragma unroll
            for (int e = 0; e < 8; ++e)
                p[e] = f2h(fmaxf(abf[2 * (kb + e)] * h2f(p[e]) + abf[2 * (kb + e) + 1], 0.f));
        } else if (TRANS == 2) {
            unsigned short* p = (unsigned short*)&xc;
            int kb = k + lc - k0c;
            #pragma unroll
            for (int e = 0; e < 8; ++e) {
                float4 qd = ABl[kb + e];
                p[e] = f2h(fmaxf(qd.x * h2f(p[e]) + qd.y, qd.z));
            }
        }
        *(uint4*)&As[lr * 32 + lc] = xc;
        *(uint4*)&Bs[lr * 32 + lc] = wb0;
        *(uint4*)&Bs[(lr + 64) * 32 + lc] = wb1;
        if (k + 32 < k1c) {
            xa = *(const uint4*)(Xp + k + 32);
            wb0 = *(const uint4*)(Wp0 + k + 32);
            wb1 = *(const uint4*)(Wp1 + k + 32);
        }
        __syncthreads();
        half8 a0 = __builtin_bit_cast(half8, *(const uint4*)&As[ar0]);
        half8 a1 = __builtin_bit_cast(half8, *(const uint4*)&As[ar0 + 16 * 32]);
        half8 b0 = __builtin_bit_cast(half8, *(const uint4*)&Bs[br0]);
        half8 b1 = __builtin_bit_cast(half8, *(const uint4*)&Bs[br0 + 16 * 32]);
        half8 b2 = __builtin_bit_cast(half8, *(const uint4*)&Bs[br0 + 32 * 32]);
        half8 b3 = __builtin_bit_cast(half8, *(const uint4*)&Bs[br0 + 48 * 32]);
        acc[0][0] = __builtin_amdgcn_mfma_f32_16x16x32_f16(a0, b0, acc[0][0], 0, 0, 0);
        acc[0][1] = __builtin_amdgcn_mfma_f32_16x16x32_f16(a0, b1, acc[0][1], 0, 0, 0);
        acc[0][2] = __builtin_amdgcn_mfma_f32_16x16x32_f16(a0, b2, acc[0][2], 0, 0, 0);
        acc[0][3] = __builtin_amdgcn_mfma_f32_16x16x32_f16(a0, b3, acc[0][3], 0, 0, 0);
        acc[1][0] = __builtin_amdgcn_mfma_f32_16x16x32_f16(a1, b0, acc[1][0], 0, 0, 0);
        acc[1][1] = __builtin_amdgcn_mfma_f32_16x16x32_f16(a1, b1, acc[1][1], 0, 0, 0);
        acc[1][2] = __builtin_amdgcn_mfma_f32_16x16x32_f16(a1, b2, acc[1][2], 0, 0, 0);
        acc[1][3] = __builtin_amdgcn_mfma_f32_16x16x32_f16(a1, b3, acc[1][3], 0, 0, 0);
    }
    unsigned short* Yp = Yh + (MODE == 2 ? (size_t)blockIdx.z * MM * yld : 0);
    #pragma unroll
    for (int i = 0; i < 2; ++i)
        #pragma unroll
        for (int j = 0; j < 4; ++j) {
            int m0 = mBase + warpM + i * 16 + (lane >> 4) * 4;
            int o = oBase + warpO + j * 16 + (lane & 15);
            #pragma unroll
            for (int r = 0; r < 4; ++r)
                Yp[(size_t)(m0 + r) * yld + o] = f2h(acc[i][j][r]);
        }
    if (MODE == 1) {
        __syncthreads();
        float* ssum = (float*)As;
        unsigned* smax = (unsigned*)As + 128;
        float* ssq = (float*)Bs;
        if (t < 128) { ssum[t] = 0.f; ssq[t] = 0.f; if (DOMAX) smax[t] = FLIP_NEG_INF; }
        __syncthreads();
        #pragma unroll
        for (int j = 0; j < 4; ++j) {
            int oc = warpO + j * 16 + (lane & 15);
            float s = 0.f, q = 0.f, mx = -__builtin_inff();
            #pragma unroll
            for (int i = 0; i < 2; ++i)
                #pragma unroll
                for (int r = 0; r < 4; ++r) {
                    float v = acc[i][j][r];
                    s += v; q += v * v; mx = fmaxf(mx, v);
                }
            atomicAdd(&ssum[oc], s);
            atomicAdd(&ssq[oc], q);
            if (DOMAX) atomicMax(&smax[oc], fflip(mx));
        }
        __syncthreads();
        if (t < 128) {
            atomicAdd(&sums[oBase + t], ssum[t]);
            atomicAdd(&sums[1024 + oBase + t], ssq[t]);
            if (DOMAX) atomicMax(&maxbu[(mBase >> 11) * 1024 + oBase + t], smax[t]);
        }
    }
}

// ---------------------------------------------------------------------------
// fp16 MFMA GEMM BM=64 BO=64 with staging-normalization.
// MODE 1: raw fp16 out (yld) + stats. MODE 3: direct (b,50,n) out + bias.
// ---------------------------------------------------------------------------
template<int MODE, int TRANS>
__global__ __launch_bounds__(256) void mgemm64_k(const unsigned short* __restrict__ X, int ldx,
                                                 const unsigned short* __restrict__ W, int ldw,
                                                 void* __restrict__ Yv, int yld, int Co, int K,
                                                 float* __restrict__ sums,
                                                 const float* __restrict__ xs, const float* __restrict__ xg,
                                                 const float* __restrict__ xb) {
    __shared__ unsigned short As[64 * 32];
    __shared__ unsigned short Bs[64 * 32];
    __shared__ float ABl[512];
    int t = threadIdx.x;
    int mBase = blockIdx.x * 64;
    int oBase = blockIdx.y * 64;
    if (TRANS == 1) {
        for (int i = t; i < K; i += 256) {
            float a, c; bncoef(xs, xg, xb, i, a, c);
            ABl[2 * i] = a; ABl[2 * i + 1] = c;
        }
    }
    int lane = t & 63, w = t >> 6;
    int warpM = (w & 1) * 32, warpO = (w >> 1) * 32;
    f32x4 acc[2][2];
    #pragma unroll
    for (int i = 0; i < 2; ++i)
        #pragma unroll
        for (int j = 0; j < 2; ++j) acc[i][j] = (f32x4){0.f, 0.f, 0.f, 0.f};
    int lr = t >> 2;
    int lc = (t & 3) * 8;
    const unsigned short* Xp = X + (size_t)(mBase + lr) * ldx + lc;
    const unsigned short* Wp = W + (size_t)(oBase + lr) * ldw + lc;
    int ar0 = (warpM + (lane & 15)) * 32 + (lane >> 4) * 8;
    int br0 = (warpO + (lane & 15)) * 32 + (lane >> 4) * 8;
    uint4 xa = *(const uint4*)(Xp);
    uint4 wb = *(const uint4*)(Wp);
    for (int k = 0; k < K; k += 32) {
        __syncthreads();
        uint4 xc = xa;
        if (TRANS == 1) {
            unsigned short* p = (unsigned short*)&xc;
            int kb = k + lc;
            #pragma unroll
            for (int e = 0; e < 8; ++e)
                p[e] = f2h(fmaxf(ABl[2 * (kb + e)] * h2f(p[e]) + ABl[2 * (kb + e) + 1], 0.f));
        }
        *(uint4*)&As[lr * 32 + lc] = xc;
        *(uint4*)&Bs[lr * 32 + lc] = wb;
        if (k + 32 < K) {
            xa = *(const uint4*)(Xp + k + 32);
            wb = *(const uint4*)(Wp + k + 32);
        }
        __syncthreads();
        half8 a0 = __builtin_bit_cast(half8, *(const uint4*)&As[ar0]);
        half8 a1 = __builtin_bit_cast(half8, *(const uint4*)&As[ar0 + 16 * 32]);
        half8 b0 = __builtin_bit_cast(half8, *(const uint4*)&Bs[br0]);
        half8 b1 = __builtin_bit_cast(half8, *(const uint4*)&Bs[br0 + 16 * 32]);
        acc[0][0] = __builtin_amdgcn_mfma_f32_16x16x32_f16(a0, b0, acc[0][0], 0, 0, 0);
        acc[0][1] = __builtin_amdgcn_mfma_f32_16x16x32_f16(a0, b1, acc[0][1], 0, 0, 0);
        acc[1][0] = __builtin_amdgcn_mfma_f32_16x16x32_f16(a1, b0, acc[1][0], 0, 0, 0);
        acc[1][1] = __builtin_amdgcn_mfma_f32_16x16x32_f16(a1, b1, acc[1][1], 0, 0, 0);
    }
    if (MODE == 3) {
        float* outp = (float*)Yv;
        #pragma unroll
        for (int i = 0; i < 2; ++i)
            #pragma unroll
            for (int j = 0; j < 2; ++j) {
                int m0 = mBase + warpM + i * 16 + (lane >> 4) * 4;
                int o = oBase + warpO + j * 16 + (lane & 15);
                if (o < 50) {
                    int bb2 = m0 >> 11, n = m0 & (NN - 1);
                    float bi = sums[o];
                    float4 v = make_float4(acc[i][j][0] + bi, acc[i][j][1] + bi,
                                           acc[i][j][2] + bi, acc[i][j][3] + bi);
                    *(float4*)&outp[((size_t)bb2 * 50 + o) * NN + n] = v;
                }
            }
    } else {
        unsigned short* Yh = (unsigned short*)Yv;
        #pragma unroll
        for (int i = 0; i < 2; ++i)
            #pragma unroll
            for (int j = 0; j < 2; ++j) {
                int m0 = mBase + warpM + i * 16 + (lane >> 4) * 4;
                int o = oBase + warpO + j * 16 + (lane & 15);
                #pragma unroll
                for (int r = 0; r < 4; ++r)
                    Yh[(size_t)(m0 + r) * yld + o] = f2h(acc[i][j][r]);
            }
        __syncthreads();
        float* ssum = (float*)As;
        float* ssq = (float*)Bs;
        if (t < 64) { ssum[t] = 0.f; ssq[t] = 0.f; }
        __syncthreads();
        #pragma unroll
        for (int j = 0; j < 2; ++j) {
            int oc = warpO + j * 16 + (lane & 15);
            float s = 0.f, q = 0.f;
            #pragma unroll
            for (int i = 0; i < 2; ++i)
                #pragma unroll
                for (int r = 0; r < 4; ++r) { float v = acc[i][j][r]; s += v; q += v * v; }
            atomicAdd(&ssum[oc], s);
            atomicAdd(&ssq[oc], q);
        }
        __syncthreads();
        if (t < 64) {
            atomicAdd(&sums[oBase + t], ssum[t]);
            atomicAdd(&sums[1024 + oBase + t], ssq[t]);
        }
    }
}

// ---------------------------------------------------------------------------
// build cls0 coefficient table AB4[1376] + normalized pf3 maxes NMAXB[4][1024]
// ---------------------------------------------------------------------------
__global__ __launch_bounds__(256) void abbuild_k(const float* __restrict__ SUMS,
                                                 const unsigned* __restrict__ MAXBu,
                                                 float4* __restrict__ AB4,
                                                 float* __restrict__ NMAXB,
                                                 const float* g0, const float* b0,
                                                 const float* g1, const float* b1,
                                                 const float* g2, const float* b2,
                                                 const float* g3, const float* b3) {
    int blk = blockIdx.x, t = threadIdx.x;
    if (blk < 6) {
        int ch = blk * 256 + t;
        if (ch >= 1376) return;
        float4 r;
        if (ch < 16) r = make_float4(1.f, 0.f, -__builtin_inff(), 0.f);
        else if (ch < 80) { float a, c; bncoef(SUMS, g0, b0, ch - 16, a, c); r = make_float4(a, c, 0.f, 0.f); }
        else if (ch < 208) { float a, c; bncoef(SUMS + 2048, g1, b1, ch - 80, a, c); r = make_float4(a, c, 0.f, 0.f); }
        else if (ch < 336) { float a, c; bncoef(SUMS + 4096, g2, b2, ch - 208, a, c); r = make_float4(a, c, 0.f, 0.f); }
        else if (ch < 1360) { float a, c; bncoef(SUMS + 6144, g3, b3, ch - 336, a, c); r = make_float4(a, c, 0.f, 0.f); }
        else r = make_float4(0.f, 0.f, 0.f, 0.f);
        AB4[ch] = r;
    } else {
        int idx = (blk - 6) * 256 + t;   // 0..4095
        int c = idx & 1023;
        float a, cc; bncoef(SUMS + 6144, g3, b3, c, a, cc);
        float raw = funflip(MAXBu[idx]);
        NMAXB[idx] = fmaxf(a * raw + cc, 0.f);
    }
}

// ---------------------------------------------------------------------------
// max-feature GEMV: contrib[b][o] = sum_c Wmax[c][o] * nmax[b][c]
// ---------------------------------------------------------------------------
__global__ __launch_bounds__(256) void gemv_k(const unsigned short* __restrict__ Wmax,
                                              const float* __restrict__ nmax,
                                              float* __restrict__ contrib) {
    int b = blockIdx.x >> 3;
    int cc = (blockIdx.x & 7) * 128;
    int o = threadIdx.x;
    const float* mv = nmax + b * 1024 + cc;
    float acc = 0.f;
    for (int c = 0; c < 128; ++c)
        acc += h2f(Wmax[(size_t)(cc + c) * 256 + o]) * mv[c];
    atomicAdd(&contrib[b * 256 + o], acc);
}

// ---------------------------------------------------------------------------
// cls0 finish: sum 4 fp16 K-split partials + contrib -> raw fp16 partial0 + stats
// ---------------------------------------------------------------------------
__global__ __launch_bounds__(256) void red4stat_k(unsigned short* __restrict__ Yh,
                                                  const float* __restrict__ contrib,
                                                  float* __restrict__ sums) {
    int o0 = blockIdx.x * 64;
    int m0 = blockIdx.y * 128;
    int t = threadIdx.x, ol = t & 63, mg = t >> 6;
    int b = m0 >> 11;
    float cb = contrib[b * 256 + o0 + ol];
    const size_t stride = (size_t)MM * 256;
    float s = 0.f, q = 0.f;
    unsigned short* p = Yh + (size_t)(m0 + mg) * 256 + o0 + ol;
    for (int i = 0; i < 32; ++i) {
        unsigned short* pp = p + (size_t)i * 4 * 256;
        float v = h2f(pp[0]) + h2f(pp[stride]) + h2f(pp[2 * stride]) + h2f(pp[3 * stride]) + cb;
        pp[0] = f2h(v);
        s += v; q += v * v;
    }
    __shared__ float ls[4][64], lq[4][64];
    ls[mg][ol] = s; lq[mg][ol] = q;
    __syncthreads();
    if (mg == 0) {
        s = ls[0][ol] + ls[1][ol] + ls[2][ol] + ls[3][ol];
        q = lq[0][ol] + lq[1][ol] + lq[2][ol] + lq[3][ol];
        atomicAdd(&sums[o0 + ol], s);
        atomicAdd(&sums[1024 + o0 + ol], q);
    }
}

// ---------------------------------------------------------------------------
extern "C" void kernel_launch(void* const* d_in, const int* in_sizes, int n_in,
                              void* d_out, int out_size, void* d_ws, size_t ws_size,
                              hipStream_t stream) {
    const float* in = (const float*)d_in[0];
    const float* pf0_w = (const float*)d_in[1];
    const float* pf_g[4] = {(const float*)d_in[2], (const float*)d_in[5], (const float*)d_in[8], (const float*)d_in[11]};
    const float* pf_b[4] = {(const float*)d_in[3], (const float*)d_in[6], (const float*)d_in[9], (const float*)d_in[12]};
    const float* pf_w[4] = {(const float*)d_in[1], (const float*)d_in[4], (const float*)d_in[7], (const float*)d_in[10]};
    const float* cls_w[3] = {(const float*)d_in[13], (const float*)d_in[16], (const float*)d_in[19]};
    const float* cls_g[3] = {(const float*)d_in[14], (const float*)d_in[17], (const float*)d_in[20]};
    const float* cls_b[3] = {(const float*)d_in[15], (const float*)d_in[18], (const float*)d_in[21]};
    const float* cls3_w = (const float*)d_in[22];
    const float* cls3_bias = (const float*)d_in[23];
    float* out = (float*)d_out;

    char* wsb = (char*)d_ws;
    float* ST = (float*)(wsb + 0);                           // 256
    float4* PQ = (float4*)(wsb + 256);                       // 131072
    float* F0 = (float*)(wsb + 131328);                      // 163840
    float* SUMS = (float*)(wsb + 295168);                    // 57344 (7 slices)
    unsigned* MAXBu = (unsigned*)(wsb + 352512);             // 16384
    float* CONTRIB = (float*)(wsb + 368896);                 // 4096
    float4* AB4 = (float4*)(wsb + 372992);                   // 22016
    float* NMAXB = (float*)(wsb + 395008);                   // 16384
    unsigned short* WB = (unsigned short*)(wsb + 411392);    // 1769472
    unsigned short* XCb = (unsigned short*)(wsb + 2180864);  // 22544384
    unsigned short* C1b = (unsigned short*)(wsb + 24725248); // 4194304
    unsigned short* C2b = (unsigned short*)(wsb + 28919552); // 4194304
    unsigned short* Yh = (unsigned short*)(wsb + 33113856);  // 33554432 (cls0 partials)

    auto SL = [&](int s) { return SUMS + (size_t)s * 2048; };

    prep_k<<<976, 256, 0, stream>>>(in, pf_w[1], pf_w[2], pf_w[3], cls_w[0], cls_w[1], cls_w[2], cls3_w,
                                    WB, ST, (unsigned*)SUMS, XCb);
    point_k<<<MM / 256, 256, 0, stream>>>(in, ST, PQ, F0);
    alpha_k<<<MM / 8, 256, 0, stream>>>(PQ, F0);

    // pf0 raw -> XCb+16; stats SL(0)
    pf0_k<<<MM / 256, 256, 0, stream>>>(F0, pf0_w, XCb + 16);
    bnstat_h<<<dim3(1, 16), 256, 0, stream>>>(XCb + 16, LDC, SL(0));
    // pf1: stage-norm SL(0); raw -> XCb+80; stats SL(1)
    mgemm64_k<1, 1><<<dim3(128, 2), 256, 0, stream>>>(XCb + 16, LDC, WB, 64, XCb + 80, LDC, 128, 64,
                                                      SL(1), SL(0), pf_g[0], pf_b[0]);
    // pf2: stage-norm SL(1); raw -> XCb+208; stats SL(2)
    mgemm64_k<1, 1><<<dim3(128, 2), 256, 0, stream>>>(XCb + 80, LDC, WB + 8192, 128, XCb + 208, LDC, 128, 128,
                                                      SL(2), SL(1), pf_g[1], pf_b[1]);
    // pf3: stage-norm SL(2); raw -> XCb+336; stats SL(3) + raw channel max
    mgemm3_k<1, 1, 1><<<dim3(128, 8, 1), 256, 0, stream>>>(XCb + 208, LDC, WB + 24576, 128, XCb + 336, LDC,
                                                           1024, 128, 128, SL(3), SL(2), pf_g[2], pf_b[2],
                                                           AB4, MAXBu);
    // coefficient table + normalized maxes
    abbuild_k<<<22, 256, 0, stream>>>(SUMS, MAXBu, AB4, NMAXB,
                                      pf_g[0], pf_b[0], pf_g[1], pf_b[1], pf_g[2], pf_b[2], pf_g[3], pf_b[3]);
    gemv_k<<<32, 256, 0, stream>>>(WB + 614400, NMAXB, CONTRIB);
    // cls0: stage-norm via AB4; K-split x4 raw fp16 partials
    mgemm3_k<2, 2, 0><<<dim3(128, 2, 4), 256, 0, stream>>>(XCb, LDC, WB + 155648, 1376, Yh, 256,
                                                           256, 1376, 352, SL(4), nullptr, nullptr, nullptr,
                                                           AB4, MAXBu);
    red4stat_k<<<dim3(4, 64), 256, 0, stream>>>(Yh, CONTRIB, SL(4));
    // cls1: stage-norm SL(4); raw -> C1b; stats SL(5)
    mgemm64_k<1, 1><<<dim3(128, 4), 256, 0, stream>>>(Yh, 256, WB + 507904, 256, C1b, 256, 256, 256,
                                                      SL(5), SL(4), cls_g[0], cls_b[0]);
    // cls2: stage-norm SL(5); raw -> C2b; stats SL(6)
    mgemm64_k<1, 1><<<dim3(128, 2), 256, 0, stream>>>(C1b, 256, WB + 507904 + 65536, 256, C2b, 128, 128, 256,
                                                      SL(6), SL(5), cls_g[1], cls_b[1]);
    // cls3: stage-norm SL(6); direct (b,50,n) output + bias
    mgemm64_k<3, 1><<<dim3(128, 1), 256, 0, stream>>>(C2b, 128, WB + 606208, 128, (void*)out, 0, 64, 128,
                                                      (float*)cls3_bias, SL(6), cls_g[2], cls_b[2]);

    (void)in_sizes; (void)n_in; (void)out_size; (void)ws_size;
}

// Round 15
// 179.923 us; speedup vs baseline: 1.6068x; 1.0181x over previous
//
#include <hip/hip_runtime.h>
#include <math.h>

#define BB 4
#define NN 2048
#define MM 8192
#define EPSF 1e-5f
#define LDC 1376   // concat stride: onehot16 | pf0 64 | pf1 128 | pf2 128 | pf3 1024 | pad16

typedef _Float16 half8 __attribute__((ext_vector_type(8)));
typedef float f32x4 __attribute__((ext_vector_type(4)));

__device__ __forceinline__ unsigned short f2h(float x) {
    _Float16 h = (_Float16)x;
    return __builtin_bit_cast(unsigned short, h);
}
__device__ __forceinline__ float h2f(unsigned short u) {
    return (float)__builtin_bit_cast(_Float16, u);
}
// order-preserving float<->unsigned for atomicMax over signed floats
__device__ __forceinline__ unsigned fflip(float x) {
    unsigned u = __builtin_bit_cast(unsigned, x);
    return (u >> 31) ? ~u : (u | 0x80000000u);
}
__device__ __forceinline__ float funflip(unsigned s) {
    unsigned u = (s >> 31) ? (s ^ 0x80000000u) : ~s;
    return __builtin_bit_cast(float, u);
}
#define FLIP_NEG_INF 0x007FFFFFu

__device__ __forceinline__ int wave_sum_dpp(int v) {
    v += __builtin_amdgcn_update_dpp(0, v, 0x111, 0xF, 0xF, true);
    v += __builtin_amdgcn_update_dpp(0, v, 0x112, 0xF, 0xF, true);
    v += __builtin_amdgcn_update_dpp(0, v, 0x114, 0xF, 0xF, true);
    v += __builtin_amdgcn_update_dpp(0, v, 0x118, 0xF, 0xF, true);
    v += __builtin_amdgcn_update_dpp(0, v, 0x142, 0xa, 0xF, true);
    v += __builtin_amdgcn_update_dpp(0, v, 0x143, 0xc, 0xF, true);
    return __builtin_amdgcn_readlane(v, 63);
}

__device__ __forceinline__ float angle3(float ux, float uy, float uz,
                                        float vx, float vy, float vz) {
    float crx = uy * vz - uz * vy;
    float cry = uz * vx - ux * vz;
    float crz = ux * vy - uy * vx;
    float s = sqrtf(crx * crx + cry * cry + crz * crz);
    float c = ux * vx + uy * vy + uz * vz;
    return atan2f(s, c);
}

// BN coefficient from a sums slice
__device__ __forceinline__ void bncoef(const float* __restrict__ sums,
                                       const float* __restrict__ g,
                                       const float* __restrict__ bb,
                                       int o, float& a, float& c) {
    float mu = sums[o] * (1.f / 8192.f);
    float var = sums[1024 + o] * (1.f / 8192.f) - mu * mu;
    var = fmaxf(var, 0.f);
    a = g[o] * (1.0f / sqrtf(var + EPSF));
    c = bb[o] - mu * a;
}

// ---------------------------------------------------------------------------
// fused preamble: wconv x4 (0..863) | stats (864..867) | init SUMS/MAXB/CONTRIB
// (868..943; MAXB gets flip(-inf)) | onehot+pad (944..975)
// ---------------------------------------------------------------------------
__global__ __launch_bounds__(256) void prep_k(const float* __restrict__ in,
                                              const float* __restrict__ w1, const float* __restrict__ w2,
                                              const float* __restrict__ w3, const float* __restrict__ w4,
                                              const float* __restrict__ w5, const float* __restrict__ w6,
                                              const float* __restrict__ w7,
                                              unsigned short* __restrict__ Wb,
                                              float* __restrict__ st,
                                              unsigned* __restrict__ zp,
                                              unsigned short* __restrict__ XCb) {
    int blk = blockIdx.x;
    int t = threadIdx.x;
    if (blk < 864) {
        int idx0 = blk * 1024 + t * 4;
        ushort4 r;
        unsigned short* rp = (unsigned short*)&r;
        #pragma unroll
        for (int e = 0; e < 4; ++e) {
            int idx = idx0 + e;
            unsigned short v;
            if (idx < 8192) v = f2h(w1[idx]);
            else if (idx < 24576) v = f2h(w2[idx - 8192]);
            else if (idx < 155648) v = f2h(w3[idx - 24576]);
            else if (idx < 507904) {
                int l = idx - 155648;
                int o = l / 1376, k = l - o * 1376;
                v = (k < 1360) ? f2h(w4[o * 2384 + k]) : (unsigned short)0;
            } else if (idx < 573440) v = f2h(w5[idx - 507904]);
            else if (idx < 606208) v = f2h(w6[idx - 573440]);
            else if (idx < 614400) {
                int l = idx - 606208;
                int o = l >> 7, k = l & 127;
                v = (o < 50) ? f2h(w7[o * 128 + k]) : (unsigned short)0;
            } else {
                int l = idx - 614400;
                int c = l >> 8, o = l & 255;
                v = (c < 1024) ? f2h(w4[o * 2384 + 1360 + c]) : (unsigned short)0;
            }
            rp[e] = v;
        }
        *(ushort4*)&Wb[idx0] = r;
    } else if (blk < 868) {
        int b = blk - 864;
        const float* base = in + (size_t)b * 22 * NN;
        float cs0 = 0.f, cs1 = 0.f, cs2 = 0.f, ns0 = 0.f, ns1 = 0.f, ns2 = 0.f;
        for (int n = t; n < NN; n += 256) {
            float cx = base[0 * NN + n], cy = base[1 * NN + n], cz = base[2 * NN + n];
            float nx = base[3 * NN + n], ny = base[4 * NN + n], nz = base[5 * NN + n];
            float inv = 1.0f / sqrtf(nx * nx + ny * ny + nz * nz);
            cs0 += cx; cs1 += cy; cs2 += cz;
            ns0 += nx * inv; ns1 += ny * inv; ns2 += nz * inv;
        }
        __shared__ float red[6][256];
        red[0][t] = cs0; red[1][t] = cs1; red[2][t] = cs2;
        red[3][t] = ns0; red[4][t] = ns1; red[5][t] = ns2;
        __syncthreads();
        for (int s = 128; s > 0; s >>= 1) {
            if (t < s) {
                #pragma unroll
                for (int i = 0; i < 6; ++i) red[i][t] += red[i][t + s];
            }
            __syncthreads();
        }
        if (t == 0) {
            float ccx = red[0][0] / (float)NN, ccy = red[1][0] / (float)NN, ccz = red[2][0] / (float)NN;
            float cnx = red[3][0] / (float)NN, cny = red[4][0] / (float)NN, cnz = red[5][0] / (float)NN;
            float inv = 1.0f / sqrtf(cnx * cnx + cny * cny + cnz * cnz);
            float* s9 = st + b * 16;
            s9[0] = ccx; s9[1] = ccy; s9[2] = ccz;
            s9[3] = cnx; s9[4] = cny; s9[5] = cnz;
            s9[6] = cnx * inv; s9[7] = cny * inv; s9[8] = cnz * inv;
        }
    } else if (blk < 944) {
        int idx = (blk - 868) * 256 + t;
        zp[idx] = (idx >= 14336 && idx < 18432) ? FLIP_NEG_INF : 0u;
    } else {
        int m = (blk - 944) * 256 + t;
        int b = m >> 11, n = m & (NN - 1);
        const float* src = in + (size_t)b * 22 * NN + 6 * NN + n;
        unsigned short vals[16];
        #pragma unroll
        for (int r = 0; r < 16; ++r) vals[r] = f2h(src[(size_t)r * NN]);
        ushort4* dst = (ushort4*)&XCb[(size_t)m * LDC];
        #pragma unroll
        for (int q = 0; q < 4; ++q)
            dst[q] = make_ushort4(vals[4 * q], vals[4 * q + 1], vals[4 * q + 2], vals[4 * q + 3]);
        ushort4 z = make_ushort4(0, 0, 0, 0);
        ushort4* pz = (ushort4*)&XCb[(size_t)m * LDC + 1360];
        pz[0] = z; pz[1] = z; pz[2] = z; pz[3] = z;
    }
}

// ---------------------------------------------------------------------------
// per-point PPF + packed projected vectors PQ = (x,y,z,|P|)
// ---------------------------------------------------------------------------
__global__ __launch_bounds__(256) void point_k(const float* __restrict__ in,
                                               const float* __restrict__ st,
                                               float4* __restrict__ PQ,
                                               float* __restrict__ F0) {
    int idx = blockIdx.x * 256 + threadIdx.x;
    int b = idx >> 11, n = idx & (NN - 1);
    const float* base = in + (size_t)b * 22 * NN;
    const float* s9 = st + b * 16;
    float cx = base[0 * NN + n], cy = base[1 * NN + n], cz = base[2 * NN + n];
    float nx = base[3 * NN + n], ny = base[4 * NN + n], nz = base[5 * NN + n];
    float inv = 1.0f / sqrtf(nx * nx + ny * ny + nz * nz);
    nx *= inv; ny *= inv; nz *= inv;
    float ccx = s9[0], ccy = s9[1], ccz = s9[2];
    float cnx = s9[3], cny = s9[4], cnz = s9[5];
    float ex = s9[6], ey = s9[7], ez = s9[8];
    float dx = cx - ccx, dy = cy - ccy, dz = cz - ccz;
    F0[0 * MM + idx] = angle3(cnx, cny, cnz, dx, dy, dz);
    F0[1 * MM + idx] = angle3(nx, ny, nz, dx, dy, dz);
    F0[2 * MM + idx] = angle3(cnx, cny, cnz, nx, ny, nz);
    F0[3 * MM + idx] = sqrtf(dx * dx + dy * dy + dz * dz);
    float dot = dx * ex + dy * ey + dz * ez;
    float px = dx - dot * cnx;
    float py = dy - dot * cny;
    float pz = dz - dot * cnz;
    PQ[idx] = make_float4(px, py, pz, sqrtf(px * px + py * py + pz * pz));
}

// ---------------------------------------------------------------------------
// per-row median. ONE row per wave; key loop chunked 4x8 with compiler
// barriers to cap in-flight float4 loads at 8 (VGPR ~90 -> 5 waves/SIMD,
// vs 128 -> 4; R14 showed the select chain is latency-bound at occ 17%).
// Hybrid per-bit counting (scalar ballot half + VALU DPP half), 17-bit
// greedy MSB select, midpoint reconstruction.
// ---------------------------------------------------------------------------
__global__ __launch_bounds__(256) void alpha_k(const float4* __restrict__ PQ,
                                               float* __restrict__ F0) {
    int row = blockIdx.x * 4 + (threadIdx.x >> 6);
    int lane = threadIdx.x & 63;
    int b = row >> 11;
    const float4* base = PQ + (size_t)b * NN;
    float4 a = base[row & (NN - 1)];
    unsigned u[32];
    #pragma unroll
    for (int c = 0; c < 4; ++c) {
        #pragma unroll
        for (int j = 0; j < 8; ++j) {
            int s2 = c * 8 + j;
            float4 bv = base[s2 * 64 + lane];
            float cx = a.y * bv.z - a.z * bv.y;
            float cy = a.z * bv.x - a.x * bv.z;
            float cz = a.x * bv.y - a.y * bv.x;
            float ss = cx * cx + cy * cy + cz * cz;
            float dc = a.x * bv.x + a.y * bv.y + a.z * bv.z;
            float den = dc + a.w * bv.w;
            float rc = __builtin_amdgcn_rcpf(den);
            float key = ss * rc * rc;
            u[s2] = (key <= 2.5e-11f) ? 0x7F800000u : __float_as_uint(key);
        }
        asm volatile("" ::: "memory");
    }
    unsigned T = 0u;
    for (int bit = 30; bit >= 14; --bit) {
        unsigned c = T | (1u << bit);
        int s0 = 0, s1 = 0;
        #pragma unroll
        for (int q = 0; q < 8; ++q) {
            s0 += (int)__popcll(__ballot(u[16 + q] < c));
            s1 += (int)__popcll(__ballot(u[24 + q] < c));
        }
        int v0 = 0, v1 = 0, v2 = 0, v3 = 0;
        #pragma unroll
        for (int q = 0; q < 4; ++q) {
            v0 += (int)(u[q] < c);
            v1 += (int)(u[4 + q] < c);
            v2 += (int)(u[8 + q] < c);
            v3 += (int)(u[12 + q] < c);
        }
        int vsum = wave_sum_dpp(v0 + v1 + v2 + v3);
        if (vsum + s0 + s1 <= 1023) T = c;
    }
    if (lane == 0)
        F0[4 * MM + row] = 2.0f * atanf(sqrtf(__uint_as_float(T + 8192u)));
}

// ---------------------------------------------------------------------------
// pf0 + fused BN stats: thread = (channel ol, row-group mg); F0 loads
// broadcast across lanes sharing a row; raw fp16 into XCb+16; stats -> sums.
// grid 16 blocks x 512 rows.
// ---------------------------------------------------------------------------
__global__ __launch_bounds__(256) void pf0s_k(const float* __restrict__ F0,
                                              const float* __restrict__ W,
                                              unsigned short* __restrict__ dst,
                                              float* __restrict__ sums) {
    __shared__ float ws[320];
    int t = threadIdx.x;
    for (int i = t; i < 320; i += 256) ws[i] = W[i];
    __syncthreads();
    int ol = t & 63, mg = t >> 6;
    int m0 = blockIdx.x * 512;
    float w0 = ws[ol * 5], w1 = ws[ol * 5 + 1], w2 = ws[ol * 5 + 2], w3 = ws[ol * 5 + 3], w4 = ws[ol * 5 + 4];
    float s = 0.f, q = 0.f;
    for (int i = 0; i < 128; ++i) {
        int m = m0 + i * 4 + mg;
        float y = w0 * F0[m] + w1 * F0[MM + m] + w2 * F0[2 * MM + m]
                + w3 * F0[3 * MM + m] + w4 * F0[4 * MM + m];
        dst[(size_t)m * LDC + ol] = f2h(y);
        s += y; q += y * y;
    }
    __shared__ float ls[4][64], lq[4][64];
    ls[mg][ol] = s; lq[mg][ol] = q;
    __syncthreads();
    if (mg == 0) {
        s = ls[0][ol] + ls[1][ol] + ls[2][ol] + ls[3][ol];
        q = lq[0][ol] + lq[1][ol] + lq[2][ol] + lq[3][ol];
        atomicAdd(&sums[ol], s);
        atomicAdd(&sums[1024 + ol], q);
    }
}

// ---------------------------------------------------------------------------
// fp16 MFMA GEMM BM=64 BO=128 with staging-normalization of X.
// TRANS: 0 none, 1 uniform (xs,xg,xb), 2 AB4 table (cls0).
// MODE: 1 raw fp16 out (yld) + stats [+DOMAX raw channel max]; 2 K-split partial.
// ---------------------------------------------------------------------------
template<int MODE, int TRANS, int DOMAX>
__global__ __launch_bounds__(256) void mgemm3_k(const unsigned short* __restrict__ X, int ldx,
                                                const unsigned short* __restrict__ W, int ldw,
                                                unsigned short* __restrict__ Yh, int yld, int Co, int K, int kchunk,
                                                float* __restrict__ sums,
                                                const float* __restrict__ xs, const float* __restrict__ xg,
                                                const float* __restrict__ xb,
                                                const float4* __restrict__ AB4,
                                                unsigned* __restrict__ maxbu) {
    __shared__ unsigned short As[64 * 32];
    __shared__ unsigned short Bs[128 * 32];
    __shared__ float4 ABl[352];
    int t = threadIdx.x;
    int mBase = blockIdx.x * 64;
    int oBase = blockIdx.y * 128;
    int k0c = blockIdx.z * kchunk;
    int k1c = k0c + kchunk; if (k1c > K) k1c = K;
    if (TRANS == 1) {
        float* abf = (float*)ABl;
        for (int i = t; i < K; i += 256) {
            float a, c; bncoef(xs, xg, xb, i, a, c);
            abf[2 * i] = a; abf[2 * i + 1] = c;
        }
    } else if (TRANS == 2) {
        for (int i = t; i < k1c - k0c; i += 256) ABl[i] = AB4[k0c + i];
    }
    int lane = t & 63, w = t >> 6;
    int warpM = (w & 1) * 32, warpO = (w >> 1) * 64;
    f32x4 acc[2][4];
    #pragma unroll
    for (int i = 0; i < 2; ++i)
        #pragma unroll
        for (int j = 0; j < 4; ++j) acc[i][j] = (f32x4){0.f, 0.f, 0.f, 0.f};
    int lr = t >> 2;
    int lc = (t & 3) * 8;
    const unsigned short* Xp = X + (size_t)(mBase + lr) * ldx + lc;
    const unsigned short* Wp0 = W + (size_t)(oBase + lr) * ldw + lc;
    const unsigned short* Wp1 = W + (size_t)(oBase + lr + 64) * ldw + lc;
    int ar0 = (warpM + (lane & 15)) * 32 + (lane >> 4) * 8;
    int br0 = (warpO + (lane & 15)) * 32 + (lane >> 4) * 8;
    uint4 xa = *(const uint4*)(Xp + k0c);
    uint4 wb0 = *(const uint4*)(Wp0 + k0c);
    uint4 wb1 = *(const uint4*)(Wp1 + k0c);
    for (int k = k0c; k < k1c; k += 32) {
        __syncthreads();
        uint4 xc = xa;
        if (TRANS == 1) {
            const float* abf = (const float*)ABl;
            unsigned short* p = (unsigned short*)&xc;
            int kb = k + lc;
            #pragma unroll
            for (int e = 0; e < 8; ++e)
                p[e] = f2h(fmaxf(abf[2 * (kb + e)] * h2f(p[e]) + abf[2 * (kb + e) + 1], 0.f));
        } else if (TRANS == 2) {
            unsigned short* p = (unsigned short*)&xc;
            int kb = k + lc - k0c;
            #pragma unroll
            for (int e = 0; e < 8; ++e) {
                float4 qd = ABl[kb + e];
                p[e] = f2h(fmaxf(qd.x * h2f(p[e]) + qd.y, qd.z));
            }
        }
        *(uint4*)&As[lr * 32 + lc] = xc;
        *(uint4*)&Bs[lr * 32 + lc] = wb0;
        *(uint4*)&Bs[(lr + 64) * 32 + lc] = wb1;
        if (k + 32 < k1c) {
            xa = *(const uint4*)(Xp + k + 32);
            wb0 = *(const uint4*)(Wp0 + k + 32);
            wb1 = *(const uint4*)(Wp1 + k + 32);
        }
        __syncthreads();
        half8 a0 = __builtin_bit_cast(half8, *(const uint4*)&As[ar0]);
        half8 a1 = __builtin_bit_cast(half8, *(const uint4*)&As[ar0 + 16 * 32]);
        half8 b0 = __builtin_bit_cast(half8, *(const uint4*)&Bs[br0]);
        half8 b1 = __builtin_bit_cast(half8, *(const uint4*)&Bs[br0 + 16 * 32]);
        half8 b2 = __builtin_bit_cast(half8, *(const uint4*)&Bs[br0 + 32 * 32]);
        half8 b3 = __builtin_bit_cast(half8, *(const uint4*)&Bs[br0 + 48 * 32]);
        acc[0][0] = __builtin_amdgcn_mfma_f32_16x16x32_f16(a0, b0, acc[0][0], 0, 0, 0);
        acc[0][1] = __builtin_amdgcn_mfma_f32_16x16x32_f16(a0, b1, acc[0][1], 0, 0, 0);
        acc[0][2] = __builtin_amdgcn_mfma_f32_16x16x32_f16(a0, b2, acc[0][2], 0, 0, 0);
        acc[0][3] = __builtin_amdgcn_mfma_f32_16x16x32_f16(a0, b3, acc[0][3], 0, 0, 0);
        acc[1][0] = __builtin_amdgcn_mfma_f32_16x16x32_f16(a1, b0, acc[1][0], 0, 0, 0);
        acc[1][1] = __builtin_amdgcn_mfma_f32_16x16x32_f16(a1, b1, acc[1][1], 0, 0, 0);
        acc[1][2] = __builtin_amdgcn_mfma_f32_16x16x32_f16(a1, b2, acc[1][2], 0, 0, 0);
        acc[1][3] = __builtin_amdgcn_mfma_f32_16x16x32_f16(a1, b3, acc[1][3], 0, 0, 0);
    }
    unsigned short* Yp = Yh + (MODE == 2 ? (size_t)blockIdx.z * MM * yld : 0);
    #pragma unroll
    for (int i = 0; i < 2; ++i)
        #pragma unroll
        for (int j = 0; j < 4; ++j) {
            int m0 = mBase + warpM + i * 16 + (lane >> 4) * 4;
            int o = oBase + warpO + j * 16 + (lane & 15);
            #pragma unroll
            for (int r = 0; r < 4; ++r)
                Yp[(size_t)(m0 + r) * yld + o] = f2h(acc[i][j][r]);
        }
    if (MODE == 1) {
        __syncthreads();
        float* ssum = (float*)As;
        unsigned* smax = (unsigned*)As + 128;
        float* ssq = (float*)Bs;
        if (t < 128) { ssum[t] = 0.f; ssq[t] = 0.f; if (DOMAX) smax[t] = FLIP_NEG_INF; }
        __syncthreads();
        #pragma unroll
        for (int j = 0; j < 4; ++j) {
            int oc = warpO + j * 16 + (lane & 15);
            float s = 0.f, q = 0.f, mx = -__builtin_inff();
            #pragma unroll
            for (int i = 0; i < 2; ++i)
                #pragma unroll
                for (int r = 0; r < 4; ++r) {
                    float v = acc[i][j][r];
                    s += v; q += v * v; mx = fmaxf(mx, v);
                }
            atomicAdd(&ssum[oc], s);
            atomicAdd(&ssq[oc], q);
            if (DOMAX) atomicMax(&smax[oc], fflip(mx));
        }
        __syncthreads();
        if (t < 128) {
            atomicAdd(&sums[oBase + t], ssum[t]);
            atomicAdd(&sums[1024 + oBase + t], ssq[t]);
            if (DOMAX) atomicMax(&maxbu[(mBase >> 11) * 1024 + oBase + t], smax[t]);
        }
    }
}

// ---------------------------------------------------------------------------
// fp16 MFMA GEMM BM=64 BO=64 with staging-normalization.
// MODE 1: raw fp16 out (yld) + stats. MODE 3: direct (b,50,n) out + bias.
// ---------------------------------------------------------------------------
template<int MODE, int TRANS>
__global__ __launch_bounds__(256) void mgemm64_k(const unsigned short* __restrict__ X, int ldx,
                                                 const unsigned short* __restrict__ W, int ldw,
                                                 void* __restrict__ Yv, int yld, int Co, int K,
                                                 float* __restrict__ sums,
                                                 const float* __restrict__ xs, const float* __restrict__ xg,
                                                 const float* __restrict__ xb) {
    __shared__ unsigned short As[64 * 32];
    __shared__ unsigned short Bs[64 * 32];
    __shared__ float ABl[512];
    int t = threadIdx.x;
    int mBase = blockIdx.x * 64;
    int oBase = blockIdx.y * 64;
    if (TRANS == 1) {
        for (int i = t; i < K; i += 256) {
            float a, c; bncoef(xs, xg, xb, i, a, c);
            ABl[2 * i] = a; ABl[2 * i + 1] = c;
        }
    }
    int lane = t & 63, w = t >> 6;
    int warpM = (w & 1) * 32, warpO = (w >> 1) * 32;
    f32x4 acc[2][2];
    #pragma unroll
    for (int i = 0; i < 2; ++i)
        #pragma unroll
        for (int j = 0; j < 2; ++j) acc[i][j] = (f32x4){0.f, 0.f, 0.f, 0.f};
    int lr = t >> 2;
    int lc = (t & 3) * 8;
    const unsigned short* Xp = X + (size_t)(mBase + lr) * ldx + lc;
    const unsigned short* Wp = W + (size_t)(oBase + lr) * ldw + lc;
    int ar0 = (warpM + (lane & 15)) * 32 + (lane >> 4) * 8;
    int br0 = (warpO + (lane & 15)) * 32 + (lane >> 4) * 8;
    uint4 xa = *(const uint4*)(Xp);
    uint4 wb = *(const uint4*)(Wp);
    for (int k = 0; k < K; k += 32) {
        __syncthreads();
        uint4 xc = xa;
        if (TRANS == 1) {
            unsigned short* p = (unsigned short*)&xc;
            int kb = k + lc;
            #pragma unroll
            for (int e = 0; e < 8; ++e)
                p[e] = f2h(fmaxf(ABl[2 * (kb + e)] * h2f(p[e]) + ABl[2 * (kb + e) + 1], 0.f));
        }
        *(uint4*)&As[lr * 32 + lc] = xc;
        *(uint4*)&Bs[lr * 32 + lc] = wb;
        if (k + 32 < K) {
            xa = *(const uint4*)(Xp + k + 32);
            wb = *(const uint4*)(Wp + k + 32);
        }
        __syncthreads();
        half8 a0 = __builtin_bit_cast(half8, *(const uint4*)&As[ar0]);
        half8 a1 = __builtin_bit_cast(half8, *(const uint4*)&As[ar0 + 16 * 32]);
        half8 b0 = __builtin_bit_cast(half8, *(const uint4*)&Bs[br0]);
        half8 b1 = __builtin_bit_cast(half8, *(const uint4*)&Bs[br0 + 16 * 32]);
        acc[0][0] = __builtin_amdgcn_mfma_f32_16x16x32_f16(a0, b0, acc[0][0], 0, 0, 0);
        acc[0][1] = __builtin_amdgcn_mfma_f32_16x16x32_f16(a0, b1, acc[0][1], 0, 0, 0);
        acc[1][0] = __builtin_amdgcn_mfma_f32_16x16x32_f16(a1, b0, acc[1][0], 0, 0, 0);
        acc[1][1] = __builtin_amdgcn_mfma_f32_16x16x32_f16(a1, b1, acc[1][1], 0, 0, 0);
    }
    if (MODE == 3) {
        float* outp = (float*)Yv;
        #pragma unroll
        for (int i = 0; i < 2; ++i)
            #pragma unroll
            for (int j = 0; j < 2; ++j) {
                int m0 = mBase + warpM + i * 16 + (lane >> 4) * 4;
                int o = oBase + warpO + j * 16 + (lane & 15);
                if (o < 50) {
                    int bb2 = m0 >> 11, n = m0 & (NN - 1);
                    float bi = sums[o];
                    float4 v = make_float4(acc[i][j][0] + bi, acc[i][j][1] + bi,
                                           acc[i][j][2] + bi, acc[i][j][3] + bi);
                    *(float4*)&outp[((size_t)bb2 * 50 + o) * NN + n] = v;
                }
            }
    } else {
        unsigned short* Yh = (unsigned short*)Yv;
        #pragma unroll
        for (int i = 0; i < 2; ++i)
            #pragma unroll
            for (int j = 0; j < 2; ++j) {
                int m0 = mBase + warpM + i * 16 + (lane >> 4) * 4;
                int o = oBase + warpO + j * 16 + (lane & 15);
                #pragma unroll
                for (int r = 0; r < 4; ++r)
                    Yh[(size_t)(m0 + r) * yld + o] = f2h(acc[i][j][r]);
            }
        __syncthreads();
        float* ssum = (float*)As;
        float* ssq = (float*)Bs;
        if (t < 64) { ssum[t] = 0.f; ssq[t] = 0.f; }
        __syncthreads();
        #pragma unroll
        for (int j = 0; j < 2; ++j) {
            int oc = warpO + j * 16 + (lane & 15);
            float s = 0.f, q = 0.f;
            #pragma unroll
            for (int i = 0; i < 2; ++i)
                #pragma unroll
                for (int r = 0; r < 4; ++r) { float v = acc[i][j][r]; s += v; q += v * v; }
            atomicAdd(&ssum[oc], s);
            atomicAdd(&ssq[oc], q);
        }
        __syncthreads();
        if (t < 64) {
            atomicAdd(&sums[oBase + t], ssum[t]);
            atomicAdd(&sums[1024 + oBase + t], ssq[t]);
        }
    }
}

// ---------------------------------------------------------------------------
// build cls0 coefficient table AB4[1376] + normalized pf3 maxes NMAXB[4][1024]
// ---------------------------------------------------------------------------
__global__ __launch_bounds__(256) void abbuild_k(const float* __restrict__ SUMS,
                                                 const unsigned* __restrict__ MAXBu,
                                                 float4* __restrict__ AB4,
                                                 float* __restrict__ NMAXB,
                                                 const float* g0, const float* b0,
                                                 const float* g1, const float* b1,
                                                 const float* g2, const float* b2,
                                                 const float* g3, const float* b3) {
    int blk = blockIdx.x, t = threadIdx.x;
    if (blk < 6) {
        int ch = blk * 256 + t;
        if (ch >= 1376) return;
        float4 r;
        if (ch < 16) r = make_float4(1.f, 0.f, -__builtin_inff(), 0.f);
        else if (ch < 80) { float a, c; bncoef(SUMS, g0, b0, ch - 16, a, c); r = make_float4(a, c, 0.f, 0.f); }
        else if (ch < 208) { float a, c; bncoef(SUMS + 2048, g1, b1, ch - 80, a, c); r = make_float4(a, c, 0.f, 0.f); }
        else if (ch < 336) { float a, c; bncoef(SUMS + 4096, g2, b2, ch - 208, a, c); r = make_float4(a, c, 0.f, 0.f); }
        else if (ch < 1360) { float a, c; bncoef(SUMS + 6144, g3, b3, ch - 336, a, c); r = make_float4(a, c, 0.f, 0.f); }
        else r = make_float4(0.f, 0.f, 0.f, 0.f);
        AB4[ch] = r;
    } else {
        int idx = (blk - 6) * 256 + t;
        int c = idx & 1023;
        float a, cc; bncoef(SUMS + 6144, g3, b3, c, a, cc);
        float raw = funflip(MAXBu[idx]);
        NMAXB[idx] = fmaxf(a * raw + cc, 0.f);
    }
}

// ---------------------------------------------------------------------------
// max-feature GEMV: contrib[b][o] = sum_c Wmax[c][o] * nmax[b][c]
// ---------------------------------------------------------------------------
__global__ __launch_bounds__(256) void gemv_k(const unsigned short* __restrict__ Wmax,
                                              const float* __restrict__ nmax,
                                              float* __restrict__ contrib) {
    int b = blockIdx.x >> 3;
    int cc = (blockIdx.x & 7) * 128;
    int o = threadIdx.x;
    const float* mv = nmax + b * 1024 + cc;
    float acc = 0.f;
    for (int c = 0; c < 128; ++c)
        acc += h2f(Wmax[(size_t)(cc + c) * 256 + o]) * mv[c];
    atomicAdd(&contrib[b * 256 + o], acc);
}

// ---------------------------------------------------------------------------
// cls0 finish: sum 4 fp16 K-split partials + contrib -> raw fp16 partial0 + stats
// ---------------------------------------------------------------------------
__global__ __launch_bounds__(256) void red4stat_k(unsigned short* __restrict__ Yh,
                                                  const float* __restrict__ contrib,
                                                  float* __restrict__ sums) {
    int o0 = blockIdx.x * 64;
    int m0 = blockIdx.y * 128;
    int t = threadIdx.x, ol = t & 63, mg = t >> 6;
    int b = m0 >> 11;
    float cb = contrib[b * 256 + o0 + ol];
    const size_t stride = (size_t)MM * 256;
    float s = 0.f, q = 0.f;
    unsigned short* p = Yh + (size_t)(m0 + mg) * 256 + o0 + ol;
    for (int i = 0; i < 32; ++i) {
        unsigned short* pp = p + (size_t)i * 4 * 256;
        float v = h2f(pp[0]) + h2f(pp[stride]) + h2f(pp[2 * stride]) + h2f(pp[3 * stride]) + cb;
        pp[0] = f2h(v);
        s += v; q += v * v;
    }
    __shared__ float ls[4][64], lq[4][64];
    ls[mg][ol] = s; lq[mg][ol] = q;
    __syncthreads();
    if (mg == 0) {
        s = ls[0][ol] + ls[1][ol] + ls[2][ol] + ls[3][ol];
        q = lq[0][ol] + lq[1][ol] + lq[2][ol] + lq[3][ol];
        atomicAdd(&sums[o0 + ol], s);
        atomicAdd(&sums[1024 + o0 + ol], q);
    }
}

// ---------------------------------------------------------------------------
extern "C" void kernel_launch(void* const* d_in, const int* in_sizes, int n_in,
                              void* d_out, int out_size, void* d_ws, size_t ws_size,
                              hipStream_t stream) {
    const float* in = (const float*)d_in[0];
    const float* pf0_w = (const float*)d_in[1];
    const float* pf_g[4] = {(const float*)d_in[2], (const float*)d_in[5], (const float*)d_in[8], (const float*)d_in[11]};
    const float* pf_b[4] = {(const float*)d_in[3], (const float*)d_in[6], (const float*)d_in[9], (const float*)d_in[12]};
    const float* pf_w[4] = {(const float*)d_in[1], (const float*)d_in[4], (const float*)d_in[7], (const float*)d_in[10]};
    const float* cls_w[3] = {(const float*)d_in[13], (const float*)d_in[16], (const float*)d_in[19]};
    const float* cls_g[3] = {(const float*)d_in[14], (const float*)d_in[17], (const float*)d_in[20]};
    const float* cls_b[3] = {(const float*)d_in[15], (const float*)d_in[18], (const float*)d_in[21]};
    const float* cls3_w = (const float*)d_in[22];
    const float* cls3_bias = (const float*)d_in[23];
    float* out = (float*)d_out;

    char* wsb = (char*)d_ws;
    float* ST = (float*)(wsb + 0);
    float4* PQ = (float4*)(wsb + 256);
    float* F0 = (float*)(wsb + 131328);
    float* SUMS = (float*)(wsb + 295168);
    unsigned* MAXBu = (unsigned*)(wsb + 352512);
    float* CONTRIB = (float*)(wsb + 368896);
    float4* AB4 = (float4*)(wsb + 372992);
    float* NMAXB = (float*)(wsb + 395008);
    unsigned short* WB = (unsigned short*)(wsb + 411392);
    unsigned short* XCb = (unsigned short*)(wsb + 2180864);
    unsigned short* C1b = (unsigned short*)(wsb + 24725248);
    unsigned short* C2b = (unsigned short*)(wsb + 28919552);
    unsigned short* Yh = (unsigned short*)(wsb + 33113856);

    auto SL = [&](int s) { return SUMS + (size_t)s * 2048; };

    prep_k<<<976, 256, 0, stream>>>(in, pf_w[1], pf_w[2], pf_w[3], cls_w[0], cls_w[1], cls_w[2], cls3_w,
                                    WB, ST, (unsigned*)SUMS, XCb);
    point_k<<<MM / 256, 256, 0, stream>>>(in, ST, PQ, F0);
    alpha_k<<<MM / 4, 256, 0, stream>>>(PQ, F0);

    // pf0 raw -> XCb+16 with fused stats SL(0)
    pf0s_k<<<16, 256, 0, stream>>>(F0, pf0_w, XCb + 16, SL(0));
    // pf1: stage-norm SL(0); raw -> XCb+80; stats SL(1)
    mgemm64_k<1, 1><<<dim3(128, 2), 256, 0, stream>>>(XCb + 16, LDC, WB, 64, XCb + 80, LDC, 128, 64,
                                                      SL(1), SL(0), pf_g[0], pf_b[0]);
    // pf2: stage-norm SL(1); raw -> XCb+208; stats SL(2)
    mgemm64_k<1, 1><<<dim3(128, 2), 256, 0, stream>>>(XCb + 80, LDC, WB + 8192, 128, XCb + 208, LDC, 128, 128,
                                                      SL(2), SL(1), pf_g[1], pf_b[1]);
    // pf3: stage-norm SL(2); raw -> XCb+336; stats SL(3) + raw channel max
    mgemm3_k<1, 1, 1><<<dim3(128, 8, 1), 256, 0, stream>>>(XCb + 208, LDC, WB + 24576, 128, XCb + 336, LDC,
                                                           1024, 128, 128, SL(3), SL(2), pf_g[2], pf_b[2],
                                                           AB4, MAXBu);
    // coefficient table + normalized maxes
    abbuild_k<<<22, 256, 0, stream>>>(SUMS, MAXBu, AB4, NMAXB,
                                      pf_g[0], pf_b[0], pf_g[1], pf_b[1], pf_g[2], pf_b[2], pf_g[3], pf_b[3]);
    gemv_k<<<32, 256, 0, stream>>>(WB + 614400, NMAXB, CONTRIB);
    // cls0: stage-norm via AB4; K-split x4 raw fp16 partials
    mgemm3_k<2, 2, 0><<<dim3(128, 2, 4), 256, 0, stream>>>(XCb, LDC, WB + 155648, 1376, Yh, 256,
                                                           256, 1376, 352, SL(4), nullptr, nullptr, nullptr,
                                                           AB4, MAXBu);
    red4stat_k<<<dim3(4, 64), 256, 0, stream>>>(Yh, CONTRIB, SL(4));
    // cls1: stage-norm SL(4); raw -> C1b; stats SL(5)
    mgemm64_k<1, 1><<<dim3(128, 4), 256, 0, stream>>>(Yh, 256, WB + 507904, 256, C1b, 256, 256, 256,
                                                      SL(5), SL(4), cls_g[0], cls_b[0]);
    // cls2: stage-norm SL(5); raw -> C2b; stats SL(6)
    mgemm64_k<1, 1><<<dim3(128, 2), 256, 0, stream>>>(C1b, 256, WB + 507904 + 65536, 256, C2b, 128, 128, 256,
                                                      SL(6), SL(5), cls_g[1], cls_b[1]);
    // cls3: stage-norm SL(6); direct (b,50,n) output + bias
    mgemm64_k<3, 1><<<dim3(128, 1), 256, 0, stream>>>(C2b, 128, WB + 606208, 128, (void*)out, 0, 64, 128,
                                                      (float*)cls3_bias, SL(6), cls_g[2], cls_b[2]);

    (void)in_sizes; (void)n_in; (void)out_size; (void)ws_size;
}

// Round 16
// 178.597 us; speedup vs baseline: 1.6187x; 1.0074x over previous
//
#include <hip/hip_runtime.h>
#include <math.h>

#define BB 4
#define NN 2048
#define MM 8192
#define EPSF 1e-5f
#define LDC 1376   // concat stride: onehot16 | pf0 64 | pf1 128 | pf2 128 | pf3 1024 | pad16

typedef _Float16 half8 __attribute__((ext_vector_type(8)));
typedef float f32x4 __attribute__((ext_vector_type(4)));

__device__ __forceinline__ unsigned short f2h(float x) {
    _Float16 h = (_Float16)x;
    return __builtin_bit_cast(unsigned short, h);
}
__device__ __forceinline__ float h2f(unsigned short u) {
    return (float)__builtin_bit_cast(_Float16, u);
}
// order-preserving float<->unsigned for atomicMax over signed floats
__device__ __forceinline__ unsigned fflip(float x) {
    unsigned u = __builtin_bit_cast(unsigned, x);
    return (u >> 31) ? ~u : (u | 0x80000000u);
}
__device__ __forceinline__ float funflip(unsigned s) {
    unsigned u = (s >> 31) ? (s ^ 0x80000000u) : ~s;
    return __builtin_bit_cast(float, u);
}
#define FLIP_NEG_INF 0x007FFFFFu

__device__ __forceinline__ int wave_sum_dpp(int v) {
    v += __builtin_amdgcn_update_dpp(0, v, 0x111, 0xF, 0xF, true);
    v += __builtin_amdgcn_update_dpp(0, v, 0x112, 0xF, 0xF, true);
    v += __builtin_amdgcn_update_dpp(0, v, 0x114, 0xF, 0xF, true);
    v += __builtin_amdgcn_update_dpp(0, v, 0x118, 0xF, 0xF, true);
    v += __builtin_amdgcn_update_dpp(0, v, 0x142, 0xa, 0xF, true);
    v += __builtin_amdgcn_update_dpp(0, v, 0x143, 0xc, 0xF, true);
    return __builtin_amdgcn_readlane(v, 63);
}

__device__ __forceinline__ float angle3(float ux, float uy, float uz,
                                        float vx, float vy, float vz) {
    float crx = uy * vz - uz * vy;
    float cry = uz * vx - ux * vz;
    float crz = ux * vy - uy * vx;
    float s = sqrtf(crx * crx + cry * cry + crz * crz);
    float c = ux * vx + uy * vy + uz * vz;
    return atan2f(s, c);
}

// BN coefficient from a sums slice
__device__ __forceinline__ void bncoef(const float* __restrict__ sums,
                                       const float* __restrict__ g,
                                       const float* __restrict__ bb,
                                       int o, float& a, float& c) {
    float mu = sums[o] * (1.f / 8192.f);
    float var = sums[1024 + o] * (1.f / 8192.f) - mu * mu;
    var = fmaxf(var, 0.f);
    a = g[o] * (1.0f / sqrtf(var + EPSF));
    c = bb[o] - mu * a;
}

// ---------------------------------------------------------------------------
// fused preamble: wconv x4 (0..863) | stats (864..867) | init SUMS/MAXB/CONTRIB
// (868..943; MAXB gets flip(-inf)) | onehot+pad (944..975)
// ---------------------------------------------------------------------------
__global__ __launch_bounds__(256) void prep_k(const float* __restrict__ in,
                                              const float* __restrict__ w1, const float* __restrict__ w2,
                                              const float* __restrict__ w3, const float* __restrict__ w4,
                                              const float* __restrict__ w5, const float* __restrict__ w6,
                                              const float* __restrict__ w7,
                                              unsigned short* __restrict__ Wb,
                                              float* __restrict__ st,
                                              unsigned* __restrict__ zp,
                                              unsigned short* __restrict__ XCb) {
    int blk = blockIdx.x;
    int t = threadIdx.x;
    if (blk < 864) {
        int idx0 = blk * 1024 + t * 4;
        ushort4 r;
        unsigned short* rp = (unsigned short*)&r;
        #pragma unroll
        for (int e = 0; e < 4; ++e) {
            int idx = idx0 + e;
            unsigned short v;
            if (idx < 8192) v = f2h(w1[idx]);
            else if (idx < 24576) v = f2h(w2[idx - 8192]);
            else if (idx < 155648) v = f2h(w3[idx - 24576]);
            else if (idx < 507904) {
                int l = idx - 155648;
                int o = l / 1376, k = l - o * 1376;
                v = (k < 1360) ? f2h(w4[o * 2384 + k]) : (unsigned short)0;
            } else if (idx < 573440) v = f2h(w5[idx - 507904]);
            else if (idx < 606208) v = f2h(w6[idx - 573440]);
            else if (idx < 614400) {
                int l = idx - 606208;
                int o = l >> 7, k = l & 127;
                v = (o < 50) ? f2h(w7[o * 128 + k]) : (unsigned short)0;
            } else {
                int l = idx - 614400;
                int c = l >> 8, o = l & 255;
                v = (c < 1024) ? f2h(w4[o * 2384 + 1360 + c]) : (unsigned short)0;
            }
            rp[e] = v;
        }
        *(ushort4*)&Wb[idx0] = r;
    } else if (blk < 868) {
        int b = blk - 864;
        const float* base = in + (size_t)b * 22 * NN;
        float cs0 = 0.f, cs1 = 0.f, cs2 = 0.f, ns0 = 0.f, ns1 = 0.f, ns2 = 0.f;
        for (int n = t; n < NN; n += 256) {
            float cx = base[0 * NN + n], cy = base[1 * NN + n], cz = base[2 * NN + n];
            float nx = base[3 * NN + n], ny = base[4 * NN + n], nz = base[5 * NN + n];
            float inv = 1.0f / sqrtf(nx * nx + ny * ny + nz * nz);
            cs0 += cx; cs1 += cy; cs2 += cz;
            ns0 += nx * inv; ns1 += ny * inv; ns2 += nz * inv;
        }
        __shared__ float red[6][256];
        red[0][t] = cs0; red[1][t] = cs1; red[2][t] = cs2;
        red[3][t] = ns0; red[4][t] = ns1; red[5][t] = ns2;
        __syncthreads();
        for (int s = 128; s > 0; s >>= 1) {
            if (t < s) {
                #pragma unroll
                for (int i = 0; i < 6; ++i) red[i][t] += red[i][t + s];
            }
            __syncthreads();
        }
        if (t == 0) {
            float ccx = red[0][0] / (float)NN, ccy = red[1][0] / (float)NN, ccz = red[2][0] / (float)NN;
            float cnx = red[3][0] / (float)NN, cny = red[4][0] / (float)NN, cnz = red[5][0] / (float)NN;
            float inv = 1.0f / sqrtf(cnx * cnx + cny * cny + cnz * cnz);
            float* s9 = st + b * 16;
            s9[0] = ccx; s9[1] = ccy; s9[2] = ccz;
            s9[3] = cnx; s9[4] = cny; s9[5] = cnz;
            s9[6] = cnx * inv; s9[7] = cny * inv; s9[8] = cnz * inv;
        }
    } else if (blk < 944) {
        int idx = (blk - 868) * 256 + t;
        zp[idx] = (idx >= 14336 && idx < 18432) ? FLIP_NEG_INF : 0u;
    } else {
        int m = (blk - 944) * 256 + t;
        int b = m >> 11, n = m & (NN - 1);
        const float* src = in + (size_t)b * 22 * NN + 6 * NN + n;
        unsigned short vals[16];
        #pragma unroll
        for (int r = 0; r < 16; ++r) vals[r] = f2h(src[(size_t)r * NN]);
        ushort4* dst = (ushort4*)&XCb[(size_t)m * LDC];
        #pragma unroll
        for (int q = 0; q < 4; ++q)
            dst[q] = make_ushort4(vals[4 * q], vals[4 * q + 1], vals[4 * q + 2], vals[4 * q + 3]);
        ushort4 z = make_ushort4(0, 0, 0, 0);
        ushort4* pz = (ushort4*)&XCb[(size_t)m * LDC + 1360];
        pz[0] = z; pz[1] = z; pz[2] = z; pz[3] = z;
    }
}

// ---------------------------------------------------------------------------
// per-point PPF + packed projected vectors PQ = (x,y,z,|P|)
// ---------------------------------------------------------------------------
__global__ __launch_bounds__(256) void point_k(const float* __restrict__ in,
                                               const float* __restrict__ st,
                                               float4* __restrict__ PQ,
                                               float* __restrict__ F0) {
    int idx = blockIdx.x * 256 + threadIdx.x;
    int b = idx >> 11, n = idx & (NN - 1);
    const float* base = in + (size_t)b * 22 * NN;
    const float* s9 = st + b * 16;
    float cx = base[0 * NN + n], cy = base[1 * NN + n], cz = base[2 * NN + n];
    float nx = base[3 * NN + n], ny = base[4 * NN + n], nz = base[5 * NN + n];
    float inv = 1.0f / sqrtf(nx * nx + ny * ny + nz * nz);
    nx *= inv; ny *= inv; nz *= inv;
    float ccx = s9[0], ccy = s9[1], ccz = s9[2];
    float cnx = s9[3], cny = s9[4], cnz = s9[5];
    float ex = s9[6], ey = s9[7], ez = s9[8];
    float dx = cx - ccx, dy = cy - ccy, dz = cz - ccz;
    F0[0 * MM + idx] = angle3(cnx, cny, cnz, dx, dy, dz);
    F0[1 * MM + idx] = angle3(nx, ny, nz, dx, dy, dz);
    F0[2 * MM + idx] = angle3(cnx, cny, cnz, nx, ny, nz);
    F0[3 * MM + idx] = sqrtf(dx * dx + dy * dy + dz * dz);
    float dot = dx * ex + dy * ey + dz * ez;
    float px = dx - dot * cnx;
    float py = dy - dot * cny;
    float pz = dz - dot * cnz;
    PQ[idx] = make_float4(px, py, pz, sqrtf(px * px + py * py + pz * pz));
}

// ---------------------------------------------------------------------------
// per-row median. ONE row per wave; keys packed as fp16 PAIRS (u[16], f2h is
// monotone so rank-select on the fp16 grid is exact) -> VGPR ~70 vs 128,
// occupancy 4 -> ~6-7 waves/SIMD (R15: select chain latency-bound at 17%).
// 15-bit greedy MSB select over packed halves; hybrid scalar/VALU counting;
// midpoint reconstruction (half-ulp).
// ---------------------------------------------------------------------------
__global__ __launch_bounds__(256) void alpha_k(const float4* __restrict__ PQ,
                                               float* __restrict__ F0) {
    int row = blockIdx.x * 4 + (threadIdx.x >> 6);
    int lane = threadIdx.x & 63;
    int b = row >> 11;
    const float4* base = PQ + (size_t)b * NN;
    float4 a = base[row & (NN - 1)];
    unsigned u[16];
    #pragma unroll
    for (int c = 0; c < 4; ++c) {
        #pragma unroll
        for (int j = 0; j < 4; ++j) {
            int s2 = c * 8 + j * 2;
            float4 bv0 = base[s2 * 64 + lane];
            float4 bv1 = base[(s2 + 1) * 64 + lane];
            float k0, k1;
            {
                float cx = a.y * bv0.z - a.z * bv0.y;
                float cy = a.z * bv0.x - a.x * bv0.z;
                float cz = a.x * bv0.y - a.y * bv0.x;
                float ss = cx * cx + cy * cy + cz * cz;
                float dc = a.x * bv0.x + a.y * bv0.y + a.z * bv0.z;
                float den = dc + a.w * bv0.w;
                float rc = __builtin_amdgcn_rcpf(den);
                k0 = ss * rc * rc;
                if (k0 <= 2.5e-11f) k0 = __builtin_inff();
            }
            {
                float cx = a.y * bv1.z - a.z * bv1.y;
                float cy = a.z * bv1.x - a.x * bv1.z;
                float cz = a.x * bv1.y - a.y * bv1.x;
                float ss = cx * cx + cy * cy + cz * cz;
                float dc = a.x * bv1.x + a.y * bv1.y + a.z * bv1.z;
                float den = dc + a.w * bv1.w;
                float rc = __builtin_amdgcn_rcpf(den);
                k1 = ss * rc * rc;
                if (k1 <= 2.5e-11f) k1 = __builtin_inff();
            }
            u[c * 4 + j] = (unsigned)f2h(k0) | ((unsigned)f2h(k1) << 16);
        }
        asm volatile("" ::: "memory");
    }
    unsigned T = 0u;
    for (int bit = 14; bit >= 0; --bit) {
        unsigned c = T | (1u << bit);
        int s0 = 0, s1 = 0;
        #pragma unroll
        for (int q = 0; q < 8; ++q) {
            s0 += (int)__popcll(__ballot((u[8 + q] & 0xFFFFu) < c));
            s1 += (int)__popcll(__ballot((u[8 + q] >> 16) < c));
        }
        int v0 = 0, v1 = 0;
        #pragma unroll
        for (int q = 0; q < 8; ++q) {
            v0 += (int)((u[q] & 0xFFFFu) < c);
            v1 += (int)((u[q] >> 16) < c);
        }
        int vsum = wave_sum_dpp(v0 + v1);
        if (vsum + s0 + s1 <= 1023) T = c;
    }
    if (lane == 0) {
        float lo = h2f((unsigned short)T);
        float hi = h2f((unsigned short)(T + 1));
        F0[4 * MM + row] = 2.0f * atanf(sqrtf(0.5f * (lo + hi)));
    }
}

// ---------------------------------------------------------------------------
// pf0 + fused BN stats: raw fp16 into XCb+16; stats -> sums.
// ---------------------------------------------------------------------------
__global__ __launch_bounds__(256) void pf0s_k(const float* __restrict__ F0,
                                              const float* __restrict__ W,
                                              unsigned short* __restrict__ dst,
                                              float* __restrict__ sums) {
    __shared__ float ws[320];
    int t = threadIdx.x;
    for (int i = t; i < 320; i += 256) ws[i] = W[i];
    __syncthreads();
    int ol = t & 63, mg = t >> 6;
    int m0 = blockIdx.x * 512;
    float w0 = ws[ol * 5], w1 = ws[ol * 5 + 1], w2 = ws[ol * 5 + 2], w3 = ws[ol * 5 + 3], w4 = ws[ol * 5 + 4];
    float s = 0.f, q = 0.f;
    for (int i = 0; i < 128; ++i) {
        int m = m0 + i * 4 + mg;
        float y = w0 * F0[m] + w1 * F0[MM + m] + w2 * F0[2 * MM + m]
                + w3 * F0[3 * MM + m] + w4 * F0[4 * MM + m];
        dst[(size_t)m * LDC + ol] = f2h(y);
        s += y; q += y * y;
    }
    __shared__ float ls[4][64], lq[4][64];
    ls[mg][ol] = s; lq[mg][ol] = q;
    __syncthreads();
    if (mg == 0) {
        s = ls[0][ol] + ls[1][ol] + ls[2][ol] + ls[3][ol];
        q = lq[0][ol] + lq[1][ol] + lq[2][ol] + lq[3][ol];
        atomicAdd(&sums[ol], s);
        atomicAdd(&sums[1024 + ol], q);
    }
}

// ---------------------------------------------------------------------------
// fp16 MFMA GEMM BM=64 BO=128 with staging-normalization of X.
// TRANS: 0 none, 1 uniform (xs,xg,xb), 2 AB4 table (cls0).
// MODE: 1 raw fp16 out (yld) + stats [+DOMAX raw channel max]; 2 K-split partial.
// ---------------------------------------------------------------------------
template<int MODE, int TRANS, int DOMAX>
__global__ __launch_bounds__(256) void mgemm3_k(const unsigned short* __restrict__ X, int ldx,
                                                const unsigned short* __restrict__ W, int ldw,
                                                unsigned short* __restrict__ Yh, int yld, int Co, int K, int kchunk,
                                                float* __restrict__ sums,
                                                const float* __restrict__ xs, const float* __restrict__ xg,
                                                const float* __restrict__ xb,
                                                const float4* __restrict__ AB4,
                                                unsigned* __restrict__ maxbu) {
    __shared__ unsigned short As[64 * 32];
    __shared__ unsigned short Bs[128 * 32];
    __shared__ float4 ABl[352];
    int t = threadIdx.x;
    int mBase = blockIdx.x * 64;
    int oBase = blockIdx.y * 128;
    int k0c = blockIdx.z * kchunk;
    int k1c = k0c + kchunk; if (k1c > K) k1c = K;
    if (TRANS == 1) {
        float* abf = (float*)ABl;
        for (int i = t; i < K; i += 256) {
            float a, c; bncoef(xs, xg, xb, i, a, c);
            abf[2 * i] = a; abf[2 * i + 1] = c;
        }
    } else if (TRANS == 2) {
        for (int i = t; i < k1c - k0c; i += 256) ABl[i] = AB4[k0c + i];
    }
    int lane = t & 63, w = t >> 6;
    int warpM = (w & 1) * 32, warpO = (w >> 1) * 64;
    f32x4 acc[2][4];
    #pragma unroll
    for (int i = 0; i < 2; ++i)
        #pragma unroll
        for (int j = 0; j < 4; ++j) acc[i][j] = (f32x4){0.f, 0.f, 0.f, 0.f};
    int lr = t >> 2;
    int lc = (t & 3) * 8;
    const unsigned short* Xp = X + (size_t)(mBase + lr) * ldx + lc;
    const unsigned short* Wp0 = W + (size_t)(oBase + lr) * ldw + lc;
    const unsigned short* Wp1 = W + (size_t)(oBase + lr + 64) * ldw + lc;
    int ar0 = (warpM + (lane & 15)) * 32 + (lane >> 4) * 8;
    int br0 = (warpO + (lane & 15)) * 32 + (lane >> 4) * 8;
    uint4 xa = *(const uint4*)(Xp + k0c);
    uint4 wb0 = *(const uint4*)(Wp0 + k0c);
    uint4 wb1 = *(const uint4*)(Wp1 + k0c);
    for (int k = k0c; k < k1c; k += 32) {
        __syncthreads();
        uint4 xc = xa;
        if (TRANS == 1) {
            const float* abf = (const float*)ABl;
            unsigned short* p = (unsigned short*)&xc;
            int kb = k + lc;
            #pragma unroll
            for (int e = 0; e < 8; ++e)
                p[e] = f2h(fmaxf(abf[2 * (kb + e)] * h2f(p[e]) + abf[2 * (kb + e) + 1], 0.f));
        } else if (TRANS == 2) {
            unsigned short* p = (unsigned short*)&xc;
            int kb = k + lc - k0c;
            #pragma unroll
            for (int e = 0; e < 8; ++e) {
                float4 qd = ABl[kb + e];
                p[e] = f2h(fmaxf(qd.x * h2f(p[e]) + qd.y, qd.z));
            }
        }
        *(uint4*)&As[lr * 32 + lc] = xc;
        *(uint4*)&Bs[lr * 32 + lc] = wb0;
        *(uint4*)&Bs[(lr + 64) * 32 + lc] = wb1;
        if (k + 32 < k1c) {
            xa = *(const uint4*)(Xp + k + 32);
            wb0 = *(const uint4*)(Wp0 + k + 32);
            wb1 = *(const uint4*)(Wp1 + k + 32);
        }
        __syncthreads();
        half8 a0 = __builtin_bit_cast(half8, *(const uint4*)&As[ar0]);
        half8 a1 = __builtin_bit_cast(half8, *(const uint4*)&As[ar0 + 16 * 32]);
        half8 b0 = __builtin_bit_cast(half8, *(const uint4*)&Bs[br0]);
        half8 b1 = __builtin_bit_cast(half8, *(const uint4*)&Bs[br0 + 16 * 32]);
        half8 b2 = __builtin_bit_cast(half8, *(const uint4*)&Bs[br0 + 32 * 32]);
        half8 b3 = __builtin_bit_cast(half8, *(const uint4*)&Bs[br0 + 48 * 32]);
        acc[0][0] = __builtin_amdgcn_mfma_f32_16x16x32_f16(a0, b0, acc[0][0], 0, 0, 0);
        acc[0][1] = __builtin_amdgcn_mfma_f32_16x16x32_f16(a0, b1, acc[0][1], 0, 0, 0);
        acc[0][2] = __builtin_amdgcn_mfma_f32_16x16x32_f16(a0, b2, acc[0][2], 0, 0, 0);
        acc[0][3] = __builtin_amdgcn_mfma_f32_16x16x32_f16(a0, b3, acc[0][3], 0, 0, 0);
        acc[1][0] = __builtin_amdgcn_mfma_f32_16x16x32_f16(a1, b0, acc[1][0], 0, 0, 0);
        acc[1][1] = __builtin_amdgcn_mfma_f32_16x16x32_f16(a1, b1, acc[1][1], 0, 0, 0);
        acc[1][2] = __builtin_amdgcn_mfma_f32_16x16x32_f16(a1, b2, acc[1][2], 0, 0, 0);
        acc[1][3] = __builtin_amdgcn_mfma_f32_16x16x32_f16(a1, b3, acc[1][3], 0, 0, 0);
    }
    unsigned short* Yp = Yh + (MODE == 2 ? (size_t)blockIdx.z * MM * yld : 0);
    #pragma unroll
    for (int i = 0; i < 2; ++i)
        #pragma unroll
        for (int j = 0; j < 4; ++j) {
            int m0 = mBase + warpM + i * 16 + (lane >> 4) * 4;
            int o = oBase + warpO + j * 16 + (lane & 15);
            #pragma unroll
            for (int r = 0; r < 4; ++r)
                Yp[(size_t)(m0 + r) * yld + o] = f2h(acc[i][j][r]);
        }
    if (MODE == 1) {
        __syncthreads();
        float* ssum = (float*)As;
        unsigned* smax = (unsigned*)As + 128;
        float* ssq = (float*)Bs;
        if (t < 128) { ssum[t] = 0.f; ssq[t] = 0.f; if (DOMAX) smax[t] = FLIP_NEG_INF; }
        __syncthreads();
        #pragma unroll
        for (int j = 0; j < 4; ++j) {
            int oc = warpO + j * 16 + (lane & 15);
            float s = 0.f, q = 0.f, mx = -__builtin_inff();
            #pragma unroll
            for (int i = 0; i < 2; ++i)
                #pragma unroll
                for (int r = 0; r < 4; ++r) {
                    float v = acc[i][j][r];
                    s += v; q += v * v; mx = fmaxf(mx, v);
                }
            atomicAdd(&ssum[oc], s);
            atomicAdd(&ssq[oc], q);
            if (DOMAX) atomicMax(&smax[oc], fflip(mx));
        }
        __syncthreads();
        if (t < 128) {
            atomicAdd(&sums[oBase + t], ssum[t]);
            atomicAdd(&sums[1024 + oBase + t], ssq[t]);
            if (DOMAX) atomicMax(&maxbu[(mBase >> 11) * 1024 + oBase + t], smax[t]);
        }
    }
}

// ---------------------------------------------------------------------------
// fp16 MFMA GEMM BM=64 BO=64 with staging-normalization.
// MODE 1: raw fp16 out (yld) + stats. MODE 3: direct (b,50,n) out + bias.
// ---------------------------------------------------------------------------
template<int MODE, int TRANS>
__global__ __launch_bounds__(256) void mgemm64_k(const unsigned short* __restrict__ X, int ldx,
                                                 const unsigned short* __restrict__ W, int ldw,
                                                 void* __restrict__ Yv, int yld, int Co, int K,
                                                 float* __restrict__ sums,
                                                 const float* __restrict__ xs, const float* __restrict__ xg,
                                                 const float* __restrict__ xb) {
    __shared__ unsigned short As[64 * 32];
    __shared__ unsigned short Bs[64 * 32];
    __shared__ float ABl[512];
    int t = threadIdx.x;
    int mBase = blockIdx.x * 64;
    int oBase = blockIdx.y * 64;
    if (TRANS == 1) {
        for (int i = t; i < K; i += 256) {
            float a, c; bncoef(xs, xg, xb, i, a, c);
            ABl[2 * i] = a; ABl[2 * i + 1] = c;
        }
    }
    int lane = t & 63, w = t >> 6;
    int warpM = (w & 1) * 32, warpO = (w >> 1) * 32;
    f32x4 acc[2][2];
    #pragma unroll
    for (int i = 0; i < 2; ++i)
        #pragma unroll
        for (int j = 0; j < 2; ++j) acc[i][j] = (f32x4){0.f, 0.f, 0.f, 0.f};
    int lr = t >> 2;
    int lc = (t & 3) * 8;
    const unsigned short* Xp = X + (size_t)(mBase + lr) * ldx + lc;
    const unsigned short* Wp = W + (size_t)(oBase + lr) * ldw + lc;
    int ar0 = (warpM + (lane & 15)) * 32 + (lane >> 4) * 8;
    int br0 = (warpO + (lane & 15)) * 32 + (lane >> 4) * 8;
    uint4 xa = *(const uint4*)(Xp);
    uint4 wb = *(const uint4*)(Wp);
    for (int k = 0; k < K; k += 32) {
        __syncthreads();
        uint4 xc = xa;
        if (TRANS == 1) {
            unsigned short* p = (unsigned short*)&xc;
            int kb = k + lc;
            #pragma unroll
            for (int e = 0; e < 8; ++e)
                p[e] = f2h(fmaxf(ABl[2 * (kb + e)] * h2f(p[e]) + ABl[2 * (kb + e) + 1], 0.f));
        }
        *(uint4*)&As[lr * 32 + lc] = xc;
        *(uint4*)&Bs[lr * 32 + lc] = wb;
        if (k + 32 < K) {
            xa = *(const uint4*)(Xp + k + 32);
            wb = *(const uint4*)(Wp + k + 32);
        }
        __syncthreads();
        half8 a0 = __builtin_bit_cast(half8, *(const uint4*)&As[ar0]);
        half8 a1 = __builtin_bit_cast(half8, *(const uint4*)&As[ar0 + 16 * 32]);
        half8 b0 = __builtin_bit_cast(half8, *(const uint4*)&Bs[br0]);
        half8 b1 = __builtin_bit_cast(half8, *(const uint4*)&Bs[br0 + 16 * 32]);
        acc[0][0] = __builtin_amdgcn_mfma_f32_16x16x32_f16(a0, b0, acc[0][0], 0, 0, 0);
        acc[0][1] = __builtin_amdgcn_mfma_f32_16x16x32_f16(a0, b1, acc[0][1], 0, 0, 0);
        acc[1][0] = __builtin_amdgcn_mfma_f32_16x16x32_f16(a1, b0, acc[1][0], 0, 0, 0);
        acc[1][1] = __builtin_amdgcn_mfma_f32_16x16x32_f16(a1, b1, acc[1][1], 0, 0, 0);
    }
    if (MODE == 3) {
        float* outp = (float*)Yv;
        #pragma unroll
        for (int i = 0; i < 2; ++i)
            #pragma unroll
            for (int j = 0; j < 2; ++j) {
                int m0 = mBase + warpM + i * 16 + (lane >> 4) * 4;
                int o = oBase + warpO + j * 16 + (lane & 15);
                if (o < 50) {
                    int bb2 = m0 >> 11, n = m0 & (NN - 1);
                    float bi = sums[o];
                    float4 v = make_float4(acc[i][j][0] + bi, acc[i][j][1] + bi,
                                           acc[i][j][2] + bi, acc[i][j][3] + bi);
                    *(float4*)&outp[((size_t)bb2 * 50 + o) * NN + n] = v;
                }
            }
    } else {
        unsigned short* Yh = (unsigned short*)Yv;
        #pragma unroll
        for (int i = 0; i < 2; ++i)
            #pragma unroll
            for (int j = 0; j < 2; ++j) {
                int m0 = mBase + warpM + i * 16 + (lane >> 4) * 4;
                int o = oBase + warpO + j * 16 + (lane & 15);
                #pragma unroll
                for (int r = 0; r < 4; ++r)
                    Yh[(size_t)(m0 + r) * yld + o] = f2h(acc[i][j][r]);
            }
        __syncthreads();
        float* ssum = (float*)As;
        float* ssq = (float*)Bs;
        if (t < 64) { ssum[t] = 0.f; ssq[t] = 0.f; }
        __syncthreads();
        #pragma unroll
        for (int j = 0; j < 2; ++j) {
            int oc = warpO + j * 16 + (lane & 15);
            float s = 0.f, q = 0.f;
            #pragma unroll
            for (int i = 0; i < 2; ++i)
                #pragma unroll
                for (int r = 0; r < 4; ++r) { float v = acc[i][j][r]; s += v; q += v * v; }
            atomicAdd(&ssum[oc], s);
            atomicAdd(&ssq[oc], q);
        }
        __syncthreads();
        if (t < 64) {
            atomicAdd(&sums[oBase + t], ssum[t]);
            atomicAdd(&sums[1024 + oBase + t], ssq[t]);
        }
    }
}

// ---------------------------------------------------------------------------
// fused: build cls0 coefficient table AB4[1376] (blocks 0..5) + max-feature
// GEMV with inline normalized maxes (blocks 6..37):
// contrib[b][o] += sum_c Wmax[c][o] * relu(a3[c]*rawmax[b][c]+c3[c])
// ---------------------------------------------------------------------------
__global__ __launch_bounds__(256) void abgemv_k(const float* __restrict__ SUMS,
                                                const unsigned* __restrict__ MAXBu,
                                                float4* __restrict__ AB4,
                                                const unsigned short* __restrict__ Wmax,
                                                float* __restrict__ contrib,
                                                const float* g0, const float* b0,
                                                const float* g1, const float* b1,
                                                const float* g2, const float* b2,
                                                const float* g3, const float* b3) {
    int blk = blockIdx.x, t = threadIdx.x;
    if (blk < 6) {
        int ch = blk * 256 + t;
        if (ch >= 1376) return;
        float4 r;
        if (ch < 16) r = make_float4(1.f, 0.f, -__builtin_inff(), 0.f);
        else if (ch < 80) { float a, c; bncoef(SUMS, g0, b0, ch - 16, a, c); r = make_float4(a, c, 0.f, 0.f); }
        else if (ch < 208) { float a, c; bncoef(SUMS + 2048, g1, b1, ch - 80, a, c); r = make_float4(a, c, 0.f, 0.f); }
        else if (ch < 336) { float a, c; bncoef(SUMS + 4096, g2, b2, ch - 208, a, c); r = make_float4(a, c, 0.f, 0.f); }
        else if (ch < 1360) { float a, c; bncoef(SUMS + 6144, g3, b3, ch - 336, a, c); r = make_float4(a, c, 0.f, 0.f); }
        else r = make_float4(0.f, 0.f, 0.f, 0.f);
        AB4[ch] = r;
    } else {
        int i = blk - 6;
        int b = i >> 3;
        int cc = (i & 7) * 128;
        __shared__ float nm[128];
        if (t < 128) {
            int c = cc + t;
            float a, cf; bncoef(SUMS + 6144, g3, b3, c, a, cf);
            float raw = funflip(MAXBu[b * 1024 + c]);
            nm[t] = fmaxf(a * raw + cf, 0.f);
        }
        __syncthreads();
        int o = t;
        float acc = 0.f;
        for (int c = 0; c < 128; ++c)
            acc += h2f(Wmax[(size_t)(cc + c) * 256 + o]) * nm[c];
        atomicAdd(&contrib[b * 256 + o], acc);
    }
}

// ---------------------------------------------------------------------------
// cls0 finish: sum 4 fp16 K-split partials + contrib -> raw fp16 partial0 + stats
// ---------------------------------------------------------------------------
__global__ __launch_bounds__(256) void red4stat_k(unsigned short* __restrict__ Yh,
                                                  const float* __restrict__ contrib,
                                                  float* __restrict__ sums) {
    int o0 = blockIdx.x * 64;
    int m0 = blockIdx.y * 128;
    int t = threadIdx.x, ol = t & 63, mg = t >> 6;
    int b = m0 >> 11;
    float cb = contrib[b * 256 + o0 + ol];
    const size_t stride = (size_t)MM * 256;
    float s = 0.f, q = 0.f;
    unsigned short* p = Yh + (size_t)(m0 + mg) * 256 + o0 + ol;
    for (int i = 0; i < 32; ++i) {
        unsigned short* pp = p + (size_t)i * 4 * 256;
        float v = h2f(pp[0]) + h2f(pp[stride]) + h2f(pp[2 * stride]) + h2f(pp[3 * stride]) + cb;
        pp[0] = f2h(v);
        s += v; q += v * v;
    }
    __shared__ float ls[4][64], lq[4][64];
    ls[mg][ol] = s; lq[mg][ol] = q;
    __syncthreads();
    if (mg == 0) {
        s = ls[0][ol] + ls[1][ol] + ls[2][ol] + ls[3][ol];
        q = lq[0][ol] + lq[1][ol] + lq[2][ol] + lq[3][ol];
        atomicAdd(&sums[o0 + ol], s);
        atomicAdd(&sums[1024 + o0 + ol], q);
    }
}

// ---------------------------------------------------------------------------
extern "C" void kernel_launch(void* const* d_in, const int* in_sizes, int n_in,
                              void* d_out, int out_size, void* d_ws, size_t ws_size,
                              hipStream_t stream) {
    const float* in = (const float*)d_in[0];
    const float* pf0_w = (const float*)d_in[1];
    const float* pf_g[4] = {(const float*)d_in[2], (const float*)d_in[5], (const float*)d_in[8], (const float*)d_in[11]};
    const float* pf_b[4] = {(const float*)d_in[3], (const float*)d_in[6], (const float*)d_in[9], (const float*)d_in[12]};
    const float* pf_w[4] = {(const float*)d_in[1], (const float*)d_in[4], (const float*)d_in[7], (const float*)d_in[10]};
    const float* cls_w[3] = {(const float*)d_in[13], (const float*)d_in[16], (const float*)d_in[19]};
    const float* cls_g[3] = {(const float*)d_in[14], (const float*)d_in[17], (const float*)d_in[20]};
    const float* cls_b[3] = {(const float*)d_in[15], (const float*)d_in[18], (const float*)d_in[21]};
    const float* cls3_w = (const float*)d_in[22];
    const float* cls3_bias = (const float*)d_in[23];
    float* out = (float*)d_out;

    char* wsb = (char*)d_ws;
    float* ST = (float*)(wsb + 0);
    float4* PQ = (float4*)(wsb + 256);
    float* F0 = (float*)(wsb + 131328);
    float* SUMS = (float*)(wsb + 295168);
    unsigned* MAXBu = (unsigned*)(wsb + 352512);
    float* CONTRIB = (float*)(wsb + 368896);
    float4* AB4 = (float4*)(wsb + 372992);
    unsigned short* WB = (unsigned short*)(wsb + 411392);
    unsigned short* XCb = (unsigned short*)(wsb + 2180864);
    unsigned short* C1b = (unsigned short*)(wsb + 24725248);
    unsigned short* C2b = (unsigned short*)(wsb + 28919552);
    unsigned short* Yh = (unsigned short*)(wsb + 33113856);

    auto SL = [&](int s) { return SUMS + (size_t)s * 2048; };

    prep_k<<<976, 256, 0, stream>>>(in, pf_w[1], pf_w[2], pf_w[3], cls_w[0], cls_w[1], cls_w[2], cls3_w,
                                    WB, ST, (unsigned*)SUMS, XCb);
    point_k<<<MM / 256, 256, 0, stream>>>(in, ST, PQ, F0);
    alpha_k<<<MM / 4, 256, 0, stream>>>(PQ, F0);

    // pf0 raw -> XCb+16 with fused stats SL(0)
    pf0s_k<<<16, 256, 0, stream>>>(F0, pf0_w, XCb + 16, SL(0));
    // pf1: stage-norm SL(0); raw -> XCb+80; stats SL(1)
    mgemm64_k<1, 1><<<dim3(128, 2), 256, 0, stream>>>(XCb + 16, LDC, WB, 64, XCb + 80, LDC, 128, 64,
                                                      SL(1), SL(0), pf_g[0], pf_b[0]);
    // pf2: stage-norm SL(1); raw -> XCb+208; stats SL(2)
    mgemm64_k<1, 1><<<dim3(128, 2), 256, 0, stream>>>(XCb + 80, LDC, WB + 8192, 128, XCb + 208, LDC, 128, 128,
                                                      SL(2), SL(1), pf_g[1], pf_b[1]);
    // pf3: stage-norm SL(2); raw -> XCb+336; stats SL(3) + raw channel max
    mgemm3_k<1, 1, 1><<<dim3(128, 8, 1), 256, 0, stream>>>(XCb + 208, LDC, WB + 24576, 128, XCb + 336, LDC,
                                                           1024, 128, 128, SL(3), SL(2), pf_g[2], pf_b[2],
                                                           AB4, MAXBu);
    // fused coefficient table + max-feature GEMV
    abgemv_k<<<38, 256, 0, stream>>>(SUMS, MAXBu, AB4, WB + 614400, CONTRIB,
                                     pf_g[0], pf_b[0], pf_g[1], pf_b[1], pf_g[2], pf_b[2], pf_g[3], pf_b[3]);
    // cls0: stage-norm via AB4; K-split x4 raw fp16 partials
    mgemm3_k<2, 2, 0><<<dim3(128, 2, 4), 256, 0, stream>>>(XCb, LDC, WB + 155648, 1376, Yh, 256,
                                                           256, 1376, 352, SL(4), nullptr, nullptr, nullptr,
                                                           AB4, MAXBu);
    red4stat_k<<<dim3(4, 64), 256, 0, stream>>>(Yh, CONTRIB, SL(4));
    // cls1: stage-norm SL(4); raw -> C1b; stats SL(5)
    mgemm64_k<1, 1><<<dim3(128, 4), 256, 0, stream>>>(Yh, 256, WB + 507904, 256, C1b, 256, 256, 256,
                                                      SL(5), SL(4), cls_g[0], cls_b[0]);
    // cls2: stage-norm SL(5); raw -> C2b; stats SL(6)
    mgemm64_k<1, 1><<<dim3(128, 2), 256, 0, stream>>>(C1b, 256, WB + 507904 + 65536, 256, C2b, 128, 128, 256,
                                                      SL(6), SL(5), cls_g[1], cls_b[1]);
    // cls3: stage-norm SL(6); direct (b,50,n) output + bias
    mgemm64_k<3, 1><<<dim3(128, 1), 256, 0, stream>>>(C2b, 128, WB + 606208, 128, (void*)out, 0, 64, 128,
                                                      (float*)cls3_bias, SL(6), cls_g[2], cls_b[2]);

    (void)in_sizes; (void)n_in; (void)out_size; (void)ws_size;
}

// Round 17
// 164.400 us; speedup vs baseline: 1.7585x; 1.0864x over previous
//
#include <hip/hip_runtime.h>
#include <math.h>

#define BB 4
#define NN 2048
#define MM 8192
#define EPSF 1e-5f
#define LDC 1376   // concat stride: onehot16 | pf0 64 | pf1 128 | pf2 128 | pf3 1024 | pad16

typedef _Float16 half8 __attribute__((ext_vector_type(8)));
typedef float f32x4 __attribute__((ext_vector_type(4)));

__device__ __forceinline__ unsigned short f2h(float x) {
    _Float16 h = (_Float16)x;
    return __builtin_bit_cast(unsigned short, h);
}
__device__ __forceinline__ float h2f(unsigned short u) {
    return (float)__builtin_bit_cast(_Float16, u);
}
// order-preserving float<->unsigned for atomicMax over signed floats
__device__ __forceinline__ unsigned fflip(float x) {
    unsigned u = __builtin_bit_cast(unsigned, x);
    return (u >> 31) ? ~u : (u | 0x80000000u);
}
__device__ __forceinline__ float funflip(unsigned s) {
    unsigned u = (s >> 31) ? (s ^ 0x80000000u) : ~s;
    return __builtin_bit_cast(float, u);
}
#define FLIP_NEG_INF 0x007FFFFFu

__device__ __forceinline__ float angle3(float ux, float uy, float uz,
                                        float vx, float vy, float vz) {
    float crx = uy * vz - uz * vy;
    float cry = uz * vx - ux * vz;
    float crz = ux * vy - uy * vx;
    float s = sqrtf(crx * crx + cry * cry + crz * crz);
    float c = ux * vx + uy * vy + uz * vz;
    return atan2f(s, c);
}

// BN coefficient from a sums slice
__device__ __forceinline__ void bncoef(const float* __restrict__ sums,
                                       const float* __restrict__ g,
                                       const float* __restrict__ bb,
                                       int o, float& a, float& c) {
    float mu = sums[o] * (1.f / 8192.f);
    float var = sums[1024 + o] * (1.f / 8192.f) - mu * mu;
    var = fmaxf(var, 0.f);
    a = g[o] * (1.0f / sqrtf(var + EPSF));
    c = bb[o] - mu * a;
}

// ---------------------------------------------------------------------------
// fused preamble: wconv x4 (0..863) | stats (864..867) | init SUMS/MAXB/CONTRIB
// (868..943; MAXB gets flip(-inf)) | onehot+pad (944..975)
// ---------------------------------------------------------------------------
__global__ __launch_bounds__(256) void prep_k(const float* __restrict__ in,
                                              const float* __restrict__ w1, const float* __restrict__ w2,
                                              const float* __restrict__ w3, const float* __restrict__ w4,
                                              const float* __restrict__ w5, const float* __restrict__ w6,
                                              const float* __restrict__ w7,
                                              unsigned short* __restrict__ Wb,
                                              float* __restrict__ st,
                                              unsigned* __restrict__ zp,
                                              unsigned short* __restrict__ XCb) {
    int blk = blockIdx.x;
    int t = threadIdx.x;
    if (blk < 864) {
        int idx0 = blk * 1024 + t * 4;
        ushort4 r;
        unsigned short* rp = (unsigned short*)&r;
        #pragma unroll
        for (int e = 0; e < 4; ++e) {
            int idx = idx0 + e;
            unsigned short v;
            if (idx < 8192) v = f2h(w1[idx]);
            else if (idx < 24576) v = f2h(w2[idx - 8192]);
            else if (idx < 155648) v = f2h(w3[idx - 24576]);
            else if (idx < 507904) {
                int l = idx - 155648;
                int o = l / 1376, k = l - o * 1376;
                v = (k < 1360) ? f2h(w4[o * 2384 + k]) : (unsigned short)0;
            } else if (idx < 573440) v = f2h(w5[idx - 507904]);
            else if (idx < 606208) v = f2h(w6[idx - 573440]);
            else if (idx < 614400) {
                int l = idx - 606208;
                int o = l >> 7, k = l & 127;
                v = (o < 50) ? f2h(w7[o * 128 + k]) : (unsigned short)0;
            } else {
                int l = idx - 614400;
                int c = l >> 8, o = l & 255;
                v = (c < 1024) ? f2h(w4[o * 2384 + 1360 + c]) : (unsigned short)0;
            }
            rp[e] = v;
        }
        *(ushort4*)&Wb[idx0] = r;
    } else if (blk < 868) {
        int b = blk - 864;
        const float* base = in + (size_t)b * 22 * NN;
        float cs0 = 0.f, cs1 = 0.f, cs2 = 0.f, ns0 = 0.f, ns1 = 0.f, ns2 = 0.f;
        for (int n = t; n < NN; n += 256) {
            float cx = base[0 * NN + n], cy = base[1 * NN + n], cz = base[2 * NN + n];
            float nx = base[3 * NN + n], ny = base[4 * NN + n], nz = base[5 * NN + n];
            float inv = 1.0f / sqrtf(nx * nx + ny * ny + nz * nz);
            cs0 += cx; cs1 += cy; cs2 += cz;
            ns0 += nx * inv; ns1 += ny * inv; ns2 += nz * inv;
        }
        __shared__ float red[6][256];
        red[0][t] = cs0; red[1][t] = cs1; red[2][t] = cs2;
        red[3][t] = ns0; red[4][t] = ns1; red[5][t] = ns2;
        __syncthreads();
        for (int s = 128; s > 0; s >>= 1) {
            if (t < s) {
                #pragma unroll
                for (int i = 0; i < 6; ++i) red[i][t] += red[i][t + s];
            }
            __syncthreads();
        }
        if (t == 0) {
            float ccx = red[0][0] / (float)NN, ccy = red[1][0] / (float)NN, ccz = red[2][0] / (float)NN;
            float cnx = red[3][0] / (float)NN, cny = red[4][0] / (float)NN, cnz = red[5][0] / (float)NN;
            float inv = 1.0f / sqrtf(cnx * cnx + cny * cny + cnz * cnz);
            float* s9 = st + b * 16;
            s9[0] = ccx; s9[1] = ccy; s9[2] = ccz;
            s9[3] = cnx; s9[4] = cny; s9[5] = cnz;
            s9[6] = cnx * inv; s9[7] = cny * inv; s9[8] = cnz * inv;
        }
    } else if (blk < 944) {
        int idx = (blk - 868) * 256 + t;
        zp[idx] = (idx >= 14336 && idx < 18432) ? FLIP_NEG_INF : 0u;
    } else {
        int m = (blk - 944) * 256 + t;
        int b = m >> 11, n = m & (NN - 1);
        const float* src = in + (size_t)b * 22 * NN + 6 * NN + n;
        unsigned short vals[16];
        #pragma unroll
        for (int r = 0; r < 16; ++r) vals[r] = f2h(src[(size_t)r * NN]);
        ushort4* dst = (ushort4*)&XCb[(size_t)m * LDC];
        #pragma unroll
        for (int q = 0; q < 4; ++q)
            dst[q] = make_ushort4(vals[4 * q], vals[4 * q + 1], vals[4 * q + 2], vals[4 * q + 3]);
        ushort4 z = make_ushort4(0, 0, 0, 0);
        ushort4* pz = (ushort4*)&XCb[(size_t)m * LDC + 1360];
        pz[0] = z; pz[1] = z; pz[2] = z; pz[3] = z;
    }
}

// ---------------------------------------------------------------------------
// per-point PPF + packed projected vectors PQ = (x,y,z,|P|)
// ---------------------------------------------------------------------------
__global__ __launch_bounds__(256) void point_k(const float* __restrict__ in,
                                               const float* __restrict__ st,
                                               float4* __restrict__ PQ,
                                               float* __restrict__ F0) {
    int idx = blockIdx.x * 256 + threadIdx.x;
    int b = idx >> 11, n = idx & (NN - 1);
    const float* base = in + (size_t)b * 22 * NN;
    const float* s9 = st + b * 16;
    float cx = base[0 * NN + n], cy = base[1 * NN + n], cz = base[2 * NN + n];
    float nx = base[3 * NN + n], ny = base[4 * NN + n], nz = base[5 * NN + n];
    float inv = 1.0f / sqrtf(nx * nx + ny * ny + nz * nz);
    nx *= inv; ny *= inv; nz *= inv;
    float ccx = s9[0], ccy = s9[1], ccz = s9[2];
    float cnx = s9[3], cny = s9[4], cnz = s9[5];
    float ex = s9[6], ey = s9[7], ez = s9[8];
    float dx = cx - ccx, dy = cy - ccy, dz = cz - ccz;
    F0[0 * MM + idx] = angle3(cnx, cny, cnz, dx, dy, dz);
    F0[1 * MM + idx] = angle3(nx, ny, nz, dx, dy, dz);
    F0[2 * MM + idx] = angle3(cnx, cny, cnz, nx, ny, nz);
    F0[3 * MM + idx] = sqrtf(dx * dx + dy * dy + dz * dz);
    float dot = dx * ex + dy * ey + dz * ez;
    float px = dx - dot * cnx;
    float py = dy - dot * cny;
    float pz = dz - dot * cnz;
    PQ[idx] = make_float4(px, py, pz, sqrtf(px * px + py * py + pz * pz));
}

// ---------------------------------------------------------------------------
// per-row median via TWO-PASS LDS HISTOGRAM over exact fp16 key codes
// (f2h monotone => exact rank select on the fp16 grid, same result as the
// bit-select of R15/R16 but with NO serial per-bit rounds — R16 showed the
// 15-round chain was the floor, not occupancy).
// Pass1: 256-bin hist of code>>7 -> byte-bin B + count-below (wave scan).
// Pass2: 128-bin hist of code&127 within bin B -> exact code.
// One row per wave, 4 waves/block, 1KB LDS hist per wave.
// ---------------------------------------------------------------------------
__global__ __launch_bounds__(256) void alpha_k(const float4* __restrict__ PQ,
                                               float* __restrict__ F0) {
    __shared__ unsigned hist[4][256];
    int wv = threadIdx.x >> 6;
    int lane = threadIdx.x & 63;
    int row = blockIdx.x * 4 + wv;
    int b = row >> 11;
    const float4* base = PQ + (size_t)b * NN;
    float4 a = base[row & (NN - 1)];
    unsigned u[16];
    #pragma unroll
    for (int c = 0; c < 4; ++c) {
        #pragma unroll
        for (int j = 0; j < 4; ++j) {
            int s2 = c * 8 + j * 2;
            float4 bv0 = base[s2 * 64 + lane];
            float4 bv1 = base[(s2 + 1) * 64 + lane];
            float k0, k1;
            {
                float cx = a.y * bv0.z - a.z * bv0.y;
                float cy = a.z * bv0.x - a.x * bv0.z;
                float cz = a.x * bv0.y - a.y * bv0.x;
                float ss = cx * cx + cy * cy + cz * cz;
                float dc = a.x * bv0.x + a.y * bv0.y + a.z * bv0.z;
                float den = dc + a.w * bv0.w;
                float rc = __builtin_amdgcn_rcpf(den);
                k0 = ss * rc * rc;
                if (k0 <= 2.5e-11f) k0 = __builtin_inff();
            }
            {
                float cx = a.y * bv1.z - a.z * bv1.y;
                float cy = a.z * bv1.x - a.x * bv1.z;
                float cz = a.x * bv1.y - a.y * bv1.x;
                float ss = cx * cx + cy * cy + cz * cz;
                float dc = a.x * bv1.x + a.y * bv1.y + a.z * bv1.z;
                float den = dc + a.w * bv1.w;
                float rc = __builtin_amdgcn_rcpf(den);
                k1 = ss * rc * rc;
                if (k1 <= 2.5e-11f) k1 = __builtin_inff();
            }
            u[c * 4 + j] = (unsigned)f2h(k0) | ((unsigned)f2h(k1) << 16);
        }
        asm volatile("" ::: "memory");
    }
    unsigned* h = hist[wv];
    h[lane] = 0; h[lane + 64] = 0; h[lane + 128] = 0; h[lane + 192] = 0;
    __syncthreads();
    #pragma unroll
    for (int q = 0; q < 16; ++q) {
        atomicAdd(&h[(u[q] & 0xFFFFu) >> 7], 1u);
        atomicAdd(&h[u[q] >> 23], 1u);
    }
    __syncthreads();
    const unsigned K = 1023;
    unsigned h0 = h[4 * lane], h1 = h[4 * lane + 1], h2 = h[4 * lane + 2], h3 = h[4 * lane + 3];
    unsigned lsum = h0 + h1 + h2 + h3;
    unsigned inc = lsum;
    #pragma unroll
    for (int d = 1; d < 64; d <<= 1) {
        unsigned tv = __shfl_up(inc, d);
        if (lane >= d) inc += tv;
    }
    unsigned excl = inc - lsum;
    bool has = (excl <= K) && (K < inc);
    unsigned long long mask = __ballot(has);
    int L = __ffsll((long long)mask) - 1;
    unsigned packed = 0;
    if (has) {
        unsigned e = excl, Bq = 4 * lane;
        if (e + h0 <= K) { e += h0; Bq++;
            if (e + h1 <= K) { e += h1; Bq++;
                if (e + h2 <= K) { e += h2; Bq++; } } }
        packed = (Bq << 16) | e;
    }
    packed = __shfl(packed, L);
    unsigned B = packed >> 16;
    unsigned k2 = K - (packed & 0xFFFFu);
    __syncthreads();
    h[lane] = 0; h[lane + 64] = 0;
    __syncthreads();
    #pragma unroll
    for (int q = 0; q < 16; ++q) {
        unsigned lo = u[q] & 0xFFFFu, hi = u[q] >> 16;
        if ((lo >> 7) == B) atomicAdd(&h[lo & 127], 1u);
        if ((hi >> 7) == B) atomicAdd(&h[hi & 127], 1u);
    }
    __syncthreads();
    unsigned g0 = h[2 * lane], g1 = h[2 * lane + 1];
    unsigned ls2 = g0 + g1, inc2 = ls2;
    #pragma unroll
    for (int d = 1; d < 64; d <<= 1) {
        unsigned tv = __shfl_up(inc2, d);
        if (lane >= d) inc2 += tv;
    }
    unsigned excl2 = inc2 - ls2;
    bool has2 = (excl2 <= k2) && (k2 < inc2);
    unsigned long long m2 = __ballot(has2);
    int L2 = __ffsll((long long)m2) - 1;
    unsigned low = 0;
    if (has2) low = 2 * lane + ((excl2 + g0 <= k2) ? 1u : 0u);
    low = __shfl(low, L2);
    unsigned T = (B << 7) | low;
    if (lane == 0) {
        float lo = h2f((unsigned short)T);
        float hi = h2f((unsigned short)(T + 1));
        F0[4 * MM + row] = 2.0f * atanf(sqrtf(0.5f * (lo + hi)));
    }
}

// ---------------------------------------------------------------------------
// pf0 + fused BN stats: raw fp16 into XCb+16; stats -> sums.
// ---------------------------------------------------------------------------
__global__ __launch_bounds__(256) void pf0s_k(const float* __restrict__ F0,
                                              const float* __restrict__ W,
                                              unsigned short* __restrict__ dst,
                                              float* __restrict__ sums) {
    __shared__ float ws[320];
    int t = threadIdx.x;
    for (int i = t; i < 320; i += 256) ws[i] = W[i];
    __syncthreads();
    int ol = t & 63, mg = t >> 6;
    int m0 = blockIdx.x * 512;
    float w0 = ws[ol * 5], w1 = ws[ol * 5 + 1], w2 = ws[ol * 5 + 2], w3 = ws[ol * 5 + 3], w4 = ws[ol * 5 + 4];
    float s = 0.f, q = 0.f;
    for (int i = 0; i < 128; ++i) {
        int m = m0 + i * 4 + mg;
        float y = w0 * F0[m] + w1 * F0[MM + m] + w2 * F0[2 * MM + m]
                + w3 * F0[3 * MM + m] + w4 * F0[4 * MM + m];
        dst[(size_t)m * LDC + ol] = f2h(y);
        s += y; q += y * y;
    }
    __shared__ float ls[4][64], lq[4][64];
    ls[mg][ol] = s; lq[mg][ol] = q;
    __syncthreads();
    if (mg == 0) {
        s = ls[0][ol] + ls[1][ol] + ls[2][ol] + ls[3][ol];
        q = lq[0][ol] + lq[1][ol] + lq[2][ol] + lq[3][ol];
        atomicAdd(&sums[ol], s);
        atomicAdd(&sums[1024 + ol], q);
    }
}

// ---------------------------------------------------------------------------
// fp16 MFMA GEMM BM=64 BO=128 with staging-normalization of X.
// TRANS: 0 none, 1 uniform (xs,xg,xb), 2 AB4 table (cls0).
// MODE: 1 raw fp16 out (yld) + stats [+DOMAX raw channel max]; 2 K-split partial.
// ---------------------------------------------------------------------------
template<int MODE, int TRANS, int DOMAX>
__global__ __launch_bounds__(256) void mgemm3_k(const unsigned short* __restrict__ X, int ldx,
                                                const unsigned short* __restrict__ W, int ldw,
                                                unsigned short* __restrict__ Yh, int yld, int Co, int K, int kchunk,
                                                float* __restrict__ sums,
                                                const float* __restrict__ xs, const float* __restrict__ xg,
                                                const float* __restrict__ xb,
                                                const float4* __restrict__ AB4,
                                                unsigned* __restrict__ maxbu) {
    __shared__ unsigned short As[64 * 32];
    __shared__ unsigned short Bs[128 * 32];
    __shared__ float4 ABl[352];
    int t = threadIdx.x;
    int mBase = blockIdx.x * 64;
    int oBase = blockIdx.y * 128;
    int k0c = blockIdx.z * kchunk;
    int k1c = k0c + kchunk; if (k1c > K) k1c = K;
    if (TRANS == 1) {
        float* abf = (float*)ABl;
        for (int i = t; i < K; i += 256) {
            float a, c; bncoef(xs, xg, xb, i, a, c);
            abf[2 * i] = a; abf[2 * i + 1] = c;
        }
    } else if (TRANS == 2) {
        for (int i = t; i < k1c - k0c; i += 256) ABl[i] = AB4[k0c + i];
    }
    int lane = t & 63, w = t >> 6;
    int warpM = (w & 1) * 32, warpO = (w >> 1) * 64;
    f32x4 acc[2][4];
    #pragma unroll
    for (int i = 0; i < 2; ++i)
        #pragma unroll
        for (int j = 0; j < 4; ++j) acc[i][j] = (f32x4){0.f, 0.f, 0.f, 0.f};
    int lr = t >> 2;
    int lc = (t & 3) * 8;
    const unsigned short* Xp = X + (size_t)(mBase + lr) * ldx + lc;
    const unsigned short* Wp0 = W + (size_t)(oBase + lr) * ldw + lc;
    const unsigned short* Wp1 = W + (size_t)(oBase + lr + 64) * ldw + lc;
    int ar0 = (warpM + (lane & 15)) * 32 + (lane >> 4) * 8;
    int br0 = (warpO + (lane & 15)) * 32 + (lane >> 4) * 8;
    uint4 xa = *(const uint4*)(Xp + k0c);
    uint4 wb0 = *(const uint4*)(Wp0 + k0c);
    uint4 wb1 = *(const uint4*)(Wp1 + k0c);
    for (int k = k0c; k < k1c; k += 32) {
        __syncthreads();
        uint4 xc = xa;
        if (TRANS == 1) {
            const float* abf = (const float*)ABl;
            unsigned short* p = (unsigned short*)&xc;
            int kb = k + lc;
            #pragma unroll
            for (int e = 0; e < 8; ++e)
                p[e] = f2h(fmaxf(abf[2 * (kb + e)] * h2f(p[e]) + abf[2 * (kb + e) + 1], 0.f));
        } else if (TRANS == 2) {
            unsigned short* p = (unsigned short*)&xc;
            int kb = k + lc - k0c;
            #pragma unroll
            for (int e = 0; e < 8; ++e) {
                float4 qd = ABl[kb + e];
                p[e] = f2h(fmaxf(qd.x * h2f(p[e]) + qd.y, qd.z));
            }
        }
        *(uint4*)&As[lr * 32 + lc] = xc;
        *(uint4*)&Bs[lr * 32 + lc] = wb0;
        *(uint4*)&Bs[(lr + 64) * 32 + lc] = wb1;
        if (k + 32 < k1c) {
            xa = *(const uint4*)(Xp + k + 32);
            wb0 = *(const uint4*)(Wp0 + k + 32);
            wb1 = *(const uint4*)(Wp1 + k + 32);
        }
        __syncthreads();
        half8 a0 = __builtin_bit_cast(half8, *(const uint4*)&As[ar0]);
        half8 a1 = __builtin_bit_cast(half8, *(const uint4*)&As[ar0 + 16 * 32]);
        half8 b0 = __builtin_bit_cast(half8, *(const uint4*)&Bs[br0]);
        half8 b1 = __builtin_bit_cast(half8, *(const uint4*)&Bs[br0 + 16 * 32]);
        half8 b2 = __builtin_bit_cast(half8, *(const uint4*)&Bs[br0 + 32 * 32]);
        half8 b3 = __builtin_bit_cast(half8, *(const uint4*)&Bs[br0 + 48 * 32]);
        acc[0][0] = __builtin_amdgcn_mfma_f32_16x16x32_f16(a0, b0, acc[0][0], 0, 0, 0);
        acc[0][1] = __builtin_amdgcn_mfma_f32_16x16x32_f16(a0, b1, acc[0][1], 0, 0, 0);
        acc[0][2] = __builtin_amdgcn_mfma_f32_16x16x32_f16(a0, b2, acc[0][2], 0, 0, 0);
        acc[0][3] = __builtin_amdgcn_mfma_f32_16x16x32_f16(a0, b3, acc[0][3], 0, 0, 0);
        acc[1][0] = __builtin_amdgcn_mfma_f32_16x16x32_f16(a1, b0, acc[1][0], 0, 0, 0);
        acc[1][1] = __builtin_amdgcn_mfma_f32_16x16x32_f16(a1, b1, acc[1][1], 0, 0, 0);
        acc[1][2] = __builtin_amdgcn_mfma_f32_16x16x32_f16(a1, b2, acc[1][2], 0, 0, 0);
        acc[1][3] = __builtin_amdgcn_mfma_f32_16x16x32_f16(a1, b3, acc[1][3], 0, 0, 0);
    }
    unsigned short* Yp = Yh + (MODE == 2 ? (size_t)blockIdx.z * MM * yld : 0);
    #pragma unroll
    for (int i = 0; i < 2; ++i)
        #pragma unroll
        for (int j = 0; j < 4; ++j) {
            int m0 = mBase + warpM + i * 16 + (lane >> 4) * 4;
            int o = oBase + warpO + j * 16 + (lane & 15);
            #pragma unroll
            for (int r = 0; r < 4; ++r)
                Yp[(size_t)(m0 + r) * yld + o] = f2h(acc[i][j][r]);
        }
    if (MODE == 1) {
        __syncthreads();
        float* ssum = (float*)As;
        unsigned* smax = (unsigned*)As + 128;
        float* ssq = (float*)Bs;
        if (t < 128) { ssum[t] = 0.f; ssq[t] = 0.f; if (DOMAX) smax[t] = FLIP_NEG_INF; }
        __syncthreads();
        #pragma unroll
        for (int j = 0; j < 4; ++j) {
            int oc = warpO + j * 16 + (lane & 15);
            float s = 0.f, q = 0.f, mx = -__builtin_inff();
            #pragma unroll
            for (int i = 0; i < 2; ++i)
                #pragma unroll
                for (int r = 0; r < 4; ++r) {
                    float v = acc[i][j][r];
                    s += v; q += v * v; mx = fmaxf(mx, v);
                }
            atomicAdd(&ssum[oc], s);
            atomicAdd(&ssq[oc], q);
            if (DOMAX) atomicMax(&smax[oc], fflip(mx));
        }
        __syncthreads();
        if (t < 128) {
            atomicAdd(&sums[oBase + t], ssum[t]);
            atomicAdd(&sums[1024 + oBase + t], ssq[t]);
            if (DOMAX) atomicMax(&maxbu[(mBase >> 11) * 1024 + oBase + t], smax[t]);
        }
    }
}

// ---------------------------------------------------------------------------
// fp16 MFMA GEMM BM=64 BO=64 with staging-normalization.
// MODE 1: raw fp16 out (yld) + stats. MODE 3: direct (b,50,n) out + bias.
// ---------------------------------------------------------------------------
template<int MODE, int TRANS>
__global__ __launch_bounds__(256) void mgemm64_k(const unsigned short* __restrict__ X, int ldx,
                                                 const unsigned short* __restrict__ W, int ldw,
                                                 void* __restrict__ Yv, int yld, int Co, int K,
                                                 float* __restrict__ sums,
                                                 const float* __restrict__ xs, const float* __restrict__ xg,
                                                 const float* __restrict__ xb) {
    __shared__ unsigned short As[64 * 32];
    __shared__ unsigned short Bs[64 * 32];
    __shared__ float ABl[512];
    int t = threadIdx.x;
    int mBase = blockIdx.x * 64;
    int oBase = blockIdx.y * 64;
    if (TRANS == 1) {
        for (int i = t; i < K; i += 256) {
            float a, c; bncoef(xs, xg, xb, i, a, c);
            ABl[2 * i] = a; ABl[2 * i + 1] = c;
        }
    }
    int lane = t & 63, w = t >> 6;
    int warpM = (w & 1) * 32, warpO = (w >> 1) * 32;
    f32x4 acc[2][2];
    #pragma unroll
    for (int i = 0; i < 2; ++i)
        #pragma unroll
        for (int j = 0; j < 2; ++j) acc[i][j] = (f32x4){0.f, 0.f, 0.f, 0.f};
    int lr = t >> 2;
    int lc = (t & 3) * 8;
    const unsigned short* Xp = X + (size_t)(mBase + lr) * ldx + lc;
    const unsigned short* Wp = W + (size_t)(oBase + lr) * ldw + lc;
    int ar0 = (warpM + (lane & 15)) * 32 + (lane >> 4) * 8;
    int br0 = (warpO + (lane & 15)) * 32 + (lane >> 4) * 8;
    uint4 xa = *(const uint4*)(Xp);
    uint4 wb = *(const uint4*)(Wp);
    for (int k = 0; k < K; k += 32) {
        __syncthreads();
        uint4 xc = xa;
        if (TRANS == 1) {
            unsigned short* p = (unsigned short*)&xc;
            int kb = k + lc;
            #pragma unroll
            for (int e = 0; e < 8; ++e)
                p[e] = f2h(fmaxf(ABl[2 * (kb + e)] * h2f(p[e]) + ABl[2 * (kb + e) + 1], 0.f));
        }
        *(uint4*)&As[lr * 32 + lc] = xc;
        *(uint4*)&Bs[lr * 32 + lc] = wb;
        if (k + 32 < K) {
            xa = *(const uint4*)(Xp + k + 32);
            wb = *(const uint4*)(Wp + k + 32);
        }
        __syncthreads();
        half8 a0 = __builtin_bit_cast(half8, *(const uint4*)&As[ar0]);
        half8 a1 = __builtin_bit_cast(half8, *(const uint4*)&As[ar0 + 16 * 32]);
        half8 b0 = __builtin_bit_cast(half8, *(const uint4*)&Bs[br0]);
        half8 b1 = __builtin_bit_cast(half8, *(const uint4*)&Bs[br0 + 16 * 32]);
        acc[0][0] = __builtin_amdgcn_mfma_f32_16x16x32_f16(a0, b0, acc[0][0], 0, 0, 0);
        acc[0][1] = __builtin_amdgcn_mfma_f32_16x16x32_f16(a0, b1, acc[0][1], 0, 0, 0);
        acc[1][0] = __builtin_amdgcn_mfma_f32_16x16x32_f16(a1, b0, acc[1][0], 0, 0, 0);
        acc[1][1] = __builtin_amdgcn_mfma_f32_16x16x32_f16(a1, b1, acc[1][1], 0, 0, 0);
    }
    if (MODE == 3) {
        float* outp = (float*)Yv;
        #pragma unroll
        for (int i = 0; i < 2; ++i)
            #pragma unroll
            for (int j = 0; j < 2; ++j) {
                int m0 = mBase + warpM + i * 16 + (lane >> 4) * 4;
                int o = oBase + warpO + j * 16 + (lane & 15);
                if (o < 50) {
                    int bb2 = m0 >> 11, n = m0 & (NN - 1);
                    float bi = sums[o];
                    float4 v = make_float4(acc[i][j][0] + bi, acc[i][j][1] + bi,
                                           acc[i][j][2] + bi, acc[i][j][3] + bi);
                    *(float4*)&outp[((size_t)bb2 * 50 + o) * NN + n] = v;
                }
            }
    } else {
        unsigned short* Yh = (unsigned short*)Yv;
        #pragma unroll
        for (int i = 0; i < 2; ++i)
            #pragma unroll
            for (int j = 0; j < 2; ++j) {
                int m0 = mBase + warpM + i * 16 + (lane >> 4) * 4;
                int o = oBase + warpO + j * 16 + (lane & 15);
                #pragma unroll
                for (int r = 0; r < 4; ++r)
                    Yh[(size_t)(m0 + r) * yld + o] = f2h(acc[i][j][r]);
            }
        __syncthreads();
        float* ssum = (float*)As;
        float* ssq = (float*)Bs;
        if (t < 64) { ssum[t] = 0.f; ssq[t] = 0.f; }
        __syncthreads();
        #pragma unroll
        for (int j = 0; j < 2; ++j) {
            int oc = warpO + j * 16 + (lane & 15);
            float s = 0.f, q = 0.f;
            #pragma unroll
            for (int i = 0; i < 2; ++i)
                #pragma unroll
                for (int r = 0; r < 4; ++r) { float v = acc[i][j][r]; s += v; q += v * v; }
            atomicAdd(&ssum[oc], s);
            atomicAdd(&ssq[oc], q);
        }
        __syncthreads();
        if (t < 64) {
            atomicAdd(&sums[oBase + t], ssum[t]);
            atomicAdd(&sums[1024 + oBase + t], ssq[t]);
        }
    }
}

// ---------------------------------------------------------------------------
// fused: build cls0 coefficient table AB4[1376] (blocks 0..5) + max-feature
// GEMV with inline normalized maxes (blocks 6..37)
// ---------------------------------------------------------------------------
__global__ __launch_bounds__(256) void abgemv_k(const float* __restrict__ SUMS,
                                                const unsigned* __restrict__ MAXBu,
                                                float4* __restrict__ AB4,
                                                const unsigned short* __restrict__ Wmax,
                                                float* __restrict__ contrib,
                                                const float* g0, const float* b0,
                                                const float* g1, const float* b1,
                                                const float* g2, const float* b2,
                                                const float* g3, const float* b3) {
    int blk = blockIdx.x, t = threadIdx.x;
    if (blk < 6) {
        int ch = blk * 256 + t;
        if (ch >= 1376) return;
        float4 r;
        if (ch < 16) r = make_float4(1.f, 0.f, -__builtin_inff(), 0.f);
        else if (ch < 80) { float a, c; bncoef(SUMS, g0, b0, ch - 16, a, c); r = make_float4(a, c, 0.f, 0.f); }
        else if (ch < 208) { float a, c; bncoef(SUMS + 2048, g1, b1, ch - 80, a, c); r = make_float4(a, c, 0.f, 0.f); }
        else if (ch < 336) { float a, c; bncoef(SUMS + 4096, g2, b2, ch - 208, a, c); r = make_float4(a, c, 0.f, 0.f); }
        else if (ch < 1360) { float a, c; bncoef(SUMS + 6144, g3, b3, ch - 336, a, c); r = make_float4(a, c, 0.f, 0.f); }
        else r = make_float4(0.f, 0.f, 0.f, 0.f);
        AB4[ch] = r;
    } else {
        int i = blk - 6;
        int b = i >> 3;
        int cc = (i & 7) * 128;
        __shared__ float nm[128];
        if (t < 128) {
            int c = cc + t;
            float a, cf; bncoef(SUMS + 6144, g3, b3, c, a, cf);
            float raw = funflip(MAXBu[b * 1024 + c]);
            nm[t] = fmaxf(a * raw + cf, 0.f);
        }
        __syncthreads();
        int o = t;
        float acc = 0.f;
        for (int c = 0; c < 128; ++c)
            acc += h2f(Wmax[(size_t)(cc + c) * 256 + o]) * nm[c];
        atomicAdd(&contrib[b * 256 + o], acc);
    }
}

// ---------------------------------------------------------------------------
// cls0 finish: sum 4 fp16 K-split partials + contrib -> raw fp16 partial0 + stats
// ---------------------------------------------------------------------------
__global__ __launch_bounds__(256) void red4stat_k(unsigned short* __restrict__ Yh,
                                                  const float* __restrict__ contrib,
                                                  float* __restrict__ sums) {
    int o0 = blockIdx.x * 64;
    int m0 = blockIdx.y * 128;
    int t = threadIdx.x, ol = t & 63, mg = t >> 6;
    int b = m0 >> 11;
    float cb = contrib[b * 256 + o0 + ol];
    const size_t stride = (size_t)MM * 256;
    float s = 0.f, q = 0.f;
    unsigned short* p = Yh + (size_t)(m0 + mg) * 256 + o0 + ol;
    for (int i = 0; i < 32; ++i) {
        unsigned short* pp = p + (size_t)i * 4 * 256;
        float v = h2f(pp[0]) + h2f(pp[stride]) + h2f(pp[2 * stride]) + h2f(pp[3 * stride]) + cb;
        pp[0] = f2h(v);
        s += v; q += v * v;
    }
    __shared__ float ls[4][64], lq[4][64];
    ls[mg][ol] = s; lq[mg][ol] = q;
    __syncthreads();
    if (mg == 0) {
        s = ls[0][ol] + ls[1][ol] + ls[2][ol] + ls[3][ol];
        q = lq[0][ol] + lq[1][ol] + lq[2][ol] + lq[3][ol];
        atomicAdd(&sums[o0 + ol], s);
        atomicAdd(&sums[1024 + o0 + ol], q);
    }
}

// ---------------------------------------------------------------------------
extern "C" void kernel_launch(void* const* d_in, const int* in_sizes, int n_in,
                              void* d_out, int out_size, void* d_ws, size_t ws_size,
                              hipStream_t stream) {
    const float* in = (const float*)d_in[0];
    const float* pf0_w = (const float*)d_in[1];
    const float* pf_g[4] = {(const float*)d_in[2], (const float*)d_in[5], (const float*)d_in[8], (const float*)d_in[11]};
    const float* pf_b[4] = {(const float*)d_in[3], (const float*)d_in[6], (const float*)d_in[9], (const float*)d_in[12]};
    const float* pf_w[4] = {(const float*)d_in[1], (const float*)d_in[4], (const float*)d_in[7], (const float*)d_in[10]};
    const float* cls_w[3] = {(const float*)d_in[13], (const float*)d_in[16], (const float*)d_in[19]};
    const float* cls_g[3] = {(const float*)d_in[14], (const float*)d_in[17], (const float*)d_in[20]};
    const float* cls_b[3] = {(const float*)d_in[15], (const float*)d_in[18], (const float*)d_in[21]};
    const float* cls3_w = (const float*)d_in[22];
    const float* cls3_bias = (const float*)d_in[23];
    float* out = (float*)d_out;

    char* wsb = (char*)d_ws;
    float* ST = (float*)(wsb + 0);
    float4* PQ = (float4*)(wsb + 256);
    float* F0 = (float*)(wsb + 131328);
    float* SUMS = (float*)(wsb + 295168);
    unsigned* MAXBu = (unsigned*)(wsb + 352512);
    float* CONTRIB = (float*)(wsb + 368896);
    float4* AB4 = (float4*)(wsb + 372992);
    unsigned short* WB = (unsigned short*)(wsb + 411392);
    unsigned short* XCb = (unsigned short*)(wsb + 2180864);
    unsigned short* C1b = (unsigned short*)(wsb + 24725248);
    unsigned short* C2b = (unsigned short*)(wsb + 28919552);
    unsigned short* Yh = (unsigned short*)(wsb + 33113856);

    auto SL = [&](int s) { return SUMS + (size_t)s * 2048; };

    prep_k<<<976, 256, 0, stream>>>(in, pf_w[1], pf_w[2], pf_w[3], cls_w[0], cls_w[1], cls_w[2], cls3_w,
                                    WB, ST, (unsigned*)SUMS, XCb);
    point_k<<<MM / 256, 256, 0, stream>>>(in, ST, PQ, F0);
    alpha_k<<<MM / 4, 256, 0, stream>>>(PQ, F0);

    // pf0 raw -> XCb+16 with fused stats SL(0)
    pf0s_k<<<16, 256, 0, stream>>>(F0, pf0_w, XCb + 16, SL(0));
    // pf1: stage-norm SL(0); raw -> XCb+80; stats SL(1)
    mgemm64_k<1, 1><<<dim3(128, 2), 256, 0, stream>>>(XCb + 16, LDC, WB, 64, XCb + 80, LDC, 128, 64,
                                                      SL(1), SL(0), pf_g[0], pf_b[0]);
    // pf2: stage-norm SL(1); raw -> XCb+208; stats SL(2)
    mgemm64_k<1, 1><<<dim3(128, 2), 256, 0, stream>>>(XCb + 80, LDC, WB + 8192, 128, XCb + 208, LDC, 128, 128,
                                                      SL(2), SL(1), pf_g[1], pf_b[1]);
    // pf3: stage-norm SL(2); raw -> XCb+336; stats SL(3) + raw channel max
    mgemm3_k<1, 1, 1><<<dim3(128, 8, 1), 256, 0, stream>>>(XCb + 208, LDC, WB + 24576, 128, XCb + 336, LDC,
                                                           1024, 128, 128, SL(3), SL(2), pf_g[2], pf_b[2],
                                                           AB4, MAXBu);
    // fused coefficient table + max-feature GEMV
    abgemv_k<<<38, 256, 0, stream>>>(SUMS, MAXBu, AB4, WB + 614400, CONTRIB,
                                     pf_g[0], pf_b[0], pf_g[1], pf_b[1], pf_g[2], pf_b[2], pf_g[3], pf_b[3]);
    // cls0: stage-norm via AB4; K-split x4 raw fp16 partials
    mgemm3_k<2, 2, 0><<<dim3(128, 2, 4), 256, 0, stream>>>(XCb, LDC, WB + 155648, 1376, Yh, 256,
                                                           256, 1376, 352, SL(4), nullptr, nullptr, nullptr,
                                                           AB4, MAXBu);
    red4stat_k<<<dim3(4, 64), 256, 0, stream>>>(Yh, CONTRIB, SL(4));
    // cls1: stage-norm SL(4); raw -> C1b; stats SL(5)
    mgemm64_k<1, 1><<<dim3(128, 4), 256, 0, stream>>>(Yh, 256, WB + 507904, 256, C1b, 256, 256, 256,
                                                      SL(5), SL(4), cls_g[0], cls_b[0]);
    // cls2: stage-norm SL(5); raw -> C2b; stats SL(6)
    mgemm64_k<1, 1><<<dim3(128, 2), 256, 0, stream>>>(C1b, 256, WB + 507904 + 65536, 256, C2b, 128, 128, 256,
                                                      SL(6), SL(5), cls_g[1], cls_b[1]);
    // cls3: stage-norm SL(6); direct (b,50,n) output + bias
    mgemm64_k<3, 1><<<dim3(128, 1), 256, 0, stream>>>(C2b, 128, WB + 606208, 128, (void*)out, 0, 64, 128,
                                                      (float*)cls3_bias, SL(6), cls_g[2], cls_b[2]);

    (void)in_sizes; (void)n_in; (void)out_size; (void)ws_size;
}

// Round 18
// 161.502 us; speedup vs baseline: 1.7900x; 1.0179x over previous
//
#include <hip/hip_runtime.h>
#include <math.h>

#define BB 4
#define NN 2048
#define MM 8192
#define EPSF 1e-5f
#define LDC 1376   // concat stride: onehot16 | pf0 64 | pf1 128 | pf2 128 | pf3 1024 | pad16

typedef _Float16 half8 __attribute__((ext_vector_type(8)));
typedef float f32x4 __attribute__((ext_vector_type(4)));

__device__ __forceinline__ unsigned short f2h(float x) {
    _Float16 h = (_Float16)x;
    return __builtin_bit_cast(unsigned short, h);
}
__device__ __forceinline__ float h2f(unsigned short u) {
    return (float)__builtin_bit_cast(_Float16, u);
}
// order-preserving float<->unsigned for atomicMax over signed floats
__device__ __forceinline__ unsigned fflip(float x) {
    unsigned u = __builtin_bit_cast(unsigned, x);
    return (u >> 31) ? ~u : (u | 0x80000000u);
}
__device__ __forceinline__ float funflip(unsigned s) {
    unsigned u = (s >> 31) ? (s ^ 0x80000000u) : ~s;
    return __builtin_bit_cast(float, u);
}
#define FLIP_NEG_INF 0x007FFFFFu

__device__ __forceinline__ float angle3(float ux, float uy, float uz,
                                        float vx, float vy, float vz) {
    float crx = uy * vz - uz * vy;
    float cry = uz * vx - ux * vz;
    float crz = ux * vy - uy * vx;
    float s = sqrtf(crx * crx + cry * cry + crz * crz);
    float c = ux * vx + uy * vy + uz * vz;
    return atan2f(s, c);
}

// BN coefficient from a sums slice
__device__ __forceinline__ void bncoef(const float* __restrict__ sums,
                                       const float* __restrict__ g,
                                       const float* __restrict__ bb,
                                       int o, float& a, float& c) {
    float mu = sums[o] * (1.f / 8192.f);
    float var = sums[1024 + o] * (1.f / 8192.f) - mu * mu;
    var = fmaxf(var, 0.f);
    a = g[o] * (1.0f / sqrtf(var + EPSF));
    c = bb[o] - mu * a;
}

// ---------------------------------------------------------------------------
// fused preamble: wconv x4 (0..863) | stats (864..867) | init SUMS/MAXB/CONTRIB
// (868..943; MAXB gets flip(-inf)) | onehot+pad (944..975)
// ---------------------------------------------------------------------------
__global__ __launch_bounds__(256) void prep_k(const float* __restrict__ in,
                                              const float* __restrict__ w1, const float* __restrict__ w2,
                                              const float* __restrict__ w3, const float* __restrict__ w4,
                                              const float* __restrict__ w5, const float* __restrict__ w6,
                                              const float* __restrict__ w7,
                                              unsigned short* __restrict__ Wb,
                                              float* __restrict__ st,
                                              unsigned* __restrict__ zp,
                                              unsigned short* __restrict__ XCb) {
    int blk = blockIdx.x;
    int t = threadIdx.x;
    if (blk < 864) {
        int idx0 = blk * 1024 + t * 4;
        ushort4 r;
        unsigned short* rp = (unsigned short*)&r;
        #pragma unroll
        for (int e = 0; e < 4; ++e) {
            int idx = idx0 + e;
            unsigned short v;
            if (idx < 8192) v = f2h(w1[idx]);
            else if (idx < 24576) v = f2h(w2[idx - 8192]);
            else if (idx < 155648) v = f2h(w3[idx - 24576]);
            else if (idx < 507904) {
                int l = idx - 155648;
                int o = l / 1376, k = l - o * 1376;
                v = (k < 1360) ? f2h(w4[o * 2384 + k]) : (unsigned short)0;
            } else if (idx < 573440) v = f2h(w5[idx - 507904]);
            else if (idx < 606208) v = f2h(w6[idx - 573440]);
            else if (idx < 614400) {
                int l = idx - 606208;
                int o = l >> 7, k = l & 127;
                v = (o < 50) ? f2h(w7[o * 128 + k]) : (unsigned short)0;
            } else {
                int l = idx - 614400;
                int c = l >> 8, o = l & 255;
                v = (c < 1024) ? f2h(w4[o * 2384 + 1360 + c]) : (unsigned short)0;
            }
            rp[e] = v;
        }
        *(ushort4*)&Wb[idx0] = r;
    } else if (blk < 868) {
        int b = blk - 864;
        const float* base = in + (size_t)b * 22 * NN;
        float cs0 = 0.f, cs1 = 0.f, cs2 = 0.f, ns0 = 0.f, ns1 = 0.f, ns2 = 0.f;
        for (int n = t; n < NN; n += 256) {
            float cx = base[0 * NN + n], cy = base[1 * NN + n], cz = base[2 * NN + n];
            float nx = base[3 * NN + n], ny = base[4 * NN + n], nz = base[5 * NN + n];
            float inv = 1.0f / sqrtf(nx * nx + ny * ny + nz * nz);
            cs0 += cx; cs1 += cy; cs2 += cz;
            ns0 += nx * inv; ns1 += ny * inv; ns2 += nz * inv;
        }
        __shared__ float red[6][256];
        red[0][t] = cs0; red[1][t] = cs1; red[2][t] = cs2;
        red[3][t] = ns0; red[4][t] = ns1; red[5][t] = ns2;
        __syncthreads();
        for (int s = 128; s > 0; s >>= 1) {
            if (t < s) {
                #pragma unroll
                for (int i = 0; i < 6; ++i) red[i][t] += red[i][t + s];
            }
            __syncthreads();
        }
        if (t == 0) {
            float ccx = red[0][0] / (float)NN, ccy = red[1][0] / (float)NN, ccz = red[2][0] / (float)NN;
            float cnx = red[3][0] / (float)NN, cny = red[4][0] / (float)NN, cnz = red[5][0] / (float)NN;
            float inv = 1.0f / sqrtf(cnx * cnx + cny * cny + cnz * cnz);
            float* s9 = st + b * 16;
            s9[0] = ccx; s9[1] = ccy; s9[2] = ccz;
            s9[3] = cnx; s9[4] = cny; s9[5] = cnz;
            s9[6] = cnx * inv; s9[7] = cny * inv; s9[8] = cnz * inv;
        }
    } else if (blk < 944) {
        int idx = (blk - 868) * 256 + t;
        zp[idx] = (idx >= 14336 && idx < 18432) ? FLIP_NEG_INF : 0u;
    } else {
        int m = (blk - 944) * 256 + t;
        int b = m >> 11, n = m & (NN - 1);
        const float* src = in + (size_t)b * 22 * NN + 6 * NN + n;
        unsigned short vals[16];
        #pragma unroll
        for (int r = 0; r < 16; ++r) vals[r] = f2h(src[(size_t)r * NN]);
        ushort4* dst = (ushort4*)&XCb[(size_t)m * LDC];
        #pragma unroll
        for (int q = 0; q < 4; ++q)
            dst[q] = make_ushort4(vals[4 * q], vals[4 * q + 1], vals[4 * q + 2], vals[4 * q + 3]);
        ushort4 z = make_ushort4(0, 0, 0, 0);
        ushort4* pz = (ushort4*)&XCb[(size_t)m * LDC + 1360];
        pz[0] = z; pz[1] = z; pz[2] = z; pz[3] = z;
    }
}

// ---------------------------------------------------------------------------
// per-point PPF + packed projected vectors PQ = (x,y,z,|P|)
// ---------------------------------------------------------------------------
__global__ __launch_bounds__(256) void point_k(const float* __restrict__ in,
                                               const float* __restrict__ st,
                                               float4* __restrict__ PQ,
                                               float* __restrict__ F0) {
    int idx = blockIdx.x * 256 + threadIdx.x;
    int b = idx >> 11, n = idx & (NN - 1);
    const float* base = in + (size_t)b * 22 * NN;
    const float* s9 = st + b * 16;
    float cx = base[0 * NN + n], cy = base[1 * NN + n], cz = base[2 * NN + n];
    float nx = base[3 * NN + n], ny = base[4 * NN + n], nz = base[5 * NN + n];
    float inv = 1.0f / sqrtf(nx * nx + ny * ny + nz * nz);
    nx *= inv; ny *= inv; nz *= inv;
    float ccx = s9[0], ccy = s9[1], ccz = s9[2];
    float cnx = s9[3], cny = s9[4], cnz = s9[5];
    float ex = s9[6], ey = s9[7], ez = s9[8];
    float dx = cx - ccx, dy = cy - ccy, dz = cz - ccz;
    F0[0 * MM + idx] = angle3(cnx, cny, cnz, dx, dy, dz);
    F0[1 * MM + idx] = angle3(nx, ny, nz, dx, dy, dz);
    F0[2 * MM + idx] = angle3(cnx, cny, cnz, nx, ny, nz);
    F0[3 * MM + idx] = sqrtf(dx * dx + dy * dy + dz * dz);
    float dot = dx * ex + dy * ey + dz * ez;
    float px = dx - dot * cnx;
    float py = dy - dot * cny;
    float pz = dz - dot * cnz;
    PQ[idx] = make_float4(px, py, pz, sqrtf(px * px + py * py + pz * pz));
}

// ---------------------------------------------------------------------------
// per-row median via two-pass LDS histogram (R17) with ALGEBRAIC key:
// tan^2(th/2) = (1-cos)/(1+cos) = (|a||b| - a.b)/(|a||b| + a.b)  — uses the
// precomputed norms in PQ.w, eliminating the 9-op cross product (~2x fewer
// VALU ops/pair; R17 showed key-compute is now the dominant cost).
// Cancellation noise in (h-dc) is ~5e-8 absolute — guard threshold 2e-7
// absorbs it (diagonal/near-parallel/antiparallel -> +inf, sorts last,
// matching the reference's at<=1e-5 -> 100 class; median-region keys O(1)
// are unaffected). Exact fp16-grid rank select as before.
// ---------------------------------------------------------------------------
__global__ __launch_bounds__(256) void alpha_k(const float4* __restrict__ PQ,
                                               float* __restrict__ F0) {
    __shared__ unsigned hist[4][256];
    int wv = threadIdx.x >> 6;
    int lane = threadIdx.x & 63;
    int row = blockIdx.x * 4 + wv;
    int b = row >> 11;
    const float4* base = PQ + (size_t)b * NN;
    float4 a = base[row & (NN - 1)];
    unsigned u[16];
    #pragma unroll
    for (int c = 0; c < 4; ++c) {
        #pragma unroll
        for (int j = 0; j < 4; ++j) {
            int s2 = c * 8 + j * 2;
            float4 bv0 = base[s2 * 64 + lane];
            float4 bv1 = base[(s2 + 1) * 64 + lane];
            float k0, k1;
            {
                float dc = a.x * bv0.x + a.y * bv0.y + a.z * bv0.z;
                float h = a.w * bv0.w;
                float rc = __builtin_amdgcn_rcpf(h + dc);
                k0 = (h - dc) * rc;
                if (k0 <= 2e-7f) k0 = __builtin_inff();
            }
            {
                float dc = a.x * bv1.x + a.y * bv1.y + a.z * bv1.z;
                float h = a.w * bv1.w;
                float rc = __builtin_amdgcn_rcpf(h + dc);
                k1 = (h - dc) * rc;
                if (k1 <= 2e-7f) k1 = __builtin_inff();
            }
            u[c * 4 + j] = (unsigned)f2h(k0) | ((unsigned)f2h(k1) << 16);
        }
        asm volatile("" ::: "memory");
    }
    unsigned* h = hist[wv];
    h[lane] = 0; h[lane + 64] = 0; h[lane + 128] = 0; h[lane + 192] = 0;
    __syncthreads();
    #pragma unroll
    for (int q = 0; q < 16; ++q) {
        atomicAdd(&h[(u[q] & 0xFFFFu) >> 7], 1u);
        atomicAdd(&h[u[q] >> 23], 1u);
    }
    __syncthreads();
    const unsigned K = 1023;
    unsigned h0 = h[4 * lane], h1 = h[4 * lane + 1], h2 = h[4 * lane + 2], h3 = h[4 * lane + 3];
    unsigned lsum = h0 + h1 + h2 + h3;
    unsigned inc = lsum;
    #pragma unroll
    for (int d = 1; d < 64; d <<= 1) {
        unsigned tv = __shfl_up(inc, d);
        if (lane >= d) inc += tv;
    }
    unsigned excl = inc - lsum;
    bool has = (excl <= K) && (K < inc);
    unsigned long long mask = __ballot(has);
    int L = __ffsll((long long)mask) - 1;
    unsigned packed = 0;
    if (has) {
        unsigned e = excl, Bq = 4 * lane;
        if (e + h0 <= K) { e += h0; Bq++;
            if (e + h1 <= K) { e += h1; Bq++;
                if (e + h2 <= K) { e += h2; Bq++; } } }
        packed = (Bq << 16) | e;
    }
    packed = __shfl(packed, L);
    unsigned B = packed >> 16;
    unsigned k2 = K - (packed & 0xFFFFu);
    __syncthreads();
    h[lane] = 0; h[lane + 64] = 0;
    __syncthreads();
    #pragma unroll
    for (int q = 0; q < 16; ++q) {
        unsigned lo = u[q] & 0xFFFFu, hi = u[q] >> 16;
        if ((lo >> 7) == B) atomicAdd(&h[lo & 127], 1u);
        if ((hi >> 7) == B) atomicAdd(&h[hi & 127], 1u);
    }
    __syncthreads();
    unsigned g0 = h[2 * lane], g1 = h[2 * lane + 1];
    unsigned ls2 = g0 + g1, inc2 = ls2;
    #pragma unroll
    for (int d = 1; d < 64; d <<= 1) {
        unsigned tv = __shfl_up(inc2, d);
        if (lane >= d) inc2 += tv;
    }
    unsigned excl2 = inc2 - ls2;
    bool has2 = (excl2 <= k2) && (k2 < inc2);
    unsigned long long m2 = __ballot(has2);
    int L2 = __ffsll((long long)m2) - 1;
    unsigned low = 0;
    if (has2) low = 2 * lane + ((excl2 + g0 <= k2) ? 1u : 0u);
    low = __shfl(low, L2);
    unsigned T = (B << 7) | low;
    if (lane == 0) {
        float lo = h2f((unsigned short)T);
        float hi = h2f((unsigned short)(T + 1));
        F0[4 * MM + row] = 2.0f * atanf(sqrtf(0.5f * (lo + hi)));
    }
}

// ---------------------------------------------------------------------------
// pf0 + fused BN stats: raw fp16 into XCb+16; stats -> sums.
// ---------------------------------------------------------------------------
__global__ __launch_bounds__(256) void pf0s_k(const float* __restrict__ F0,
                                              const float* __restrict__ W,
                                              unsigned short* __restrict__ dst,
                                              float* __restrict__ sums) {
    __shared__ float ws[320];
    int t = threadIdx.x;
    for (int i = t; i < 320; i += 256) ws[i] = W[i];
    __syncthreads();
    int ol = t & 63, mg = t >> 6;
    int m0 = blockIdx.x * 512;
    float w0 = ws[ol * 5], w1 = ws[ol * 5 + 1], w2 = ws[ol * 5 + 2], w3 = ws[ol * 5 + 3], w4 = ws[ol * 5 + 4];
    float s = 0.f, q = 0.f;
    for (int i = 0; i < 128; ++i) {
        int m = m0 + i * 4 + mg;
        float y = w0 * F0[m] + w1 * F0[MM + m] + w2 * F0[2 * MM + m]
                + w3 * F0[3 * MM + m] + w4 * F0[4 * MM + m];
        dst[(size_t)m * LDC + ol] = f2h(y);
        s += y; q += y * y;
    }
    __shared__ float ls[4][64], lq[4][64];
    ls[mg][ol] = s; lq[mg][ol] = q;
    __syncthreads();
    if (mg == 0) {
        s = ls[0][ol] + ls[1][ol] + ls[2][ol] + ls[3][ol];
        q = lq[0][ol] + lq[1][ol] + lq[2][ol] + lq[3][ol];
        atomicAdd(&sums[ol], s);
        atomicAdd(&sums[1024 + ol], q);
    }
}

// ---------------------------------------------------------------------------
// fp16 MFMA GEMM BM=64 BO=128 with staging-normalization of X.
// TRANS: 0 none, 1 uniform (xs,xg,xb), 2 AB4 table (cls0).
// MODE: 1 raw fp16 out (yld) + stats [+DOMAX raw channel max]; 2 K-split partial.
// ---------------------------------------------------------------------------
template<int MODE, int TRANS, int DOMAX>
__global__ __launch_bounds__(256) void mgemm3_k(const unsigned short* __restrict__ X, int ldx,
                                                const unsigned short* __restrict__ W, int ldw,
                                                unsigned short* __restrict__ Yh, int yld, int Co, int K, int kchunk,
                                                float* __restrict__ sums,
                                                const float* __restrict__ xs, const float* __restrict__ xg,
                                                const float* __restrict__ xb,
                                                const float4* __restrict__ AB4,
                                                unsigned* __restrict__ maxbu) {
    __shared__ unsigned short As[64 * 32];
    __shared__ unsigned short Bs[128 * 32];
    __shared__ float4 ABl[352];
    int t = threadIdx.x;
    int mBase = blockIdx.x * 64;
    int oBase = blockIdx.y * 128;
    int k0c = blockIdx.z * kchunk;
    int k1c = k0c + kchunk; if (k1c > K) k1c = K;
    if (TRANS == 1) {
        float* abf = (float*)ABl;
        for (int i = t; i < K; i += 256) {
            float a, c; bncoef(xs, xg, xb, i, a, c);
            abf[2 * i] = a; abf[2 * i + 1] = c;
        }
    } else if (TRANS == 2) {
        for (int i = t; i < k1c - k0c; i += 256) ABl[i] = AB4[k0c + i];
    }
    int lane = t & 63, w = t >> 6;
    int warpM = (w & 1) * 32, warpO = (w >> 1) * 64;
    f32x4 acc[2][4];
    #pragma unroll
    for (int i = 0; i < 2; ++i)
        #pragma unroll
        for (int j = 0; j < 4; ++j) acc[i][j] = (f32x4){0.f, 0.f, 0.f, 0.f};
    int lr = t >> 2;
    int lc = (t & 3) * 8;
    const unsigned short* Xp = X + (size_t)(mBase + lr) * ldx + lc;
    const unsigned short* Wp0 = W + (size_t)(oBase + lr) * ldw + lc;
    const unsigned short* Wp1 = W + (size_t)(oBase + lr + 64) * ldw + lc;
    int ar0 = (warpM + (lane & 15)) * 32 + (lane >> 4) * 8;
    int br0 = (warpO + (lane & 15)) * 32 + (lane >> 4) * 8;
    uint4 xa = *(const uint4*)(Xp + k0c);
    uint4 wb0 = *(const uint4*)(Wp0 + k0c);
    uint4 wb1 = *(const uint4*)(Wp1 + k0c);
    for (int k = k0c; k < k1c; k += 32) {
        __syncthreads();
        uint4 xc = xa;
        if (TRANS == 1) {
            const float* abf = (const float*)ABl;
            unsigned short* p = (unsigned short*)&xc;
            int kb = k + lc;
            #pragma unroll
            for (int e = 0; e < 8; ++e)
                p[e] = f2h(fmaxf(abf[2 * (kb + e)] * h2f(p[e]) + abf[2 * (kb + e) + 1], 0.f));
        } else if (TRANS == 2) {
            unsigned short* p = (unsigned short*)&xc;
            int kb = k + lc - k0c;
            #pragma unroll
            for (int e = 0; e < 8; ++e) {
                float4 qd = ABl[kb + e];
                p[e] = f2h(fmaxf(qd.x * h2f(p[e]) + qd.y, qd.z));
            }
        }
        *(uint4*)&As[lr * 32 + lc] = xc;
        *(uint4*)&Bs[lr * 32 + lc] = wb0;
        *(uint4*)&Bs[(lr + 64) * 32 + lc] = wb1;
        if (k + 32 < k1c) {
            xa = *(const uint4*)(Xp + k + 32);
            wb0 = *(const uint4*)(Wp0 + k + 32);
            wb1 = *(const uint4*)(Wp1 + k + 32);
        }
        __syncthreads();
        half8 a0 = __builtin_bit_cast(half8, *(const uint4*)&As[ar0]);
        half8 a1 = __builtin_bit_cast(half8, *(const uint4*)&As[ar0 + 16 * 32]);
        half8 b0 = __builtin_bit_cast(half8, *(const uint4*)&Bs[br0]);
        half8 b1 = __builtin_bit_cast(half8, *(const uint4*)&Bs[br0 + 16 * 32]);
        half8 b2 = __builtin_bit_cast(half8, *(const uint4*)&Bs[br0 + 32 * 32]);
        half8 b3 = __builtin_bit_cast(half8, *(const uint4*)&Bs[br0 + 48 * 32]);
        acc[0][0] = __builtin_amdgcn_mfma_f32_16x16x32_f16(a0, b0, acc[0][0], 0, 0, 0);
        acc[0][1] = __builtin_amdgcn_mfma_f32_16x16x32_f16(a0, b1, acc[0][1], 0, 0, 0);
        acc[0][2] = __builtin_amdgcn_mfma_f32_16x16x32_f16(a0, b2, acc[0][2], 0, 0, 0);
        acc[0][3] = __builtin_amdgcn_mfma_f32_16x16x32_f16(a0, b3, acc[0][3], 0, 0, 0);
        acc[1][0] = __builtin_amdgcn_mfma_f32_16x16x32_f16(a1, b0, acc[1][0], 0, 0, 0);
        acc[1][1] = __builtin_amdgcn_mfma_f32_16x16x32_f16(a1, b1, acc[1][1], 0, 0, 0);
        acc[1][2] = __builtin_amdgcn_mfma_f32_16x16x32_f16(a1, b2, acc[1][2], 0, 0, 0);
        acc[1][3] = __builtin_amdgcn_mfma_f32_16x16x32_f16(a1, b3, acc[1][3], 0, 0, 0);
    }
    unsigned short* Yp = Yh + (MODE == 2 ? (size_t)blockIdx.z * MM * yld : 0);
    #pragma unroll
    for (int i = 0; i < 2; ++i)
        #pragma unroll
        for (int j = 0; j < 4; ++j) {
            int m0 = mBase + warpM + i * 16 + (lane >> 4) * 4;
            int o = oBase + warpO + j * 16 + (lane & 15);
            #pragma unroll
            for (int r = 0; r < 4; ++r)
                Yp[(size_t)(m0 + r) * yld + o] = f2h(acc[i][j][r]);
        }
    if (MODE == 1) {
        __syncthreads();
        float* ssum = (float*)As;
        unsigned* smax = (unsigned*)As + 128;
        float* ssq = (float*)Bs;
        if (t < 128) { ssum[t] = 0.f; ssq[t] = 0.f; if (DOMAX) smax[t] = FLIP_NEG_INF; }
        __syncthreads();
        #pragma unroll
        for (int j = 0; j < 4; ++j) {
            int oc = warpO + j * 16 + (lane & 15);
            float s = 0.f, q = 0.f, mx = -__builtin_inff();
            #pragma unroll
            for (int i = 0; i < 2; ++i)
                #pragma unroll
                for (int r = 0; r < 4; ++r) {
                    float v = acc[i][j][r];
                    s += v; q += v * v; mx = fmaxf(mx, v);
                }
            atomicAdd(&ssum[oc], s);
            atomicAdd(&ssq[oc], q);
            if (DOMAX) atomicMax(&smax[oc], fflip(mx));
        }
        __syncthreads();
        if (t < 128) {
            atomicAdd(&sums[oBase + t], ssum[t]);
            atomicAdd(&sums[1024 + oBase + t], ssq[t]);
            if (DOMAX) atomicMax(&maxbu[(mBase >> 11) * 1024 + oBase + t], smax[t]);
        }
    }
}

// ---------------------------------------------------------------------------
// fp16 MFMA GEMM BM=64 BO=64 with staging-normalization.
// MODE 1: raw fp16 out (yld) + stats. MODE 3: direct (b,50,n) out + bias.
// ---------------------------------------------------------------------------
template<int MODE, int TRANS>
__global__ __launch_bounds__(256) void mgemm64_k(const unsigned short* __restrict__ X, int ldx,
                                                 const unsigned short* __restrict__ W, int ldw,
                                                 void* __restrict__ Yv, int yld, int Co, int K,
                                                 float* __restrict__ sums,
                                                 const float* __restrict__ xs, const float* __restrict__ xg,
                                                 const float* __restrict__ xb) {
    __shared__ unsigned short As[64 * 32];
    __shared__ unsigned short Bs[64 * 32];
    __shared__ float ABl[512];
    int t = threadIdx.x;
    int mBase = blockIdx.x * 64;
    int oBase = blockIdx.y * 64;
    if (TRANS == 1) {
        for (int i = t; i < K; i += 256) {
            float a, c; bncoef(xs, xg, xb, i, a, c);
            ABl[2 * i] = a; ABl[2 * i + 1] = c;
        }
    }
    int lane = t & 63, w = t >> 6;
    int warpM = (w & 1) * 32, warpO = (w >> 1) * 32;
    f32x4 acc[2][2];
    #pragma unroll
    for (int i = 0; i < 2; ++i)
        #pragma unroll
        for (int j = 0; j < 2; ++j) acc[i][j] = (f32x4){0.f, 0.f, 0.f, 0.f};
    int lr = t >> 2;
    int lc = (t & 3) * 8;
    const unsigned short* Xp = X + (size_t)(mBase + lr) * ldx + lc;
    const unsigned short* Wp = W + (size_t)(oBase + lr) * ldw + lc;
    int ar0 = (warpM + (lane & 15)) * 32 + (lane >> 4) * 8;
    int br0 = (warpO + (lane & 15)) * 32 + (lane >> 4) * 8;
    uint4 xa = *(const uint4*)(Xp);
    uint4 wb = *(const uint4*)(Wp);
    for (int k = 0; k < K; k += 32) {
        __syncthreads();
        uint4 xc = xa;
        if (TRANS == 1) {
            unsigned short* p = (unsigned short*)&xc;
            int kb = k + lc;
            #pragma unroll
            for (int e = 0; e < 8; ++e)
                p[e] = f2h(fmaxf(ABl[2 * (kb + e)] * h2f(p[e]) + ABl[2 * (kb + e) + 1], 0.f));
        }
        *(uint4*)&As[lr * 32 + lc] = xc;
        *(uint4*)&Bs[lr * 32 + lc] = wb;
        if (k + 32 < K) {
            xa = *(const uint4*)(Xp + k + 32);
            wb = *(const uint4*)(Wp + k + 32);
        }
        __syncthreads();
        half8 a0 = __builtin_bit_cast(half8, *(const uint4*)&As[ar0]);
        half8 a1 = __builtin_bit_cast(half8, *(const uint4*)&As[ar0 + 16 * 32]);
        half8 b0 = __builtin_bit_cast(half8, *(const uint4*)&Bs[br0]);
        half8 b1 = __builtin_bit_cast(half8, *(const uint4*)&Bs[br0 + 16 * 32]);
        acc[0][0] = __builtin_amdgcn_mfma_f32_16x16x32_f16(a0, b0, acc[0][0], 0, 0, 0);
        acc[0][1] = __builtin_amdgcn_mfma_f32_16x16x32_f16(a0, b1, acc[0][1], 0, 0, 0);
        acc[1][0] = __builtin_amdgcn_mfma_f32_16x16x32_f16(a1, b0, acc[1][0], 0, 0, 0);
        acc[1][1] = __builtin_amdgcn_mfma_f32_16x16x32_f16(a1, b1, acc[1][1], 0, 0, 0);
    }
    if (MODE == 3) {
        float* outp = (float*)Yv;
        #pragma unroll
        for (int i = 0; i < 2; ++i)
            #pragma unroll
            for (int j = 0; j < 2; ++j) {
                int m0 = mBase + warpM + i * 16 + (lane >> 4) * 4;
                int o = oBase + warpO + j * 16 + (lane & 15);
                if (o < 50) {
                    int bb2 = m0 >> 11, n = m0 & (NN - 1);
                    float bi = sums[o];
                    float4 v = make_float4(acc[i][j][0] + bi, acc[i][j][1] + bi,
                                           acc[i][j][2] + bi, acc[i][j][3] + bi);
                    *(float4*)&outp[((size_t)bb2 * 50 + o) * NN + n] = v;
                }
            }
    } else {
        unsigned short* Yh = (unsigned short*)Yv;
        #pragma unroll
        for (int i = 0; i < 2; ++i)
            #pragma unroll
            for (int j = 0; j < 2; ++j) {
                int m0 = mBase + warpM + i * 16 + (lane >> 4) * 4;
                int o = oBase + warpO + j * 16 + (lane & 15);
                #pragma unroll
                for (int r = 0; r < 4; ++r)
                    Yh[(size_t)(m0 + r) * yld + o] = f2h(acc[i][j][r]);
            }
        __syncthreads();
        float* ssum = (float*)As;
        float* ssq = (float*)Bs;
        if (t < 64) { ssum[t] = 0.f; ssq[t] = 0.f; }
        __syncthreads();
        #pragma unroll
        for (int j = 0; j < 2; ++j) {
            int oc = warpO + j * 16 + (lane & 15);
            float s = 0.f, q = 0.f;
            #pragma unroll
            for (int i = 0; i < 2; ++i)
                #pragma unroll
                for (int r = 0; r < 4; ++r) { float v = acc[i][j][r]; s += v; q += v * v; }
            atomicAdd(&ssum[oc], s);
            atomicAdd(&ssq[oc], q);
        }
        __syncthreads();
        if (t < 64) {
            atomicAdd(&sums[oBase + t], ssum[t]);
            atomicAdd(&sums[1024 + oBase + t], ssq[t]);
        }
    }
}

// ---------------------------------------------------------------------------
// fused: build cls0 coefficient table AB4[1376] (blocks 0..5) + max-feature
// GEMV with inline normalized maxes (blocks 6..37)
// ---------------------------------------------------------------------------
__global__ __launch_bounds__(256) void abgemv_k(const float* __restrict__ SUMS,
                                                const unsigned* __restrict__ MAXBu,
                                                float4* __restrict__ AB4,
                                                const unsigned short* __restrict__ Wmax,
                                                float* __restrict__ contrib,
                                                const float* g0, const float* b0,
                                                const float* g1, const float* b1,
                                                const float* g2, const float* b2,
                                                const float* g3, const float* b3) {
    int blk = blockIdx.x, t = threadIdx.x;
    if (blk < 6) {
        int ch = blk * 256 + t;
        if (ch >= 1376) return;
        float4 r;
        if (ch < 16) r = make_float4(1.f, 0.f, -__builtin_inff(), 0.f);
        else if (ch < 80) { float a, c; bncoef(SUMS, g0, b0, ch - 16, a, c); r = make_float4(a, c, 0.f, 0.f); }
        else if (ch < 208) { float a, c; bncoef(SUMS + 2048, g1, b1, ch - 80, a, c); r = make_float4(a, c, 0.f, 0.f); }
        else if (ch < 336) { float a, c; bncoef(SUMS + 4096, g2, b2, ch - 208, a, c); r = make_float4(a, c, 0.f, 0.f); }
        else if (ch < 1360) { float a, c; bncoef(SUMS + 6144, g3, b3, ch - 336, a, c); r = make_float4(a, c, 0.f, 0.f); }
        else r = make_float4(0.f, 0.f, 0.f, 0.f);
        AB4[ch] = r;
    } else {
        int i = blk - 6;
        int b = i >> 3;
        int cc = (i & 7) * 128;
        __shared__ float nm[128];
        if (t < 128) {
            int c = cc + t;
            float a, cf; bncoef(SUMS + 6144, g3, b3, c, a, cf);
            float raw = funflip(MAXBu[b * 1024 + c]);
            nm[t] = fmaxf(a * raw + cf, 0.f);
        }
        __syncthreads();
        int o = t;
        float acc = 0.f;
        for (int c = 0; c < 128; ++c)
            acc += h2f(Wmax[(size_t)(cc + c) * 256 + o]) * nm[c];
        atomicAdd(&contrib[b * 256 + o], acc);
    }
}

// ---------------------------------------------------------------------------
// cls0 finish: sum 4 fp16 K-split partials + contrib -> raw fp16 partial0 + stats
// ---------------------------------------------------------------------------
__global__ __launch_bounds__(256) void red4stat_k(unsigned short* __restrict__ Yh,
                                                  const float* __restrict__ contrib,
                                                  float* __restrict__ sums) {
    int o0 = blockIdx.x * 64;
    int m0 = blockIdx.y * 128;
    int t = threadIdx.x, ol = t & 63, mg = t >> 6;
    int b = m0 >> 11;
    float cb = contrib[b * 256 + o0 + ol];
    const size_t stride = (size_t)MM * 256;
    float s = 0.f, q = 0.f;
    unsigned short* p = Yh + (size_t)(m0 + mg) * 256 + o0 + ol;
    for (int i = 0; i < 32; ++i) {
        unsigned short* pp = p + (size_t)i * 4 * 256;
        float v = h2f(pp[0]) + h2f(pp[stride]) + h2f(pp[2 * stride]) + h2f(pp[3 * stride]) + cb;
        pp[0] = f2h(v);
        s += v; q += v * v;
    }
    __shared__ float ls[4][64], lq[4][64];
    ls[mg][ol] = s; lq[mg][ol] = q;
    __syncthreads();
    if (mg == 0) {
        s = ls[0][ol] + ls[1][ol] + ls[2][ol] + ls[3][ol];
        q = lq[0][ol] + lq[1][ol] + lq[2][ol] + lq[3][ol];
        atomicAdd(&sums[o0 + ol], s);
        atomicAdd(&sums[1024 + o0 + ol], q);
    }
}

// ---------------------------------------------------------------------------
extern "C" void kernel_launch(void* const* d_in, const int* in_sizes, int n_in,
                              void* d_out, int out_size, void* d_ws, size_t ws_size,
                              hipStream_t stream) {
    const float* in = (const float*)d_in[0];
    const float* pf0_w = (const float*)d_in[1];
    const float* pf_g[4] = {(const float*)d_in[2], (const float*)d_in[5], (const float*)d_in[8], (const float*)d_in[11]};
    const float* pf_b[4] = {(const float*)d_in[3], (const float*)d_in[6], (const float*)d_in[9], (const float*)d_in[12]};
    const float* pf_w[4] = {(const float*)d_in[1], (const float*)d_in[4], (const float*)d_in[7], (const float*)d_in[10]};
    const float* cls_w[3] = {(const float*)d_in[13], (const float*)d_in[16], (const float*)d_in[19]};
    const float* cls_g[3] = {(const float*)d_in[14], (const float*)d_in[17], (const float*)d_in[20]};
    const float* cls_b[3] = {(const float*)d_in[15], (const float*)d_in[18], (const float*)d_in[21]};
    const float* cls3_w = (const float*)d_in[22];
    const float* cls3_bias = (const float*)d_in[23];
    float* out = (float*)d_out;

    char* wsb = (char*)d_ws;
    float* ST = (float*)(wsb + 0);
    float4* PQ = (float4*)(wsb + 256);
    float* F0 = (float*)(wsb + 131328);
    float* SUMS = (float*)(wsb + 295168);
    unsigned* MAXBu = (unsigned*)(wsb + 352512);
    float* CONTRIB = (float*)(wsb + 368896);
    float4* AB4 = (float4*)(wsb + 372992);
    unsigned short* WB = (unsigned short*)(wsb + 411392);
    unsigned short* XCb = (unsigned short*)(wsb + 2180864);
    unsigned short* C1b = (unsigned short*)(wsb + 24725248);
    unsigned short* C2b = (unsigned short*)(wsb + 28919552);
    unsigned short* Yh = (unsigned short*)(wsb + 33113856);

    auto SL = [&](int s) { return SUMS + (size_t)s * 2048; };

    prep_k<<<976, 256, 0, stream>>>(in, pf_w[1], pf_w[2], pf_w[3], cls_w[0], cls_w[1], cls_w[2], cls3_w,
                                    WB, ST, (unsigned*)SUMS, XCb);
    point_k<<<MM / 256, 256, 0, stream>>>(in, ST, PQ, F0);
    alpha_k<<<MM / 4, 256, 0, stream>>>(PQ, F0);

    // pf0 raw -> XCb+16 with fused stats SL(0)
    pf0s_k<<<16, 256, 0, stream>>>(F0, pf0_w, XCb + 16, SL(0));
    // pf1: stage-norm SL(0); raw -> XCb+80; stats SL(1)
    mgemm64_k<1, 1><<<dim3(128, 2), 256, 0, stream>>>(XCb + 16, LDC, WB, 64, XCb + 80, LDC, 128, 64,
                                                      SL(1), SL(0), pf_g[0], pf_b[0]);
    // pf2: stage-norm SL(1); raw -> XCb+208; stats SL(2)
    mgemm64_k<1, 1><<<dim3(128, 2), 256, 0, stream>>>(XCb + 80, LDC, WB + 8192, 128, XCb + 208, LDC, 128, 128,
                                                      SL(2), SL(1), pf_g[1], pf_b[1]);
    // pf3: stage-norm SL(2); raw -> XCb+336; stats SL(3) + raw channel max
    mgemm3_k<1, 1, 1><<<dim3(128, 8, 1), 256, 0, stream>>>(XCb + 208, LDC, WB + 24576, 128, XCb + 336, LDC,
                                                           1024, 128, 128, SL(3), SL(2), pf_g[2], pf_b[2],
                                                           AB4, MAXBu);
    // fused coefficient table + max-feature GEMV
    abgemv_k<<<38, 256, 0, stream>>>(SUMS, MAXBu, AB4, WB + 614400, CONTRIB,
                                     pf_g[0], pf_b[0], pf_g[1], pf_b[1], pf_g[2], pf_b[2], pf_g[3], pf_b[3]);
    // cls0: stage-norm via AB4; K-split x4 raw fp16 partials
    mgemm3_k<2, 2, 0><<<dim3(128, 2, 4), 256, 0, stream>>>(XCb, LDC, WB + 155648, 1376, Yh, 256,
                                                           256, 1376, 352, SL(4), nullptr, nullptr, nullptr,
                                                           AB4, MAXBu);
    red4stat_k<<<dim3(4, 64), 256, 0, stream>>>(Yh, CONTRIB, SL(4));
    // cls1: stage-norm SL(4); raw -> C1b; stats SL(5)
    mgemm64_k<1, 1><<<dim3(128, 4), 256, 0, stream>>>(Yh, 256, WB + 507904, 256, C1b, 256, 256, 256,
                                                      SL(5), SL(4), cls_g[0], cls_b[0]);
    // cls2: stage-norm SL(5); raw -> C2b; stats SL(6)
    mgemm64_k<1, 1><<<dim3(128, 2), 256, 0, stream>>>(C1b, 256, WB + 507904 + 65536, 256, C2b, 128, 128, 256,
                                                      SL(6), SL(5), cls_g[1], cls_b[1]);
    // cls3: stage-norm SL(6); direct (b,50,n) output + bias
    mgemm64_k<3, 1><<<dim3(128, 1), 256, 0, stream>>>(C2b, 128, WB + 606208, 128, (void*)out, 0, 64, 128,
                                                      (float*)cls3_bias, SL(6), cls_g[2], cls_b[2]);

    (void)in_sizes; (void)n_in; (void)out_size; (void)ws_size;
}

// Round 19
// 143.521 us; speedup vs baseline: 2.0143x; 1.1253x over previous
//
#include <hip/hip_runtime.h>
#include <math.h>

#define BB 4
#define NN 2048
#define MM 8192
#define EPSF 1e-5f
#define LDC 1376   // concat stride: onehot16 | pf0 64 | pf1 128 | pf2 128 | pf3 1024 | pad16

typedef _Float16 half8 __attribute__((ext_vector_type(8)));
typedef float f32x4 __attribute__((ext_vector_type(4)));

__device__ __forceinline__ unsigned short f2h(float x) {
    _Float16 h = (_Float16)x;
    return __builtin_bit_cast(unsigned short, h);
}
__device__ __forceinline__ float h2f(unsigned short u) {
    return (float)__builtin_bit_cast(_Float16, u);
}
// order-preserving float<->unsigned for atomicMax over signed floats
__device__ __forceinline__ unsigned fflip(float x) {
    unsigned u = __builtin_bit_cast(unsigned, x);
    return (u >> 31) ? ~u : (u | 0x80000000u);
}
__device__ __forceinline__ float funflip(unsigned s) {
    unsigned u = (s >> 31) ? (s ^ 0x80000000u) : ~s;
    return __builtin_bit_cast(float, u);
}
#define FLIP_NEG_INF 0x007FFFFFu

__device__ __forceinline__ float angle3(float ux, float uy, float uz,
                                        float vx, float vy, float vz) {
    float crx = uy * vz - uz * vy;
    float cry = uz * vx - ux * vz;
    float crz = ux * vy - uy * vx;
    float s = sqrtf(crx * crx + cry * cry + crz * crz);
    float c = ux * vx + uy * vy + uz * vz;
    return atan2f(s, c);
}

// BN coefficient from a sums slice
__device__ __forceinline__ void bncoef(const float* __restrict__ sums,
                                       const float* __restrict__ g,
                                       const float* __restrict__ bb,
                                       int o, float& a, float& c) {
    float mu = sums[o] * (1.f / 8192.f);
    float var = sums[1024 + o] * (1.f / 8192.f) - mu * mu;
    var = fmaxf(var, 0.f);
    a = g[o] * (1.0f / sqrtf(var + EPSF));
    c = bb[o] - mu * a;
}

// ---------------------------------------------------------------------------
// fused preamble: wconv x4 (0..863) | stats (864..867) | init SUMS/MAXB/CONTRIB
// (868..943; MAXB gets flip(-inf)) | onehot+pad (944..975)
// ---------------------------------------------------------------------------
__global__ __launch_bounds__(256) void prep_k(const float* __restrict__ in,
                                              const float* __restrict__ w1, const float* __restrict__ w2,
                                              const float* __restrict__ w3, const float* __restrict__ w4,
                                              const float* __restrict__ w5, const float* __restrict__ w6,
                                              const float* __restrict__ w7,
                                              unsigned short* __restrict__ Wb,
                                              float* __restrict__ st,
                                              unsigned* __restrict__ zp,
                                              unsigned short* __restrict__ XCb) {
    int blk = blockIdx.x;
    int t = threadIdx.x;
    if (blk < 864) {
        int idx0 = blk * 1024 + t * 4;
        ushort4 r;
        unsigned short* rp = (unsigned short*)&r;
        #pragma unroll
        for (int e = 0; e < 4; ++e) {
            int idx = idx0 + e;
            unsigned short v;
            if (idx < 8192) v = f2h(w1[idx]);
            else if (idx < 24576) v = f2h(w2[idx - 8192]);
            else if (idx < 155648) v = f2h(w3[idx - 24576]);
            else if (idx < 507904) {
                int l = idx - 155648;
                int o = l / 1376, k = l - o * 1376;
                v = (k < 1360) ? f2h(w4[o * 2384 + k]) : (unsigned short)0;
            } else if (idx < 573440) v = f2h(w5[idx - 507904]);
            else if (idx < 606208) v = f2h(w6[idx - 573440]);
            else if (idx < 614400) {
                int l = idx - 606208;
                int o = l >> 7, k = l & 127;
                v = (o < 50) ? f2h(w7[o * 128 + k]) : (unsigned short)0;
            } else {
                int l = idx - 614400;
                int c = l >> 8, o = l & 255;
                v = (c < 1024) ? f2h(w4[o * 2384 + 1360 + c]) : (unsigned short)0;
            }
            rp[e] = v;
        }
        *(ushort4*)&Wb[idx0] = r;
    } else if (blk < 868) {
        int b = blk - 864;
        const float* base = in + (size_t)b * 22 * NN;
        float cs0 = 0.f, cs1 = 0.f, cs2 = 0.f, ns0 = 0.f, ns1 = 0.f, ns2 = 0.f;
        for (int n = t; n < NN; n += 256) {
            float cx = base[0 * NN + n], cy = base[1 * NN + n], cz = base[2 * NN + n];
            float nx = base[3 * NN + n], ny = base[4 * NN + n], nz = base[5 * NN + n];
            float inv = 1.0f / sqrtf(nx * nx + ny * ny + nz * nz);
            cs0 += cx; cs1 += cy; cs2 += cz;
            ns0 += nx * inv; ns1 += ny * inv; ns2 += nz * inv;
        }
        __shared__ float red[6][256];
        red[0][t] = cs0; red[1][t] = cs1; red[2][t] = cs2;
        red[3][t] = ns0; red[4][t] = ns1; red[5][t] = ns2;
        __syncthreads();
        for (int s = 128; s > 0; s >>= 1) {
            if (t < s) {
                #pragma unroll
                for (int i = 0; i < 6; ++i) red[i][t] += red[i][t + s];
            }
            __syncthreads();
        }
        if (t == 0) {
            float ccx = red[0][0] / (float)NN, ccy = red[1][0] / (float)NN, ccz = red[2][0] / (float)NN;
            float cnx = red[3][0] / (float)NN, cny = red[4][0] / (float)NN, cnz = red[5][0] / (float)NN;
            float inv = 1.0f / sqrtf(cnx * cnx + cny * cny + cnz * cnz);
            float* s9 = st + b * 16;
            s9[0] = ccx; s9[1] = ccy; s9[2] = ccz;
            s9[3] = cnx; s9[4] = cny; s9[5] = cnz;
            s9[6] = cnx * inv; s9[7] = cny * inv; s9[8] = cnz * inv;
        }
    } else if (blk < 944) {
        int idx = (blk - 868) * 256 + t;
        zp[idx] = (idx >= 14336 && idx < 18432) ? FLIP_NEG_INF : 0u;
    } else {
        int m = (blk - 944) * 256 + t;
        int b = m >> 11, n = m & (NN - 1);
        const float* src = in + (size_t)b * 22 * NN + 6 * NN + n;
        unsigned short vals[16];
        #pragma unroll
        for (int r = 0; r < 16; ++r) vals[r] = f2h(src[(size_t)r * NN]);
        ushort4* dst = (ushort4*)&XCb[(size_t)m * LDC];
        #pragma unroll
        for (int q = 0; q < 4; ++q)
            dst[q] = make_ushort4(vals[4 * q], vals[4 * q + 1], vals[4 * q + 2], vals[4 * q + 3]);
        ushort4 z = make_ushort4(0, 0, 0, 0);
        ushort4* pz = (ushort4*)&XCb[(size_t)m * LDC + 1360];
        pz[0] = z; pz[1] = z; pz[2] = z; pz[3] = z;
    }
}

// ---------------------------------------------------------------------------
// per-point PPF + packed projected vectors PQ = (x,y,z,|P|)
// ---------------------------------------------------------------------------
__global__ __launch_bounds__(256) void point_k(const float* __restrict__ in,
                                               const float* __restrict__ st,
                                               float4* __restrict__ PQ,
                                               float* __restrict__ F0) {
    int idx = blockIdx.x * 256 + threadIdx.x;
    int b = idx >> 11, n = idx & (NN - 1);
    const float* base = in + (size_t)b * 22 * NN;
    const float* s9 = st + b * 16;
    float cx = base[0 * NN + n], cy = base[1 * NN + n], cz = base[2 * NN + n];
    float nx = base[3 * NN + n], ny = base[4 * NN + n], nz = base[5 * NN + n];
    float inv = 1.0f / sqrtf(nx * nx + ny * ny + nz * nz);
    nx *= inv; ny *= inv; nz *= inv;
    float ccx = s9[0], ccy = s9[1], ccz = s9[2];
    float cnx = s9[3], cny = s9[4], cnz = s9[5];
    float ex = s9[6], ey = s9[7], ez = s9[8];
    float dx = cx - ccx, dy = cy - ccy, dz = cz - ccz;
    F0[0 * MM + idx] = angle3(cnx, cny, cnz, dx, dy, dz);
    F0[1 * MM + idx] = angle3(nx, ny, nz, dx, dy, dz);
    F0[2 * MM + idx] = angle3(cnx, cny, cnz, nx, ny, nz);
    F0[3 * MM + idx] = sqrtf(dx * dx + dy * dy + dz * dz);
    float dot = dx * ex + dy * ey + dz * ez;
    float px = dx - dot * cnx;
    float py = dy - dot * cny;
    float pz = dz - dot * cnz;
    PQ[idx] = make_float4(px, py, pz, sqrtf(px * px + py * py + pz * pz));
}

// ---------------------------------------------------------------------------
// per-row median via two-pass LDS histogram with algebraic fp16 key
// (R17/R18 structure, unchanged).
// ---------------------------------------------------------------------------
__global__ __launch_bounds__(256) void alpha_k(const float4* __restrict__ PQ,
                                               float* __restrict__ F0) {
    __shared__ unsigned hist[4][256];
    int wv = threadIdx.x >> 6;
    int lane = threadIdx.x & 63;
    int row = blockIdx.x * 4 + wv;
    int b = row >> 11;
    const float4* base = PQ + (size_t)b * NN;
    float4 a = base[row & (NN - 1)];
    unsigned u[16];
    #pragma unroll
    for (int c = 0; c < 4; ++c) {
        #pragma unroll
        for (int j = 0; j < 4; ++j) {
            int s2 = c * 8 + j * 2;
            float4 bv0 = base[s2 * 64 + lane];
            float4 bv1 = base[(s2 + 1) * 64 + lane];
            float k0, k1;
            {
                float dc = a.x * bv0.x + a.y * bv0.y + a.z * bv0.z;
                float h = a.w * bv0.w;
                float rc = __builtin_amdgcn_rcpf(h + dc);
                k0 = (h - dc) * rc;
                if (k0 <= 2e-7f) k0 = __builtin_inff();
            }
            {
                float dc = a.x * bv1.x + a.y * bv1.y + a.z * bv1.z;
                float h = a.w * bv1.w;
                float rc = __builtin_amdgcn_rcpf(h + dc);
                k1 = (h - dc) * rc;
                if (k1 <= 2e-7f) k1 = __builtin_inff();
            }
            u[c * 4 + j] = (unsigned)f2h(k0) | ((unsigned)f2h(k1) << 16);
        }
        asm volatile("" ::: "memory");
    }
    unsigned* h = hist[wv];
    h[lane] = 0; h[lane + 64] = 0; h[lane + 128] = 0; h[lane + 192] = 0;
    __syncthreads();
    #pragma unroll
    for (int q = 0; q < 16; ++q) {
        atomicAdd(&h[(u[q] & 0xFFFFu) >> 7], 1u);
        atomicAdd(&h[u[q] >> 23], 1u);
    }
    __syncthreads();
    const unsigned K = 1023;
    unsigned h0 = h[4 * lane], h1 = h[4 * lane + 1], h2 = h[4 * lane + 2], h3 = h[4 * lane + 3];
    unsigned lsum = h0 + h1 + h2 + h3;
    unsigned inc = lsum;
    #pragma unroll
    for (int d = 1; d < 64; d <<= 1) {
        unsigned tv = __shfl_up(inc, d);
        if (lane >= d) inc += tv;
    }
    unsigned excl = inc - lsum;
    bool has = (excl <= K) && (K < inc);
    unsigned long long mask = __ballot(has);
    int L = __ffsll((long long)mask) - 1;
    unsigned packed = 0;
    if (has) {
        unsigned e = excl, Bq = 4 * lane;
        if (e + h0 <= K) { e += h0; Bq++;
            if (e + h1 <= K) { e += h1; Bq++;
                if (e + h2 <= K) { e += h2; Bq++; } } }
        packed = (Bq << 16) | e;
    }
    packed = __shfl(packed, L);
    unsigned B = packed >> 16;
    unsigned k2 = K - (packed & 0xFFFFu);
    __syncthreads();
    h[lane] = 0; h[lane + 64] = 0;
    __syncthreads();
    #pragma unroll
    for (int q = 0; q < 16; ++q) {
        unsigned lo = u[q] & 0xFFFFu, hi = u[q] >> 16;
        if ((lo >> 7) == B) atomicAdd(&h[lo & 127], 1u);
        if ((hi >> 7) == B) atomicAdd(&h[hi & 127], 1u);
    }
    __syncthreads();
    unsigned g0 = h[2 * lane], g1 = h[2 * lane + 1];
    unsigned ls2 = g0 + g1, inc2 = ls2;
    #pragma unroll
    for (int d = 1; d < 64; d <<= 1) {
        unsigned tv = __shfl_up(inc2, d);
        if (lane >= d) inc2 += tv;
    }
    unsigned excl2 = inc2 - ls2;
    bool has2 = (excl2 <= k2) && (k2 < inc2);
    unsigned long long m2 = __ballot(has2);
    int L2 = __ffsll((long long)m2) - 1;
    unsigned low = 0;
    if (has2) low = 2 * lane + ((excl2 + g0 <= k2) ? 1u : 0u);
    low = __shfl(low, L2);
    unsigned T = (B << 7) | low;
    if (lane == 0) {
        float lo = h2f((unsigned short)T);
        float hi = h2f((unsigned short)(T + 1));
        F0[4 * MM + row] = 2.0f * atanf(sqrtf(0.5f * (lo + hi)));
    }
}

// ---------------------------------------------------------------------------
// pf0 + fused BN stats: raw fp16 into XCb+16; stats -> sums.
// ---------------------------------------------------------------------------
__global__ __launch_bounds__(256) void pf0s_k(const float* __restrict__ F0,
                                              const float* __restrict__ W,
                                              unsigned short* __restrict__ dst,
                                              float* __restrict__ sums) {
    __shared__ float ws[320];
    int t = threadIdx.x;
    for (int i = t; i < 320; i += 256) ws[i] = W[i];
    __syncthreads();
    int ol = t & 63, mg = t >> 6;
    int m0 = blockIdx.x * 512;
    float w0 = ws[ol * 5], w1 = ws[ol * 5 + 1], w2 = ws[ol * 5 + 2], w3 = ws[ol * 5 + 3], w4 = ws[ol * 5 + 4];
    float s = 0.f, q = 0.f;
    for (int i = 0; i < 128; ++i) {
        int m = m0 + i * 4 + mg;
        float y = w0 * F0[m] + w1 * F0[MM + m] + w2 * F0[2 * MM + m]
                + w3 * F0[3 * MM + m] + w4 * F0[4 * MM + m];
        dst[(size_t)m * LDC + ol] = f2h(y);
        s += y; q += y * y;
    }
    __shared__ float ls[4][64], lq[4][64];
    ls[mg][ol] = s; lq[mg][ol] = q;
    __syncthreads();
    if (mg == 0) {
        s = ls[0][ol] + ls[1][ol] + ls[2][ol] + ls[3][ol];
        q = lq[0][ol] + lq[1][ol] + lq[2][ol] + lq[3][ol];
        atomicAdd(&sums[ol], s);
        atomicAdd(&sums[1024 + ol], q);
    }
}

// ---------------------------------------------------------------------------
// fp16 MFMA GEMM, 128x128 block tile, 4 waves (2x2), each wave 64x64
// (4x4 16x16x32 frags -> 16 MFMA : 8 ds_read_b128, 2x the 64-tile density).
// TRANS: 0 none, 1 uniform (xs,xg,xb), 2 AB4 table (cls0).
// MODE: 1 raw fp16 out (yld) + stats [+DOMAX raw channel max]; 2 K-split partial.
// K-loop order identical to the 64-tile version -> bit-identical outputs.
// ---------------------------------------------------------------------------
template<int MODE, int TRANS, int DOMAX>
__global__ __launch_bounds__(256) void mgemm128_k(const unsigned short* __restrict__ X, int ldx,
                                                  const unsigned short* __restrict__ W, int ldw,
                                                  unsigned short* __restrict__ Yh, int yld, int Co, int K, int kchunk,
                                                  float* __restrict__ sums,
                                                  const float* __restrict__ xs, const float* __restrict__ xg,
                                                  const float* __restrict__ xb,
                                                  const float4* __restrict__ AB4,
                                                  unsigned* __restrict__ maxbu) {
    __shared__ unsigned short As[128 * 32];   // 8KB
    __shared__ unsigned short Bs[128 * 32];   // 8KB
    __shared__ float4 ABl[352];
    int t = threadIdx.x;
    int mBase = blockIdx.x * 128;
    int oBase = blockIdx.y * 128;
    int k0c = blockIdx.z * kchunk;
    int k1c = k0c + kchunk; if (k1c > K) k1c = K;
    if (TRANS == 1) {
        float* abf = (float*)ABl;
        for (int i = t; i < K; i += 256) {
            float a, c; bncoef(xs, xg, xb, i, a, c);
            abf[2 * i] = a; abf[2 * i + 1] = c;
        }
    } else if (TRANS == 2) {
        for (int i = t; i < k1c - k0c; i += 256) ABl[i] = AB4[k0c + i];
    }
    int lane = t & 63, w = t >> 6;
    int warpM = (w & 1) * 64, warpO = (w >> 1) * 64;
    f32x4 acc[4][4];
    #pragma unroll
    for (int i = 0; i < 4; ++i)
        #pragma unroll
        for (int j = 0; j < 4; ++j) acc[i][j] = (f32x4){0.f, 0.f, 0.f, 0.f};
    int lr = t >> 1;           // 0..127
    int lc = (t & 1) * 16;     // 0 or 16
    const unsigned short* Xp = X + (size_t)(mBase + lr) * ldx + lc;
    const unsigned short* Wp = W + (size_t)(oBase + lr) * ldw + lc;
    int ar0 = (warpM + (lane & 15)) * 32 + (lane >> 4) * 8;
    int br0 = (warpO + (lane & 15)) * 32 + (lane >> 4) * 8;
    uint4 xa0 = *(const uint4*)(Xp + k0c);
    uint4 xa1 = *(const uint4*)(Xp + k0c + 8);
    uint4 wb0 = *(const uint4*)(Wp + k0c);
    uint4 wb1 = *(const uint4*)(Wp + k0c + 8);
    for (int k = k0c; k < k1c; k += 32) {
        __syncthreads();
        uint4 xc0 = xa0, xc1 = xa1;
        if (TRANS == 1) {
            const float* abf = (const float*)ABl;
            unsigned short* p0 = (unsigned short*)&xc0;
            unsigned short* p1 = (unsigned short*)&xc1;
            int kb = k + lc;
            #pragma unroll
            for (int e = 0; e < 8; ++e) {
                p0[e] = f2h(fmaxf(abf[2 * (kb + e)] * h2f(p0[e]) + abf[2 * (kb + e) + 1], 0.f));
                p1[e] = f2h(fmaxf(abf[2 * (kb + 8 + e)] * h2f(p1[e]) + abf[2 * (kb + 8 + e) + 1], 0.f));
            }
        } else if (TRANS == 2) {
            unsigned short* p0 = (unsigned short*)&xc0;
            unsigned short* p1 = (unsigned short*)&xc1;
            int kb = k + lc - k0c;
            #pragma unroll
            for (int e = 0; e < 8; ++e) {
                float4 q0 = ABl[kb + e];
                float4 q1 = ABl[kb + 8 + e];
                p0[e] = f2h(fmaxf(q0.x * h2f(p0[e]) + q0.y, q0.z));
                p1[e] = f2h(fmaxf(q1.x * h2f(p1[e]) + q1.y, q1.z));
            }
        }
        *(uint4*)&As[lr * 32 + lc] = xc0;
        *(uint4*)&As[lr * 32 + lc + 8] = xc1;
        *(uint4*)&Bs[lr * 32 + lc] = wb0;
        *(uint4*)&Bs[lr * 32 + lc + 8] = wb1;
        if (k + 32 < k1c) {
            xa0 = *(const uint4*)(Xp + k + 32);
            xa1 = *(const uint4*)(Xp + k + 40);
            wb0 = *(const uint4*)(Wp + k + 32);
            wb1 = *(const uint4*)(Wp + k + 40);
        }
        __syncthreads();
        half8 af[4], bf[4];
        #pragma unroll
        for (int i = 0; i < 4; ++i) {
            af[i] = __builtin_bit_cast(half8, *(const uint4*)&As[ar0 + i * 16 * 32]);
            bf[i] = __builtin_bit_cast(half8, *(const uint4*)&Bs[br0 + i * 16 * 32]);
        }
        #pragma unroll
        for (int i = 0; i < 4; ++i)
            #pragma unroll
            for (int j = 0; j < 4; ++j)
                acc[i][j] = __builtin_amdgcn_mfma_f32_16x16x32_f16(af[i], bf[j], acc[i][j], 0, 0, 0);
    }
    unsigned short* Yp = Yh + (MODE == 2 ? (size_t)blockIdx.z * MM * yld : 0);
    #pragma unroll
    for (int i = 0; i < 4; ++i)
        #pragma unroll
        for (int j = 0; j < 4; ++j) {
            int m0 = mBase + warpM + i * 16 + (lane >> 4) * 4;
            int o = oBase + warpO + j * 16 + (lane & 15);
            #pragma unroll
            for (int r = 0; r < 4; ++r)
                Yp[(size_t)(m0 + r) * yld + o] = f2h(acc[i][j][r]);
        }
    if (MODE == 1) {
        __syncthreads();
        float* ssum = (float*)As;
        unsigned* smax = (unsigned*)As + 128;
        float* ssq = (float*)Bs;
        if (t < 128) { ssum[t] = 0.f; ssq[t] = 0.f; if (DOMAX) smax[t] = FLIP_NEG_INF; }
        __syncthreads();
        #pragma unroll
        for (int j = 0; j < 4; ++j) {
            int oc = warpO + j * 16 + (lane & 15);
            float s = 0.f, q = 0.f, mx = -__builtin_inff();
            #pragma unroll
            for (int i = 0; i < 4; ++i)
                #pragma unroll
                for (int r = 0; r < 4; ++r) {
                    float v = acc[i][j][r];
                    s += v; q += v * v; mx = fmaxf(mx, v);
                }
            atomicAdd(&ssum[oc], s);
            atomicAdd(&ssq[oc], q);
            if (DOMAX) atomicMax(&smax[oc], fflip(mx));
        }
        __syncthreads();
        if (t < 128) {
            atomicAdd(&sums[oBase + t], ssum[t]);
            atomicAdd(&sums[1024 + oBase + t], ssq[t]);
            if (DOMAX) atomicMax(&maxbu[(mBase >> 11) * 1024 + oBase + t], smax[t]);
        }
    }
}

// ---------------------------------------------------------------------------
// fp16 MFMA GEMM BM=64 BO=64 with staging-normalization.
// MODE 1: raw fp16 out (yld) + stats. MODE 3: direct (b,50,n) out + bias.
// ---------------------------------------------------------------------------
template<int MODE, int TRANS>
__global__ __launch_bounds__(256) void mgemm64_k(const unsigned short* __restrict__ X, int ldx,
                                                 const unsigned short* __restrict__ W, int ldw,
                                                 void* __restrict__ Yv, int yld, int Co, int K,
                                                 float* __restrict__ sums,
                                                 const float* __restrict__ xs, const float* __restrict__ xg,
                                                 const float* __restrict__ xb) {
    __shared__ unsigned short As[64 * 32];
    __shared__ unsigned short Bs[64 * 32];
    __shared__ float ABl[512];
    int t = threadIdx.x;
    int mBase = blockIdx.x * 64;
    int oBase = blockIdx.y * 64;
    if (TRANS == 1) {
        for (int i = t; i < K; i += 256) {
            float a, c; bncoef(xs, xg, xb, i, a, c);
            ABl[2 * i] = a; ABl[2 * i + 1] = c;
        }
    }
    int lane = t & 63, w = t >> 6;
    int warpM = (w & 1) * 32, warpO = (w >> 1) * 32;
    f32x4 acc[2][2];
    #pragma unroll
    for (int i = 0; i < 2; ++i)
        #pragma unroll
        for (int j = 0; j < 2; ++j) acc[i][j] = (f32x4){0.f, 0.f, 0.f, 0.f};
    int lr = t >> 2;
    int lc = (t & 3) * 8;
    const unsigned short* Xp = X + (size_t)(mBase + lr) * ldx + lc;
    const unsigned short* Wp = W + (size_t)(oBase + lr) * ldw + lc;
    int ar0 = (warpM + (lane & 15)) * 32 + (lane >> 4) * 8;
    int br0 = (warpO + (lane & 15)) * 32 + (lane >> 4) * 8;
    uint4 xa = *(const uint4*)(Xp);
    uint4 wb = *(const uint4*)(Wp);
    for (int k = 0; k < K; k += 32) {
        __syncthreads();
        uint4 xc = xa;
        if (TRANS == 1) {
            unsigned short* p = (unsigned short*)&xc;
            int kb = k + lc;
            #pragma unroll
            for (int e = 0; e < 8; ++e)
                p[e] = f2h(fmaxf(ABl[2 * (kb + e)] * h2f(p[e]) + ABl[2 * (kb + e) + 1], 0.f));
        }
        *(uint4*)&As[lr * 32 + lc] = xc;
        *(uint4*)&Bs[lr * 32 + lc] = wb;
        if (k + 32 < K) {
            xa = *(const uint4*)(Xp + k + 32);
            wb = *(const uint4*)(Wp + k + 32);
        }
        __syncthreads();
        half8 a0 = __builtin_bit_cast(half8, *(const uint4*)&As[ar0]);
        half8 a1 = __builtin_bit_cast(half8, *(const uint4*)&As[ar0 + 16 * 32]);
        half8 b0 = __builtin_bit_cast(half8, *(const uint4*)&Bs[br0]);
        half8 b1 = __builtin_bit_cast(half8, *(const uint4*)&Bs[br0 + 16 * 32]);
        acc[0][0] = __builtin_amdgcn_mfma_f32_16x16x32_f16(a0, b0, acc[0][0], 0, 0, 0);
        acc[0][1] = __builtin_amdgcn_mfma_f32_16x16x32_f16(a0, b1, acc[0][1], 0, 0, 0);
        acc[1][0] = __builtin_amdgcn_mfma_f32_16x16x32_f16(a1, b0, acc[1][0], 0, 0, 0);
        acc[1][1] = __builtin_amdgcn_mfma_f32_16x16x32_f16(a1, b1, acc[1][1], 0, 0, 0);
    }
    if (MODE == 3) {
        float* outp = (float*)Yv;
        #pragma unroll
        for (int i = 0; i < 2; ++i)
            #pragma unroll
            for (int j = 0; j < 2; ++j) {
                int m0 = mBase + warpM + i * 16 + (lane >> 4) * 4;
                int o = oBase + warpO + j * 16 + (lane & 15);
                if (o < 50) {
                    int bb2 = m0 >> 11, n = m0 & (NN - 1);
                    float bi = sums[o];
                    float4 v = make_float4(acc[i][j][0] + bi, acc[i][j][1] + bi,
                                           acc[i][j][2] + bi, acc[i][j][3] + bi);
                    *(float4*)&outp[((size_t)bb2 * 50 + o) * NN + n] = v;
                }
            }
    } else {
        unsigned short* Yh = (unsigned short*)Yv;
        #pragma unroll
        for (int i = 0; i < 2; ++i)
            #pragma unroll
            for (int j = 0; j < 2; ++j) {
                int m0 = mBase + warpM + i * 16 + (lane >> 4) * 4;
                int o = oBase + warpO + j * 16 + (lane & 15);
                #pragma unroll
                for (int r = 0; r < 4; ++r)
                    Yh[(size_t)(m0 + r) * yld + o] = f2h(acc[i][j][r]);
            }
        __syncthreads();
        float* ssum = (float*)As;
        float* ssq = (float*)Bs;
        if (t < 64) { ssum[t] = 0.f; ssq[t] = 0.f; }
        __syncthreads();
        #pragma unroll
        for (int j = 0; j < 2; ++j) {
            int oc = warpO + j * 16 + (lane & 15);
            float s = 0.f, q = 0.f;
            #pragma unroll
            for (int i = 0; i < 2; ++i)
                #pragma unroll
                for (int r = 0; r < 4; ++r) { float v = acc[i][j][r]; s += v; q += v * v; }
            atomicAdd(&ssum[oc], s);
            atomicAdd(&ssq[oc], q);
        }
        __syncthreads();
        if (t < 64) {
            atomicAdd(&sums[oBase + t], ssum[t]);
            atomicAdd(&sums[1024 + oBase + t], ssq[t]);
        }
    }
}

// ---------------------------------------------------------------------------
// fused: build cls0 coefficient table AB4[1376] (blocks 0..5) + max-feature
// GEMV with inline normalized maxes (blocks 6..37)
// ---------------------------------------------------------------------------
__global__ __launch_bounds__(256) void abgemv_k(const float* __restrict__ SUMS,
                                                const unsigned* __restrict__ MAXBu,
                                                float4* __restrict__ AB4,
                                                const unsigned short* __restrict__ Wmax,
                                                float* __restrict__ contrib,
                                                const float* g0, const float* b0,
                                                const float* g1, const float* b1,
                                                const float* g2, const float* b2,
                                                const float* g3, const float* b3) {
    int blk = blockIdx.x, t = threadIdx.x;
    if (blk < 6) {
        int ch = blk * 256 + t;
        if (ch >= 1376) return;
        float4 r;
        if (ch < 16) r = make_float4(1.f, 0.f, -__builtin_inff(), 0.f);
        else if (ch < 80) { float a, c; bncoef(SUMS, g0, b0, ch - 16, a, c); r = make_float4(a, c, 0.f, 0.f); }
        else if (ch < 208) { float a, c; bncoef(SUMS + 2048, g1, b1, ch - 80, a, c); r = make_float4(a, c, 0.f, 0.f); }
        else if (ch < 336) { float a, c; bncoef(SUMS + 4096, g2, b2, ch - 208, a, c); r = make_float4(a, c, 0.f, 0.f); }
        else if (ch < 1360) { float a, c; bncoef(SUMS + 6144, g3, b3, ch - 336, a, c); r = make_float4(a, c, 0.f, 0.f); }
        else r = make_float4(0.f, 0.f, 0.f, 0.f);
        AB4[ch] = r;
    } else {
        int i = blk - 6;
        int b = i >> 3;
        int cc = (i & 7) * 128;
        __shared__ float nm[128];
        if (t < 128) {
            int c = cc + t;
            float a, cf; bncoef(SUMS + 6144, g3, b3, c, a, cf);
            float raw = funflip(MAXBu[b * 1024 + c]);
            nm[t] = fmaxf(a * raw + cf, 0.f);
        }
        __syncthreads();
        int o = t;
        float acc = 0.f;
        for (int c = 0; c < 128; ++c)
            acc += h2f(Wmax[(size_t)(cc + c) * 256 + o]) * nm[c];
        atomicAdd(&contrib[b * 256 + o], acc);
    }
}

// ---------------------------------------------------------------------------
// cls0 finish: sum 4 fp16 K-split partials + contrib -> raw fp16 partial0 + stats
// ---------------------------------------------------------------------------
__global__ __launch_bounds__(256) void red4stat_k(unsigned short* __restrict__ Yh,
                                                  const float* __restrict__ contrib,
                                                  float* __restrict__ sums) {
    int o0 = blockIdx.x * 64;
    int m0 = blockIdx.y * 128;
    int t = threadIdx.x, ol = t & 63, mg = t >> 6;
    int b = m0 >> 11;
    float cb = contrib[b * 256 + o0 + ol];
    const size_t stride = (size_t)MM * 256;
    float s = 0.f, q = 0.f;
    unsigned short* p = Yh + (size_t)(m0 + mg) * 256 + o0 + ol;
    for (int i = 0; i < 32; ++i) {
        unsigned short* pp = p + (size_t)i * 4 * 256;
        float v = h2f(pp[0]) + h2f(pp[stride]) + h2f(pp[2 * stride]) + h2f(pp[3 * stride]) + cb;
        pp[0] = f2h(v);
        s += v; q += v * v;
    }
    __shared__ float ls[4][64], lq[4][64];
    ls[mg][ol] = s; lq[mg][ol] = q;
    __syncthreads();
    if (mg == 0) {
        s = ls[0][ol] + ls[1][ol] + ls[2][ol] + ls[3][ol];
        q = lq[0][ol] + lq[1][ol] + lq[2][ol] + lq[3][ol];
        atomicAdd(&sums[o0 + ol], s);
        atomicAdd(&sums[1024 + o0 + ol], q);
    }
}

// ---------------------------------------------------------------------------
extern "C" void kernel_launch(void* const* d_in, const int* in_sizes, int n_in,
                              void* d_out, int out_size, void* d_ws, size_t ws_size,
                              hipStream_t stream) {
    const float* in = (const float*)d_in[0];
    const float* pf0_w = (const float*)d_in[1];
    const float* pf_g[4] = {(const float*)d_in[2], (const float*)d_in[5], (const float*)d_in[8], (const float*)d_in[11]};
    const float* pf_b[4] = {(const float*)d_in[3], (const float*)d_in[6], (const float*)d_in[9], (const float*)d_in[12]};
    const float* pf_w[4] = {(const float*)d_in[1], (const float*)d_in[4], (const float*)d_in[7], (const float*)d_in[10]};
    const float* cls_w[3] = {(const float*)d_in[13], (const float*)d_in[16], (const float*)d_in[19]};
    const float* cls_g[3] = {(const float*)d_in[14], (const float*)d_in[17], (const float*)d_in[20]};
    const float* cls_b[3] = {(const float*)d_in[15], (const float*)d_in[18], (const float*)d_in[21]};
    const float* cls3_w = (const float*)d_in[22];
    const float* cls3_bias = (const float*)d_in[23];
    float* out = (float*)d_out;

    char* wsb = (char*)d_ws;
    float* ST = (float*)(wsb + 0);
    float4* PQ = (float4*)(wsb + 256);
    float* F0 = (float*)(wsb + 131328);
    float* SUMS = (float*)(wsb + 295168);
    unsigned* MAXBu = (unsigned*)(wsb + 352512);
    float* CONTRIB = (float*)(wsb + 368896);
    float4* AB4 = (float4*)(wsb + 372992);
    unsigned short* WB = (unsigned short*)(wsb + 411392);
    unsigned short* XCb = (unsigned short*)(wsb + 2180864);
    unsigned short* C1b = (unsigned short*)(wsb + 24725248);
    unsigned short* C2b = (unsigned short*)(wsb + 28919552);
    unsigned short* Yh = (unsigned short*)(wsb + 33113856);

    auto SL = [&](int s) { return SUMS + (size_t)s * 2048; };

    prep_k<<<976, 256, 0, stream>>>(in, pf_w[1], pf_w[2], pf_w[3], cls_w[0], cls_w[1], cls_w[2], cls3_w,
                                    WB, ST, (unsigned*)SUMS, XCb);
    point_k<<<MM / 256, 256, 0, stream>>>(in, ST, PQ, F0);
    alpha_k<<<MM / 4, 256, 0, stream>>>(PQ, F0);

    // pf0 raw -> XCb+16 with fused stats SL(0)
    pf0s_k<<<16, 256, 0, stream>>>(F0, pf0_w, XCb + 16, SL(0));
    // pf1: stage-norm SL(0); raw -> XCb+80; stats SL(1)
    mgemm64_k<1, 1><<<dim3(128, 2), 256, 0, stream>>>(XCb + 16, LDC, WB, 64, XCb + 80, LDC, 128, 64,
                                                      SL(1), SL(0), pf_g[0], pf_b[0]);
    // pf2: stage-norm SL(1); raw -> XCb+208; stats SL(2)
    mgemm64_k<1, 1><<<dim3(128, 2), 256, 0, stream>>>(XCb + 80, LDC, WB + 8192, 128, XCb + 208, LDC, 128, 128,
                                                      SL(2), SL(1), pf_g[1], pf_b[1]);
    // pf3: 128-tile; stage-norm SL(2); raw -> XCb+336; stats SL(3) + raw channel max
    mgemm128_k<1, 1, 1><<<dim3(64, 8, 1), 256, 0, stream>>>(XCb + 208, LDC, WB + 24576, 128, XCb + 336, LDC,
                                                            1024, 128, 128, SL(3), SL(2), pf_g[2], pf_b[2],
                                                            AB4, MAXBu);
    // fused coefficient table + max-feature GEMV
    abgemv_k<<<38, 256, 0, stream>>>(SUMS, MAXBu, AB4, WB + 614400, CONTRIB,
                                     pf_g[0], pf_b[0], pf_g[1], pf_b[1], pf_g[2], pf_b[2], pf_g[3], pf_b[3]);
    // cls0: 128-tile; stage-norm via AB4; K-split x4 raw fp16 partials
    mgemm128_k<2, 2, 0><<<dim3(64, 2, 4), 256, 0, stream>>>(XCb, LDC, WB + 155648, 1376, Yh, 256,
                                                            256, 1376, 352, SL(4), nullptr, nullptr, nullptr,
                                                            AB4, MAXBu);
    red4stat_k<<<dim3(4, 64), 256, 0, stream>>>(Yh, CONTRIB, SL(4));
    // cls1: stage-norm SL(4); raw -> C1b; stats SL(5)
    mgemm64_k<1, 1><<<dim3(128, 4), 256, 0, stream>>>(Yh, 256, WB + 507904, 256, C1b, 256, 256, 256,
                                                      SL(5), SL(4), cls_g[0], cls_b[0]);
    // cls2: stage-norm SL(5); raw -> C2b; stats SL(6)
    mgemm64_k<1, 1><<<dim3(128, 2), 256, 0, stream>>>(C1b, 256, WB + 507904 + 65536, 256, C2b, 128, 128, 256,
                                                      SL(6), SL(5), cls_g[1], cls_b[1]);
    // cls3: stage-norm SL(6); direct (b,50,n) output + bias
    mgemm64_k<3, 1><<<dim3(128, 1), 256, 0, stream>>>(C2b, 128, WB + 606208, 128, (void*)out, 0, 64, 128,
                                                      (float*)cls3_bias, SL(6), cls_g[2], cls_b[2]);

    (void)in_sizes; (void)n_in; (void)out_size; (void)ws_size;
}